// Round 1
// baseline (4992.803 us; speedup 1.0000x reference)
//
#include <hip/hip_runtime.h>
#include <hip/hip_bf16.h>
#include <math.h>

// ---- problem constants -----------------------------------------------------
#define B_    16
#define H_    22
#define W_    20480
#define EMB   35
#define GH_   11
#define GW_   1280
#define L_    1280
#define DM_   385
#define DI_   256
#define N_    4
#define K_    4
#define DTR_  25
#define ROWS_ (B_*L_)              // 20480
#define NX_   ((long)ROWS_*DM_)    // 7,884,800
#define LDM_  ((long)L_*DM_)       // 492,800

// ---- helpers ---------------------------------------------------------------
__device__ __forceinline__ void atomicMaxF(float* a, float v) {
  // v >= 0 always; for non-negative floats the int bit pattern is monotone.
  atomicMax(reinterpret_cast<int*>(a), __float_as_int(v));
}

// faithful fq: s = max(mx,1e-8)/127; q = clip(rint(x/s),-128,127)*s
__device__ __forceinline__ float fq_apply(float x, float s) {
  float r = rintf(x / s);
  r = fminf(fmaxf(r, -128.f), 127.f);
  return r * s;
}
__device__ __forceinline__ float fq_scale(const float* pmax) {
  return fmaxf(pmax[0], 1e-8f) / 127.f;
}

// block max -> atomicMax(out). All threads must reach this. sm: >= blockDim/64 floats.
__device__ __forceinline__ void blockAtomicMax(float v, float* out, float* sm) {
  #pragma unroll
  for (int o = 32; o > 0; o >>= 1) v = fmaxf(v, __shfl_down(v, o));
  if ((threadIdx.x & 63) == 0) sm[threadIdx.x >> 6] = v;
  __syncthreads();
  if (threadIdx.x == 0) {
    int nw = (blockDim.x + 63) >> 6;
    for (int i = 1; i < nw; i++) v = fmaxf(v, sm[i]);
    atomicMaxF(out, v);
  }
}

// ---- small utility kernels -------------------------------------------------
__global__ void k_zero(float* s) { if (threadIdx.x < 64) s[threadIdx.x] = 0.f; }

__global__ void k_absmax(const float* __restrict__ src, long n, float* __restrict__ out) {
  __shared__ float smr[8];
  float m = 0.f;
  for (long i = (long)blockIdx.x * blockDim.x + threadIdx.x; i < n;
       i += (long)gridDim.x * blockDim.x)
    m = fmaxf(m, fabsf(src[i]));
  blockAtomicMax(m, out, smr);
}

// dst = fq(src, *pmax); optionally accumulate absmax(dst) into *nextmax. dst may == src.
__global__ void k_fq(const float* __restrict__ src, float* __restrict__ dst, long n,
                     const float* __restrict__ pmax, float* __restrict__ nextmax) {
  __shared__ float smr[8];
  float s = fq_scale(pmax);
  float m = 0.f;
  for (long i = (long)blockIdx.x * blockDim.x + threadIdx.x; i < n;
       i += (long)gridDim.x * blockDim.x) {
    float q = fq_apply(src[i], s);
    dst[i] = q;
    m = fmaxf(m, fabsf(q));
  }
  if (nextmax) blockAtomicMax(m, nextmax, smr);
}

// x[i] = fq(x[i], *pmax) + p2[i % LDM]; absmax -> nextmax
__global__ void k_addpos(float* __restrict__ x, const float* __restrict__ p2, long n,
                         const float* __restrict__ pmax, float* __restrict__ nextmax) {
  __shared__ float smr[8];
  float s = fq_scale(pmax);
  float m = 0.f;
  for (long i = (long)blockIdx.x * blockDim.x + threadIdx.x; i < n;
       i += (long)gridDim.x * blockDim.x) {
    float v = fq_apply(x[i], s) + p2[i % LDM_];
    x[i] = v;
    m = fmaxf(m, fabsf(v));
  }
  blockAtomicMax(m, nextmax, smr);
}

// ---- patch embed (conv2d stride==kernel, fq on x and w inline) --------------
// out layout: [(b*L + gw)*DM + gh*EMB + e] == linear idx over (b,gw,gh,e)
__global__ void k_patch(const float* __restrict__ x, const float* __restrict__ pew,
                        const float* __restrict__ peb, const float* __restrict__ sx_,
                        const float* __restrict__ sw_, float* __restrict__ out,
                        float* __restrict__ nextmax) {
  __shared__ float smr[8];
  long idx = (long)blockIdx.x * 256 + threadIdx.x;   // exactly NX_ threads
  int e = (int)(idx % EMB);
  long r = idx / EMB;
  int gh = (int)(r % GH_); r /= GH_;
  int gw = (int)(r % GW_);
  int b  = (int)(r / GW_);
  float sx = fq_scale(sx_), sw = fq_scale(sw_);
  float acc = 0.f;
  #pragma unroll
  for (int ph = 0; ph < 2; ph++) {
    const float* xr = x + ((long)b * H_ + (gh * 2 + ph)) * W_ + (long)gw * 16;
    const float* wr = pew + (e * 2 + ph) * 16;
    #pragma unroll
    for (int pw = 0; pw < 16; pw++) {
      float xv = fq_apply(xr[pw], sx);
      float wv = fq_apply(wr[pw], sw);
      acc = fmaf(xv, wv, acc);
    }
  }
  acc += peb[e];
  out[idx] = acc;
  blockAtomicMax(fabsf(acc), nextmax, smr);
}

// ---- generic fp32 tiled GEMM: C[M,N] = A[M,K] @ W[K,N] ----------------------
template<bool AMAX>
__global__ __launch_bounds__(256) void k_gemm(const float* __restrict__ A,
                                              const float* __restrict__ W,
                                              float* __restrict__ C,
                                              int M, int N, int Kd,
                                              float* __restrict__ amax_out) {
  __shared__ __align__(16) float As[16][68];
  __shared__ __align__(16) float Bs[16][68];
  __shared__ float smr[8];
  int tx = threadIdx.x & 15, ty = threadIdx.x >> 4;
  int m0 = blockIdx.y * 64, n0 = blockIdx.x * 64;
  float acc[4][4] = {};
  for (int k0 = 0; k0 < Kd; k0 += 16) {
    #pragma unroll
    for (int r = 0; r < 4; r++) {
      int id = threadIdx.x + r * 256;
      int mm = id >> 4, kk = id & 15;
      int gm = m0 + mm, gk = k0 + kk;
      As[kk][mm] = (gm < M && gk < Kd) ? A[(long)gm * Kd + gk] : 0.f;
    }
    #pragma unroll
    for (int r = 0; r < 4; r++) {
      int id = threadIdx.x + r * 256;
      int kk = id >> 6, nn = id & 63;
      int gk = k0 + kk, gn = n0 + nn;
      Bs[kk][nn] = (gk < Kd && gn < N) ? W[(long)gk * N + gn] : 0.f;
    }
    __syncthreads();
    #pragma unroll
    for (int kk = 0; kk < 16; kk++) {
      float4 a4 = *reinterpret_cast<const float4*>(&As[kk][ty * 4]);
      float4 b4 = *reinterpret_cast<const float4*>(&Bs[kk][tx * 4]);
      float av[4] = {a4.x, a4.y, a4.z, a4.w};
      float bv[4] = {b4.x, b4.y, b4.z, b4.w};
      #pragma unroll
      for (int i = 0; i < 4; i++)
        #pragma unroll
        for (int j = 0; j < 4; j++)
          acc[i][j] = fmaf(av[i], bv[j], acc[i][j]);
    }
    __syncthreads();
  }
  float mx = 0.f;
  #pragma unroll
  for (int i = 0; i < 4; i++) {
    int gm = m0 + ty * 4 + i;
    if (gm < M) {
      #pragma unroll
      for (int j = 0; j < 4; j++) {
        int gn = n0 + tx * 4 + j;
        if (gn < N) {
          C[(long)gm * N + gn] = acc[i][j];
          mx = fmaxf(mx, fabsf(acc[i][j]));
        }
      }
    }
  }
  if (AMAX) blockAtomicMax(mx, amax_out, smr);
}

// ---- depthwise causal conv1d (K=4) + SiLU, direction-aware ------------------
__global__ void k_conv(const float* __restrict__ xz, const float* __restrict__ cw,
                       const float* __restrict__ cb, float* __restrict__ xcout, int rev) {
  long idx = (long)blockIdx.x * 256 + threadIdx.x;   // B*L*DI threads
  int d = (int)(idx & 255);
  int t = (int)((idx >> 8) % L_);
  int b = (int)(idx / (256L * L_));
  long base = (long)b * L_;
  float acc = cb[d];
  #pragma unroll
  for (int j = 0; j < K_; j++) {
    int tau = t - (K_ - 1) + j;
    if (tau >= 0) {
      int p = rev ? (L_ - 1 - tau) : tau;
      acc = fmaf(cw[d * K_ + j], xz[(base + p) * (2 * DI_) + d], acc);
    }
  }
  float sig = 1.f / (1.f + expf(-acc));
  int pt = rev ? (L_ - 1 - t) : t;
  xcout[(base + pt) * DI_ + d] = acc * sig;
}

// ---- dt = softplus(dtr @ dt_w + dt_b) ---------------------------------------
__global__ __launch_bounds__(256) void k_dt(const float* __restrict__ proj,
                                            const float* __restrict__ dw,
                                            const float* __restrict__ db,
                                            float* __restrict__ dtout) {
  __shared__ float pr[DTR_];
  long row = blockIdx.x;
  if (threadIdx.x < DTR_) pr[threadIdx.x] = proj[row * 33 + threadIdx.x];
  __syncthreads();
  int d = threadIdx.x;
  float acc = db[d];
  #pragma unroll
  for (int r = 0; r < DTR_; r++) acc = fmaf(pr[r], dw[r * DI_ + d], acc);
  // jax.nn.softplus = logaddexp(x, 0)
  float sp = fmaxf(acc, 0.f) + log1pf(expf(-fabsf(acc)));
  dtout[row * DI_ + d] = sp;
}

// ---- selective scan (sequential over L, distance-2 prefetch) ----------------
struct SReg { float dt, xc, z, Bv[4], Cv[4]; };

__device__ __forceinline__ SReg scan_load(const float* __restrict__ dt,
                                          const float* __restrict__ xc,
                                          const float* __restrict__ xz,
                                          const float* __restrict__ proj,
                                          long row, int d) {
  SReg r;
  r.dt = dt[row * DI_ + d];
  r.xc = xc[row * DI_ + d];
  r.z  = xz[row * (2 * DI_) + DI_ + d];
  #pragma unroll
  for (int n = 0; n < N_; n++) {
    r.Bv[n] = proj[row * 33 + DTR_ + n];
    r.Cv[n] = proj[row * 33 + DTR_ + N_ + n];
  }
  return r;
}

__global__ __launch_bounds__(64) void k_scan(const float* __restrict__ xc,
                                             const float* __restrict__ dt,
                                             const float* __restrict__ proj,
                                             const float* __restrict__ A_log,
                                             const float* __restrict__ Dp,
                                             const float* __restrict__ xz,
                                             float* __restrict__ y, int rev, int accum) {
  int b = blockIdx.x;
  int d = blockIdx.y * 64 + threadIdx.x;
  float A[4], h[4];
  #pragma unroll
  for (int n = 0; n < 4; n++) { A[n] = -expf(A_log[d * 4 + n]); h[n] = 0.f; }
  float Dv = Dp[d];
  long base = (long)b * L_;
  SReg q0 = scan_load(dt, xc, xz, proj, base + (rev ? L_ - 1 : 0), d);
  SReg q1 = scan_load(dt, xc, xz, proj, base + (rev ? L_ - 2 : 1), d);
  for (int t = 0; t < L_; t++) {
    SReg cur = q0; q0 = q1;
    if (t + 2 < L_)
      q1 = scan_load(dt, xc, xz, proj, base + (rev ? (L_ - 3 - t) : (t + 2)), d);
    float acc = 0.f;
    #pragma unroll
    for (int n = 0; n < 4; n++) {
      float dA = expf(cur.dt * A[n]);
      h[n] = dA * h[n] + (cur.dt * cur.Bv[n]) * cur.xc;   // (dt*B)*x order
      acc += h[n] * cur.Cv[n];
    }
    float yv = acc + Dv * cur.xc;
    float sig = 1.f / (1.f + expf(-cur.z));
    yv *= cur.z * sig;                                    // y * silu(z)
    long oi = (base + (rev ? (L_ - 1 - t) : t)) * DI_ + d;
    if (accum) yv += y[oi];
    y[oi] = yv;
  }
}

// ---- residual + fq(mamba_out) + layernorm (in-place on mo) ------------------
__global__ __launch_bounds__(128) void k_ln(const float* __restrict__ x2,
                                            float* __restrict__ mo,
                                            const float* __restrict__ smo,
                                            const float* __restrict__ g,
                                            const float* __restrict__ bta,
                                            float* __restrict__ nextmax) {
  __shared__ float sm[2];
  long row = blockIdx.x;
  float s = fq_scale(smo);
  float v[4];
  float lsum = 0.f;
  #pragma unroll
  for (int k2 = 0; k2 < 4; k2++) {
    int c = threadIdx.x + k2 * 128;
    float t = 0.f;
    if (c < DM_) {
      float m = fq_apply(mo[row * DM_ + c], s);
      t = x2[row * DM_ + c] + m;
    }
    v[k2] = t; lsum += t;
  }
  float w = lsum;
  #pragma unroll
  for (int o = 32; o > 0; o >>= 1) w += __shfl_down(w, o);
  if ((threadIdx.x & 63) == 0) sm[threadIdx.x >> 6] = w;
  __syncthreads();
  float mean = (sm[0] + sm[1]) / 385.f;
  __syncthreads();
  float lvar = 0.f;
  #pragma unroll
  for (int k2 = 0; k2 < 4; k2++) {
    int c = threadIdx.x + k2 * 128;
    if (c < DM_) { float dd = v[k2] - mean; lvar += dd * dd; }
  }
  w = lvar;
  #pragma unroll
  for (int o = 32; o > 0; o >>= 1) w += __shfl_down(w, o);
  if ((threadIdx.x & 63) == 0) sm[threadIdx.x >> 6] = w;
  __syncthreads();
  float var = (sm[0] + sm[1]) / 385.f;
  float rs = 1.f / sqrtf(var + 1e-5f);
  float lmax = 0.f;
  #pragma unroll
  for (int k2 = 0; k2 < 4; k2++) {
    int c = threadIdx.x + k2 * 128;
    if (c < DM_) {
      float o2 = (v[k2] - mean) * rs * g[c] + bta[c];
      mo[row * DM_ + c] = o2;
      lmax = fmaxf(lmax, fabsf(o2));
    }
  }
  __syncthreads();
  w = lmax;
  #pragma unroll
  for (int o = 32; o > 0; o >>= 1) w = fmaxf(w, __shfl_down(w, o));
  if ((threadIdx.x & 63) == 0) sm[threadIdx.x >> 6] = w;
  __syncthreads();
  if (threadIdx.x == 0) atomicMaxF(nextmax, fmaxf(sm[0], sm[1]));
}

// ---- mean pool over L + absmax ----------------------------------------------
__global__ void k_pool(const float* __restrict__ x2, float* __restrict__ pool,
                       float* __restrict__ nextmax) {
  __shared__ float smr[8];
  int idx = blockIdx.x * 256 + threadIdx.x;
  float mv = 0.f;
  if (idx < B_ * DM_) {
    int b = idx / DM_, c = idx % DM_;
    const float* p = x2 + (long)b * L_ * DM_ + c;
    float sum = 0.f;
    for (int l = 0; l < L_; l++) sum += p[(long)l * DM_];
    float mean = sum / (float)L_;
    pool[idx] = mean;
    mv = fabsf(mean);
  }
  blockAtomicMax(mv, nextmax, smr);
}

// ---- classifier --------------------------------------------------------------
__global__ void k_cls(const float* __restrict__ pool, const float* __restrict__ clsw,
                      const float* __restrict__ clsb, const float* __restrict__ sp_,
                      const float* __restrict__ sw_, float* __restrict__ out) {
  int tid = threadIdx.x;
  if (tid >= B_ * 2) return;
  int b = tid >> 1, c = tid & 1;
  float sp = fq_scale(sp_), sw = fq_scale(sw_);
  float acc = 0.f;
  for (int k2 = 0; k2 < DM_; k2++) {
    float xv = fq_apply(pool[b * DM_ + k2], sp);
    float wv = fq_apply(clsw[k2 * 2 + c], sw);
    acc = fmaf(xv, wv, acc);
  }
  out[b * 2 + c] = acc + clsb[c];
}

// ---- launch ------------------------------------------------------------------
extern "C" void kernel_launch(void* const* d_in, const int* in_sizes, int n_in,
                              void* d_out, int out_size, void* d_ws, size_t ws_size,
                              hipStream_t stream) {
  const float* x    = (const float*)d_in[0];
  const float* pew  = (const float*)d_in[1];
  const float* peb  = (const float*)d_in[2];
  const float* pos  = (const float*)d_in[3];
  const float* in_w = (const float*)d_in[4];
  const float* cw   = (const float*)d_in[5];
  const float* cb   = (const float*)d_in[6];
  const float* xpw  = (const float*)d_in[7];
  const float* dtw  = (const float*)d_in[8];
  const float* dtb  = (const float*)d_in[9];
  const float* alog = (const float*)d_in[10];
  const float* dp   = (const float*)d_in[11];
  const float* outw = (const float*)d_in[12];
  const float* lng  = (const float*)d_in[13];
  const float* lnb  = (const float*)d_in[14];
  const float* clsw = (const float*)d_in[15];
  const float* clsb = (const float*)d_in[16];

  float* ws   = (float*)d_ws;
  float* SCAL = ws;                               // 16 scalars used (256 reserved)
  float* P2   = ws + 256;                         // 492,800
  float* X2   = P2 + LDM_;                        // 7,884,800
  float* XZ   = X2 + NX_;                         // 20480*512
  float* XC   = XZ + (long)ROWS_ * 512;           // 20480*256
  float* PROJ = XC + (long)ROWS_ * DI_;           // 20480*33
  float* DT   = PROJ + (long)ROWS_ * 33;          // 20480*256
  float* Y    = DT + (long)ROWS_ * DI_;           // 20480*256
  float* MO   = Y + (long)ROWS_ * DI_;            // 7,884,800
  // total ≈ 43.16M floats ≈ 165 MiB
  float* POOL = MO + NX_;                         // 6160

  k_zero<<<1, 64, 0, stream>>>(SCAL);

  // input fq + patch-embed weight fq
  k_absmax<<<2048, 256, 0, stream>>>(x, (long)B_ * H_ * W_, SCAL + 0);
  k_absmax<<<8, 256, 0, stream>>>(pew, EMB * 2 * 16, SCAL + 1);
  k_patch<<<30800, 256, 0, stream>>>(x, pew, peb, SCAL + 0, SCAL + 1, X2, SCAL + 2);
  k_fq<<<2048, 256, 0, stream>>>(X2, X2, NX_, SCAL + 2, SCAL + 3);       // x = fq(x)

  // pos = fq(fq(pos_embed))
  k_absmax<<<512, 256, 0, stream>>>(pos, LDM_, SCAL + 4);
  k_fq<<<512, 256, 0, stream>>>(pos, P2, LDM_, SCAL + 4, SCAL + 5);
  k_fq<<<512, 256, 0, stream>>>(P2, P2, LDM_, SCAL + 5, nullptr);

  // x = fq(fq(x) + pos)
  k_addpos<<<2048, 256, 0, stream>>>(X2, P2, NX_, SCAL + 3, SCAL + 6);
  k_fq<<<2048, 256, 0, stream>>>(X2, X2, NX_, SCAL + 6, nullptr);

  for (int blk = 0; blk < 2; blk++) {
    // in-proj (shared between directions: flip commutes with row-wise matmul)
    k_gemm<false><<<dim3(8, 320), 256, 0, stream>>>(
        X2, in_w + (long)blk * DM_ * 512, XZ, ROWS_, 512, DM_, nullptr);
    for (int dir = 0; dir < 2; dir++) {
      k_conv<<<20480, 256, 0, stream>>>(XZ, cw + blk * DI_ * K_, cb + blk * DI_, XC, dir);
      k_gemm<false><<<dim3(1, 320), 256, 0, stream>>>(
          XC, xpw + (long)blk * DI_ * 33, PROJ, ROWS_, 33, DI_, nullptr);
      k_dt<<<20480, 256, 0, stream>>>(PROJ, dtw + blk * DTR_ * DI_, dtb + blk * DI_, DT);
      // dir==1 accumulates into Y (y_fwd + y_bwd_flipped)
      k_scan<<<dim3(16, 4), 64, 0, stream>>>(XC, DT, PROJ, alog + blk * DI_ * N_,
                                             dp + blk * DI_, XZ, Y, dir, dir);
    }
    // out-proj on summed y; fused absmax for fq(fwd+bwd)
    k_gemm<true><<<dim3(7, 320), 256, 0, stream>>>(
        Y, outw + (long)blk * DI_ * DM_, MO, ROWS_, DM_, DI_, SCAL + 7 + blk * 2);
    // x = fq(layernorm(x + fq(mo)))
    k_ln<<<20480, 128, 0, stream>>>(X2, MO, SCAL + 7 + blk * 2,
                                    lng + blk * DM_, lnb + blk * DM_, SCAL + 8 + blk * 2);
    k_fq<<<2048, 256, 0, stream>>>(MO, X2, NX_, SCAL + 8 + blk * 2, nullptr);
  }

  // mean-pool, fq, classifier with fq(cls_w)
  k_pool<<<25, 256, 0, stream>>>(X2, POOL, SCAL + 11);
  k_absmax<<<4, 256, 0, stream>>>(clsw, DM_ * 2, SCAL + 12);
  k_cls<<<1, 64, 0, stream>>>(POOL, clsw, clsb, SCAL + 11, SCAL + 12, (float*)d_out);
}

// Round 2
// 2183.330 us; speedup vs baseline: 2.2868x; 2.2868x over previous
//
#include <hip/hip_runtime.h>
#include <hip/hip_bf16.h>
#include <math.h>

// ---- problem constants -----------------------------------------------------
#define B_    16
#define H_    22
#define W_    20480
#define EMB   35
#define GH_   11
#define GW_   1280
#define L_    1280
#define DM_   385
#define DI_   256
#define N_    4
#define K_    4
#define DTR_  25
#define ROWS_ (B_*L_)              // 20480
#define NX_   ((long)ROWS_*DM_)    // 7,884,800
#define LDM_  ((long)L_*DM_)       // 492,800
#define CH_   64                   // scan chunks
#define CHL_  20                   // steps per chunk (CH_*CHL_ == L_)

// ---- helpers ---------------------------------------------------------------
__device__ __forceinline__ void atomicMaxF(float* a, float v) {
  // v >= 0 always; for non-negative floats the int bit pattern is monotone.
  atomicMax(reinterpret_cast<int*>(a), __float_as_int(v));
}

// faithful fq: s = max(mx,1e-8)/127; q = clip(rint(x/s),-128,127)*s
__device__ __forceinline__ float fq_apply(float x, float s) {
  float r = rintf(x / s);
  r = fminf(fmaxf(r, -128.f), 127.f);
  return r * s;
}
__device__ __forceinline__ float fq_scale(const float* pmax) {
  return fmaxf(pmax[0], 1e-8f) / 127.f;
}

// block max -> atomicMax(out). All threads must reach this. sm: >= blockDim/64 floats.
__device__ __forceinline__ void blockAtomicMax(float v, float* out, float* sm) {
  #pragma unroll
  for (int o = 32; o > 0; o >>= 1) v = fmaxf(v, __shfl_down(v, o));
  if ((threadIdx.x & 63) == 0) sm[threadIdx.x >> 6] = v;
  __syncthreads();
  if (threadIdx.x == 0) {
    int nw = (blockDim.x + 63) >> 6;
    for (int i = 1; i < nw; i++) v = fmaxf(v, sm[i]);
    atomicMaxF(out, v);
  }
}

// ---- small utility kernels -------------------------------------------------
__global__ void k_zero(float* s) { if (threadIdx.x < 64) s[threadIdx.x] = 0.f; }

__global__ void k_absmax(const float* __restrict__ src, long n, float* __restrict__ out) {
  __shared__ float smr[8];
  float m = 0.f;
  for (long i = (long)blockIdx.x * blockDim.x + threadIdx.x; i < n;
       i += (long)gridDim.x * blockDim.x)
    m = fmaxf(m, fabsf(src[i]));
  blockAtomicMax(m, out, smr);
}

// dst = fq(src, *pmax); optionally accumulate absmax(dst) into *nextmax. dst may == src.
__global__ void k_fq(const float* __restrict__ src, float* __restrict__ dst, long n,
                     const float* __restrict__ pmax, float* __restrict__ nextmax) {
  __shared__ float smr[8];
  float s = fq_scale(pmax);
  float m = 0.f;
  for (long i = (long)blockIdx.x * blockDim.x + threadIdx.x; i < n;
       i += (long)gridDim.x * blockDim.x) {
    float q = fq_apply(src[i], s);
    dst[i] = q;
    m = fmaxf(m, fabsf(q));
  }
  if (nextmax) blockAtomicMax(m, nextmax, smr);
}

// x[i] = fq(x[i], *pmax) + p2[i % LDM]; absmax -> nextmax
__global__ void k_addpos(float* __restrict__ x, const float* __restrict__ p2, long n,
                         const float* __restrict__ pmax, float* __restrict__ nextmax) {
  __shared__ float smr[8];
  float s = fq_scale(pmax);
  float m = 0.f;
  for (long i = (long)blockIdx.x * blockDim.x + threadIdx.x; i < n;
       i += (long)gridDim.x * blockDim.x) {
    float v = fq_apply(x[i], s) + p2[i % LDM_];
    x[i] = v;
    m = fmaxf(m, fabsf(v));
  }
  blockAtomicMax(m, nextmax, smr);
}

// ---- patch embed (conv2d stride==kernel, fq on x and w inline) --------------
// out layout: [(b*L + gw)*DM + gh*EMB + e] == linear idx over (b,gw,gh,e)
__global__ void k_patch(const float* __restrict__ x, const float* __restrict__ pew,
                        const float* __restrict__ peb, const float* __restrict__ sx_,
                        const float* __restrict__ sw_, float* __restrict__ out,
                        float* __restrict__ nextmax) {
  __shared__ float smr[8];
  long idx = (long)blockIdx.x * 256 + threadIdx.x;   // exactly NX_ threads
  int e = (int)(idx % EMB);
  long r = idx / EMB;
  int gh = (int)(r % GH_); r /= GH_;
  int gw = (int)(r % GW_);
  int b  = (int)(r / GW_);
  float sx = fq_scale(sx_), sw = fq_scale(sw_);
  float acc = 0.f;
  #pragma unroll
  for (int ph = 0; ph < 2; ph++) {
    const float* xr = x + ((long)b * H_ + (gh * 2 + ph)) * W_ + (long)gw * 16;
    const float* wr = pew + (e * 2 + ph) * 16;
    #pragma unroll
    for (int pw = 0; pw < 16; pw++) {
      float xv = fq_apply(xr[pw], sx);
      float wv = fq_apply(wr[pw], sw);
      acc = fmaf(xv, wv, acc);
    }
  }
  acc += peb[e];
  out[idx] = acc;
  blockAtomicMax(fabsf(acc), nextmax, smr);
}

// ---- generic fp32 tiled GEMM: C[M,N] = A[M,K] @ W[K,N] ----------------------
template<bool AMAX>
__global__ __launch_bounds__(256) void k_gemm(const float* __restrict__ A,
                                              const float* __restrict__ W,
                                              float* __restrict__ C,
                                              int M, int N, int Kd,
                                              float* __restrict__ amax_out) {
  __shared__ __align__(16) float As[16][68];
  __shared__ __align__(16) float Bs[16][68];
  __shared__ float smr[8];
  int tx = threadIdx.x & 15, ty = threadIdx.x >> 4;
  int m0 = blockIdx.y * 64, n0 = blockIdx.x * 64;
  float acc[4][4] = {};
  for (int k0 = 0; k0 < Kd; k0 += 16) {
    #pragma unroll
    for (int r = 0; r < 4; r++) {
      int id = threadIdx.x + r * 256;
      int mm = id >> 4, kk = id & 15;
      int gm = m0 + mm, gk = k0 + kk;
      As[kk][mm] = (gm < M && gk < Kd) ? A[(long)gm * Kd + gk] : 0.f;
    }
    #pragma unroll
    for (int r = 0; r < 4; r++) {
      int id = threadIdx.x + r * 256;
      int kk = id >> 6, nn = id & 63;
      int gk = k0 + kk, gn = n0 + nn;
      Bs[kk][nn] = (gk < Kd && gn < N) ? W[(long)gk * N + gn] : 0.f;
    }
    __syncthreads();
    #pragma unroll
    for (int kk = 0; kk < 16; kk++) {
      float4 a4 = *reinterpret_cast<const float4*>(&As[kk][ty * 4]);
      float4 b4 = *reinterpret_cast<const float4*>(&Bs[kk][tx * 4]);
      float av[4] = {a4.x, a4.y, a4.z, a4.w};
      float bv[4] = {b4.x, b4.y, b4.z, b4.w};
      #pragma unroll
      for (int i = 0; i < 4; i++)
        #pragma unroll
        for (int j = 0; j < 4; j++)
          acc[i][j] = fmaf(av[i], bv[j], acc[i][j]);
    }
    __syncthreads();
  }
  float mx = 0.f;
  #pragma unroll
  for (int i = 0; i < 4; i++) {
    int gm = m0 + ty * 4 + i;
    if (gm < M) {
      #pragma unroll
      for (int j = 0; j < 4; j++) {
        int gn = n0 + tx * 4 + j;
        if (gn < N) {
          C[(long)gm * N + gn] = acc[i][j];
          mx = fmaxf(mx, fabsf(acc[i][j]));
        }
      }
    }
  }
  if (AMAX) blockAtomicMax(mx, amax_out, smr);
}

// ---- depthwise causal conv1d (K=4) + SiLU, direction-aware ------------------
__global__ void k_conv(const float* __restrict__ xz, const float* __restrict__ cw,
                       const float* __restrict__ cb, float* __restrict__ xcout, int rev) {
  long idx = (long)blockIdx.x * 256 + threadIdx.x;   // B*L*DI threads
  int d = (int)(idx & 255);
  int t = (int)((idx >> 8) % L_);
  int b = (int)(idx / (256L * L_));
  long base = (long)b * L_;
  float acc = cb[d];
  #pragma unroll
  for (int j = 0; j < K_; j++) {
    int tau = t - (K_ - 1) + j;
    if (tau >= 0) {
      int p = rev ? (L_ - 1 - tau) : tau;
      acc = fmaf(cw[d * K_ + j], xz[(base + p) * (2 * DI_) + d], acc);
    }
  }
  float sig = 1.f / (1.f + expf(-acc));
  int pt = rev ? (L_ - 1 - t) : t;
  xcout[(base + pt) * DI_ + d] = acc * sig;
}

// ---- dt = softplus(dtr @ dt_w + dt_b) ---------------------------------------
__global__ __launch_bounds__(256) void k_dt(const float* __restrict__ proj,
                                            const float* __restrict__ dw,
                                            const float* __restrict__ db,
                                            float* __restrict__ dtout) {
  __shared__ float pr[DTR_];
  long row = blockIdx.x;
  if (threadIdx.x < DTR_) pr[threadIdx.x] = proj[row * 33 + threadIdx.x];
  __syncthreads();
  int d = threadIdx.x;
  float acc = db[d];
  #pragma unroll
  for (int r = 0; r < DTR_; r++) acc = fmaf(pr[r], dw[r * DI_ + d], acc);
  // jax.nn.softplus = logaddexp(x, 0)
  float sp = fmaxf(acc, 0.f) + log1pf(expf(-fabsf(acc)));
  dtout[row * DI_ + d] = sp;
}

// ---- chunked parallel selective scan ----------------------------------------
// Pass 1: per-chunk local scan (h0 = 0); emit chunk-end state H and dA-product P.
__global__ __launch_bounds__(256) void k_scan1(const float* __restrict__ xc,
                                               const float* __restrict__ dt,
                                               const float* __restrict__ proj,
                                               const float* __restrict__ A_log,
                                               float* __restrict__ Hend,
                                               float* __restrict__ Pend, int rev) {
  int b = blockIdx.y, c = blockIdx.x, d = threadIdx.x;
  float A[4];
  #pragma unroll
  for (int n = 0; n < 4; n++) A[n] = -expf(A_log[d * 4 + n]);
  float h[4] = {0.f, 0.f, 0.f, 0.f};
  float P[4] = {1.f, 1.f, 1.f, 1.f};
  long base = (long)b * L_;
  for (int s = 0; s < CHL_; s++) {
    int step = c * CHL_ + s;
    long row = base + (rev ? (L_ - 1 - step) : step);
    float dtv = dt[row * DI_ + d];
    float xcv = xc[row * DI_ + d];
    float dx = dtv * xcv;
    #pragma unroll
    for (int n = 0; n < 4; n++) {
      float Bn = proj[row * 33 + DTR_ + n];
      float dA = expf(dtv * A[n]);
      h[n] = dA * h[n] + dx * Bn;
      P[n] *= dA;
    }
  }
  long o = ((long)b * CH_ + c) * 1024 + d * 4;
  *reinterpret_cast<float4*>(Hend + o) = make_float4(h[0], h[1], h[2], h[3]);
  *reinterpret_cast<float4*>(Pend + o) = make_float4(P[0], P[1], P[2], P[3]);
}

// Pass 2: sequential carry over the CH_ chunk summaries. Carry[c] = h at chunk start.
__global__ __launch_bounds__(256) void k_carry(const float* __restrict__ Hend,
                                               const float* __restrict__ Pend,
                                               float* __restrict__ Carry) {
  int tid = blockIdx.x * 256 + threadIdx.x;   // B_*1024 = 16384 lanes
  int b = tid >> 10, i = tid & 1023;
  float carry = 0.f;
  for (int c = 0; c < CH_; c++) {
    long o = ((long)b * CH_ + c) * 1024 + i;
    Carry[o] = carry;
    carry = Pend[o] * carry + Hend[o];
  }
}

// Pass 3: rerun the recurrence seeded with the carry; fuse +D*xc, *silu(z), fwd/bwd add.
__global__ __launch_bounds__(256) void k_scan2(const float* __restrict__ xc,
                                               const float* __restrict__ dt,
                                               const float* __restrict__ proj,
                                               const float* __restrict__ A_log,
                                               const float* __restrict__ Dp,
                                               const float* __restrict__ xz,
                                               const float* __restrict__ Carry,
                                               float* __restrict__ y, int rev, int accum) {
  int b = blockIdx.y, c = blockIdx.x, d = threadIdx.x;
  float A[4];
  #pragma unroll
  for (int n = 0; n < 4; n++) A[n] = -expf(A_log[d * 4 + n]);
  long o = ((long)b * CH_ + c) * 1024 + d * 4;
  float4 cv = *reinterpret_cast<const float4*>(Carry + o);
  float h[4] = {cv.x, cv.y, cv.z, cv.w};
  float Dv = Dp[d];
  long base = (long)b * L_;
  for (int s = 0; s < CHL_; s++) {
    int step = c * CHL_ + s;
    long row = base + (rev ? (L_ - 1 - step) : step);
    float dtv = dt[row * DI_ + d];
    float xcv = xc[row * DI_ + d];
    float zv  = xz[row * (2 * DI_) + DI_ + d];
    float dx = dtv * xcv;
    float acc = 0.f;
    #pragma unroll
    for (int n = 0; n < 4; n++) {
      float Bn = proj[row * 33 + DTR_ + n];
      float Cn = proj[row * 33 + DTR_ + N_ + n];
      float dA = expf(dtv * A[n]);
      h[n] = dA * h[n] + dx * Bn;
      acc = fmaf(h[n], Cn, acc);
    }
    float yv = acc + Dv * xcv;
    float sig = 1.f / (1.f + expf(-zv));
    yv *= zv * sig;                                    // y * silu(z)
    long oi = row * DI_ + d;
    if (accum) yv += y[oi];
    y[oi] = yv;
  }
}

// ---- residual + fq(mamba_out) + layernorm (in-place on mo) ------------------
__global__ __launch_bounds__(128) void k_ln(const float* __restrict__ x2,
                                            float* __restrict__ mo,
                                            const float* __restrict__ smo,
                                            const float* __restrict__ g,
                                            const float* __restrict__ bta,
                                            float* __restrict__ nextmax) {
  __shared__ float sm[2];
  long row = blockIdx.x;
  float s = fq_scale(smo);
  float v[4];
  float lsum = 0.f;
  #pragma unroll
  for (int k2 = 0; k2 < 4; k2++) {
    int c = threadIdx.x + k2 * 128;
    float t = 0.f;
    if (c < DM_) {
      float m = fq_apply(mo[row * DM_ + c], s);
      t = x2[row * DM_ + c] + m;
    }
    v[k2] = t; lsum += t;
  }
  float w = lsum;
  #pragma unroll
  for (int o = 32; o > 0; o >>= 1) w += __shfl_down(w, o);
  if ((threadIdx.x & 63) == 0) sm[threadIdx.x >> 6] = w;
  __syncthreads();
  float mean = (sm[0] + sm[1]) / 385.f;
  __syncthreads();
  float lvar = 0.f;
  #pragma unroll
  for (int k2 = 0; k2 < 4; k2++) {
    int c = threadIdx.x + k2 * 128;
    if (c < DM_) { float dd = v[k2] - mean; lvar += dd * dd; }
  }
  w = lvar;
  #pragma unroll
  for (int o = 32; o > 0; o >>= 1) w += __shfl_down(w, o);
  if ((threadIdx.x & 63) == 0) sm[threadIdx.x >> 6] = w;
  __syncthreads();
  float var = (sm[0] + sm[1]) / 385.f;
  float rs = 1.f / sqrtf(var + 1e-5f);
  float lmax = 0.f;
  #pragma unroll
  for (int k2 = 0; k2 < 4; k2++) {
    int c = threadIdx.x + k2 * 128;
    if (c < DM_) {
      float o2 = (v[k2] - mean) * rs * g[c] + bta[c];
      mo[row * DM_ + c] = o2;
      lmax = fmaxf(lmax, fabsf(o2));
    }
  }
  __syncthreads();
  w = lmax;
  #pragma unroll
  for (int o = 32; o > 0; o >>= 1) w = fmaxf(w, __shfl_down(w, o));
  if ((threadIdx.x & 63) == 0) sm[threadIdx.x >> 6] = w;
  __syncthreads();
  if (threadIdx.x == 0) atomicMaxF(nextmax, fmaxf(sm[0], sm[1]));
}

// ---- mean pool over L + absmax ----------------------------------------------
__global__ void k_pool(const float* __restrict__ x2, float* __restrict__ pool,
                       float* __restrict__ nextmax) {
  __shared__ float smr[8];
  int idx = blockIdx.x * 256 + threadIdx.x;
  float mv = 0.f;
  if (idx < B_ * DM_) {
    int b = idx / DM_, c = idx % DM_;
    const float* p = x2 + (long)b * L_ * DM_ + c;
    float sum = 0.f;
    for (int l = 0; l < L_; l++) sum += p[(long)l * DM_];
    float mean = sum / (float)L_;
    pool[idx] = mean;
    mv = fabsf(mean);
  }
  blockAtomicMax(mv, nextmax, smr);
}

// ---- classifier --------------------------------------------------------------
__global__ void k_cls(const float* __restrict__ pool, const float* __restrict__ clsw,
                      const float* __restrict__ clsb, const float* __restrict__ sp_,
                      const float* __restrict__ sw_, float* __restrict__ out) {
  int tid = threadIdx.x;
  if (tid >= B_ * 2) return;
  int b = tid >> 1, c = tid & 1;
  float sp = fq_scale(sp_), sw = fq_scale(sw_);
  float acc = 0.f;
  for (int k2 = 0; k2 < DM_; k2++) {
    float xv = fq_apply(pool[b * DM_ + k2], sp);
    float wv = fq_apply(clsw[k2 * 2 + c], sw);
    acc = fmaf(xv, wv, acc);
  }
  out[b * 2 + c] = acc + clsb[c];
}

// ---- launch ------------------------------------------------------------------
extern "C" void kernel_launch(void* const* d_in, const int* in_sizes, int n_in,
                              void* d_out, int out_size, void* d_ws, size_t ws_size,
                              hipStream_t stream) {
  const float* x    = (const float*)d_in[0];
  const float* pew  = (const float*)d_in[1];
  const float* peb  = (const float*)d_in[2];
  const float* pos  = (const float*)d_in[3];
  const float* in_w = (const float*)d_in[4];
  const float* cw   = (const float*)d_in[5];
  const float* cb   = (const float*)d_in[6];
  const float* xpw  = (const float*)d_in[7];
  const float* dtw  = (const float*)d_in[8];
  const float* dtb  = (const float*)d_in[9];
  const float* alog = (const float*)d_in[10];
  const float* dp   = (const float*)d_in[11];
  const float* outw = (const float*)d_in[12];
  const float* lng  = (const float*)d_in[13];
  const float* lnb  = (const float*)d_in[14];
  const float* clsw = (const float*)d_in[15];
  const float* clsb = (const float*)d_in[16];

  float* ws   = (float*)d_ws;
  float* SCAL = ws;                               // 16 scalars used (256 reserved)
  float* P2   = ws + 256;                         // 492,800
  float* X2   = P2 + LDM_;                        // 7,884,800
  float* XZ   = X2 + NX_;                         // 20480*512
  float* XC   = XZ + (long)ROWS_ * 512;           // 20480*256
  float* PROJ = XC + (long)ROWS_ * DI_;           // 20480*33
  float* DT   = PROJ + (long)ROWS_ * 33;          // 20480*256
  float* Y    = DT + (long)ROWS_ * DI_;           // 20480*256
  float* MO   = Y + (long)ROWS_ * DI_;            // 7,884,800
  float* POOL = MO + NX_;                         // 6160
  float* HEND = POOL + 8192;                      // 16*64*1024 = 1,048,576
  float* PEND = HEND + (long)B_ * CH_ * 1024;     // 1,048,576
  float* CARR = PEND + (long)B_ * CH_ * 1024;     // 1,048,576
  // total ≈ 46.3M floats ≈ 186 MiB

  k_zero<<<1, 64, 0, stream>>>(SCAL);

  // input fq + patch-embed weight fq
  k_absmax<<<2048, 256, 0, stream>>>(x, (long)B_ * H_ * W_, SCAL + 0);
  k_absmax<<<8, 256, 0, stream>>>(pew, EMB * 2 * 16, SCAL + 1);
  k_patch<<<30800, 256, 0, stream>>>(x, pew, peb, SCAL + 0, SCAL + 1, X2, SCAL + 2);
  k_fq<<<2048, 256, 0, stream>>>(X2, X2, NX_, SCAL + 2, SCAL + 3);       // x = fq(x)

  // pos = fq(fq(pos_embed))
  k_absmax<<<512, 256, 0, stream>>>(pos, LDM_, SCAL + 4);
  k_fq<<<512, 256, 0, stream>>>(pos, P2, LDM_, SCAL + 4, SCAL + 5);
  k_fq<<<512, 256, 0, stream>>>(P2, P2, LDM_, SCAL + 5, nullptr);

  // x = fq(fq(x) + pos)
  k_addpos<<<2048, 256, 0, stream>>>(X2, P2, NX_, SCAL + 3, SCAL + 6);
  k_fq<<<2048, 256, 0, stream>>>(X2, X2, NX_, SCAL + 6, nullptr);

  for (int blk = 0; blk < 2; blk++) {
    // in-proj (shared between directions: flip commutes with row-wise matmul)
    k_gemm<false><<<dim3(8, 320), 256, 0, stream>>>(
        X2, in_w + (long)blk * DM_ * 512, XZ, ROWS_, 512, DM_, nullptr);
    for (int dir = 0; dir < 2; dir++) {
      k_conv<<<20480, 256, 0, stream>>>(XZ, cw + blk * DI_ * K_, cb + blk * DI_, XC, dir);
      k_gemm<false><<<dim3(1, 320), 256, 0, stream>>>(
          XC, xpw + (long)blk * DI_ * 33, PROJ, ROWS_, 33, DI_, nullptr);
      k_dt<<<20480, 256, 0, stream>>>(PROJ, dtw + blk * DTR_ * DI_, dtb + blk * DI_, DT);
      // chunked parallel scan (dir==1 accumulates into Y)
      k_scan1<<<dim3(CH_, B_), 256, 0, stream>>>(XC, DT, PROJ, alog + blk * DI_ * N_,
                                                 HEND, PEND, dir);
      k_carry<<<64, 256, 0, stream>>>(HEND, PEND, CARR);
      k_scan2<<<dim3(CH_, B_), 256, 0, stream>>>(XC, DT, PROJ, alog + blk * DI_ * N_,
                                                 dp + blk * DI_, XZ, CARR, Y, dir, dir);
    }
    // out-proj on summed y; fused absmax for fq(fwd+bwd)
    k_gemm<true><<<dim3(7, 320), 256, 0, stream>>>(
        Y, outw + (long)blk * DI_ * DM_, MO, ROWS_, DM_, DI_, SCAL + 7 + blk * 2);
    // x = fq(layernorm(x + fq(mo)))
    k_ln<<<20480, 128, 0, stream>>>(X2, MO, SCAL + 7 + blk * 2,
                                    lng + blk * DM_, lnb + blk * DM_, SCAL + 8 + blk * 2);
    k_fq<<<2048, 256, 0, stream>>>(MO, X2, NX_, SCAL + 8 + blk * 2, nullptr);
  }

  // mean-pool, fq, classifier with fq(cls_w)
  k_pool<<<25, 256, 0, stream>>>(X2, POOL, SCAL + 11);
  k_absmax<<<4, 256, 0, stream>>>(clsw, DM_ * 2, SCAL + 12);
  k_cls<<<1, 64, 0, stream>>>(POOL, clsw, clsb, SCAL + 11, SCAL + 12, (float*)d_out);
}

// Round 3
// 1899.097 us; speedup vs baseline: 2.6290x; 1.1497x over previous
//
#include <hip/hip_runtime.h>
#include <hip/hip_bf16.h>
#include <math.h>

// ---- problem constants -----------------------------------------------------
#define B_    16
#define H_    22
#define W_    20480
#define EMB   35
#define GH_   11
#define GW_   1280
#define L_    1280
#define DM_   385
#define DI_   256
#define N_    4
#define K_    4
#define DTR_  25
#define ROWS_ (B_*L_)              // 20480
#define NX_   ((long)ROWS_*DM_)    // 7,884,800
#define LDM_  ((long)L_*DM_)       // 492,800
#define CH_   64                   // scan chunks
#define CHL_  20                   // steps per chunk (CH_*CHL_ == L_)
#define KPI_  800                  // in_proj padded K' (2*385 -> 800)
#define KPO_  768                  // out_proj padded K' (3*256)

typedef __attribute__((ext_vector_type(8))) short short8;
typedef __attribute__((ext_vector_type(4))) float f32x4;
typedef unsigned short ushort;

// ---- helpers ---------------------------------------------------------------
__device__ __forceinline__ void atomicMaxF(float* a, float v) {
  atomicMax(reinterpret_cast<int*>(a), __float_as_int(v));
}

// faithful fq: s = max(mx,1e-8)/127; q = clip(rint(x/s),-128,127)*s
__device__ __forceinline__ float fq_apply(float x, float s) {
  float r = rintf(x / s);
  r = fminf(fmaxf(r, -128.f), 127.f);
  return r * s;
}
__device__ __forceinline__ float fq_scale(const float* pmax) {
  return fmaxf(pmax[0], 1e-8f) / 127.f;
}

__device__ __forceinline__ ushort f2bf(float f) {  // round-to-nearest-even
  union { float f; unsigned u; } v; v.f = f;
  unsigned r = v.u + 0x7FFF + ((v.u >> 16) & 1);
  return (ushort)(r >> 16);
}
__device__ __forceinline__ float bf2f(ushort h) {
  union { unsigned u; float f; } v; v.u = ((unsigned)h) << 16;
  return v.f;
}

__device__ __forceinline__ void blockAtomicMax(float v, float* out, float* sm) {
  #pragma unroll
  for (int o = 32; o > 0; o >>= 1) v = fmaxf(v, __shfl_down(v, o));
  if ((threadIdx.x & 63) == 0) sm[threadIdx.x >> 6] = v;
  __syncthreads();
  if (threadIdx.x == 0) {
    int nw = (blockDim.x + 63) >> 6;
    for (int i = 1; i < nw; i++) v = fmaxf(v, sm[i]);
    atomicMaxF(out, v);
  }
}

// ---- small utility kernels -------------------------------------------------
__global__ void k_zero(float* s) { if (threadIdx.x < 64) s[threadIdx.x] = 0.f; }

__global__ void k_absmax(const float* __restrict__ src, long n, float* __restrict__ out) {
  __shared__ float smr[8];
  float m = 0.f;
  for (long i = (long)blockIdx.x * blockDim.x + threadIdx.x; i < n;
       i += (long)gridDim.x * blockDim.x)
    m = fmaxf(m, fabsf(src[i]));
  blockAtomicMax(m, out, smr);
}

// dst = fq(src); optional absmax(dst) -> nextmax; optional bf16 q-emit into A2
// (A2 layout [M][KPI_], q duplicated at cols k and 385+k). dst may == src.
__global__ void k_fq(const float* __restrict__ src, float* __restrict__ dst, long n,
                     const float* __restrict__ pmax, float* __restrict__ nextmax,
                     ushort* __restrict__ a2) {
  __shared__ float smr[8];
  float s = fq_scale(pmax);
  float m = 0.f;
  for (long i = (long)blockIdx.x * blockDim.x + threadIdx.x; i < n;
       i += (long)gridDim.x * blockDim.x) {
    float r = rintf(src[i] / s);
    r = fminf(fmaxf(r, -128.f), 127.f);
    float q = r * s;
    dst[i] = q;
    if (a2) {
      long mm = i / 385; int kk = (int)(i - mm * 385);
      ushort b = f2bf(r);                       // exact: |r| <= 128 integer
      a2[mm * KPI_ + kk] = b;
      a2[mm * KPI_ + 385 + kk] = b;
    }
    m = fmaxf(m, fabsf(q));
  }
  if (nextmax) blockAtomicMax(m, nextmax, smr);
}

// x[i] = fq(x[i]) + p2[i % LDM]; absmax -> nextmax
__global__ void k_addpos(float* __restrict__ x, const float* __restrict__ p2, long n,
                         const float* __restrict__ pmax, float* __restrict__ nextmax) {
  __shared__ float smr[8];
  float s = fq_scale(pmax);
  float m = 0.f;
  for (long i = (long)blockIdx.x * blockDim.x + threadIdx.x; i < n;
       i += (long)gridDim.x * blockDim.x) {
    float v = fq_apply(x[i], s) + p2[i % LDM_];
    x[i] = v;
    m = fmaxf(m, fabsf(v));
  }
  blockAtomicMax(m, nextmax, smr);
}

// simple elementwise fq into a fresh buffer (input / patch weights)
__global__ void k_qx(const float* __restrict__ src, float* __restrict__ dst, long n,
                     const float* __restrict__ pmax) {
  float s = fq_scale(pmax);
  for (long i = (long)blockIdx.x * blockDim.x + threadIdx.x; i < n;
       i += (long)gridDim.x * blockDim.x)
    dst[i] = fq_apply(src[i], s);
}

// ---- patch embed on pre-quantized inputs ------------------------------------
__global__ void k_patch2(const float* __restrict__ xq, const float* __restrict__ wq,
                         const float* __restrict__ peb, float* __restrict__ out,
                         float* __restrict__ nextmax) {
  __shared__ float smr[8];
  long idx = (long)blockIdx.x * 256 + threadIdx.x;   // exactly NX_ threads
  int e = (int)(idx % EMB);
  long r = idx / EMB;
  int gh = (int)(r % GH_); r /= GH_;
  int gw = (int)(r % GW_);
  int b  = (int)(r / GW_);
  float acc = peb[e];
  #pragma unroll
  for (int ph = 0; ph < 2; ph++) {
    const float* xr = xq + ((long)b * H_ + (gh * 2 + ph)) * W_ + (long)gw * 16;
    const float* wr = wq + (e * 2 + ph) * 16;
    #pragma unroll
    for (int pw = 0; pw < 16; pw++) acc = fmaf(xr[pw], wr[pw], acc);
  }
  out[idx] = acc;
  blockAtomicMax(fabsf(acc), nextmax, smr);
}

// ---- weight split: W[K][N] f32 -> W2T[Npad][Kp] bf16, terms {hi,lo[,hi]} ----
__global__ void k_wsplit(const float* __restrict__ W, ushort* __restrict__ out,
                         int K, int N, int Kp, long total, int terms) {
  long idx = (long)blockIdx.x * 256 + threadIdx.x;
  if (idx >= total) return;
  int k = (int)(idx % Kp);
  int n = (int)(idx / Kp);
  int t = k / K, kk = k - t * K;
  ushort r = 0;
  if (n < N && t < terms) {
    float w = W[(long)kk * N + n];
    ushort hi = f2bf(w);
    r = (t == 1) ? f2bf(w - bf2f(hi)) : hi;
  }
  out[idx] = r;
}

// ---- activation split: Y[M][256] f32 -> A2[M][768] bf16 {hi,hi,lo} ----------
__global__ void k_asplit(const float* __restrict__ Y, ushort* __restrict__ A2) {
  long idx = (long)blockIdx.x * 256 + threadIdx.x;   // M*768 threads
  long m = idx / KPO_; int k = (int)(idx - m * KPO_);
  int t = k >> 8, kk = k & 255;
  float v = Y[m * DI_ + kk];
  ushort hi = f2bf(v);
  A2[idx] = (t == 2) ? f2bf(v - bf2f(hi)) : hi;
}

// zero the pad columns [770, 800) of A2 (in_proj)
__global__ void k_padzero(ushort* __restrict__ A2) {
  long idx = (long)blockIdx.x * 256 + threadIdx.x;   // ROWS_*30 threads
  long m = idx / 30; int c = (int)(idx - m * 30);
  A2[m * KPI_ + 770 + c] = 0;
}

// ---- bf16 MFMA GEMM: C[M][Nreal] = scale * (A2[M][Kp] @ W2T[Npad][Kp]^T) ----
// 128x128 tile, BK=32, 4 waves (2x2), 16x16x32 MFMA.
template<bool AMAX>
__global__ __launch_bounds__(256) void k_mgemm(const ushort* __restrict__ A2,
                                               const ushort* __restrict__ W2T,
                                               float* __restrict__ C,
                                               int Nreal, int Kp,
                                               const float* __restrict__ sptr,
                                               float* __restrict__ amax_out) {
  __shared__ ushort Alds[4][128][8];   // [k-slot][row][8k] 8 KB
  __shared__ ushort Blds[4][128][8];   // [k-slot][col][8k] 8 KB
  __shared__ float smr[8];
  int tid = threadIdx.x;
  int lane = tid & 63, wave = tid >> 6;
  int wm = wave >> 1, wn = wave & 1;
  int m0 = blockIdx.y * 128, n0 = blockIdx.x * 128;
  f32x4 acc[4][4];
  #pragma unroll
  for (int i = 0; i < 4; i++)
    #pragma unroll
    for (int j = 0; j < 4; j++) acc[i][j] = (f32x4){0.f, 0.f, 0.f, 0.f};

  for (int k0 = 0; k0 < Kp; k0 += 32) {
    #pragma unroll
    for (int r = 0; r < 2; r++) {
      int id = tid + r * 256;            // 0..511
      int row = id >> 2, sl = id & 3;    // coalesced 64B global segments
      short8 va = *reinterpret_cast<const short8*>(A2 + (long)(m0 + row) * Kp + k0 + sl * 8);
      *reinterpret_cast<short8*>(&Alds[sl][row][0]) = va;
      short8 vb = *reinterpret_cast<const short8*>(W2T + (long)(n0 + row) * Kp + k0 + sl * 8);
      *reinterpret_cast<short8*>(&Blds[sl][row][0]) = vb;
    }
    __syncthreads();
    int sl = lane >> 4, rr = lane & 15;
    short8 af[4], bf4[4];
    #pragma unroll
    for (int i = 0; i < 4; i++)
      af[i] = *reinterpret_cast<const short8*>(&Alds[sl][wm * 64 + i * 16 + rr][0]);
    #pragma unroll
    for (int j = 0; j < 4; j++)
      bf4[j] = *reinterpret_cast<const short8*>(&Blds[sl][wn * 64 + j * 16 + rr][0]);
    #pragma unroll
    for (int i = 0; i < 4; i++)
      #pragma unroll
      for (int j = 0; j < 4; j++)
        acc[i][j] = __builtin_amdgcn_mfma_f32_16x16x32_bf16(af[i], bf4[j], acc[i][j], 0, 0, 0);
    __syncthreads();
  }

  float s = sptr ? fq_scale(sptr) : 1.0f;
  float mx = 0.f;
  int cfr = lane & 15, rbase = (lane >> 4) * 4;
  #pragma unroll
  for (int i = 0; i < 4; i++) {
    int gmb = m0 + wm * 64 + i * 16 + rbase;
    #pragma unroll
    for (int j = 0; j < 4; j++) {
      int gn = n0 + wn * 64 + j * 16 + cfr;
      if (gn < Nreal) {
        #pragma unroll
        for (int rg = 0; rg < 4; rg++) {
          float v = acc[i][j][rg] * s;
          C[(long)(gmb + rg) * Nreal + gn] = v;
          mx = fmaxf(mx, fabsf(v));
        }
      }
    }
  }
  if (AMAX) blockAtomicMax(mx, amax_out, smr);
}

// ---- generic fp32 tiled GEMM (kept for the skinny xp projection) ------------
template<bool AMAX>
__global__ __launch_bounds__(256) void k_gemm(const float* __restrict__ A,
                                              const float* __restrict__ W,
                                              float* __restrict__ C,
                                              int M, int N, int Kd,
                                              float* __restrict__ amax_out) {
  __shared__ __align__(16) float As[16][68];
  __shared__ __align__(16) float Bs[16][68];
  __shared__ float smr[8];
  int tx = threadIdx.x & 15, ty = threadIdx.x >> 4;
  int m0 = blockIdx.y * 64, n0 = blockIdx.x * 64;
  float acc[4][4] = {};
  for (int k0 = 0; k0 < Kd; k0 += 16) {
    #pragma unroll
    for (int r = 0; r < 4; r++) {
      int id = threadIdx.x + r * 256;
      int mm = id >> 4, kk = id & 15;
      int gm = m0 + mm, gk = k0 + kk;
      As[kk][mm] = (gm < M && gk < Kd) ? A[(long)gm * Kd + gk] : 0.f;
    }
    #pragma unroll
    for (int r = 0; r < 4; r++) {
      int id = threadIdx.x + r * 256;
      int kk = id >> 6, nn = id & 63;
      int gk = k0 + kk, gn = n0 + nn;
      Bs[kk][nn] = (gk < Kd && gn < N) ? W[(long)gk * N + gn] : 0.f;
    }
    __syncthreads();
    #pragma unroll
    for (int kk = 0; kk < 16; kk++) {
      float4 a4 = *reinterpret_cast<const float4*>(&As[kk][ty * 4]);
      float4 b4 = *reinterpret_cast<const float4*>(&Bs[kk][tx * 4]);
      float av[4] = {a4.x, a4.y, a4.z, a4.w};
      float bv[4] = {b4.x, b4.y, b4.z, b4.w};
      #pragma unroll
      for (int i = 0; i < 4; i++)
        #pragma unroll
        for (int j = 0; j < 4; j++)
          acc[i][j] = fmaf(av[i], bv[j], acc[i][j]);
    }
    __syncthreads();
  }
  float mx = 0.f;
  #pragma unroll
  for (int i = 0; i < 4; i++) {
    int gm = m0 + ty * 4 + i;
    if (gm < M) {
      #pragma unroll
      for (int j = 0; j < 4; j++) {
        int gn = n0 + tx * 4 + j;
        if (gn < N) {
          C[(long)gm * N + gn] = acc[i][j];
          mx = fmaxf(mx, fabsf(acc[i][j]));
        }
      }
    }
  }
  if (AMAX) blockAtomicMax(mx, amax_out, smr);
}

// ---- depthwise causal conv1d (K=4) + SiLU, direction-aware ------------------
__global__ void k_conv(const float* __restrict__ xz, const float* __restrict__ cw,
                       const float* __restrict__ cb, float* __restrict__ xcout, int rev) {
  long idx = (long)blockIdx.x * 256 + threadIdx.x;   // B*L*DI threads
  int d = (int)(idx & 255);
  int t = (int)((idx >> 8) % L_);
  int b = (int)(idx / (256L * L_));
  long base = (long)b * L_;
  float acc = cb[d];
  #pragma unroll
  for (int j = 0; j < K_; j++) {
    int tau = t - (K_ - 1) + j;
    if (tau >= 0) {
      int p = rev ? (L_ - 1 - tau) : tau;
      acc = fmaf(cw[d * K_ + j], xz[(base + p) * (2 * DI_) + d], acc);
    }
  }
  float sig = 1.f / (1.f + expf(-acc));
  int pt = rev ? (L_ - 1 - t) : t;
  xcout[(base + pt) * DI_ + d] = acc * sig;
}

// ---- dt = softplus(dtr @ dt_w + dt_b) ---------------------------------------
__global__ __launch_bounds__(256) void k_dt(const float* __restrict__ proj,
                                            const float* __restrict__ dw,
                                            const float* __restrict__ db,
                                            float* __restrict__ dtout) {
  __shared__ float pr[DTR_];
  long row = blockIdx.x;
  if (threadIdx.x < DTR_) pr[threadIdx.x] = proj[row * 33 + threadIdx.x];
  __syncthreads();
  int d = threadIdx.x;
  float acc = db[d];
  #pragma unroll
  for (int r = 0; r < DTR_; r++) acc = fmaf(pr[r], dw[r * DI_ + d], acc);
  float sp = fmaxf(acc, 0.f) + log1pf(expf(-fabsf(acc)));
  dtout[row * DI_ + d] = sp;
}

// ---- chunked parallel selective scan ----------------------------------------
__global__ __launch_bounds__(256) void k_scan1(const float* __restrict__ xc,
                                               const float* __restrict__ dt,
                                               const float* __restrict__ proj,
                                               const float* __restrict__ A_log,
                                               float* __restrict__ Hend,
                                               float* __restrict__ Pend, int rev) {
  int b = blockIdx.y, c = blockIdx.x, d = threadIdx.x;
  float A[4];
  #pragma unroll
  for (int n = 0; n < 4; n++) A[n] = -expf(A_log[d * 4 + n]);
  float h[4] = {0.f, 0.f, 0.f, 0.f};
  float P[4] = {1.f, 1.f, 1.f, 1.f};
  long base = (long)b * L_;
  for (int s = 0; s < CHL_; s++) {
    int step = c * CHL_ + s;
    long row = base + (rev ? (L_ - 1 - step) : step);
    float dtv = dt[row * DI_ + d];
    float xcv = xc[row * DI_ + d];
    float dx = dtv * xcv;
    #pragma unroll
    for (int n = 0; n < 4; n++) {
      float Bn = proj[row * 33 + DTR_ + n];
      float dA = expf(dtv * A[n]);
      h[n] = dA * h[n] + dx * Bn;
      P[n] *= dA;
    }
  }
  long o = ((long)b * CH_ + c) * 1024 + d * 4;
  *reinterpret_cast<float4*>(Hend + o) = make_float4(h[0], h[1], h[2], h[3]);
  *reinterpret_cast<float4*>(Pend + o) = make_float4(P[0], P[1], P[2], P[3]);
}

__global__ __launch_bounds__(256) void k_carry(const float* __restrict__ Hend,
                                               const float* __restrict__ Pend,
                                               float* __restrict__ Carry) {
  int tid = blockIdx.x * 256 + threadIdx.x;   // B_*1024 lanes
  int b = tid >> 10, i = tid & 1023;
  float carry = 0.f;
  for (int c = 0; c < CH_; c++) {
    long o = ((long)b * CH_ + c) * 1024 + i;
    Carry[o] = carry;
    carry = Pend[o] * carry + Hend[o];
  }
}

__global__ __launch_bounds__(256) void k_scan2(const float* __restrict__ xc,
                                               const float* __restrict__ dt,
                                               const float* __restrict__ proj,
                                               const float* __restrict__ A_log,
                                               const float* __restrict__ Dp,
                                               const float* __restrict__ xz,
                                               const float* __restrict__ Carry,
                                               float* __restrict__ y, int rev, int accum) {
  int b = blockIdx.y, c = blockIdx.x, d = threadIdx.x;
  float A[4];
  #pragma unroll
  for (int n = 0; n < 4; n++) A[n] = -expf(A_log[d * 4 + n]);
  long o = ((long)b * CH_ + c) * 1024 + d * 4;
  float4 cv = *reinterpret_cast<const float4*>(Carry + o);
  float h[4] = {cv.x, cv.y, cv.z, cv.w};
  float Dv = Dp[d];
  long base = (long)b * L_;
  for (int s = 0; s < CHL_; s++) {
    int step = c * CHL_ + s;
    long row = base + (rev ? (L_ - 1 - step) : step);
    float dtv = dt[row * DI_ + d];
    float xcv = xc[row * DI_ + d];
    float zv  = xz[row * (2 * DI_) + DI_ + d];
    float dx = dtv * xcv;
    float acc = 0.f;
    #pragma unroll
    for (int n = 0; n < 4; n++) {
      float Bn = proj[row * 33 + DTR_ + n];
      float Cn = proj[row * 33 + DTR_ + N_ + n];
      float dA = expf(dtv * A[n]);
      h[n] = dA * h[n] + dx * Bn;
      acc = fmaf(h[n], Cn, acc);
    }
    float yv = acc + Dv * xcv;
    float sig = 1.f / (1.f + expf(-zv));
    yv *= zv * sig;
    long oi = row * DI_ + d;
    if (accum) yv += y[oi];
    y[oi] = yv;
  }
}

// ---- residual + fq(mamba_out) + layernorm (in-place on mo) ------------------
__global__ __launch_bounds__(128) void k_ln(const float* __restrict__ x2,
                                            float* __restrict__ mo,
                                            const float* __restrict__ smo,
                                            const float* __restrict__ g,
                                            const float* __restrict__ bta,
                                            float* __restrict__ nextmax) {
  __shared__ float sm[2];
  long row = blockIdx.x;
  float s = fq_scale(smo);
  float v[4];
  float lsum = 0.f;
  #pragma unroll
  for (int k2 = 0; k2 < 4; k2++) {
    int c = threadIdx.x + k2 * 128;
    float t = 0.f;
    if (c < DM_) {
      float m = fq_apply(mo[row * DM_ + c], s);
      t = x2[row * DM_ + c] + m;
    }
    v[k2] = t; lsum += t;
  }
  float w = lsum;
  #pragma unroll
  for (int o = 32; o > 0; o >>= 1) w += __shfl_down(w, o);
  if ((threadIdx.x & 63) == 0) sm[threadIdx.x >> 6] = w;
  __syncthreads();
  float mean = (sm[0] + sm[1]) / 385.f;
  __syncthreads();
  float lvar = 0.f;
  #pragma unroll
  for (int k2 = 0; k2 < 4; k2++) {
    int c = threadIdx.x + k2 * 128;
    if (c < DM_) { float dd = v[k2] - mean; lvar += dd * dd; }
  }
  w = lvar;
  #pragma unroll
  for (int o = 32; o > 0; o >>= 1) w += __shfl_down(w, o);
  if ((threadIdx.x & 63) == 0) sm[threadIdx.x >> 6] = w;
  __syncthreads();
  float var = (sm[0] + sm[1]) / 385.f;
  float rs = 1.f / sqrtf(var + 1e-5f);
  float lmax = 0.f;
  #pragma unroll
  for (int k2 = 0; k2 < 4; k2++) {
    int c = threadIdx.x + k2 * 128;
    if (c < DM_) {
      float o2 = (v[k2] - mean) * rs * g[c] + bta[c];
      mo[row * DM_ + c] = o2;
      lmax = fmaxf(lmax, fabsf(o2));
    }
  }
  __syncthreads();
  w = lmax;
  #pragma unroll
  for (int o = 32; o > 0; o >>= 1) w = fmaxf(w, __shfl_down(w, o));
  if ((threadIdx.x & 63) == 0) sm[threadIdx.x >> 6] = w;
  __syncthreads();
  if (threadIdx.x == 0) atomicMaxF(nextmax, fmaxf(sm[0], sm[1]));
}

// ---- mean pool over L + absmax ----------------------------------------------
__global__ void k_pool(const float* __restrict__ x2, float* __restrict__ pool,
                       float* __restrict__ nextmax) {
  __shared__ float smr[8];
  int idx = blockIdx.x * 256 + threadIdx.x;
  float mv = 0.f;
  if (idx < B_ * DM_) {
    int b = idx / DM_, c = idx % DM_;
    const float* p = x2 + (long)b * L_ * DM_ + c;
    float sum = 0.f;
    for (int l = 0; l < L_; l++) sum += p[(long)l * DM_];
    float mean = sum / (float)L_;
    pool[idx] = mean;
    mv = fabsf(mean);
  }
  blockAtomicMax(mv, nextmax, smr);
}

// ---- classifier --------------------------------------------------------------
__global__ void k_cls(const float* __restrict__ pool, const float* __restrict__ clsw,
                      const float* __restrict__ clsb, const float* __restrict__ sp_,
                      const float* __restrict__ sw_, float* __restrict__ out) {
  int tid = threadIdx.x;
  if (tid >= B_ * 2) return;
  int b = tid >> 1, c = tid & 1;
  float sp = fq_scale(sp_), sw = fq_scale(sw_);
  float acc = 0.f;
  for (int k2 = 0; k2 < DM_; k2++) {
    float xv = fq_apply(pool[b * DM_ + k2], sp);
    float wv = fq_apply(clsw[k2 * 2 + c], sw);
    acc = fmaf(xv, wv, acc);
  }
  out[b * 2 + c] = acc + clsb[c];
}

// ---- launch ------------------------------------------------------------------
extern "C" void kernel_launch(void* const* d_in, const int* in_sizes, int n_in,
                              void* d_out, int out_size, void* d_ws, size_t ws_size,
                              hipStream_t stream) {
  const float* x    = (const float*)d_in[0];
  const float* pew  = (const float*)d_in[1];
  const float* peb  = (const float*)d_in[2];
  const float* pos  = (const float*)d_in[3];
  const float* in_w = (const float*)d_in[4];
  const float* cw   = (const float*)d_in[5];
  const float* cb   = (const float*)d_in[6];
  const float* xpw  = (const float*)d_in[7];
  const float* dtw  = (const float*)d_in[8];
  const float* dtb  = (const float*)d_in[9];
  const float* alog = (const float*)d_in[10];
  const float* dp   = (const float*)d_in[11];
  const float* outw = (const float*)d_in[12];
  const float* lng  = (const float*)d_in[13];
  const float* lnb  = (const float*)d_in[14];
  const float* clsw = (const float*)d_in[15];
  const float* clsb = (const float*)d_in[16];

  float* ws    = (float*)d_ws;
  float* SCAL  = ws;                              // 64 scalars
  float* WQ    = ws + 256;                        // 2048 (1120 used)
  float* P2    = WQ + 2048;                       // 492,800
  float* X2    = P2 + LDM_;                       // 7,884,800
  float* XZ    = X2 + NX_;                        // 10,485,760
  float* XC    = XZ + (long)ROWS_ * 512;          // 5,242,880
  float* PROJ  = XC + (long)ROWS_ * DI_;          // 675,840
  float* DT    = PROJ + (long)ROWS_ * 33;         // 5,242,880
  float* Y     = DT + (long)ROWS_ * DI_;          // 5,242,880
  float* MO    = Y + (long)ROWS_ * DI_;           // 7,884,800
  float* POOL  = MO + NX_;                        // 8,192
  float* A2IN_f= POOL + 8192;                     // 8,192,000 f (ushort overlay)
  float* W2I_f = A2IN_f + 8192000;                // 409,600 f
  float* W2O_f = W2I_f + 409600;                  // 393,216 f
  // aliases (disjoint lifetimes):
  float*  XQ   = MO;                              // fq(x), dead after k_patch2
  float*  HEND = MO;                              // scan summaries, dead before out-GEMM
  float*  PEND = MO + 1048576;
  float*  CARR = MO + 2097152;
  ushort* A2Y  = (ushort*)XZ;                     // [20480][768], dead before next in-GEMM
  ushort* A2IN = (ushort*)A2IN_f;                 // [20480][800]
  ushort* W2TI = (ushort*)W2I_f;                  // 2 x [512][800]
  ushort* W2TO = (ushort*)W2O_f;                  // 2 x [512][768]
  // total ≈ 52.2M floats ≈ 209 MB

  k_zero<<<1, 64, 0, stream>>>(SCAL);

  // weight splits for MFMA GEMMs (tiny)
  for (int blk = 0; blk < 2; blk++) {
    k_wsplit<<<1600, 256, 0, stream>>>(in_w + (long)blk * DM_ * 512,
                                       W2TI + (long)blk * 512 * KPI_,
                                       DM_, 512, KPI_, 512L * KPI_, 2);
    k_wsplit<<<1536, 256, 0, stream>>>(outw + (long)blk * DI_ * DM_,
                                       W2TO + (long)blk * 512 * KPO_,
                                       DI_, DM_, KPO_, 512L * KPO_, 3);
  }
  k_padzero<<<2400, 256, 0, stream>>>(A2IN);

  // input fq + patch-embed (pre-quantized operands)
  k_absmax<<<2048, 256, 0, stream>>>(x, (long)B_ * H_ * W_, SCAL + 0);
  k_absmax<<<8, 256, 0, stream>>>(pew, EMB * 2 * 16, SCAL + 1);
  k_qx<<<2048, 256, 0, stream>>>(x, XQ, (long)B_ * H_ * W_, SCAL + 0);
  k_qx<<<5, 256, 0, stream>>>(pew, WQ, EMB * 2 * 16, SCAL + 1);
  k_patch2<<<30800, 256, 0, stream>>>(XQ, WQ, peb, X2, SCAL + 2);
  k_fq<<<2048, 256, 0, stream>>>(X2, X2, NX_, SCAL + 2, SCAL + 3, nullptr);

  // pos = fq(fq(pos_embed))
  k_absmax<<<512, 256, 0, stream>>>(pos, LDM_, SCAL + 4);
  k_fq<<<512, 256, 0, stream>>>(pos, P2, LDM_, SCAL + 4, SCAL + 5, nullptr);
  k_fq<<<512, 256, 0, stream>>>(P2, P2, LDM_, SCAL + 5, nullptr, nullptr);

  // x = fq(fq(x) + pos); emit bf16 q for blk0 in-proj
  k_addpos<<<2048, 256, 0, stream>>>(X2, P2, NX_, SCAL + 3, SCAL + 6);
  k_fq<<<2048, 256, 0, stream>>>(X2, X2, NX_, SCAL + 6, nullptr, A2IN);

  const float* in_scale[2] = {SCAL + 6, SCAL + 8};
  for (int blk = 0; blk < 2; blk++) {
    // in-proj: XZ = s * (q @ [w_hi; w_lo])   (MFMA bf16)
    k_mgemm<false><<<dim3(4, 160), 256, 0, stream>>>(
        A2IN, W2TI + (long)blk * 512 * KPI_, XZ, 512, KPI_, in_scale[blk], nullptr);
    for (int dir = 0; dir < 2; dir++) {
      k_conv<<<20480, 256, 0, stream>>>(XZ, cw + blk * DI_ * K_, cb + blk * DI_, XC, dir);
      k_gemm<false><<<dim3(1, 320), 256, 0, stream>>>(
          XC, xpw + (long)blk * DI_ * 33, PROJ, ROWS_, 33, DI_, nullptr);
      k_dt<<<20480, 256, 0, stream>>>(PROJ, dtw + blk * DTR_ * DI_, dtb + blk * DI_, DT);
      k_scan1<<<dim3(CH_, B_), 256, 0, stream>>>(XC, DT, PROJ, alog + blk * DI_ * N_,
                                                 HEND, PEND, dir);
      k_carry<<<64, 256, 0, stream>>>(HEND, PEND, CARR);
      k_scan2<<<dim3(CH_, B_), 256, 0, stream>>>(XC, DT, PROJ, alog + blk * DI_ * N_,
                                                 dp + blk * DI_, XZ, CARR, Y, dir, dir);
    }
    // out-proj: MO = [y_hi,y_hi,y_lo] @ [w_hi;w_lo;w_hi]  (MFMA bf16, amax fused)
    k_asplit<<<61440, 256, 0, stream>>>(Y, A2Y);
    k_mgemm<true><<<dim3(4, 160), 256, 0, stream>>>(
        A2Y, W2TO + (long)blk * 512 * KPO_, MO, DM_, KPO_, nullptr, SCAL + 7 + blk * 2);
    // x = fq(layernorm(x + fq(mo))); emit q for next block's in-proj
    k_ln<<<20480, 128, 0, stream>>>(X2, MO, SCAL + 7 + blk * 2,
                                    lng + blk * DM_, lnb + blk * DM_, SCAL + 8 + blk * 2);
    k_fq<<<2048, 256, 0, stream>>>(MO, X2, NX_, SCAL + 8 + blk * 2, nullptr,
                                   blk == 0 ? A2IN : nullptr);
  }

  // mean-pool, fq, classifier with fq(cls_w)
  k_pool<<<25, 256, 0, stream>>>(X2, POOL, SCAL + 11);
  k_absmax<<<4, 256, 0, stream>>>(clsw, DM_ * 2, SCAL + 12);
  k_cls<<<1, 64, 0, stream>>>(POOL, clsw, clsb, SCAL + 11, SCAL + 12, (float*)d_out);
}

// Round 4
// 1538.456 us; speedup vs baseline: 3.2453x; 1.2344x over previous
//
#include <hip/hip_runtime.h>
#include <hip/hip_bf16.h>
#include <math.h>

// ---- problem constants -----------------------------------------------------
#define B_    16
#define H_    22
#define W_    20480
#define EMB   35
#define GH_   11
#define GW_   1280
#define L_    1280
#define DM_   385
#define DI_   256
#define N_    4
#define K_    4
#define DTR_  25
#define ROWS_ (B_*L_)              // 20480
#define NX_   ((long)ROWS_*DM_)    // 7,884,800
#define LDM_  ((long)L_*DM_)       // 492,800
#define CH_   64                   // scan chunks
#define CHL_  20                   // steps per chunk (CH_*CHL_ == L_)
#define KPI_  800                  // in_proj padded K' (2*385 -> 800)
#define KPO_  768                  // out_proj padded K' (3*256)

typedef __attribute__((ext_vector_type(8))) short short8;
typedef __attribute__((ext_vector_type(4))) float f32x4;
typedef unsigned short ushort;

// ---- helpers ---------------------------------------------------------------
__device__ __forceinline__ void atomicMaxF(float* a, float v) {
  atomicMax(reinterpret_cast<int*>(a), __float_as_int(v));
}

// faithful fq: s = max(mx,1e-8)/127; q = clip(rint(x/s),-128,127)*s
__device__ __forceinline__ float fq_apply(float x, float s) {
  float r = rintf(x / s);
  r = fminf(fmaxf(r, -128.f), 127.f);
  return r * s;
}
__device__ __forceinline__ float fq_scale(const float* pmax) {
  return fmaxf(pmax[0], 1e-8f) / 127.f;
}

__device__ __forceinline__ ushort f2bf(float f) {  // round-to-nearest-even
  union { float f; unsigned u; } v; v.f = f;
  unsigned r = v.u + 0x7FFF + ((v.u >> 16) & 1);
  return (ushort)(r >> 16);
}
__device__ __forceinline__ float bf2f(ushort h) {
  union { unsigned u; float f; } v; v.u = ((unsigned)h) << 16;
  return v.f;
}

__device__ __forceinline__ void blockAtomicMax(float v, float* out, float* sm) {
  #pragma unroll
  for (int o = 32; o > 0; o >>= 1) v = fmaxf(v, __shfl_down(v, o));
  if ((threadIdx.x & 63) == 0) sm[threadIdx.x >> 6] = v;
  __syncthreads();
  if (threadIdx.x == 0) {
    int nw = (blockDim.x + 63) >> 6;
    for (int i = 1; i < nw; i++) v = fmaxf(v, sm[i]);
    atomicMaxF(out, v);
  }
}

// ---- small utility kernels -------------------------------------------------
__global__ void k_zero(float* s) { if (threadIdx.x < 64) s[threadIdx.x] = 0.f; }

__global__ void k_absmax(const float* __restrict__ src, long n, float* __restrict__ out) {
  __shared__ float smr[8];
  float m = 0.f;
  for (long i = (long)blockIdx.x * blockDim.x + threadIdx.x; i < n;
       i += (long)gridDim.x * blockDim.x)
    m = fmaxf(m, fabsf(src[i]));
  blockAtomicMax(m, out, smr);
}

// vectorized fq: dst4 = fq(src4); optional absmax -> nextmax; optional bf16
// q-emit into A2 [M][KPI_] (dup at cols k and 385+k). dst may == src.
__global__ void k_fq4(const float4* __restrict__ src, float4* __restrict__ dst, long n4,
                      const float* __restrict__ pmax, float* __restrict__ nextmax,
                      ushort* __restrict__ a2) {
  __shared__ float smr[8];
  float s = fq_scale(pmax);
  float m = 0.f;
  for (long i = (long)blockIdx.x * blockDim.x + threadIdx.x; i < n4;
       i += (long)gridDim.x * blockDim.x) {
    float4 v = src[i];
    float r0 = fminf(fmaxf(rintf(v.x / s), -128.f), 127.f);
    float r1 = fminf(fmaxf(rintf(v.y / s), -128.f), 127.f);
    float r2 = fminf(fmaxf(rintf(v.z / s), -128.f), 127.f);
    float r3 = fminf(fmaxf(rintf(v.w / s), -128.f), 127.f);
    float4 q = make_float4(r0 * s, r1 * s, r2 * s, r3 * s);
    dst[i] = q;
    m = fmaxf(m, fmaxf(fmaxf(fabsf(q.x), fabsf(q.y)), fmaxf(fabsf(q.z), fabsf(q.w))));
    if (a2) {
      long ii = i * 4;
      long mm = ii / 385; int kk = (int)(ii - mm * 385);
      float rr[4] = {r0, r1, r2, r3};
      #pragma unroll
      for (int j = 0; j < 4; j++) {
        ushort bv = f2bf(rr[j]);
        a2[mm * KPI_ + kk] = bv;
        a2[mm * KPI_ + 385 + kk] = bv;
        if (++kk == 385) { kk = 0; mm++; }
      }
    }
  }
  if (nextmax) blockAtomicMax(m, nextmax, smr);
}

// x4[i] = fq(x4[i]) + p2[i % LDM/4]; absmax -> nextmax
__global__ void k_addpos4(float4* __restrict__ x, const float4* __restrict__ p2,
                          const float* __restrict__ pmax, float* __restrict__ nextmax) {
  __shared__ float smr[8];
  float s = fq_scale(pmax);
  float m = 0.f;
  const long n4 = NX_ / 4, l4 = LDM_ / 4;
  for (long i = (long)blockIdx.x * blockDim.x + threadIdx.x; i < n4;
       i += (long)gridDim.x * blockDim.x) {
    float4 v = x[i];
    float4 p = p2[i % l4];
    float4 o;
    o.x = fq_apply(v.x, s) + p.x;
    o.y = fq_apply(v.y, s) + p.y;
    o.z = fq_apply(v.z, s) + p.z;
    o.w = fq_apply(v.w, s) + p.w;
    x[i] = o;
    m = fmaxf(m, fmaxf(fmaxf(fabsf(o.x), fabsf(o.y)), fmaxf(fabsf(o.z), fabsf(o.w))));
  }
  blockAtomicMax(m, nextmax, smr);
}

// simple elementwise fq into a fresh buffer (patch weights only; tiny)
__global__ void k_qx(const float* __restrict__ src, float* __restrict__ dst, long n,
                     const float* __restrict__ pmax) {
  float s = fq_scale(pmax);
  for (long i = (long)blockIdx.x * blockDim.x + threadIdx.x; i < n;
       i += (long)gridDim.x * blockDim.x)
    dst[i] = fq_apply(src[i], s);
}

// ---- fused patch embed: LDS-staged x (fq inline), weights in VGPRs ----------
// block = (gw-tile of 64, gh, b); 320 threads (280 active in compute)
__global__ __launch_bounds__(320) void k_patchfq(const float* __restrict__ x,
                                                 const float* __restrict__ wq,
                                                 const float* __restrict__ peb,
                                                 const float* __restrict__ sx_,
                                                 float* __restrict__ out,
                                                 float* __restrict__ nextmax) {
  __shared__ float xs[2][64][20];   // [ph][gw_local][pw] padded to 20
  __shared__ float smr[8];
  int tid = threadIdx.x;
  int gwt = blockIdx.x, gh = blockIdx.y, b = blockIdx.z;
  float sx = fq_scale(sx_);
  if (tid < 256) {
    int gwl = tid >> 2, pw = (tid & 3) * 4;
    #pragma unroll
    for (int ph = 0; ph < 2; ph++) {
      const float* src = x + ((long)b * H_ + gh * 2 + ph) * W_ + (long)gwt * 1024 + tid * 4;
      float4 v = *reinterpret_cast<const float4*>(src);
      xs[ph][gwl][pw + 0] = fq_apply(v.x, sx);
      xs[ph][gwl][pw + 1] = fq_apply(v.y, sx);
      xs[ph][gwl][pw + 2] = fq_apply(v.z, sx);
      xs[ph][gwl][pw + 3] = fq_apply(v.w, sx);
    }
  }
  __syncthreads();
  float mx = 0.f;
  if (tid < 280) {
    int e = tid % 35;
    int g0 = (tid / 35) * 8;
    float w[32];
    #pragma unroll
    for (int j = 0; j < 32; j++) w[j] = wq[e * 32 + j];
    float bias = peb[e];
    long obase = ((long)b * GW_ + (long)gwt * 64) * DM_ + gh * 35 + e;
    #pragma unroll
    for (int gi = 0; gi < 8; gi++) {
      int gw = g0 + gi;
      float acc = bias;
      #pragma unroll
      for (int pw = 0; pw < 16; pw++) {
        acc = fmaf(xs[0][gw][pw], w[pw], acc);
        acc = fmaf(xs[1][gw][pw], w[16 + pw], acc);
      }
      out[obase + (long)gw * DM_] = acc;
      mx = fmaxf(mx, fabsf(acc));
    }
  }
  blockAtomicMax(mx, nextmax, smr);
}

// ---- weight split: W[K][N] f32 -> W2T[Npad][Kp] bf16, terms {hi,lo[,hi]} ----
__global__ void k_wsplit(const float* __restrict__ W, ushort* __restrict__ out,
                         int K, int N, int Kp, long total, int terms) {
  long idx = (long)blockIdx.x * 256 + threadIdx.x;
  if (idx >= total) return;
  int k = (int)(idx % Kp);
  int n = (int)(idx / Kp);
  int t = k / K, kk = k - t * K;
  ushort r = 0;
  if (n < N && t < terms) {
    float w = W[(long)kk * N + n];
    ushort hi = f2bf(w);
    r = (t == 1) ? f2bf(w - bf2f(hi)) : hi;
  }
  out[idx] = r;
}

// ---- activation split: (Y0+Y1)[M][256] f32 -> A2[M][768] bf16 {hi,hi,lo} ----
__global__ void k_asplit2(const float* __restrict__ Y, ushort* __restrict__ A2) {
  long idx = (long)blockIdx.x * 256 + threadIdx.x;   // M*768 threads
  long m = idx / KPO_; int k = (int)(idx - m * KPO_);
  int t = k >> 8, kk = k & 255;
  float v = Y[m * DI_ + kk] + Y[(m + ROWS_) * DI_ + kk];
  ushort hi = f2bf(v);
  A2[idx] = (t == 2) ? f2bf(v - bf2f(hi)) : hi;
}

// zero the pad columns [770, 800) of A2 (in_proj)
__global__ void k_padzero(ushort* __restrict__ A2) {
  long idx = (long)blockIdx.x * 256 + threadIdx.x;   // ROWS_*30 threads
  long m = idx / 30; int c = (int)(idx - m * 30);
  A2[m * KPI_ + 770 + c] = 0;
}

// ---- bf16 MFMA GEMM: C[M][Nreal] = scale * (A2[M][Kp] @ W2T[Npad][Kp]^T) ----
// 128x128 tile, BK=32, 4 waves (2x2), 16x16x32 MFMA.
template<bool AMAX>
__global__ __launch_bounds__(256) void k_mgemm(const ushort* __restrict__ A2,
                                               const ushort* __restrict__ W2T,
                                               float* __restrict__ C,
                                               int Nreal, int Kp,
                                               const float* __restrict__ sptr,
                                               float* __restrict__ amax_out) {
  __shared__ ushort Alds[4][128][8];   // [k-slot][row][8k] 8 KB
  __shared__ ushort Blds[4][128][8];   // [k-slot][col][8k] 8 KB
  __shared__ float smr[8];
  int tid = threadIdx.x;
  int lane = tid & 63, wave = tid >> 6;
  int wm = wave >> 1, wn = wave & 1;
  int m0 = blockIdx.y * 128, n0 = blockIdx.x * 128;
  f32x4 acc[4][4];
  #pragma unroll
  for (int i = 0; i < 4; i++)
    #pragma unroll
    for (int j = 0; j < 4; j++) acc[i][j] = (f32x4){0.f, 0.f, 0.f, 0.f};

  for (int k0 = 0; k0 < Kp; k0 += 32) {
    #pragma unroll
    for (int r = 0; r < 2; r++) {
      int id = tid + r * 256;            // 0..511
      int row = id >> 2, sl = id & 3;    // coalesced 64B global segments
      short8 va = *reinterpret_cast<const short8*>(A2 + (long)(m0 + row) * Kp + k0 + sl * 8);
      *reinterpret_cast<short8*>(&Alds[sl][row][0]) = va;
      short8 vb = *reinterpret_cast<const short8*>(W2T + (long)(n0 + row) * Kp + k0 + sl * 8);
      *reinterpret_cast<short8*>(&Blds[sl][row][0]) = vb;
    }
    __syncthreads();
    int sl = lane >> 4, rr = lane & 15;
    short8 af[4], bf4[4];
    #pragma unroll
    for (int i = 0; i < 4; i++)
      af[i] = *reinterpret_cast<const short8*>(&Alds[sl][wm * 64 + i * 16 + rr][0]);
    #pragma unroll
    for (int j = 0; j < 4; j++)
      bf4[j] = *reinterpret_cast<const short8*>(&Blds[sl][wn * 64 + j * 16 + rr][0]);
    #pragma unroll
    for (int i = 0; i < 4; i++)
      #pragma unroll
      for (int j = 0; j < 4; j++)
        acc[i][j] = __builtin_amdgcn_mfma_f32_16x16x32_bf16(af[i], bf4[j], acc[i][j], 0, 0, 0);
    __syncthreads();
  }

  float s = sptr ? fq_scale(sptr) : 1.0f;
  float mx = 0.f;
  int cfr = lane & 15, rbase = (lane >> 4) * 4;
  #pragma unroll
  for (int i = 0; i < 4; i++) {
    int gmb = m0 + wm * 64 + i * 16 + rbase;
    #pragma unroll
    for (int j = 0; j < 4; j++) {
      int gn = n0 + wn * 64 + j * 16 + cfr;
      if (gn < Nreal) {
        #pragma unroll
        for (int rg = 0; rg < 4; rg++) {
          float v = acc[i][j][rg] * s;
          C[(long)(gmb + rg) * Nreal + gn] = v;
          mx = fmaxf(mx, fabsf(v));
        }
      }
    }
  }
  if (AMAX) blockAtomicMax(mx, amax_out, smr);
}

// ---- generic fp32 tiled GEMM (skinny xp projection, both dirs batched) ------
template<bool AMAX>
__global__ __launch_bounds__(256) void k_gemm(const float* __restrict__ A,
                                              const float* __restrict__ W,
                                              float* __restrict__ C,
                                              int M, int N, int Kd,
                                              float* __restrict__ amax_out) {
  __shared__ __align__(16) float As[16][68];
  __shared__ __align__(16) float Bs[16][68];
  __shared__ float smr[8];
  int tx = threadIdx.x & 15, ty = threadIdx.x >> 4;
  int m0 = blockIdx.y * 64, n0 = blockIdx.x * 64;
  float acc[4][4] = {};
  for (int k0 = 0; k0 < Kd; k0 += 16) {
    #pragma unroll
    for (int r = 0; r < 4; r++) {
      int id = threadIdx.x + r * 256;
      int mm = id >> 4, kk = id & 15;
      int gm = m0 + mm, gk = k0 + kk;
      As[kk][mm] = (gm < M && gk < Kd) ? A[(long)gm * Kd + gk] : 0.f;
    }
    #pragma unroll
    for (int r = 0; r < 4; r++) {
      int id = threadIdx.x + r * 256;
      int kk = id >> 6, nn = id & 63;
      int gk = k0 + kk, gn = n0 + nn;
      Bs[kk][nn] = (gk < Kd && gn < N) ? W[(long)gk * N + gn] : 0.f;
    }
    __syncthreads();
    #pragma unroll
    for (int kk = 0; kk < 16; kk++) {
      float4 a4 = *reinterpret_cast<const float4*>(&As[kk][ty * 4]);
      float4 b4 = *reinterpret_cast<const float4*>(&Bs[kk][tx * 4]);
      float av[4] = {a4.x, a4.y, a4.z, a4.w};
      float bv[4] = {b4.x, b4.y, b4.z, b4.w};
      #pragma unroll
      for (int i = 0; i < 4; i++)
        #pragma unroll
        for (int j = 0; j < 4; j++)
          acc[i][j] = fmaf(av[i], bv[j], acc[i][j]);
    }
    __syncthreads();
  }
  float mx = 0.f;
  #pragma unroll
  for (int i = 0; i < 4; i++) {
    int gm = m0 + ty * 4 + i;
    if (gm < M) {
      #pragma unroll
      for (int j = 0; j < 4; j++) {
        int gn = n0 + tx * 4 + j;
        if (gn < N) {
          C[(long)gm * N + gn] = acc[i][j];
          mx = fmaxf(mx, fabsf(acc[i][j]));
        }
      }
    }
  }
  if (AMAX) blockAtomicMax(mx, amax_out, smr);
}

// ---- depthwise causal conv1d (K=4) + SiLU, both directions in one grid ------
__global__ void k_conv(const float* __restrict__ xz, const float* __restrict__ cw,
                       const float* __restrict__ cb, float* __restrict__ xcout) {
  long idx = (long)blockIdx.x * 256 + threadIdx.x;   // 2*B*L*DI threads
  int d = (int)(idx & 255);
  long rest = idx >> 8;                               // (dir, b, t)
  int dir = (int)(rest / (L_ * B_));
  int rem = (int)(rest - (long)dir * L_ * B_);
  int b = rem / L_, t = rem - (rem / L_) * L_;
  long base = (long)b * L_;
  float acc = cb[d];
  #pragma unroll
  for (int j = 0; j < K_; j++) {
    int tau = t - (K_ - 1) + j;
    if (tau >= 0) {
      int p = dir ? (L_ - 1 - tau) : tau;
      acc = fmaf(cw[d * K_ + j], xz[(base + p) * (2 * DI_) + d], acc);
    }
  }
  float sig = 1.f / (1.f + expf(-acc));
  int pt = dir ? (L_ - 1 - t) : t;
  xcout[((long)dir * ROWS_ + base + pt) * DI_ + d] = acc * sig;
}

// ---- chunked parallel selective scan (dt fused, both dirs in grid.z) --------
__device__ __forceinline__ float softplusf(float x) {
  return fmaxf(x, 0.f) + log1pf(expf(-fabsf(x)));
}

__global__ __launch_bounds__(256) void k_scan1(const float* __restrict__ xc,
                                               const float* __restrict__ proj,
                                               const float* __restrict__ A_log,
                                               const float* __restrict__ dtw,
                                               const float* __restrict__ dtb,
                                               float* __restrict__ Hend,
                                               float* __restrict__ Pend) {
  int b = blockIdx.y, c = blockIdx.x, d = threadIdx.x, dir = blockIdx.z;
  const float* xcD = xc + (long)dir * ROWS_ * DI_;
  const float* prD = proj + (long)dir * ROWS_ * 33;
  float A[4];
  #pragma unroll
  for (int n = 0; n < 4; n++) A[n] = -expf(A_log[d * 4 + n]);
  float dwr[DTR_];
  #pragma unroll
  for (int r = 0; r < DTR_; r++) dwr[r] = dtw[r * DI_ + d];
  float dbv = dtb[d];
  float h[4] = {0.f, 0.f, 0.f, 0.f};
  float P[4] = {1.f, 1.f, 1.f, 1.f};
  long base = (long)b * L_;
  #pragma unroll 2
  for (int s = 0; s < CHL_; s++) {
    int step = c * CHL_ + s;
    long row = base + (dir ? (L_ - 1 - step) : step);
    const float* p = prD + row * 33;
    float dtr = dbv;
    #pragma unroll
    for (int r = 0; r < DTR_; r++) dtr = fmaf(p[r], dwr[r], dtr);
    float dtv = softplusf(dtr);
    float xcv = xcD[row * DI_ + d];
    float dx = dtv * xcv;
    #pragma unroll
    for (int n = 0; n < 4; n++) {
      float Bn = p[DTR_ + n];
      float dA = expf(dtv * A[n]);
      h[n] = dA * h[n] + dx * Bn;
      P[n] *= dA;
    }
  }
  long o = (((long)dir * B_ + b) * CH_ + c) * 1024 + d * 4;
  *reinterpret_cast<float4*>(Hend + o) = make_float4(h[0], h[1], h[2], h[3]);
  *reinterpret_cast<float4*>(Pend + o) = make_float4(P[0], P[1], P[2], P[3]);
}

__global__ __launch_bounds__(256) void k_carry(const float* __restrict__ Hend,
                                               const float* __restrict__ Pend,
                                               float* __restrict__ Carry) {
  int tid = blockIdx.x * 256 + threadIdx.x;   // 2*B_*1024 lanes
  int be = tid >> 10, i = tid & 1023;         // be = dir*16+b
  float carry = 0.f;
  for (int c = 0; c < CH_; c++) {
    long o = ((long)be * CH_ + c) * 1024 + i;
    Carry[o] = carry;
    carry = Pend[o] * carry + Hend[o];
  }
}

__global__ __launch_bounds__(256) void k_scan2(const float* __restrict__ xc,
                                               const float* __restrict__ proj,
                                               const float* __restrict__ A_log,
                                               const float* __restrict__ dtw,
                                               const float* __restrict__ dtb,
                                               const float* __restrict__ Dp,
                                               const float* __restrict__ xz,
                                               const float* __restrict__ Carry,
                                               float* __restrict__ y) {
  int b = blockIdx.y, c = blockIdx.x, d = threadIdx.x, dir = blockIdx.z;
  const float* xcD = xc + (long)dir * ROWS_ * DI_;
  const float* prD = proj + (long)dir * ROWS_ * 33;
  float* yD = y + (long)dir * ROWS_ * DI_;
  float A[4];
  #pragma unroll
  for (int n = 0; n < 4; n++) A[n] = -expf(A_log[d * 4 + n]);
  float dwr[DTR_];
  #pragma unroll
  for (int r = 0; r < DTR_; r++) dwr[r] = dtw[r * DI_ + d];
  float dbv = dtb[d];
  long o = (((long)dir * B_ + b) * CH_ + c) * 1024 + d * 4;
  float4 cv = *reinterpret_cast<const float4*>(Carry + o);
  float h[4] = {cv.x, cv.y, cv.z, cv.w};
  float Dv = Dp[d];
  long base = (long)b * L_;
  #pragma unroll 2
  for (int s = 0; s < CHL_; s++) {
    int step = c * CHL_ + s;
    long row = base + (dir ? (L_ - 1 - step) : step);
    const float* p = prD + row * 33;
    float dtr = dbv;
    #pragma unroll
    for (int r = 0; r < DTR_; r++) dtr = fmaf(p[r], dwr[r], dtr);
    float dtv = softplusf(dtr);
    float xcv = xcD[row * DI_ + d];
    float zv  = xz[row * (2 * DI_) + DI_ + d];
    float dx = dtv * xcv;
    float acc = 0.f;
    #pragma unroll
    for (int n = 0; n < 4; n++) {
      float Bn = p[DTR_ + n];
      float Cn = p[DTR_ + N_ + n];
      float dA = expf(dtv * A[n]);
      h[n] = dA * h[n] + dx * Bn;
      acc = fmaf(h[n], Cn, acc);
    }
    float yv = acc + Dv * xcv;
    float sig = 1.f / (1.f + expf(-zv));
    yv *= zv * sig;
    yD[row * DI_ + d] = yv;
  }
}

// ---- residual + fq(mamba_out) + layernorm (in-place on mo) ------------------
__global__ __launch_bounds__(128) void k_ln(const float* __restrict__ x2,
                                            float* __restrict__ mo,
                                            const float* __restrict__ smo,
                                            const float* __restrict__ g,
                                            const float* __restrict__ bta,
                                            float* __restrict__ nextmax) {
  __shared__ float sm[2];
  long row = blockIdx.x;
  float s = fq_scale(smo);
  float v[4];
  float lsum = 0.f;
  #pragma unroll
  for (int k2 = 0; k2 < 4; k2++) {
    int c = threadIdx.x + k2 * 128;
    float t = 0.f;
    if (c < DM_) {
      float m = fq_apply(mo[row * DM_ + c], s);
      t = x2[row * DM_ + c] + m;
    }
    v[k2] = t; lsum += t;
  }
  float w = lsum;
  #pragma unroll
  for (int o = 32; o > 0; o >>= 1) w += __shfl_down(w, o);
  if ((threadIdx.x & 63) == 0) sm[threadIdx.x >> 6] = w;
  __syncthreads();
  float mean = (sm[0] + sm[1]) / 385.f;
  __syncthreads();
  float lvar = 0.f;
  #pragma unroll
  for (int k2 = 0; k2 < 4; k2++) {
    int c = threadIdx.x + k2 * 128;
    if (c < DM_) { float dd = v[k2] - mean; lvar += dd * dd; }
  }
  w = lvar;
  #pragma unroll
  for (int o = 32; o > 0; o >>= 1) w += __shfl_down(w, o);
  if ((threadIdx.x & 63) == 0) sm[threadIdx.x >> 6] = w;
  __syncthreads();
  float var = (sm[0] + sm[1]) / 385.f;
  float rs = 1.f / sqrtf(var + 1e-5f);
  float lmax = 0.f;
  #pragma unroll
  for (int k2 = 0; k2 < 4; k2++) {
    int c = threadIdx.x + k2 * 128;
    if (c < DM_) {
      float o2 = (v[k2] - mean) * rs * g[c] + bta[c];
      mo[row * DM_ + c] = o2;
      lmax = fmaxf(lmax, fabsf(o2));
    }
  }
  __syncthreads();
  w = lmax;
  #pragma unroll
  for (int o = 32; o > 0; o >>= 1) w = fmaxf(w, __shfl_down(w, o));
  if ((threadIdx.x & 63) == 0) sm[threadIdx.x >> 6] = w;
  __syncthreads();
  if (threadIdx.x == 0) atomicMaxF(nextmax, fmaxf(sm[0], sm[1]));
}

// ---- mean pool over L (two-stage, coalesced, deterministic) ------------------
__global__ __launch_bounds__(256) void k_pool1(const float* __restrict__ x2,
                                               float* __restrict__ part) {
  int b = blockIdx.x, ch = blockIdx.y, tid = threadIdx.x;
  float s0 = 0.f, s1 = 0.f;
  for (int l = ch * 128; l < ch * 128 + 128; l++) {
    const float* row = x2 + ((long)b * L_ + l) * DM_;
    s0 += row[tid];
    if (tid < DM_ - 256) s1 += row[tid + 256];
  }
  long o = ((long)b * 10 + ch) * DM_;
  part[o + tid] = s0;
  if (tid < DM_ - 256) part[o + tid + 256] = s1;
}

__global__ void k_pool2(const float* __restrict__ part, float* __restrict__ pool,
                        float* __restrict__ nextmax) {
  __shared__ float smr[8];
  int idx = blockIdx.x * 256 + threadIdx.x;
  float mv = 0.f;
  if (idx < B_ * DM_) {
    int b = idx / DM_, c = idx % DM_;
    float s = 0.f;
    for (int ch = 0; ch < 10; ch++) s += part[((long)b * 10 + ch) * DM_ + c];
    float mean = s / (float)L_;
    pool[idx] = mean;
    mv = fabsf(mean);
  }
  blockAtomicMax(mv, nextmax, smr);
}

// ---- classifier --------------------------------------------------------------
__global__ void k_cls(const float* __restrict__ pool, const float* __restrict__ clsw,
                      const float* __restrict__ clsb, const float* __restrict__ sp_,
                      const float* __restrict__ sw_, float* __restrict__ out) {
  int tid = threadIdx.x;
  if (tid >= B_ * 2) return;
  int b = tid >> 1, c = tid & 1;
  float sp = fq_scale(sp_), sw = fq_scale(sw_);
  float acc = 0.f;
  for (int k2 = 0; k2 < DM_; k2++) {
    float xv = fq_apply(pool[b * DM_ + k2], sp);
    float wv = fq_apply(clsw[k2 * 2 + c], sw);
    acc = fmaf(xv, wv, acc);
  }
  out[b * 2 + c] = acc + clsb[c];
}

// ---- launch ------------------------------------------------------------------
extern "C" void kernel_launch(void* const* d_in, const int* in_sizes, int n_in,
                              void* d_out, int out_size, void* d_ws, size_t ws_size,
                              hipStream_t stream) {
  const float* x    = (const float*)d_in[0];
  const float* pew  = (const float*)d_in[1];
  const float* peb  = (const float*)d_in[2];
  const float* pos  = (const float*)d_in[3];
  const float* in_w = (const float*)d_in[4];
  const float* cw   = (const float*)d_in[5];
  const float* cb   = (const float*)d_in[6];
  const float* xpw  = (const float*)d_in[7];
  const float* dtw  = (const float*)d_in[8];
  const float* dtb  = (const float*)d_in[9];
  const float* alog = (const float*)d_in[10];
  const float* dp   = (const float*)d_in[11];
  const float* outw = (const float*)d_in[12];
  const float* lng  = (const float*)d_in[13];
  const float* lnb  = (const float*)d_in[14];
  const float* clsw = (const float*)d_in[15];
  const float* clsb = (const float*)d_in[16];

  float* ws    = (float*)d_ws;
  float* SCAL  = ws;                              // 64 scalars
  float* WQ    = ws + 256;                        // 2048 (1120 used)
  float* P2    = WQ + 2048;                       // 492,800
  float* X2    = P2 + LDM_;                       // 7,884,800
  float* XZ    = X2 + NX_;                        // 10,485,760
  float* XC    = XZ + (long)ROWS_ * 512;          // 2 x 5,242,880
  float* PROJ  = XC + 2L * ROWS_ * DI_;           // 2 x 675,840
  float* Y     = PROJ + 2L * ROWS_ * 33;          // 2 x 5,242,880
  float* MO    = Y + 2L * ROWS_ * DI_;            // 7,884,800
  float* POOL  = MO + NX_;                        // 8,192
  float* PART  = POOL + 8192;                     // 61,600 (+pad)
  float* A2IN_f= PART + 65536;                    // 8,192,000 f (ushort overlay)
  float* W2I_f = A2IN_f + 8192000;                // 409,600 f
  float* W2O_f = W2I_f + 409600;                  // 393,216 f
  // aliases (disjoint lifetimes):
  float*  HEND = MO;                              // scan summaries, dead before out-GEMM
  float*  PEND = MO + 2097152;
  float*  CARR = MO + 4194304;
  ushort* A2Y  = (ushort*)XZ;                     // [20480][768], dead before next in-GEMM
  ushort* A2IN = (ushort*)A2IN_f;                 // [20480][800]
  ushort* W2TI = (ushort*)W2I_f;                  // 2 x [512][800]
  ushort* W2TO = (ushort*)W2O_f;                  // 2 x [512][768]
  // total ≈ 58.1M floats ≈ 233 MB

  k_zero<<<1, 64, 0, stream>>>(SCAL);

  // weight splits for MFMA GEMMs (tiny)
  for (int blk = 0; blk < 2; blk++) {
    k_wsplit<<<1600, 256, 0, stream>>>(in_w + (long)blk * DM_ * 512,
                                       W2TI + (long)blk * 512 * KPI_,
                                       DM_, 512, KPI_, 512L * KPI_, 2);
    k_wsplit<<<1536, 256, 0, stream>>>(outw + (long)blk * DI_ * DM_,
                                       W2TO + (long)blk * 512 * KPO_,
                                       DI_, DM_, KPO_, 512L * KPO_, 3);
  }
  k_padzero<<<2400, 256, 0, stream>>>(A2IN);

  // input fq + fused patch-embed
  k_absmax<<<2048, 256, 0, stream>>>(x, (long)B_ * H_ * W_, SCAL + 0);
  k_absmax<<<8, 256, 0, stream>>>(pew, EMB * 2 * 16, SCAL + 1);
  k_qx<<<5, 256, 0, stream>>>(pew, WQ, EMB * 2 * 16, SCAL + 1);
  k_patchfq<<<dim3(20, 11, 16), 320, 0, stream>>>(x, WQ, peb, SCAL + 0, X2, SCAL + 2);
  k_fq4<<<2048, 256, 0, stream>>>((const float4*)X2, (float4*)X2, NX_ / 4,
                                  SCAL + 2, SCAL + 3, nullptr);

  // pos = fq(fq(pos_embed))
  k_absmax<<<512, 256, 0, stream>>>(pos, LDM_, SCAL + 4);
  k_fq4<<<512, 256, 0, stream>>>((const float4*)pos, (float4*)P2, LDM_ / 4,
                                 SCAL + 4, SCAL + 5, nullptr);
  k_fq4<<<512, 256, 0, stream>>>((const float4*)P2, (float4*)P2, LDM_ / 4,
                                 SCAL + 5, nullptr, nullptr);

  // x = fq(fq(x) + pos); emit bf16 q for blk0 in-proj
  k_addpos4<<<2048, 256, 0, stream>>>((float4*)X2, (const float4*)P2, SCAL + 3, SCAL + 6);
  k_fq4<<<2048, 256, 0, stream>>>((const float4*)X2, (float4*)X2, NX_ / 4,
                                  SCAL + 6, nullptr, A2IN);

  const float* in_scale[2] = {SCAL + 6, SCAL + 8};
  for (int blk = 0; blk < 2; blk++) {
    // in-proj: XZ = s * (q @ [w_hi; w_lo])   (MFMA bf16)
    k_mgemm<false><<<dim3(4, 160), 256, 0, stream>>>(
        A2IN, W2TI + (long)blk * 512 * KPI_, XZ, 512, KPI_, in_scale[blk], nullptr);
    // conv (both dirs), xp-proj (both dirs), chunked scan (both dirs)
    k_conv<<<40960, 256, 0, stream>>>(XZ, cw + blk * DI_ * K_, cb + blk * DI_, XC);
    k_gemm<false><<<dim3(1, 640), 256, 0, stream>>>(
        XC, xpw + (long)blk * DI_ * 33, PROJ, 2 * ROWS_, 33, DI_, nullptr);
    k_scan1<<<dim3(CH_, B_, 2), 256, 0, stream>>>(XC, PROJ, alog + blk * DI_ * N_,
                                                  dtw + blk * DTR_ * DI_, dtb + blk * DI_,
                                                  HEND, PEND);
    k_carry<<<128, 256, 0, stream>>>(HEND, PEND, CARR);
    k_scan2<<<dim3(CH_, B_, 2), 256, 0, stream>>>(XC, PROJ, alog + blk * DI_ * N_,
                                                  dtw + blk * DTR_ * DI_, dtb + blk * DI_,
                                                  dp + blk * DI_, XZ, CARR, Y);
    // out-proj: MO = [y_hi,y_hi,y_lo] @ [w_hi;w_lo;w_hi]  (MFMA bf16, amax fused)
    k_asplit2<<<61440, 256, 0, stream>>>(Y, A2Y);
    k_mgemm<true><<<dim3(4, 160), 256, 0, stream>>>(
        A2Y, W2TO + (long)blk * 512 * KPO_, MO, DM_, KPO_, nullptr, SCAL + 7 + blk * 2);
    // x = fq(layernorm(x + fq(mo))); emit q for next block's in-proj
    k_ln<<<20480, 128, 0, stream>>>(X2, MO, SCAL + 7 + blk * 2,
                                    lng + blk * DM_, lnb + blk * DM_, SCAL + 8 + blk * 2);
    k_fq4<<<2048, 256, 0, stream>>>((const float4*)MO, (float4*)X2, NX_ / 4,
                                    SCAL + 8 + blk * 2, nullptr,
                                    blk == 0 ? A2IN : nullptr);
  }

  // mean-pool (2-stage), fq, classifier with fq(cls_w)
  k_pool1<<<dim3(16, 10), 256, 0, stream>>>(X2, PART);
  k_pool2<<<25, 256, 0, stream>>>(PART, POOL, SCAL + 11);
  k_absmax<<<4, 256, 0, stream>>>(clsw, DM_ * 2, SCAL + 12);
  k_cls<<<1, 64, 0, stream>>>(POOL, clsw, clsb, SCAL + 11, SCAL + 12, (float*)d_out);
}

// Round 5
// 1001.879 us; speedup vs baseline: 4.9834x; 1.5356x over previous
//
#include <hip/hip_runtime.h>
#include <hip/hip_bf16.h>
#include <math.h>

// ---- problem constants -----------------------------------------------------
#define B_    16
#define H_    22
#define W_    20480
#define EMB   35
#define GH_   11
#define GW_   1280
#define L_    1280
#define DM_   385
#define DI_   256
#define N_    4
#define K_    4
#define DTR_  25
#define ROWS_ (B_*L_)              // 20480
#define NX_   ((long)ROWS_*DM_)    // 7,884,800
#define LDM_  ((long)L_*DM_)       // 492,800
#define CH_   64                   // scan chunks
#define CHL_  20                   // steps per chunk (CH_*CHL_ == L_)
#define KPI_  800                  // in_proj padded K' (2*385 -> 800)
#define KPO_  768                  // out_proj padded K' (3*256)

// amax scalars: 8 slots x 64B apart to break single-address atomic serialization
#define NSLOT 8
#define SSTR  16                   // floats between slots (64 B)
#define SCALW 128                  // floats per logical scalar (8 slots)

typedef __attribute__((ext_vector_type(8))) short short8;
typedef __attribute__((ext_vector_type(4))) float f32x4;
typedef unsigned short ushort;

// ---- helpers ---------------------------------------------------------------
__device__ __forceinline__ void atomicMaxF(float* a, float v) {
  atomicMax(reinterpret_cast<int*>(a), __float_as_int(v));
}

// faithful fq: s = max(mx,1e-8)/127 where mx = max over the 8 slots
__device__ __forceinline__ float fq_scale(const float* pmax) {
  float m = pmax[0];
  #pragma unroll
  for (int i = 1; i < NSLOT; i++) m = fmaxf(m, pmax[i * SSTR]);
  return fmaxf(m, 1e-8f) / 127.f;
}
__device__ __forceinline__ float fq_apply(float x, float s) {
  float r = rintf(x / s);
  r = fminf(fmaxf(r, -128.f), 127.f);
  return r * s;
}

__device__ __forceinline__ ushort f2bf(float f) {  // round-to-nearest-even
  union { float f; unsigned u; } v; v.f = f;
  unsigned r = v.u + 0x7FFF + ((v.u >> 16) & 1);
  return (ushort)(r >> 16);
}
__device__ __forceinline__ float bf2f(ushort h) {
  union { unsigned u; float f; } v; v.u = ((unsigned)h) << 16;
  return v.f;
}

// block max -> atomicMax into one of 8 slots (by block id). sm >= blockDim/64.
__device__ __forceinline__ void blockAtomicMax(float v, float* out, float* sm) {
  #pragma unroll
  for (int o = 32; o > 0; o >>= 1) v = fmaxf(v, __shfl_down(v, o));
  if ((threadIdx.x & 63) == 0) sm[threadIdx.x >> 6] = v;
  __syncthreads();
  if (threadIdx.x == 0) {
    int nw = (blockDim.x + 63) >> 6;
    for (int i = 1; i < nw; i++) v = fmaxf(v, sm[i]);
    int slot = (blockIdx.x + blockIdx.y * 4 + blockIdx.z) & (NSLOT - 1);
    atomicMaxF(out + slot * SSTR, v);
  }
}

// ---- small utility kernels -------------------------------------------------
__global__ void k_zero(float* s) { s[blockIdx.x * 256 + threadIdx.x] = 0.f; }

__global__ void k_absmax(const float* __restrict__ src, long n, float* __restrict__ out) {
  __shared__ float smr[8];
  float m = 0.f;
  for (long i = (long)blockIdx.x * blockDim.x + threadIdx.x; i < n;
       i += (long)gridDim.x * blockDim.x)
    m = fmaxf(m, fabsf(src[i]));
  blockAtomicMax(m, out, smr);
}

// vectorized fq: dst4 = fq(src4); optional absmax -> nextmax; optional bf16
// q-emit into A2 [M][KPI_] (dup at cols k and 385+k). dst may == src.
__global__ void k_fq4(const float4* __restrict__ src, float4* __restrict__ dst, long n4,
                      const float* __restrict__ pmax, float* __restrict__ nextmax,
                      ushort* __restrict__ a2) {
  __shared__ float smr[8];
  float s = fq_scale(pmax);
  float m = 0.f;
  for (long i = (long)blockIdx.x * blockDim.x + threadIdx.x; i < n4;
       i += (long)gridDim.x * blockDim.x) {
    float4 v = src[i];
    float r0 = fminf(fmaxf(rintf(v.x / s), -128.f), 127.f);
    float r1 = fminf(fmaxf(rintf(v.y / s), -128.f), 127.f);
    float r2 = fminf(fmaxf(rintf(v.z / s), -128.f), 127.f);
    float r3 = fminf(fmaxf(rintf(v.w / s), -128.f), 127.f);
    float4 q = make_float4(r0 * s, r1 * s, r2 * s, r3 * s);
    dst[i] = q;
    m = fmaxf(m, fmaxf(fmaxf(fabsf(q.x), fabsf(q.y)), fmaxf(fabsf(q.z), fabsf(q.w))));
    if (a2) {
      long ii = i * 4;
      long mm = ii / 385; int kk = (int)(ii - mm * 385);
      float rr[4] = {r0, r1, r2, r3};
      #pragma unroll
      for (int j = 0; j < 4; j++) {
        ushort bv = f2bf(rr[j]);
        a2[mm * KPI_ + kk] = bv;
        a2[mm * KPI_ + 385 + kk] = bv;
        if (++kk == 385) { kk = 0; mm++; }
      }
    }
  }
  if (nextmax) blockAtomicMax(m, nextmax, smr);
}

// x4[i] = fq(x4[i]) + p2[i % LDM/4]; absmax -> nextmax
__global__ void k_addpos4(float4* __restrict__ x, const float4* __restrict__ p2,
                          const float* __restrict__ pmax, float* __restrict__ nextmax) {
  __shared__ float smr[8];
  float s = fq_scale(pmax);
  float m = 0.f;
  const long n4 = NX_ / 4, l4 = LDM_ / 4;
  for (long i = (long)blockIdx.x * blockDim.x + threadIdx.x; i < n4;
       i += (long)gridDim.x * blockDim.x) {
    float4 v = x[i];
    float4 p = p2[i % l4];
    float4 o;
    o.x = fq_apply(v.x, s) + p.x;
    o.y = fq_apply(v.y, s) + p.y;
    o.z = fq_apply(v.z, s) + p.z;
    o.w = fq_apply(v.w, s) + p.w;
    x[i] = o;
    m = fmaxf(m, fmaxf(fmaxf(fabsf(o.x), fabsf(o.y)), fmaxf(fabsf(o.z), fabsf(o.w))));
  }
  blockAtomicMax(m, nextmax, smr);
}

// simple elementwise fq into a fresh buffer (patch weights only; tiny)
__global__ void k_qx(const float* __restrict__ src, float* __restrict__ dst, long n,
                     const float* __restrict__ pmax) {
  float s = fq_scale(pmax);
  for (long i = (long)blockIdx.x * blockDim.x + threadIdx.x; i < n;
       i += (long)gridDim.x * blockDim.x)
    dst[i] = fq_apply(src[i], s);
}

// ---- fused patch embed: LDS-staged x (fq inline), weights in VGPRs ----------
// block = (gw-tile of 64, gh, b); 320 threads (280 active in compute)
__global__ __launch_bounds__(320) void k_patchfq(const float* __restrict__ x,
                                                 const float* __restrict__ wq,
                                                 const float* __restrict__ peb,
                                                 const float* __restrict__ sx_,
                                                 float* __restrict__ out,
                                                 float* __restrict__ nextmax) {
  __shared__ float xs[2][64][20];   // [ph][gw_local][pw] padded to 20
  __shared__ float smr[8];
  int tid = threadIdx.x;
  int gwt = blockIdx.x, gh = blockIdx.y, b = blockIdx.z;
  float sx = fq_scale(sx_);
  if (tid < 256) {
    int gwl = tid >> 2, pw = (tid & 3) * 4;
    #pragma unroll
    for (int ph = 0; ph < 2; ph++) {
      const float* src = x + ((long)b * H_ + gh * 2 + ph) * W_ + (long)gwt * 1024 + tid * 4;
      float4 v = *reinterpret_cast<const float4*>(src);
      xs[ph][gwl][pw + 0] = fq_apply(v.x, sx);
      xs[ph][gwl][pw + 1] = fq_apply(v.y, sx);
      xs[ph][gwl][pw + 2] = fq_apply(v.z, sx);
      xs[ph][gwl][pw + 3] = fq_apply(v.w, sx);
    }
  }
  __syncthreads();
  float mx = 0.f;
  if (tid < 280) {
    int e = tid % 35;
    int g0 = (tid / 35) * 8;
    float w[32];
    #pragma unroll
    for (int j = 0; j < 32; j++) w[j] = wq[e * 32 + j];
    float bias = peb[e];
    long obase = ((long)b * GW_ + (long)gwt * 64) * DM_ + gh * 35 + e;
    #pragma unroll
    for (int gi = 0; gi < 8; gi++) {
      int gw = g0 + gi;
      float acc = bias;
      #pragma unroll
      for (int pw = 0; pw < 16; pw++) {
        acc = fmaf(xs[0][gw][pw], w[pw], acc);
        acc = fmaf(xs[1][gw][pw], w[16 + pw], acc);
      }
      out[obase + (long)gw * DM_] = acc;
      mx = fmaxf(mx, fabsf(acc));
    }
  }
  blockAtomicMax(mx, nextmax, smr);
}

// ---- weight split: W[K][N] f32 -> W2T[Npad][Kp] bf16, terms {hi,lo[,hi]} ----
__global__ void k_wsplit(const float* __restrict__ W, ushort* __restrict__ out,
                         int K, int N, int Kp, long total, int terms) {
  long idx = (long)blockIdx.x * 256 + threadIdx.x;
  if (idx >= total) return;
  int k = (int)(idx % Kp);
  int n = (int)(idx / Kp);
  int t = k / K, kk = k - t * K;
  ushort r = 0;
  if (n < N && t < terms) {
    float w = W[(long)kk * N + n];
    ushort hi = f2bf(w);
    r = (t == 1) ? f2bf(w - bf2f(hi)) : hi;
  }
  out[idx] = r;
}

// ---- activation split: (Y0+Y1)[M][256] f32 -> A2[M][768] bf16 {hi,hi,lo} ----
__global__ void k_asplit2(const float* __restrict__ Y, ushort* __restrict__ A2) {
  long idx = (long)blockIdx.x * 256 + threadIdx.x;   // M*768 threads
  long m = idx / KPO_; int k = (int)(idx - m * KPO_);
  int t = k >> 8, kk = k & 255;
  float v = Y[m * DI_ + kk] + Y[(m + ROWS_) * DI_ + kk];
  ushort hi = f2bf(v);
  A2[idx] = (t == 2) ? f2bf(v - bf2f(hi)) : hi;
}

// zero the pad columns [770, 800) of A2 (in_proj)
__global__ void k_padzero(ushort* __restrict__ A2) {
  long idx = (long)blockIdx.x * 256 + threadIdx.x;   // ROWS_*30 threads
  long m = idx / 30; int c = (int)(idx - m * 30);
  A2[m * KPI_ + 770 + c] = 0;
}

// ---- bf16 MFMA GEMM: C[M][Nreal] = scale * (A2[M][Kp] @ W2T[Npad][Kp]^T) ----
// 128x128 tile, BK=32, 4 waves (2x2), 16x16x32 MFMA.
template<bool AMAX>
__global__ __launch_bounds__(256) void k_mgemm(const ushort* __restrict__ A2,
                                               const ushort* __restrict__ W2T,
                                               float* __restrict__ C,
                                               int Nreal, int Kp,
                                               const float* __restrict__ sptr,
                                               float* __restrict__ amax_out) {
  __shared__ ushort Alds[4][128][8];   // [k-slot][row][8k] 8 KB
  __shared__ ushort Blds[4][128][8];   // [k-slot][col][8k] 8 KB
  __shared__ float smr[8];
  int tid = threadIdx.x;
  int lane = tid & 63, wave = tid >> 6;
  int wm = wave >> 1, wn = wave & 1;
  int m0 = blockIdx.y * 128, n0 = blockIdx.x * 128;
  f32x4 acc[4][4];
  #pragma unroll
  for (int i = 0; i < 4; i++)
    #pragma unroll
    for (int j = 0; j < 4; j++) acc[i][j] = (f32x4){0.f, 0.f, 0.f, 0.f};

  for (int k0 = 0; k0 < Kp; k0 += 32) {
    #pragma unroll
    for (int r = 0; r < 2; r++) {
      int id = tid + r * 256;            // 0..511
      int row = id >> 2, sl = id & 3;    // coalesced 64B global segments
      short8 va = *reinterpret_cast<const short8*>(A2 + (long)(m0 + row) * Kp + k0 + sl * 8);
      *reinterpret_cast<short8*>(&Alds[sl][row][0]) = va;
      short8 vb = *reinterpret_cast<const short8*>(W2T + (long)(n0 + row) * Kp + k0 + sl * 8);
      *reinterpret_cast<short8*>(&Blds[sl][row][0]) = vb;
    }
    __syncthreads();
    int sl = lane >> 4, rr = lane & 15;
    short8 af[4], bf4[4];
    #pragma unroll
    for (int i = 0; i < 4; i++)
      af[i] = *reinterpret_cast<const short8*>(&Alds[sl][wm * 64 + i * 16 + rr][0]);
    #pragma unroll
    for (int j = 0; j < 4; j++)
      bf4[j] = *reinterpret_cast<const short8*>(&Blds[sl][wn * 64 + j * 16 + rr][0]);
    #pragma unroll
    for (int i = 0; i < 4; i++)
      #pragma unroll
      for (int j = 0; j < 4; j++)
        acc[i][j] = __builtin_amdgcn_mfma_f32_16x16x32_bf16(af[i], bf4[j], acc[i][j], 0, 0, 0);
    __syncthreads();
  }

  float s = sptr ? fq_scale(sptr) : 1.0f;
  float mx = 0.f;
  int cfr = lane & 15, rbase = (lane >> 4) * 4;
  #pragma unroll
  for (int i = 0; i < 4; i++) {
    int gmb = m0 + wm * 64 + i * 16 + rbase;
    #pragma unroll
    for (int j = 0; j < 4; j++) {
      int gn = n0 + wn * 64 + j * 16 + cfr;
      if (gn < Nreal) {
        #pragma unroll
        for (int rg = 0; rg < 4; rg++) {
          float v = acc[i][j][rg] * s;
          C[(long)(gmb + rg) * Nreal + gn] = v;
          mx = fmaxf(mx, fabsf(v));
        }
      }
    }
  }
  if (AMAX) blockAtomicMax(mx, amax_out, smr);
}

// ---- generic fp32 tiled GEMM (skinny xp projection, both dirs batched) ------
template<bool AMAX>
__global__ __launch_bounds__(256) void k_gemm(const float* __restrict__ A,
                                              const float* __restrict__ W,
                                              float* __restrict__ C,
                                              int M, int N, int Kd,
                                              float* __restrict__ amax_out) {
  __shared__ __align__(16) float As[16][68];
  __shared__ __align__(16) float Bs[16][68];
  __shared__ float smr[8];
  int tx = threadIdx.x & 15, ty = threadIdx.x >> 4;
  int m0 = blockIdx.y * 64, n0 = blockIdx.x * 64;
  float acc[4][4] = {};
  for (int k0 = 0; k0 < Kd; k0 += 16) {
    #pragma unroll
    for (int r = 0; r < 4; r++) {
      int id = threadIdx.x + r * 256;
      int mm = id >> 4, kk = id & 15;
      int gm = m0 + mm, gk = k0 + kk;
      As[kk][mm] = (gm < M && gk < Kd) ? A[(long)gm * Kd + gk] : 0.f;
    }
    #pragma unroll
    for (int r = 0; r < 4; r++) {
      int id = threadIdx.x + r * 256;
      int kk = id >> 6, nn = id & 63;
      int gk = k0 + kk, gn = n0 + nn;
      Bs[kk][nn] = (gk < Kd && gn < N) ? W[(long)gk * N + gn] : 0.f;
    }
    __syncthreads();
    #pragma unroll
    for (int kk = 0; kk < 16; kk++) {
      float4 a4 = *reinterpret_cast<const float4*>(&As[kk][ty * 4]);
      float4 b4 = *reinterpret_cast<const float4*>(&Bs[kk][tx * 4]);
      float av[4] = {a4.x, a4.y, a4.z, a4.w};
      float bv[4] = {b4.x, b4.y, b4.z, b4.w};
      #pragma unroll
      for (int i = 0; i < 4; i++)
        #pragma unroll
        for (int j = 0; j < 4; j++)
          acc[i][j] = fmaf(av[i], bv[j], acc[i][j]);
    }
    __syncthreads();
  }
  float mx = 0.f;
  #pragma unroll
  for (int i = 0; i < 4; i++) {
    int gm = m0 + ty * 4 + i;
    if (gm < M) {
      #pragma unroll
      for (int j = 0; j < 4; j++) {
        int gn = n0 + tx * 4 + j;
        if (gn < N) {
          C[(long)gm * N + gn] = acc[i][j];
          mx = fmaxf(mx, fabsf(acc[i][j]));
        }
      }
    }
  }
  if (AMAX) blockAtomicMax(mx, amax_out, smr);
}

// ---- depthwise causal conv1d (K=4) + SiLU, both directions in one grid ------
__global__ void k_conv(const float* __restrict__ xz, const float* __restrict__ cw,
                       const float* __restrict__ cb, float* __restrict__ xcout) {
  long idx = (long)blockIdx.x * 256 + threadIdx.x;   // 2*B*L*DI threads
  int d = (int)(idx & 255);
  long rest = idx >> 8;                               // (dir, b, t)
  int dir = (int)(rest / (L_ * B_));
  int rem = (int)(rest - (long)dir * L_ * B_);
  int b = rem / L_, t = rem - (rem / L_) * L_;
  long base = (long)b * L_;
  float acc = cb[d];
  #pragma unroll
  for (int j = 0; j < K_; j++) {
    int tau = t - (K_ - 1) + j;
    if (tau >= 0) {
      int p = dir ? (L_ - 1 - tau) : tau;
      acc = fmaf(cw[d * K_ + j], xz[(base + p) * (2 * DI_) + d], acc);
    }
  }
  float sig = 1.f / (1.f + expf(-acc));
  int pt = dir ? (L_ - 1 - t) : t;
  xcout[((long)dir * ROWS_ + base + pt) * DI_ + d] = acc * sig;
}

// ---- chunked parallel selective scan (dt fused, both dirs in grid.z) --------
__device__ __forceinline__ float softplusf(float x) {
  return fmaxf(x, 0.f) + log1pf(expf(-fabsf(x)));
}

__global__ __launch_bounds__(256) void k_scan1(const float* __restrict__ xc,
                                               const float* __restrict__ proj,
                                               const float* __restrict__ A_log,
                                               const float* __restrict__ dtw,
                                               const float* __restrict__ dtb,
                                               float* __restrict__ Hend,
                                               float* __restrict__ Pend) {
  int b = blockIdx.y, c = blockIdx.x, d = threadIdx.x, dir = blockIdx.z;
  const float* xcD = xc + (long)dir * ROWS_ * DI_;
  const float* prD = proj + (long)dir * ROWS_ * 33;
  float A[4];
  #pragma unroll
  for (int n = 0; n < 4; n++) A[n] = -expf(A_log[d * 4 + n]);
  float dwr[DTR_];
  #pragma unroll
  for (int r = 0; r < DTR_; r++) dwr[r] = dtw[r * DI_ + d];
  float dbv = dtb[d];
  float h[4] = {0.f, 0.f, 0.f, 0.f};
  float P[4] = {1.f, 1.f, 1.f, 1.f};
  long base = (long)b * L_;
  #pragma unroll 2
  for (int s = 0; s < CHL_; s++) {
    int step = c * CHL_ + s;
    long row = base + (dir ? (L_ - 1 - step) : step);
    const float* p = prD + row * 33;
    float dtr = dbv;
    #pragma unroll
    for (int r = 0; r < DTR_; r++) dtr = fmaf(p[r], dwr[r], dtr);
    float dtv = softplusf(dtr);
    float xcv = xcD[row * DI_ + d];
    float dx = dtv * xcv;
    #pragma unroll
    for (int n = 0; n < 4; n++) {
      float Bn = p[DTR_ + n];
      float dA = expf(dtv * A[n]);
      h[n] = dA * h[n] + dx * Bn;
      P[n] *= dA;
    }
  }
  long o = (((long)dir * B_ + b) * CH_ + c) * 1024 + d * 4;
  *reinterpret_cast<float4*>(Hend + o) = make_float4(h[0], h[1], h[2], h[3]);
  *reinterpret_cast<float4*>(Pend + o) = make_float4(P[0], P[1], P[2], P[3]);
}

__global__ __launch_bounds__(256) void k_carry(const float* __restrict__ Hend,
                                               const float* __restrict__ Pend,
                                               float* __restrict__ Carry) {
  int tid = blockIdx.x * 256 + threadIdx.x;   // 2*B_*1024 lanes
  int be = tid >> 10, i = tid & 1023;         // be = dir*16+b
  float carry = 0.f;
  for (int c = 0; c < CH_; c++) {
    long o = ((long)be * CH_ + c) * 1024 + i;
    Carry[o] = carry;
    carry = Pend[o] * carry + Hend[o];
  }
}

__global__ __launch_bounds__(256) void k_scan2(const float* __restrict__ xc,
                                               const float* __restrict__ proj,
                                               const float* __restrict__ A_log,
                                               const float* __restrict__ dtw,
                                               const float* __restrict__ dtb,
                                               const float* __restrict__ Dp,
                                               const float* __restrict__ xz,
                                               const float* __restrict__ Carry,
                                               float* __restrict__ y) {
  int b = blockIdx.y, c = blockIdx.x, d = threadIdx.x, dir = blockIdx.z;
  const float* xcD = xc + (long)dir * ROWS_ * DI_;
  const float* prD = proj + (long)dir * ROWS_ * 33;
  float* yD = y + (long)dir * ROWS_ * DI_;
  float A[4];
  #pragma unroll
  for (int n = 0; n < 4; n++) A[n] = -expf(A_log[d * 4 + n]);
  float dwr[DTR_];
  #pragma unroll
  for (int r = 0; r < DTR_; r++) dwr[r] = dtw[r * DI_ + d];
  float dbv = dtb[d];
  long o = (((long)dir * B_ + b) * CH_ + c) * 1024 + d * 4;
  float4 cv = *reinterpret_cast<const float4*>(Carry + o);
  float h[4] = {cv.x, cv.y, cv.z, cv.w};
  float Dv = Dp[d];
  long base = (long)b * L_;
  #pragma unroll 2
  for (int s = 0; s < CHL_; s++) {
    int step = c * CHL_ + s;
    long row = base + (dir ? (L_ - 1 - step) : step);
    const float* p = prD + row * 33;
    float dtr = dbv;
    #pragma unroll
    for (int r = 0; r < DTR_; r++) dtr = fmaf(p[r], dwr[r], dtr);
    float dtv = softplusf(dtr);
    float xcv = xcD[row * DI_ + d];
    float zv  = xz[row * (2 * DI_) + DI_ + d];
    float dx = dtv * xcv;
    float acc = 0.f;
    #pragma unroll
    for (int n = 0; n < 4; n++) {
      float Bn = p[DTR_ + n];
      float Cn = p[DTR_ + N_ + n];
      float dA = expf(dtv * A[n]);
      h[n] = dA * h[n] + dx * Bn;
      acc = fmaf(h[n], Cn, acc);
    }
    float yv = acc + Dv * xcv;
    float sig = 1.f / (1.f + expf(-zv));
    yv *= zv * sig;
    yD[row * DI_ + d] = yv;
  }
}

// ---- residual + fq(mamba_out) + layernorm, wave-per-row ----------------------
// grid 640 x 256 (4 waves/block); each wave owns rows strided by 2560.
__global__ __launch_bounds__(256) void k_ln(const float* __restrict__ x2,
                                            float* __restrict__ mo,
                                            const float* __restrict__ smo,
                                            const float* __restrict__ g,
                                            const float* __restrict__ bta,
                                            float* __restrict__ nextmax) {
  __shared__ float smr[4];
  int lane = threadIdx.x & 63;
  int wid = blockIdx.x * 4 + (threadIdx.x >> 6);
  float s = fq_scale(smo);
  float wmax = 0.f;
  for (int row = wid; row < ROWS_; row += 2560) {
    const float* xr = x2 + (long)row * DM_;
    float* mr = mo + (long)row * DM_;
    float v[7];
    float lsum = 0.f;
    #pragma unroll
    for (int k = 0; k < 6; k++) {
      int c = lane + k * 64;
      v[k] = xr[c] + fq_apply(mr[c], s);
      lsum += v[k];
    }
    v[6] = 0.f;
    if (lane == 0) v[6] = xr[384] + fq_apply(mr[384], s);
    lsum += v[6];
    #pragma unroll
    for (int o = 32; o > 0; o >>= 1) lsum += __shfl_xor(lsum, o);
    float mean = lsum / 385.f;
    float lvar = 0.f;
    #pragma unroll
    for (int k = 0; k < 6; k++) { float dd = v[k] - mean; lvar += dd * dd; }
    if (lane == 0) { float dd = v[6] - mean; lvar += dd * dd; }
    #pragma unroll
    for (int o = 32; o > 0; o >>= 1) lvar += __shfl_xor(lvar, o);
    float rs = 1.f / sqrtf(lvar / 385.f + 1e-5f);
    #pragma unroll
    for (int k = 0; k < 6; k++) {
      int c = lane + k * 64;
      float o2 = (v[k] - mean) * rs * g[c] + bta[c];
      mr[c] = o2;
      wmax = fmaxf(wmax, fabsf(o2));
    }
    if (lane == 0) {
      float o2 = (v[6] - mean) * rs * g[384] + bta[384];
      mr[384] = o2;
      wmax = fmaxf(wmax, fabsf(o2));
    }
  }
  blockAtomicMax(wmax, nextmax, smr);
}

// ---- mean pool over L (two-stage, coalesced, deterministic) ------------------
__global__ __launch_bounds__(256) void k_pool1(const float* __restrict__ x2,
                                               float* __restrict__ part) {
  int b = blockIdx.x, ch = blockIdx.y, tid = threadIdx.x;
  float s0 = 0.f, s1 = 0.f;
  for (int l = ch * 128; l < ch * 128 + 128; l++) {
    const float* row = x2 + ((long)b * L_ + l) * DM_;
    s0 += row[tid];
    if (tid < DM_ - 256) s1 += row[tid + 256];
  }
  long o = ((long)b * 10 + ch) * DM_;
  part[o + tid] = s0;
  if (tid < DM_ - 256) part[o + tid + 256] = s1;
}

__global__ void k_pool2(const float* __restrict__ part, float* __restrict__ pool,
                        float* __restrict__ nextmax) {
  __shared__ float smr[8];
  int idx = blockIdx.x * 256 + threadIdx.x;
  float mv = 0.f;
  if (idx < B_ * DM_) {
    int b = idx / DM_, c = idx % DM_;
    float s = 0.f;
    for (int ch = 0; ch < 10; ch++) s += part[((long)b * 10 + ch) * DM_ + c];
    float mean = s / (float)L_;
    pool[idx] = mean;
    mv = fabsf(mean);
  }
  blockAtomicMax(mv, nextmax, smr);
}

// ---- classifier --------------------------------------------------------------
__global__ void k_cls(const float* __restrict__ pool, const float* __restrict__ clsw,
                      const float* __restrict__ clsb, const float* __restrict__ sp_,
                      const float* __restrict__ sw_, float* __restrict__ out) {
  int tid = threadIdx.x;
  if (tid >= B_ * 2) return;
  int b = tid >> 1, c = tid & 1;
  float sp = fq_scale(sp_), sw = fq_scale(sw_);
  float acc = 0.f;
  for (int k2 = 0; k2 < DM_; k2++) {
    float xv = fq_apply(pool[b * DM_ + k2], sp);
    float wv = fq_apply(clsw[k2 * 2 + c], sw);
    acc = fmaf(xv, wv, acc);
  }
  out[b * 2 + c] = acc + clsb[c];
}

// ---- launch ------------------------------------------------------------------
extern "C" void kernel_launch(void* const* d_in, const int* in_sizes, int n_in,
                              void* d_out, int out_size, void* d_ws, size_t ws_size,
                              hipStream_t stream) {
  const float* x    = (const float*)d_in[0];
  const float* pew  = (const float*)d_in[1];
  const float* peb  = (const float*)d_in[2];
  const float* pos  = (const float*)d_in[3];
  const float* in_w = (const float*)d_in[4];
  const float* cw   = (const float*)d_in[5];
  const float* cb   = (const float*)d_in[6];
  const float* xpw  = (const float*)d_in[7];
  const float* dtw  = (const float*)d_in[8];
  const float* dtb  = (const float*)d_in[9];
  const float* alog = (const float*)d_in[10];
  const float* dp   = (const float*)d_in[11];
  const float* outw = (const float*)d_in[12];
  const float* lng  = (const float*)d_in[13];
  const float* lnb  = (const float*)d_in[14];
  const float* clsw = (const float*)d_in[15];
  const float* clsb = (const float*)d_in[16];

  float* ws    = (float*)d_ws;
  float* SCAL  = ws;                              // 13 scalars x 128 floats (8 slots)
  float* WQ    = ws + 2048;                       // 2048 (1120 used)
  float* P2    = WQ + 2048;                       // 492,800
  float* X2    = P2 + LDM_;                       // 7,884,800
  float* XZ    = X2 + NX_;                        // 10,485,760
  float* XC    = XZ + (long)ROWS_ * 512;          // 2 x 5,242,880
  float* PROJ  = XC + 2L * ROWS_ * DI_;           // 2 x 675,840
  float* Y     = PROJ + 2L * ROWS_ * 33;          // 2 x 5,242,880
  float* MO    = Y + 2L * ROWS_ * DI_;            // 7,884,800
  float* POOL  = MO + NX_;                        // 8,192
  float* PART  = POOL + 8192;                     // 61,600 (+pad)
  float* A2IN_f= PART + 65536;                    // 8,192,000 f (ushort overlay)
  float* W2I_f = A2IN_f + 8192000;                // 409,600 f
  float* W2O_f = W2I_f + 409600;                  // 393,216 f
  // aliases (disjoint lifetimes):
  float*  HEND = MO;                              // scan summaries, dead before out-GEMM
  float*  PEND = MO + 2097152;
  float*  CARR = MO + 4194304;
  ushort* A2Y  = (ushort*)XZ;                     // [20480][768], dead before next in-GEMM
  ushort* A2IN = (ushort*)A2IN_f;                 // [20480][800]
  ushort* W2TI = (ushort*)W2I_f;                  // 2 x [512][800]
  ushort* W2TO = (ushort*)W2O_f;                  // 2 x [512][768]

  // scalar entry i lives at SCAL + i*SCALW (8 slots, 64B apart)
  #define SC(i) (SCAL + (i) * SCALW)

  k_zero<<<8, 256, 0, stream>>>(SCAL);

  // weight splits for MFMA GEMMs (tiny)
  for (int blk = 0; blk < 2; blk++) {
    k_wsplit<<<1600, 256, 0, stream>>>(in_w + (long)blk * DM_ * 512,
                                       W2TI + (long)blk * 512 * KPI_,
                                       DM_, 512, KPI_, 512L * KPI_, 2);
    k_wsplit<<<1536, 256, 0, stream>>>(outw + (long)blk * DI_ * DM_,
                                       W2TO + (long)blk * 512 * KPO_,
                                       DI_, DM_, KPO_, 512L * KPO_, 3);
  }
  k_padzero<<<2400, 256, 0, stream>>>(A2IN);

  // input fq + fused patch-embed
  k_absmax<<<2048, 256, 0, stream>>>(x, (long)B_ * H_ * W_, SC(0));
  k_absmax<<<8, 256, 0, stream>>>(pew, EMB * 2 * 16, SC(1));
  k_qx<<<5, 256, 0, stream>>>(pew, WQ, EMB * 2 * 16, SC(1));
  k_patchfq<<<dim3(20, 11, 16), 320, 0, stream>>>(x, WQ, peb, SC(0), X2, SC(2));
  k_fq4<<<2048, 256, 0, stream>>>((const float4*)X2, (float4*)X2, NX_ / 4,
                                  SC(2), SC(3), nullptr);

  // pos = fq(fq(pos_embed))
  k_absmax<<<512, 256, 0, stream>>>(pos, LDM_, SC(4));
  k_fq4<<<512, 256, 0, stream>>>((const float4*)pos, (float4*)P2, LDM_ / 4,
                                 SC(4), SC(5), nullptr);
  k_fq4<<<512, 256, 0, stream>>>((const float4*)P2, (float4*)P2, LDM_ / 4,
                                 SC(5), nullptr, nullptr);

  // x = fq(fq(x) + pos); emit bf16 q for blk0 in-proj
  k_addpos4<<<2048, 256, 0, stream>>>((float4*)X2, (const float4*)P2, SC(3), SC(6));
  k_fq4<<<2048, 256, 0, stream>>>((const float4*)X2, (float4*)X2, NX_ / 4,
                                  SC(6), nullptr, A2IN);

  const float* in_scale[2] = {SC(6), SC(8)};
  for (int blk = 0; blk < 2; blk++) {
    // in-proj: XZ = s * (q @ [w_hi; w_lo])   (MFMA bf16)
    k_mgemm<false><<<dim3(4, 160), 256, 0, stream>>>(
        A2IN, W2TI + (long)blk * 512 * KPI_, XZ, 512, KPI_, in_scale[blk], nullptr);
    // conv (both dirs), xp-proj (both dirs), chunked scan (both dirs)
    k_conv<<<40960, 256, 0, stream>>>(XZ, cw + blk * DI_ * K_, cb + blk * DI_, XC);
    k_gemm<false><<<dim3(1, 640), 256, 0, stream>>>(
        XC, xpw + (long)blk * DI_ * 33, PROJ, 2 * ROWS_, 33, DI_, nullptr);
    k_scan1<<<dim3(CH_, B_, 2), 256, 0, stream>>>(XC, PROJ, alog + blk * DI_ * N_,
                                                  dtw + blk * DTR_ * DI_, dtb + blk * DI_,
                                                  HEND, PEND);
    k_carry<<<128, 256, 0, stream>>>(HEND, PEND, CARR);
    k_scan2<<<dim3(CH_, B_, 2), 256, 0, stream>>>(XC, PROJ, alog + blk * DI_ * N_,
                                                  dtw + blk * DTR_ * DI_, dtb + blk * DI_,
                                                  dp + blk * DI_, XZ, CARR, Y);
    // out-proj: MO = [y_hi,y_hi,y_lo] @ [w_hi;w_lo;w_hi]  (MFMA bf16, amax fused)
    k_asplit2<<<61440, 256, 0, stream>>>(Y, A2Y);
    k_mgemm<true><<<dim3(4, 160), 256, 0, stream>>>(
        A2Y, W2TO + (long)blk * 512 * KPO_, MO, DM_, KPO_, nullptr, SC(7 + blk * 2));
    // x = fq(layernorm(x + fq(mo))); emit q for next block's in-proj
    k_ln<<<640, 256, 0, stream>>>(X2, MO, SC(7 + blk * 2),
                                  lng + blk * DM_, lnb + blk * DM_, SC(8 + blk * 2));
    k_fq4<<<2048, 256, 0, stream>>>((const float4*)MO, (float4*)X2, NX_ / 4,
                                    SC(8 + blk * 2), nullptr,
                                    blk == 0 ? A2IN : nullptr);
  }

  // mean-pool (2-stage), fq, classifier with fq(cls_w)
  k_pool1<<<dim3(16, 10), 256, 0, stream>>>(X2, PART);
  k_pool2<<<25, 256, 0, stream>>>(PART, POOL, SC(11));
  k_absmax<<<4, 256, 0, stream>>>(clsw, DM_ * 2, SC(12));
  k_cls<<<1, 64, 0, stream>>>(POOL, clsw, clsb, SC(11), SC(12), (float*)d_out);
}

// Round 6
// 862.418 us; speedup vs baseline: 5.7893x; 1.1617x over previous
//
#include <hip/hip_runtime.h>
#include <hip/hip_bf16.h>
#include <math.h>

// ---- problem constants -----------------------------------------------------
#define B_    16
#define H_    22
#define W_    20480
#define EMB   35
#define GH_   11
#define GW_   1280
#define L_    1280
#define DM_   385
#define DI_   256
#define N_    4
#define K_    4
#define DTR_  25
#define ROWS_ (B_*L_)              // 20480
#define NX_   ((long)ROWS_*DM_)    // 7,884,800
#define LDM_  ((long)L_*DM_)       // 492,800
#define CH_   64                   // scan chunks
#define CHL_  20                   // steps per chunk (CH_*CHL_ == L_)
#define KPI_  800                  // in_proj W K' (2 terms x 400)
#define KPA_  400                  // in_proj A width (q stored once, padded)
#define KPO_  768                  // out_proj W K' (3 terms x 256)
#define WAO_  512                  // out_proj A width ({hi,lo})

// amax scalars: 8 slots x 64B apart to break single-address atomic serialization
#define NSLOT 8
#define SSTR  16                   // floats between slots (64 B)
#define SCALW 128                  // floats per logical scalar (8 slots)

typedef __attribute__((ext_vector_type(8))) short short8;
typedef __attribute__((ext_vector_type(4))) float f32x4;
typedef unsigned short ushort;

// ---- helpers ---------------------------------------------------------------
__device__ __forceinline__ void atomicMaxF(float* a, float v) {
  atomicMax(reinterpret_cast<int*>(a), __float_as_int(v));
}

// faithful fq: s = max(mx,1e-8)/127 where mx = max over the 8 slots
__device__ __forceinline__ float fq_scale(const float* pmax) {
  float m = pmax[0];
  #pragma unroll
  for (int i = 1; i < NSLOT; i++) m = fmaxf(m, pmax[i * SSTR]);
  return fmaxf(m, 1e-8f) / 127.f;
}
__device__ __forceinline__ float fq_apply(float x, float s) {
  float r = rintf(x / s);
  r = fminf(fmaxf(r, -128.f), 127.f);
  return r * s;
}

__device__ __forceinline__ ushort f2bf(float f) {  // round-to-nearest-even
  union { float f; unsigned u; } v; v.f = f;
  unsigned r = v.u + 0x7FFF + ((v.u >> 16) & 1);
  return (ushort)(r >> 16);
}
__device__ __forceinline__ float bf2f(ushort h) {
  union { unsigned u; float f; } v; v.u = ((unsigned)h) << 16;
  return v.f;
}

// block max -> atomicMax into one of 8 slots (by block id). sm >= blockDim/64.
__device__ __forceinline__ void blockAtomicMax(float v, float* out, float* sm) {
  #pragma unroll
  for (int o = 32; o > 0; o >>= 1) v = fmaxf(v, __shfl_down(v, o));
  if ((threadIdx.x & 63) == 0) sm[threadIdx.x >> 6] = v;
  __syncthreads();
  if (threadIdx.x == 0) {
    int nw = (blockDim.x + 63) >> 6;
    for (int i = 1; i < nw; i++) v = fmaxf(v, sm[i]);
    int slot = (blockIdx.x + blockIdx.y * 4 + blockIdx.z) & (NSLOT - 1);
    atomicMaxF(out + slot * SSTR, v);
  }
}

// ---- small utility kernels -------------------------------------------------
__global__ void k_zero(float* s) { s[blockIdx.x * 256 + threadIdx.x] = 0.f; }

__global__ void k_absmax(const float* __restrict__ src, long n, float* __restrict__ out) {
  __shared__ float smr[8];
  float m = 0.f;
  for (long i = (long)blockIdx.x * blockDim.x + threadIdx.x; i < n;
       i += (long)gridDim.x * blockDim.x)
    m = fmaxf(m, fabsf(src[i]));
  blockAtomicMax(m, out, smr);
}

// vectorized fq: dst4 = fq(src4); optional absmax -> nextmax; optional bf16
// q-emit into A2 [M][KPA_]. dst may == src.
__global__ void k_fq4(const float4* __restrict__ src, float4* __restrict__ dst, long n4,
                      const float* __restrict__ pmax, float* __restrict__ nextmax,
                      ushort* __restrict__ a2) {
  __shared__ float smr[8];
  float s = fq_scale(pmax);
  float m = 0.f;
  for (long i = (long)blockIdx.x * blockDim.x + threadIdx.x; i < n4;
       i += (long)gridDim.x * blockDim.x) {
    float4 v = src[i];
    float r0 = fminf(fmaxf(rintf(v.x / s), -128.f), 127.f);
    float r1 = fminf(fmaxf(rintf(v.y / s), -128.f), 127.f);
    float r2 = fminf(fmaxf(rintf(v.z / s), -128.f), 127.f);
    float r3 = fminf(fmaxf(rintf(v.w / s), -128.f), 127.f);
    float4 q = make_float4(r0 * s, r1 * s, r2 * s, r3 * s);
    dst[i] = q;
    m = fmaxf(m, fmaxf(fmaxf(fabsf(q.x), fabsf(q.y)), fmaxf(fabsf(q.z), fabsf(q.w))));
    if (a2) {
      long ii = i * 4;
      long mm = ii / 385; int kk = (int)(ii - mm * 385);
      float rr[4] = {r0, r1, r2, r3};
      #pragma unroll
      for (int j = 0; j < 4; j++) {
        a2[mm * KPA_ + kk] = f2bf(rr[j]);
        if (++kk == 385) { kk = 0; mm++; }
      }
    }
  }
  if (nextmax) blockAtomicMax(m, nextmax, smr);
}

// x4[i] = fq(x4[i], s_pmax) + p2[i % LDM/4]; absmax -> nextmax
// (the reference's extra fq() layers are identities: fq(fq(t)) == fq(t))
__global__ void k_addpos4(float4* __restrict__ x, const float4* __restrict__ p2,
                          const float* __restrict__ pmax, float* __restrict__ nextmax) {
  __shared__ float smr[8];
  float s = fq_scale(pmax);
  float m = 0.f;
  const long n4 = NX_ / 4, l4 = LDM_ / 4;
  for (long i = (long)blockIdx.x * blockDim.x + threadIdx.x; i < n4;
       i += (long)gridDim.x * blockDim.x) {
    float4 v = x[i];
    float4 p = p2[i % l4];
    float4 o;
    o.x = fq_apply(v.x, s) + p.x;
    o.y = fq_apply(v.y, s) + p.y;
    o.z = fq_apply(v.z, s) + p.z;
    o.w = fq_apply(v.w, s) + p.w;
    x[i] = o;
    m = fmaxf(m, fmaxf(fmaxf(fabsf(o.x), fabsf(o.y)), fmaxf(fabsf(o.z), fabsf(o.w))));
  }
  blockAtomicMax(m, nextmax, smr);
}

// ---- fused patch embed: LDS-staged x (fq inline), fq'd weights in VGPRs -----
// block = (gw-tile of 64, gh, b); 320 threads (280 active in compute)
__global__ __launch_bounds__(320) void k_patchfq(const float* __restrict__ x,
                                                 const float* __restrict__ pew,
                                                 const float* __restrict__ peb,
                                                 const float* __restrict__ sx_,
                                                 const float* __restrict__ sw_,
                                                 float* __restrict__ out,
                                                 float* __restrict__ nextmax) {
  __shared__ float xs[2][64][20];   // [ph][gw_local][pw] padded to 20
  __shared__ float smr[8];
  int tid = threadIdx.x;
  int gwt = blockIdx.x, gh = blockIdx.y, b = blockIdx.z;
  float sx = fq_scale(sx_), sw = fq_scale(sw_);
  if (tid < 256) {
    int gwl = tid >> 2, pw = (tid & 3) * 4;
    #pragma unroll
    for (int ph = 0; ph < 2; ph++) {
      const float* src = x + ((long)b * H_ + gh * 2 + ph) * W_ + (long)gwt * 1024 + tid * 4;
      float4 v = *reinterpret_cast<const float4*>(src);
      xs[ph][gwl][pw + 0] = fq_apply(v.x, sx);
      xs[ph][gwl][pw + 1] = fq_apply(v.y, sx);
      xs[ph][gwl][pw + 2] = fq_apply(v.z, sx);
      xs[ph][gwl][pw + 3] = fq_apply(v.w, sx);
    }
  }
  __syncthreads();
  float mx = 0.f;
  if (tid < 280) {
    int e = tid % 35;
    int g0 = (tid / 35) * 8;
    float w[32];
    #pragma unroll
    for (int j = 0; j < 32; j++) w[j] = fq_apply(pew[e * 32 + j], sw);
    float bias = peb[e];
    long obase = ((long)b * GW_ + (long)gwt * 64) * DM_ + gh * 35 + e;
    #pragma unroll
    for (int gi = 0; gi < 8; gi++) {
      int gw = g0 + gi;
      float acc = bias;
      #pragma unroll
      for (int pw = 0; pw < 16; pw++) {
        acc = fmaf(xs[0][gw][pw], w[pw], acc);
        acc = fmaf(xs[1][gw][pw], w[16 + pw], acc);
      }
      out[obase + (long)gw * DM_] = acc;
      mx = fmaxf(mx, fabsf(acc));
    }
  }
  blockAtomicMax(mx, nextmax, smr);
}

// ---- weight split: W[K][N] f32 -> W2T[Npad][Kp] bf16 ------------------------
// term t occupies cols [t*Kw, t*Kw+K); value = lo at t==terms-1 else hi.
__global__ void k_wsplit(const float* __restrict__ W, ushort* __restrict__ out,
                         int K, int N, int Kw, int Kp, long total, int terms) {
  long idx = (long)blockIdx.x * 256 + threadIdx.x;
  if (idx >= total) return;
  int k = (int)(idx % Kp);
  int n = (int)(idx / Kp);
  int t = k / Kw, kk = k - t * Kw;
  ushort r = 0;
  if (n < N && kk < K) {
    float w = W[(long)kk * N + n];
    ushort hi = f2bf(w);
    r = (t == terms - 1) ? f2bf(w - bf2f(hi)) : hi;
  }
  out[idx] = r;
}

// ---- activation split: (Y0+Y1)[M][256] f32 -> A2[M][512] bf16 {hi,lo} -------
__global__ void k_asplit2(const float* __restrict__ Y, ushort* __restrict__ A2) {
  long idx = (long)blockIdx.x * 256 + threadIdx.x;   // M*512 threads
  long m = idx >> 9; int k = (int)(idx & 511);
  int t = k >> 8, kk = k & 255;
  float v = Y[m * DI_ + kk] + Y[(m + ROWS_) * DI_ + kk];
  ushort hi = f2bf(v);
  A2[idx] = t ? f2bf(v - bf2f(hi)) : hi;
}

// zero the pad columns [385, 400) of A2IN
__global__ void k_padzero(ushort* __restrict__ A2) {
  long idx = (long)blockIdx.x * 256 + threadIdx.x;   // ROWS_*15 threads
  long m = idx / 15; int c = (int)(idx - m * 15);
  A2[m * KPA_ + 385 + c] = 0;
}

// ---- bf16 MFMA GEMM: C[M][Nreal] = scale * (A2[M][Wa,wrapped] @ W2T[Npad][Kp]^T)
// A column for global k is (k % Wa) -- A stores each distinct segment once.
// 128x128 tile, BK=32, 4 waves (2x2), 16x16x32 MFMA.
template<bool AMAX>
__global__ __launch_bounds__(256) void k_mgemm(const ushort* __restrict__ A2,
                                               const ushort* __restrict__ W2T,
                                               float* __restrict__ C,
                                               int Nreal, int Kp, int Wa,
                                               const float* __restrict__ sptr,
                                               float* __restrict__ amax_out) {
  __shared__ ushort Alds[4][128][8];   // [k-slot][row][8k] 8 KB
  __shared__ ushort Blds[4][128][8];   // [k-slot][col][8k] 8 KB
  __shared__ float smr[8];
  int tid = threadIdx.x;
  int lane = tid & 63, wave = tid >> 6;
  int wm = wave >> 1, wn = wave & 1;
  int m0 = blockIdx.y * 128, n0 = blockIdx.x * 128;
  f32x4 acc[4][4];
  #pragma unroll
  for (int i = 0; i < 4; i++)
    #pragma unroll
    for (int j = 0; j < 4; j++) acc[i][j] = (f32x4){0.f, 0.f, 0.f, 0.f};

  for (int k0 = 0; k0 < Kp; k0 += 32) {
    #pragma unroll
    for (int r = 0; r < 2; r++) {
      int id = tid + r * 256;            // 0..511
      int row = id >> 2, sl = id & 3;    // coalesced 64B global segments
      int kc = k0 + sl * 8; if (kc >= Wa) kc -= Wa;   // A k-wrap (8-aligned)
      short8 va = *reinterpret_cast<const short8*>(A2 + (long)(m0 + row) * Wa + kc);
      *reinterpret_cast<short8*>(&Alds[sl][row][0]) = va;
      short8 vb = *reinterpret_cast<const short8*>(W2T + (long)(n0 + row) * Kp + k0 + sl * 8);
      *reinterpret_cast<short8*>(&Blds[sl][row][0]) = vb;
    }
    __syncthreads();
    int sl = lane >> 4, rr = lane & 15;
    short8 af[4], bf4[4];
    #pragma unroll
    for (int i = 0; i < 4; i++)
      af[i] = *reinterpret_cast<const short8*>(&Alds[sl][wm * 64 + i * 16 + rr][0]);
    #pragma unroll
    for (int j = 0; j < 4; j++)
      bf4[j] = *reinterpret_cast<const short8*>(&Blds[sl][wn * 64 + j * 16 + rr][0]);
    #pragma unroll
    for (int i = 0; i < 4; i++)
      #pragma unroll
      for (int j = 0; j < 4; j++)
        acc[i][j] = __builtin_amdgcn_mfma_f32_16x16x32_bf16(af[i], bf4[j], acc[i][j], 0, 0, 0);
    __syncthreads();
  }

  float s = sptr ? fq_scale(sptr) : 1.0f;
  float mx = 0.f;
  int cfr = lane & 15, rbase = (lane >> 4) * 4;
  #pragma unroll
  for (int i = 0; i < 4; i++) {
    int gmb = m0 + wm * 64 + i * 16 + rbase;
    #pragma unroll
    for (int j = 0; j < 4; j++) {
      int gn = n0 + wn * 64 + j * 16 + cfr;
      if (gn < Nreal) {
        #pragma unroll
        for (int rg = 0; rg < 4; rg++) {
          float v = acc[i][j][rg] * s;
          C[(long)(gmb + rg) * Nreal + gn] = v;
          mx = fmaxf(mx, fabsf(v));
        }
      }
    }
  }
  if (AMAX) blockAtomicMax(mx, amax_out, smr);
}

// ---- generic fp32 tiled GEMM (skinny xp projection, both dirs batched) ------
template<bool AMAX>
__global__ __launch_bounds__(256) void k_gemm(const float* __restrict__ A,
                                              const float* __restrict__ W,
                                              float* __restrict__ C,
                                              int M, int N, int Kd,
                                              float* __restrict__ amax_out) {
  __shared__ __align__(16) float As[16][68];
  __shared__ __align__(16) float Bs[16][68];
  __shared__ float smr[8];
  int tx = threadIdx.x & 15, ty = threadIdx.x >> 4;
  int m0 = blockIdx.y * 64, n0 = blockIdx.x * 64;
  float acc[4][4] = {};
  for (int k0 = 0; k0 < Kd; k0 += 16) {
    #pragma unroll
    for (int r = 0; r < 4; r++) {
      int id = threadIdx.x + r * 256;
      int mm = id >> 4, kk = id & 15;
      int gm = m0 + mm, gk = k0 + kk;
      As[kk][mm] = (gm < M && gk < Kd) ? A[(long)gm * Kd + gk] : 0.f;
    }
    #pragma unroll
    for (int r = 0; r < 4; r++) {
      int id = threadIdx.x + r * 256;
      int kk = id >> 6, nn = id & 63;
      int gk = k0 + kk, gn = n0 + nn;
      Bs[kk][nn] = (gk < Kd && gn < N) ? W[(long)gk * N + gn] : 0.f;
    }
    __syncthreads();
    #pragma unroll
    for (int kk = 0; kk < 16; kk++) {
      float4 a4 = *reinterpret_cast<const float4*>(&As[kk][ty * 4]);
      float4 b4 = *reinterpret_cast<const float4*>(&Bs[kk][tx * 4]);
      float av[4] = {a4.x, a4.y, a4.z, a4.w};
      float bv[4] = {b4.x, b4.y, b4.z, b4.w};
      #pragma unroll
      for (int i = 0; i < 4; i++)
        #pragma unroll
        for (int j = 0; j < 4; j++)
          acc[i][j] = fmaf(av[i], bv[j], acc[i][j]);
    }
    __syncthreads();
  }
  float mx = 0.f;
  #pragma unroll
  for (int i = 0; i < 4; i++) {
    int gm = m0 + ty * 4 + i;
    if (gm < M) {
      #pragma unroll
      for (int j = 0; j < 4; j++) {
        int gn = n0 + tx * 4 + j;
        if (gn < N) {
          C[(long)gm * N + gn] = acc[i][j];
          mx = fmaxf(mx, fabsf(acc[i][j]));
        }
      }
    }
  }
  if (AMAX) blockAtomicMax(mx, amax_out, smr);
}

// ---- depthwise causal conv1d (K=4) + SiLU, both directions in one grid ------
__global__ void k_conv(const float* __restrict__ xz, const float* __restrict__ cw,
                       const float* __restrict__ cb, float* __restrict__ xcout) {
  long idx = (long)blockIdx.x * 256 + threadIdx.x;   // 2*B*L*DI threads
  int d = (int)(idx & 255);
  long rest = idx >> 8;                               // (dir, b, t)
  int dir = (int)(rest / (L_ * B_));
  int rem = (int)(rest - (long)dir * L_ * B_);
  int b = rem / L_, t = rem - (rem / L_) * L_;
  long base = (long)b * L_;
  float acc = cb[d];
  #pragma unroll
  for (int j = 0; j < K_; j++) {
    int tau = t - (K_ - 1) + j;
    if (tau >= 0) {
      int p = dir ? (L_ - 1 - tau) : tau;
      acc = fmaf(cw[d * K_ + j], xz[(base + p) * (2 * DI_) + d], acc);
    }
  }
  float sig = 1.f / (1.f + expf(-acc));
  int pt = dir ? (L_ - 1 - t) : t;
  xcout[((long)dir * ROWS_ + base + pt) * DI_ + d] = acc * sig;
}

// ---- chunked parallel selective scan (dt fused, both dirs in grid.z) --------
__device__ __forceinline__ float softplusf(float x) {
  return fmaxf(x, 0.f) + log1pf(expf(-fabsf(x)));
}

__global__ __launch_bounds__(256) void k_scan1(const float* __restrict__ xc,
                                               const float* __restrict__ proj,
                                               const float* __restrict__ A_log,
                                               const float* __restrict__ dtw,
                                               const float* __restrict__ dtb,
                                               float* __restrict__ Hend,
                                               float* __restrict__ Pend) {
  int b = blockIdx.y, c = blockIdx.x, d = threadIdx.x, dir = blockIdx.z;
  const float* xcD = xc + (long)dir * ROWS_ * DI_;
  const float* prD = proj + (long)dir * ROWS_ * 33;
  float A[4];
  #pragma unroll
  for (int n = 0; n < 4; n++) A[n] = -expf(A_log[d * 4 + n]);
  float dwr[DTR_];
  #pragma unroll
  for (int r = 0; r < DTR_; r++) dwr[r] = dtw[r * DI_ + d];
  float dbv = dtb[d];
  float h[4] = {0.f, 0.f, 0.f, 0.f};
  float P[4] = {1.f, 1.f, 1.f, 1.f};
  long base = (long)b * L_;
  #pragma unroll 2
  for (int s = 0; s < CHL_; s++) {
    int step = c * CHL_ + s;
    long row = base + (dir ? (L_ - 1 - step) : step);
    const float* p = prD + row * 33;
    float dtr = dbv;
    #pragma unroll
    for (int r = 0; r < DTR_; r++) dtr = fmaf(p[r], dwr[r], dtr);
    float dtv = softplusf(dtr);
    float xcv = xcD[row * DI_ + d];
    float dx = dtv * xcv;
    #pragma unroll
    for (int n = 0; n < 4; n++) {
      float Bn = p[DTR_ + n];
      float dA = expf(dtv * A[n]);
      h[n] = dA * h[n] + dx * Bn;
      P[n] *= dA;
    }
  }
  long o = (((long)dir * B_ + b) * CH_ + c) * 1024 + d * 4;
  *reinterpret_cast<float4*>(Hend + o) = make_float4(h[0], h[1], h[2], h[3]);
  *reinterpret_cast<float4*>(Pend + o) = make_float4(P[0], P[1], P[2], P[3]);
}

__global__ __launch_bounds__(256) void k_carry(const float* __restrict__ Hend,
                                               const float* __restrict__ Pend,
                                               float* __restrict__ Carry) {
  int tid = blockIdx.x * 256 + threadIdx.x;   // 2*B_*1024 lanes
  int be = tid >> 10, i = tid & 1023;         // be = dir*16+b
  float carry = 0.f;
  for (int c = 0; c < CH_; c++) {
    long o = ((long)be * CH_ + c) * 1024 + i;
    Carry[o] = carry;
    carry = Pend[o] * carry + Hend[o];
  }
}

__global__ __launch_bounds__(256) void k_scan2(const float* __restrict__ xc,
                                               const float* __restrict__ proj,
                                               const float* __restrict__ A_log,
                                               const float* __restrict__ dtw,
                                               const float* __restrict__ dtb,
                                               const float* __restrict__ Dp,
                                               const float* __restrict__ xz,
                                               const float* __restrict__ Carry,
                                               float* __restrict__ y) {
  int b = blockIdx.y, c = blockIdx.x, d = threadIdx.x, dir = blockIdx.z;
  const float* xcD = xc + (long)dir * ROWS_ * DI_;
  const float* prD = proj + (long)dir * ROWS_ * 33;
  float* yD = y + (long)dir * ROWS_ * DI_;
  float A[4];
  #pragma unroll
  for (int n = 0; n < 4; n++) A[n] = -expf(A_log[d * 4 + n]);
  float dwr[DTR_];
  #pragma unroll
  for (int r = 0; r < DTR_; r++) dwr[r] = dtw[r * DI_ + d];
  float dbv = dtb[d];
  long o = (((long)dir * B_ + b) * CH_ + c) * 1024 + d * 4;
  float4 cv = *reinterpret_cast<const float4*>(Carry + o);
  float h[4] = {cv.x, cv.y, cv.z, cv.w};
  float Dv = Dp[d];
  long base = (long)b * L_;
  #pragma unroll 2
  for (int s = 0; s < CHL_; s++) {
    int step = c * CHL_ + s;
    long row = base + (dir ? (L_ - 1 - step) : step);
    const float* p = prD + row * 33;
    float dtr = dbv;
    #pragma unroll
    for (int r = 0; r < DTR_; r++) dtr = fmaf(p[r], dwr[r], dtr);
    float dtv = softplusf(dtr);
    float xcv = xcD[row * DI_ + d];
    float zv  = xz[row * (2 * DI_) + DI_ + d];
    float dx = dtv * xcv;
    float acc = 0.f;
    #pragma unroll
    for (int n = 0; n < 4; n++) {
      float Bn = p[DTR_ + n];
      float Cn = p[DTR_ + N_ + n];
      float dA = expf(dtv * A[n]);
      h[n] = dA * h[n] + dx * Bn;
      acc = fmaf(h[n], Cn, acc);
    }
    float yv = acc + Dv * xcv;
    float sig = 1.f / (1.f + expf(-zv));
    yv *= zv * sig;
    yD[row * DI_ + d] = yv;
  }
}

// ---- residual + fq(mamba_out) + layernorm, wave-per-row ----------------------
// grid 640 x 256 (4 waves/block); each wave owns rows strided by 2560.
__global__ __launch_bounds__(256) void k_ln(const float* __restrict__ x2,
                                            float* __restrict__ mo,
                                            const float* __restrict__ smo,
                                            const float* __restrict__ g,
                                            const float* __restrict__ bta,
                                            float* __restrict__ nextmax) {
  __shared__ float smr[4];
  int lane = threadIdx.x & 63;
  int wid = blockIdx.x * 4 + (threadIdx.x >> 6);
  float s = fq_scale(smo);
  float wmax = 0.f;
  for (int row = wid; row < ROWS_; row += 2560) {
    const float* xr = x2 + (long)row * DM_;
    float* mr = mo + (long)row * DM_;
    float v[7];
    float lsum = 0.f;
    #pragma unroll
    for (int k = 0; k < 6; k++) {
      int c = lane + k * 64;
      v[k] = xr[c] + fq_apply(mr[c], s);
      lsum += v[k];
    }
    v[6] = 0.f;
    if (lane == 0) v[6] = xr[384] + fq_apply(mr[384], s);
    lsum += v[6];
    #pragma unroll
    for (int o = 32; o > 0; o >>= 1) lsum += __shfl_xor(lsum, o);
    float mean = lsum / 385.f;
    float lvar = 0.f;
    #pragma unroll
    for (int k = 0; k < 6; k++) { float dd = v[k] - mean; lvar += dd * dd; }
    if (lane == 0) { float dd = v[6] - mean; lvar += dd * dd; }
    #pragma unroll
    for (int o = 32; o > 0; o >>= 1) lvar += __shfl_xor(lvar, o);
    float rs = 1.f / sqrtf(lvar / 385.f + 1e-5f);
    #pragma unroll
    for (int k = 0; k < 6; k++) {
      int c = lane + k * 64;
      float o2 = (v[k] - mean) * rs * g[c] + bta[c];
      mr[c] = o2;
      wmax = fmaxf(wmax, fabsf(o2));
    }
    if (lane == 0) {
      float o2 = (v[6] - mean) * rs * g[384] + bta[384];
      mr[384] = o2;
      wmax = fmaxf(wmax, fabsf(o2));
    }
  }
  blockAtomicMax(wmax, nextmax, smr);
}

// ---- mean pool over L (two-stage, coalesced, deterministic) ------------------
__global__ __launch_bounds__(256) void k_pool1(const float* __restrict__ x2,
                                               float* __restrict__ part) {
  int b = blockIdx.x, ch = blockIdx.y, tid = threadIdx.x;
  float s0 = 0.f, s1 = 0.f;
  for (int l = ch * 64; l < ch * 64 + 64; l++) {
    const float* row = x2 + ((long)b * L_ + l) * DM_;
    s0 += row[tid];
    if (tid < DM_ - 256) s1 += row[tid + 256];
  }
  long o = ((long)b * 20 + ch) * DM_;
  part[o + tid] = s0;
  if (tid < DM_ - 256) part[o + tid + 256] = s1;
}

__global__ void k_pool2(const float* __restrict__ part, float* __restrict__ pool,
                        float* __restrict__ nextmax) {
  __shared__ float smr[8];
  int idx = blockIdx.x * 256 + threadIdx.x;
  float mv = 0.f;
  if (idx < B_ * DM_) {
    int b = idx / DM_, c = idx % DM_;
    float s = 0.f;
    for (int ch = 0; ch < 20; ch++) s += part[((long)b * 20 + ch) * DM_ + c];
    float mean = s / (float)L_;
    pool[idx] = mean;
    mv = fabsf(mean);
  }
  blockAtomicMax(mv, nextmax, smr);
}

// ---- classifier (parallel): grid 32 = (b,c), 128 threads reduce over K=385 --
__global__ __launch_bounds__(128) void k_cls(const float* __restrict__ pool,
                                             const float* __restrict__ clsw,
                                             const float* __restrict__ clsb,
                                             const float* __restrict__ sp_,
                                             const float* __restrict__ sw_,
                                             float* __restrict__ out) {
  __shared__ float smr[2];
  int b = blockIdx.x >> 1, c = blockIdx.x & 1;
  float sp = fq_scale(sp_), sw = fq_scale(sw_);
  float acc = 0.f;
  for (int k = threadIdx.x; k < DM_; k += 128) {
    float xv = fq_apply(pool[b * DM_ + k], sp);
    float wv = fq_apply(clsw[k * 2 + c], sw);
    acc = fmaf(xv, wv, acc);
  }
  #pragma unroll
  for (int o = 32; o > 0; o >>= 1) acc += __shfl_down(acc, o);
  if ((threadIdx.x & 63) == 0) smr[threadIdx.x >> 6] = acc;
  __syncthreads();
  if (threadIdx.x == 0) out[blockIdx.x] = smr[0] + smr[1] + clsb[c];
}

// ---- launch ------------------------------------------------------------------
extern "C" void kernel_launch(void* const* d_in, const int* in_sizes, int n_in,
                              void* d_out, int out_size, void* d_ws, size_t ws_size,
                              hipStream_t stream) {
  const float* x    = (const float*)d_in[0];
  const float* pew  = (const float*)d_in[1];
  const float* peb  = (const float*)d_in[2];
  const float* pos  = (const float*)d_in[3];
  const float* in_w = (const float*)d_in[4];
  const float* cw   = (const float*)d_in[5];
  const float* cb   = (const float*)d_in[6];
  const float* xpw  = (const float*)d_in[7];
  const float* dtw  = (const float*)d_in[8];
  const float* dtb  = (const float*)d_in[9];
  const float* alog = (const float*)d_in[10];
  const float* dp   = (const float*)d_in[11];
  const float* outw = (const float*)d_in[12];
  const float* lng  = (const float*)d_in[13];
  const float* lnb  = (const float*)d_in[14];
  const float* clsw = (const float*)d_in[15];
  const float* clsb = (const float*)d_in[16];

  float* ws    = (float*)d_ws;
  float* SCAL  = ws;                              // 13 scalars x 128 floats (8 slots)
  float* P2    = ws + 2048;                       // 492,800
  float* X2    = P2 + LDM_;                       // 7,884,800
  float* XZ    = X2 + NX_;                        // 10,485,760
  float* XC    = XZ + (long)ROWS_ * 512;          // 2 x 5,242,880
  float* PROJ  = XC + 2L * ROWS_ * DI_;           // 2 x 675,840
  float* Y     = PROJ + 2L * ROWS_ * 33;          // 2 x 5,242,880
  float* MO    = Y + 2L * ROWS_ * DI_;            // 7,884,800
  float* POOL  = MO + NX_;                        // 8,192
  float* PART  = POOL + 8192;                     // 123,200 (+pad)
  float* A2IN_f= PART + 131072;                   // 4,096,000 f (ushort overlay)
  float* W2I_f = A2IN_f + 4096000;                // 409,600 f
  float* W2O_f = W2I_f + 409600;                  // 393,216 f
  // aliases (disjoint lifetimes):
  float*  HEND = MO;                              // scan summaries, dead before out-GEMM
  float*  PEND = MO + 2097152;
  float*  CARR = MO + 4194304;
  ushort* A2Y  = (ushort*)XZ;                     // [20480][512], dead before next in-GEMM
  ushort* A2IN = (ushort*)A2IN_f;                 // [20480][400]
  ushort* W2TI = (ushort*)W2I_f;                  // 2 x [512][800]
  ushort* W2TO = (ushort*)W2O_f;                  // 2 x [512][768]

  // scalar entry i lives at SCAL + i*SCALW (8 slots, 64B apart)
  #define SC(i) (SCAL + (i) * SCALW)

  k_zero<<<8, 256, 0, stream>>>(SCAL);

  // weight splits for MFMA GEMMs (tiny)
  for (int blk = 0; blk < 2; blk++) {
    k_wsplit<<<1600, 256, 0, stream>>>(in_w + (long)blk * DM_ * 512,
                                       W2TI + (long)blk * 512 * KPI_,
                                       DM_, 512, KPA_, KPI_, 512L * KPI_, 2);
    k_wsplit<<<1536, 256, 0, stream>>>(outw + (long)blk * DI_ * DM_,
                                       W2TO + (long)blk * 512 * KPO_,
                                       DI_, DM_, 256, KPO_, 512L * KPO_, 3);
  }
  k_padzero<<<1200, 256, 0, stream>>>(A2IN);

  // absmaxes + fused patch-embed (x and w fq'd inline)
  k_absmax<<<2048, 256, 0, stream>>>(x, (long)B_ * H_ * W_, SC(0));
  k_absmax<<<8, 256, 0, stream>>>(pew, EMB * 2 * 16, SC(1));
  k_absmax<<<512, 256, 0, stream>>>(pos, LDM_, SC(4));
  k_patchfq<<<dim3(20, 11, 16), 320, 0, stream>>>(x, pew, peb, SC(0), SC(1), X2, SC(2));

  // pos = fq(fq(pos_embed)) == fq(pos_embed)  (fq idempotent)
  k_fq4<<<512, 256, 0, stream>>>((const float4*)pos, (float4*)P2, LDM_ / 4,
                                 SC(4), nullptr, nullptr);

  // x = fq(fq(x) + pos) with inner fq(x) = fq(patch_out, s2) (outer chain identity)
  k_addpos4<<<2048, 256, 0, stream>>>((float4*)X2, (const float4*)P2, SC(2), SC(6));
  k_fq4<<<2048, 256, 0, stream>>>((const float4*)X2, (float4*)X2, NX_ / 4,
                                  SC(6), nullptr, A2IN);

  const float* in_scale[2] = {SC(6), SC(8)};
  for (int blk = 0; blk < 2; blk++) {
    // in-proj: XZ = s * (q @ [w_hi; w_lo])   (MFMA bf16, A k-wrapped at 400)
    k_mgemm<false><<<dim3(4, 160), 256, 0, stream>>>(
        A2IN, W2TI + (long)blk * 512 * KPI_, XZ, 512, KPI_, KPA_, in_scale[blk], nullptr);
    // conv (both dirs), xp-proj (both dirs), chunked scan (both dirs)
    k_conv<<<40960, 256, 0, stream>>>(XZ, cw + blk * DI_ * K_, cb + blk * DI_, XC);
    k_gemm<false><<<dim3(1, 640), 256, 0, stream>>>(
        XC, xpw + (long)blk * DI_ * 33, PROJ, 2 * ROWS_, 33, DI_, nullptr);
    k_scan1<<<dim3(CH_, B_, 2), 256, 0, stream>>>(XC, PROJ, alog + blk * DI_ * N_,
                                                  dtw + blk * DTR_ * DI_, dtb + blk * DI_,
                                                  HEND, PEND);
    k_carry<<<128, 256, 0, stream>>>(HEND, PEND, CARR);
    k_scan2<<<dim3(CH_, B_, 2), 256, 0, stream>>>(XC, PROJ, alog + blk * DI_ * N_,
                                                  dtw + blk * DTR_ * DI_, dtb + blk * DI_,
                                                  dp + blk * DI_, XZ, CARR, Y);
    // out-proj: MO = [y_hi | y_lo] (wrapped) @ [w_hi; w_hi; w_lo]  (amax fused)
    k_asplit2<<<40960, 256, 0, stream>>>(Y, A2Y);
    k_mgemm<true><<<dim3(4, 160), 256, 0, stream>>>(
        A2Y, W2TO + (long)blk * 512 * KPO_, MO, DM_, KPO_, WAO_, nullptr, SC(7 + blk * 2));
    // x = fq(layernorm(x + fq(mo))); emit q for next block's in-proj
    k_ln<<<640, 256, 0, stream>>>(X2, MO, SC(7 + blk * 2),
                                  lng + blk * DM_, lnb + blk * DM_, SC(8 + blk * 2));
    k_fq4<<<2048, 256, 0, stream>>>((const float4*)MO, (float4*)X2, NX_ / 4,
                                    SC(8 + blk * 2), nullptr,
                                    blk == 0 ? A2IN : nullptr);
  }

  // mean-pool (2-stage), fq, classifier with fq(cls_w)
  k_pool1<<<dim3(16, 20), 256, 0, stream>>>(X2, PART);
  k_pool2<<<25, 256, 0, stream>>>(PART, POOL, SC(11));
  k_absmax<<<4, 256, 0, stream>>>(clsw, DM_ * 2, SC(12));
  k_cls<<<32, 128, 0, stream>>>(POOL, clsw, clsb, SC(11), SC(12), (float*)d_out);
}

// Round 7
// 770.191 us; speedup vs baseline: 6.4826x; 1.1197x over previous
//
#include <hip/hip_runtime.h>
#include <hip/hip_bf16.h>
#include <math.h>

// ---- problem constants -----------------------------------------------------
#define B_    16
#define H_    22
#define W_    20480
#define EMB   35
#define GH_   11
#define GW_   1280
#define L_    1280
#define DM_   385
#define DI_   256
#define N_    4
#define K_    4
#define DTR_  25
#define ROWS_ (B_*L_)              // 20480
#define NX_   ((long)ROWS_*DM_)    // 7,884,800
#define LDM_  ((long)L_*DM_)       // 492,800
#define CH_   64                   // scan chunks
#define CHL_  20                   // steps per chunk (CH_*CHL_ == L_)
#define KPI_  800                  // in_proj W K' (2 terms x 400)
#define KPA_  400                  // in_proj A width (q stored once, padded)
#define KPO_  768                  // out_proj W K' (3 terms x 256)
#define WAO_  512                  // out_proj A width ({hi,lo})

// amax scalars: 8 slots x 64B apart to break single-address atomic serialization
#define NSLOT 8
#define SSTR  16                   // floats between slots (64 B)
#define SCALW 128                  // floats per logical scalar (8 slots)

typedef __attribute__((ext_vector_type(8))) short short8;
typedef __attribute__((ext_vector_type(4))) float f32x4;
typedef unsigned short ushort;

// ---- helpers ---------------------------------------------------------------
__device__ __forceinline__ void atomicMaxF(float* a, float v) {
  atomicMax(reinterpret_cast<int*>(a), __float_as_int(v));
}

// faithful fq: s = max(mx,1e-8)/127 where mx = max over the 8 slots
__device__ __forceinline__ float fq_scale(const float* pmax) {
  float m = pmax[0];
  #pragma unroll
  for (int i = 1; i < NSLOT; i++) m = fmaxf(m, pmax[i * SSTR]);
  return fmaxf(m, 1e-8f) / 127.f;
}
__device__ __forceinline__ float fq_apply(float x, float s) {
  float r = rintf(x / s);
  r = fminf(fmaxf(r, -128.f), 127.f);
  return r * s;
}

__device__ __forceinline__ ushort f2bf(float f) {  // round-to-nearest-even
  union { float f; unsigned u; } v; v.f = f;
  unsigned r = v.u + 0x7FFF + ((v.u >> 16) & 1);
  return (ushort)(r >> 16);
}
__device__ __forceinline__ float bf2f(ushort h) {
  union { unsigned u; float f; } v; v.u = ((unsigned)h) << 16;
  return v.f;
}

// block max -> atomicMax into one of 8 slots (by block id). sm >= blockDim/64.
__device__ __forceinline__ void blockAtomicMax(float v, float* out, float* sm) {
  #pragma unroll
  for (int o = 32; o > 0; o >>= 1) v = fmaxf(v, __shfl_down(v, o));
  if ((threadIdx.x & 63) == 0) sm[threadIdx.x >> 6] = v;
  __syncthreads();
  if (threadIdx.x == 0) {
    int nw = (blockDim.x + 63) >> 6;
    for (int i = 1; i < nw; i++) v = fmaxf(v, sm[i]);
    int slot = (blockIdx.x + blockIdx.y * 4 + blockIdx.z) & (NSLOT - 1);
    atomicMaxF(out + slot * SSTR, v);
  }
}

// ---- small utility kernels -------------------------------------------------
__global__ void k_zero(float* s) { s[blockIdx.x * 256 + threadIdx.x] = 0.f; }

__global__ void k_absmax(const float* __restrict__ src, long n, float* __restrict__ out) {
  __shared__ float smr[8];
  float m = 0.f;
  for (long i = (long)blockIdx.x * blockDim.x + threadIdx.x; i < n;
       i += (long)gridDim.x * blockDim.x)
    m = fmaxf(m, fabsf(src[i]));
  blockAtomicMax(m, out, smr);
}

// vectorized fq: dst4 = fq(src4); optional absmax -> nextmax; optional bf16
// q-emit into A2 [M][KPA_]. dst may == src.
__global__ void k_fq4(const float4* __restrict__ src, float4* __restrict__ dst, long n4,
                      const float* __restrict__ pmax, float* __restrict__ nextmax,
                      ushort* __restrict__ a2) {
  __shared__ float smr[8];
  float s = fq_scale(pmax);
  float m = 0.f;
  for (long i = (long)blockIdx.x * blockDim.x + threadIdx.x; i < n4;
       i += (long)gridDim.x * blockDim.x) {
    float4 v = src[i];
    float r0 = fminf(fmaxf(rintf(v.x / s), -128.f), 127.f);
    float r1 = fminf(fmaxf(rintf(v.y / s), -128.f), 127.f);
    float r2 = fminf(fmaxf(rintf(v.z / s), -128.f), 127.f);
    float r3 = fminf(fmaxf(rintf(v.w / s), -128.f), 127.f);
    float4 q = make_float4(r0 * s, r1 * s, r2 * s, r3 * s);
    dst[i] = q;
    m = fmaxf(m, fmaxf(fmaxf(fabsf(q.x), fabsf(q.y)), fmaxf(fabsf(q.z), fabsf(q.w))));
    if (a2) {
      long ii = i * 4;
      long mm = ii / 385; int kk = (int)(ii - mm * 385);
      float rr[4] = {r0, r1, r2, r3};
      #pragma unroll
      for (int j = 0; j < 4; j++) {
        a2[mm * KPA_ + kk] = f2bf(rr[j]);
        if (++kk == 385) { kk = 0; mm++; }
      }
    }
  }
  if (nextmax) blockAtomicMax(m, nextmax, smr);
}

// x4[i] = fq(x4[i], s_pmax) + p2[i % LDM/4]; absmax -> nextmax
// (the reference's extra fq() layers are identities: fq(fq(t)) == fq(t))
__global__ void k_addpos4(float4* __restrict__ x, const float4* __restrict__ p2,
                          const float* __restrict__ pmax, float* __restrict__ nextmax) {
  __shared__ float smr[8];
  float s = fq_scale(pmax);
  float m = 0.f;
  const long n4 = NX_ / 4, l4 = LDM_ / 4;
  for (long i = (long)blockIdx.x * blockDim.x + threadIdx.x; i < n4;
       i += (long)gridDim.x * blockDim.x) {
    float4 v = x[i];
    float4 p = p2[i % l4];
    float4 o;
    o.x = fq_apply(v.x, s) + p.x;
    o.y = fq_apply(v.y, s) + p.y;
    o.z = fq_apply(v.z, s) + p.z;
    o.w = fq_apply(v.w, s) + p.w;
    x[i] = o;
    m = fmaxf(m, fmaxf(fmaxf(fabsf(o.x), fabsf(o.y)), fmaxf(fabsf(o.z), fabsf(o.w))));
  }
  blockAtomicMax(m, nextmax, smr);
}

// ---- fused patch embed: LDS-staged x (fq inline), fq'd weights in VGPRs -----
// block = (gw-tile of 64, gh, b); 320 threads (280 active in compute)
__global__ __launch_bounds__(320) void k_patchfq(const float* __restrict__ x,
                                                 const float* __restrict__ pew,
                                                 const float* __restrict__ peb,
                                                 const float* __restrict__ sx_,
                                                 const float* __restrict__ sw_,
                                                 float* __restrict__ out,
                                                 float* __restrict__ nextmax) {
  __shared__ float xs[2][64][20];   // [ph][gw_local][pw] padded to 20
  __shared__ float smr[8];
  int tid = threadIdx.x;
  int gwt = blockIdx.x, gh = blockIdx.y, b = blockIdx.z;
  float sx = fq_scale(sx_), sw = fq_scale(sw_);
  if (tid < 256) {
    int gwl = tid >> 2, pw = (tid & 3) * 4;
    #pragma unroll
    for (int ph = 0; ph < 2; ph++) {
      const float* src = x + ((long)b * H_ + gh * 2 + ph) * W_ + (long)gwt * 1024 + tid * 4;
      float4 v = *reinterpret_cast<const float4*>(src);
      xs[ph][gwl][pw + 0] = fq_apply(v.x, sx);
      xs[ph][gwl][pw + 1] = fq_apply(v.y, sx);
      xs[ph][gwl][pw + 2] = fq_apply(v.z, sx);
      xs[ph][gwl][pw + 3] = fq_apply(v.w, sx);
    }
  }
  __syncthreads();
  float mx = 0.f;
  if (tid < 280) {
    int e = tid % 35;
    int g0 = (tid / 35) * 8;
    float w[32];
    #pragma unroll
    for (int j = 0; j < 32; j++) w[j] = fq_apply(pew[e * 32 + j], sw);
    float bias = peb[e];
    long obase = ((long)b * GW_ + (long)gwt * 64) * DM_ + gh * 35 + e;
    #pragma unroll
    for (int gi = 0; gi < 8; gi++) {
      int gw = g0 + gi;
      float acc = bias;
      #pragma unroll
      for (int pw = 0; pw < 16; pw++) {
        acc = fmaf(xs[0][gw][pw], w[pw], acc);
        acc = fmaf(xs[1][gw][pw], w[16 + pw], acc);
      }
      out[obase + (long)gw * DM_] = acc;
      mx = fmaxf(mx, fabsf(acc));
    }
  }
  blockAtomicMax(mx, nextmax, smr);
}

// ---- weight split: W[K][N] f32 -> W2T[Npad][Kp] bf16 ------------------------
// term t occupies cols [t*Kw, t*Kw+K); value = lo at t==terms-1 else hi.
__global__ void k_wsplit(const float* __restrict__ W, ushort* __restrict__ out,
                         int K, int N, int Kw, int Kp, long total, int terms) {
  long idx = (long)blockIdx.x * 256 + threadIdx.x;
  if (idx >= total) return;
  int k = (int)(idx % Kp);
  int n = (int)(idx / Kp);
  int t = k / Kw, kk = k - t * Kw;
  ushort r = 0;
  if (n < N && kk < K) {
    float w = W[(long)kk * N + n];
    ushort hi = f2bf(w);
    r = (t == terms - 1) ? f2bf(w - bf2f(hi)) : hi;
  }
  out[idx] = r;
}

// ---- activation split: (Y0+Y1)[M][256] f32 -> A2[M][512] bf16 {hi,lo} -------
__global__ void k_asplit2(const float* __restrict__ Y, ushort* __restrict__ A2) {
  long idx = (long)blockIdx.x * 256 + threadIdx.x;   // M*512 threads
  long m = idx >> 9; int k = (int)(idx & 511);
  int t = k >> 8, kk = k & 255;
  float v = Y[m * DI_ + kk] + Y[(m + ROWS_) * DI_ + kk];
  ushort hi = f2bf(v);
  A2[idx] = t ? f2bf(v - bf2f(hi)) : hi;
}

// zero the pad columns [385, 400) of A2IN
__global__ void k_padzero(ushort* __restrict__ A2) {
  long idx = (long)blockIdx.x * 256 + threadIdx.x;   // ROWS_*15 threads
  long m = idx / 15; int c = (int)(idx - m * 15);
  A2[m * KPA_ + 385 + c] = 0;
}

// ---- bf16 MFMA GEMM: C[M][Nreal] = scale * (A2[M][Wa,wrapped] @ W2T[Npad][Kp]^T)
// A column for global k is (k % Wa) -- A stores each distinct segment once.
// 128x128 tile, BK=32, 4 waves (2x2), 16x16x32 MFMA.
template<bool AMAX>
__global__ __launch_bounds__(256) void k_mgemm(const ushort* __restrict__ A2,
                                               const ushort* __restrict__ W2T,
                                               float* __restrict__ C,
                                               int Nreal, int Kp, int Wa,
                                               const float* __restrict__ sptr,
                                               float* __restrict__ amax_out) {
  __shared__ ushort Alds[4][128][8];   // [k-slot][row][8k] 8 KB
  __shared__ ushort Blds[4][128][8];   // [k-slot][col][8k] 8 KB
  __shared__ float smr[8];
  int tid = threadIdx.x;
  int lane = tid & 63, wave = tid >> 6;
  int wm = wave >> 1, wn = wave & 1;
  int m0 = blockIdx.y * 128, n0 = blockIdx.x * 128;
  f32x4 acc[4][4];
  #pragma unroll
  for (int i = 0; i < 4; i++)
    #pragma unroll
    for (int j = 0; j < 4; j++) acc[i][j] = (f32x4){0.f, 0.f, 0.f, 0.f};

  for (int k0 = 0; k0 < Kp; k0 += 32) {
    #pragma unroll
    for (int r = 0; r < 2; r++) {
      int id = tid + r * 256;            // 0..511
      int row = id >> 2, sl = id & 3;    // coalesced 64B global segments
      int kc = k0 + sl * 8; if (kc >= Wa) kc -= Wa;   // A k-wrap (8-aligned)
      short8 va = *reinterpret_cast<const short8*>(A2 + (long)(m0 + row) * Wa + kc);
      *reinterpret_cast<short8*>(&Alds[sl][row][0]) = va;
      short8 vb = *reinterpret_cast<const short8*>(W2T + (long)(n0 + row) * Kp + k0 + sl * 8);
      *reinterpret_cast<short8*>(&Blds[sl][row][0]) = vb;
    }
    __syncthreads();
    int sl = lane >> 4, rr = lane & 15;
    short8 af[4], bf4[4];
    #pragma unroll
    for (int i = 0; i < 4; i++)
      af[i] = *reinterpret_cast<const short8*>(&Alds[sl][wm * 64 + i * 16 + rr][0]);
    #pragma unroll
    for (int j = 0; j < 4; j++)
      bf4[j] = *reinterpret_cast<const short8*>(&Blds[sl][wn * 64 + j * 16 + rr][0]);
    #pragma unroll
    for (int i = 0; i < 4; i++)
      #pragma unroll
      for (int j = 0; j < 4; j++)
        acc[i][j] = __builtin_amdgcn_mfma_f32_16x16x32_bf16(af[i], bf4[j], acc[i][j], 0, 0, 0);
    __syncthreads();
  }

  float s = sptr ? fq_scale(sptr) : 1.0f;
  float mx = 0.f;
  int cfr = lane & 15, rbase = (lane >> 4) * 4;
  #pragma unroll
  for (int i = 0; i < 4; i++) {
    int gmb = m0 + wm * 64 + i * 16 + rbase;
    #pragma unroll
    for (int j = 0; j < 4; j++) {
      int gn = n0 + wn * 64 + j * 16 + cfr;
      if (gn < Nreal) {
        #pragma unroll
        for (int rg = 0; rg < 4; rg++) {
          float v = acc[i][j][rg] * s;
          C[(long)(gmb + rg) * Nreal + gn] = v;
          mx = fmaxf(mx, fabsf(v));
        }
      }
    }
  }
  if (AMAX) blockAtomicMax(mx, amax_out, smr);
}

// ---- generic fp32 tiled GEMM (skinny xp projection, both dirs batched) ------
template<bool AMAX>
__global__ __launch_bounds__(256) void k_gemm(const float* __restrict__ A,
                                              const float* __restrict__ W,
                                              float* __restrict__ C,
                                              int M, int N, int Kd,
                                              float* __restrict__ amax_out) {
  __shared__ __align__(16) float As[16][68];
  __shared__ __align__(16) float Bs[16][68];
  __shared__ float smr[8];
  int tx = threadIdx.x & 15, ty = threadIdx.x >> 4;
  int m0 = blockIdx.y * 64, n0 = blockIdx.x * 64;
  float acc[4][4] = {};
  for (int k0 = 0; k0 < Kd; k0 += 16) {
    #pragma unroll
    for (int r = 0; r < 4; r++) {
      int id = threadIdx.x + r * 256;
      int mm = id >> 4, kk = id & 15;
      int gm = m0 + mm, gk = k0 + kk;
      As[kk][mm] = (gm < M && gk < Kd) ? A[(long)gm * Kd + gk] : 0.f;
    }
    #pragma unroll
    for (int r = 0; r < 4; r++) {
      int id = threadIdx.x + r * 256;
      int kk = id >> 6, nn = id & 63;
      int gk = k0 + kk, gn = n0 + nn;
      Bs[kk][nn] = (gk < Kd && gn < N) ? W[(long)gk * N + gn] : 0.f;
    }
    __syncthreads();
    #pragma unroll
    for (int kk = 0; kk < 16; kk++) {
      float4 a4 = *reinterpret_cast<const float4*>(&As[kk][ty * 4]);
      float4 b4 = *reinterpret_cast<const float4*>(&Bs[kk][tx * 4]);
      float av[4] = {a4.x, a4.y, a4.z, a4.w};
      float bv[4] = {b4.x, b4.y, b4.z, b4.w};
      #pragma unroll
      for (int i = 0; i < 4; i++)
        #pragma unroll
        for (int j = 0; j < 4; j++)
          acc[i][j] = fmaf(av[i], bv[j], acc[i][j]);
    }
    __syncthreads();
  }
  float mx = 0.f;
  #pragma unroll
  for (int i = 0; i < 4; i++) {
    int gm = m0 + ty * 4 + i;
    if (gm < M) {
      #pragma unroll
      for (int j = 0; j < 4; j++) {
        int gn = n0 + tx * 4 + j;
        if (gn < N) {
          C[(long)gm * N + gn] = acc[i][j];
          mx = fmaxf(mx, fabsf(acc[i][j]));
        }
      }
    }
  }
  if (AMAX) blockAtomicMax(mx, amax_out, smr);
}

// ---- depthwise causal conv1d (K=4) + SiLU, both directions in one grid ------
__global__ void k_conv(const float* __restrict__ xz, const float* __restrict__ cw,
                       const float* __restrict__ cb, float* __restrict__ xcout) {
  long idx = (long)blockIdx.x * 256 + threadIdx.x;   // 2*B*L*DI threads
  int d = (int)(idx & 255);
  long rest = idx >> 8;                               // (dir, b, t)
  int dir = (int)(rest / (L_ * B_));
  int rem = (int)(rest - (long)dir * L_ * B_);
  int b = rem / L_, t = rem - (rem / L_) * L_;
  long base = (long)b * L_;
  float acc = cb[d];
  #pragma unroll
  for (int j = 0; j < K_; j++) {
    int tau = t - (K_ - 1) + j;
    if (tau >= 0) {
      int p = dir ? (L_ - 1 - tau) : tau;
      acc = fmaf(cw[d * K_ + j], xz[(base + p) * (2 * DI_) + d], acc);
    }
  }
  float sig = 1.f / (1.f + expf(-acc));
  int pt = dir ? (L_ - 1 - t) : t;
  xcout[((long)dir * ROWS_ + base + pt) * DI_ + d] = acc * sig;
}

// ---- dt precompute: dty[g][d] = softplus(proj[g][0:25] @ dtw[:,d] + dtb[d]) --
// g spans both dirs (2*ROWS rows). Written into the Y buffer (see aliasing note
// at k_scan2: scan2 reads dt then overwrites the same element with y).
__device__ __forceinline__ float softplusf(float x) {
  return fmaxf(x, 0.f) + log1pf(expf(-fabsf(x)));
}

__global__ __launch_bounds__(256) void k_dtp(const float* __restrict__ proj,
                                             const float* __restrict__ dtw,
                                             const float* __restrict__ dtb,
                                             float* __restrict__ dty) {
  __shared__ float pr[16][26];
  int d = threadIdx.x;
  long g0 = (long)blockIdx.x * 16;
  for (int i = threadIdx.x; i < 16 * DTR_; i += 256) {
    int r = i / DTR_, j = i - r * DTR_;
    pr[r][j] = proj[(g0 + r) * 33 + j];
  }
  float dwr[DTR_];
  #pragma unroll
  for (int r = 0; r < DTR_; r++) dwr[r] = dtw[r * DI_ + d];
  float dbv = dtb[d];
  __syncthreads();
  #pragma unroll
  for (int r = 0; r < 16; r++) {
    float acc = dbv;
    #pragma unroll
    for (int j = 0; j < DTR_; j++) acc = fmaf(pr[r][j], dwr[j], acc);
    dty[(g0 + r) * DI_ + d] = softplusf(acc);
  }
}

// ---- chunked parallel selective scan (dt preloaded, both dirs in grid.z) ----
__global__ __launch_bounds__(256) void k_scan1(const float* __restrict__ xc,
                                               const float* __restrict__ proj,
                                               const float* __restrict__ A_log,
                                               const float* __restrict__ dty,
                                               float* __restrict__ Hend,
                                               float* __restrict__ Pend) {
  int b = blockIdx.y, c = blockIdx.x, d = threadIdx.x, dir = blockIdx.z;
  float A[4];
  #pragma unroll
  for (int n = 0; n < 4; n++) A[n] = -expf(A_log[d * 4 + n]);
  long base = (long)b * L_;
  int step0 = c * CHL_;
  long row0 = base + (dir ? (L_ - 1 - step0) : step0);
  long doff = (long)dir * ROWS_;
  int rs = dir ? -1 : 1;
  long dstr = (long)rs * DI_;
  const float* pdt = dty + (doff + row0) * DI_ + d;
  const float* pxc = xc + (doff + row0) * DI_ + d;
  const float* pp  = proj + (doff + row0) * 33;
  float h[4] = {0.f, 0.f, 0.f, 0.f};
  float P[4] = {1.f, 1.f, 1.f, 1.f};
  for (int s = 0; s < CHL_; s++) {
    float dtv = *pdt;
    float xcv = *pxc;
    float dx = dtv * xcv;
    #pragma unroll
    for (int n = 0; n < 4; n++) {
      float dA = expf(dtv * A[n]);
      h[n] = dA * h[n] + dx * pp[DTR_ + n];
      P[n] *= dA;
    }
    pdt += dstr; pxc += dstr; pp += rs * 33;
  }
  long o = (((long)dir * B_ + b) * CH_ + c) * 1024 + d * 4;
  *reinterpret_cast<float4*>(Hend + o) = make_float4(h[0], h[1], h[2], h[3]);
  *reinterpret_cast<float4*>(Pend + o) = make_float4(P[0], P[1], P[2], P[3]);
}

__global__ __launch_bounds__(256) void k_carry(const float* __restrict__ Hend,
                                               const float* __restrict__ Pend,
                                               float* __restrict__ Carry) {
  int tid = blockIdx.x * 256 + threadIdx.x;   // 2*B_*1024 lanes
  int be = tid >> 10, i = tid & 1023;         // be = dir*16+b
  float carry = 0.f;
  for (int c = 0; c < CH_; c++) {
    long o = ((long)be * CH_ + c) * 1024 + i;
    Carry[o] = carry;
    carry = Pend[o] * carry + Hend[o];
  }
}

// dty holds dt on entry; each element is read once then overwritten with y
// by the unique owning thread (read-before-write, no cross-thread sharing).
__global__ __launch_bounds__(256) void k_scan2(const float* __restrict__ xc,
                                               const float* __restrict__ proj,
                                               const float* __restrict__ A_log,
                                               const float* __restrict__ Dp,
                                               const float* __restrict__ xz,
                                               const float* __restrict__ Carry,
                                               float* dty) {
  int b = blockIdx.y, c = blockIdx.x, d = threadIdx.x, dir = blockIdx.z;
  float A[4];
  #pragma unroll
  for (int n = 0; n < 4; n++) A[n] = -expf(A_log[d * 4 + n]);
  long base = (long)b * L_;
  int step0 = c * CHL_;
  long row0 = base + (dir ? (L_ - 1 - step0) : step0);
  long doff = (long)dir * ROWS_;
  int rs = dir ? -1 : 1;
  long dstr = (long)rs * DI_;
  float* pdy = dty + (doff + row0) * DI_ + d;
  const float* pxc = xc + (doff + row0) * DI_ + d;
  const float* pz  = xz + row0 * (2 * DI_) + DI_ + d;
  const float* pp  = proj + (doff + row0) * 33;
  long o = (((long)dir * B_ + b) * CH_ + c) * 1024 + d * 4;
  float4 cv = *reinterpret_cast<const float4*>(Carry + o);
  float h[4] = {cv.x, cv.y, cv.z, cv.w};
  float Dv = Dp[d];
  for (int s = 0; s < CHL_; s++) {
    float dtv = *pdy;
    float xcv = *pxc;
    float zv  = *pz;
    float dx = dtv * xcv;
    float acc = 0.f;
    #pragma unroll
    for (int n = 0; n < 4; n++) {
      float dA = expf(dtv * A[n]);
      h[n] = dA * h[n] + dx * pp[DTR_ + n];
      acc = fmaf(h[n], pp[DTR_ + N_ + n], acc);
    }
    float yv = fmaf(Dv, xcv, acc);
    float sig = 1.f / (1.f + expf(-zv));
    yv *= zv * sig;
    *pdy = yv;
    pdy += dstr; pxc += dstr; pz += rs * (2 * DI_); pp += rs * 33;
  }
}

// ---- residual + fq(mamba_out) + layernorm, wave-per-row ----------------------
// grid 640 x 256 (4 waves/block); each wave owns rows strided by 2560.
__global__ __launch_bounds__(256) void k_ln(const float* __restrict__ x2,
                                            float* __restrict__ mo,
                                            const float* __restrict__ smo,
                                            const float* __restrict__ g,
                                            const float* __restrict__ bta,
                                            float* __restrict__ nextmax) {
  __shared__ float smr[4];
  int lane = threadIdx.x & 63;
  int wid = blockIdx.x * 4 + (threadIdx.x >> 6);
  float s = fq_scale(smo);
  float wmax = 0.f;
  for (int row = wid; row < ROWS_; row += 2560) {
    const float* xr = x2 + (long)row * DM_;
    float* mr = mo + (long)row * DM_;
    float v[7];
    float lsum = 0.f;
    #pragma unroll
    for (int k = 0; k < 6; k++) {
      int c = lane + k * 64;
      v[k] = xr[c] + fq_apply(mr[c], s);
      lsum += v[k];
    }
    v[6] = 0.f;
    if (lane == 0) v[6] = xr[384] + fq_apply(mr[384], s);
    lsum += v[6];
    #pragma unroll
    for (int o = 32; o > 0; o >>= 1) lsum += __shfl_xor(lsum, o);
    float mean = lsum / 385.f;
    float lvar = 0.f;
    #pragma unroll
    for (int k = 0; k < 6; k++) { float dd = v[k] - mean; lvar += dd * dd; }
    if (lane == 0) { float dd = v[6] - mean; lvar += dd * dd; }
    #pragma unroll
    for (int o = 32; o > 0; o >>= 1) lvar += __shfl_xor(lvar, o);
    float rs = 1.f / sqrtf(lvar / 385.f + 1e-5f);
    #pragma unroll
    for (int k = 0; k < 6; k++) {
      int c = lane + k * 64;
      float o2 = (v[k] - mean) * rs * g[c] + bta[c];
      mr[c] = o2;
      wmax = fmaxf(wmax, fabsf(o2));
    }
    if (lane == 0) {
      float o2 = (v[6] - mean) * rs * g[384] + bta[384];
      mr[384] = o2;
      wmax = fmaxf(wmax, fabsf(o2));
    }
  }
  blockAtomicMax(wmax, nextmax, smr);
}

// ---- mean pool over L (two-stage, coalesced, deterministic) ------------------
__global__ __launch_bounds__(256) void k_pool1(const float* __restrict__ x2,
                                               float* __restrict__ part) {
  int b = blockIdx.x, ch = blockIdx.y, tid = threadIdx.x;
  float s0 = 0.f, s1 = 0.f;
  for (int l = ch * 64; l < ch * 64 + 64; l++) {
    const float* row = x2 + ((long)b * L_ + l) * DM_;
    s0 += row[tid];
    if (tid < DM_ - 256) s1 += row[tid + 256];
  }
  long o = ((long)b * 20 + ch) * DM_;
  part[o + tid] = s0;
  if (tid < DM_ - 256) part[o + tid + 256] = s1;
}

__global__ void k_pool2(const float* __restrict__ part, float* __restrict__ pool,
                        float* __restrict__ nextmax) {
  __shared__ float smr[8];
  int idx = blockIdx.x * 256 + threadIdx.x;
  float mv = 0.f;
  if (idx < B_ * DM_) {
    int b = idx / DM_, c = idx % DM_;
    float s = 0.f;
    for (int ch = 0; ch < 20; ch++) s += part[((long)b * 20 + ch) * DM_ + c];
    float mean = s / (float)L_;
    pool[idx] = mean;
    mv = fabsf(mean);
  }
  blockAtomicMax(mv, nextmax, smr);
}

// ---- classifier (parallel): grid 32 = (b,c), 128 threads reduce over K=385 --
__global__ __launch_bounds__(128) void k_cls(const float* __restrict__ pool,
                                             const float* __restrict__ clsw,
                                             const float* __restrict__ clsb,
                                             const float* __restrict__ sp_,
                                             const float* __restrict__ sw_,
                                             float* __restrict__ out) {
  __shared__ float smr[2];
  int b = blockIdx.x >> 1, c = blockIdx.x & 1;
  float sp = fq_scale(sp_), sw = fq_scale(sw_);
  float acc = 0.f;
  for (int k = threadIdx.x; k < DM_; k += 128) {
    float xv = fq_apply(pool[b * DM_ + k], sp);
    float wv = fq_apply(clsw[k * 2 + c], sw);
    acc = fmaf(xv, wv, acc);
  }
  #pragma unroll
  for (int o = 32; o > 0; o >>= 1) acc += __shfl_down(acc, o);
  if ((threadIdx.x & 63) == 0) smr[threadIdx.x >> 6] = acc;
  __syncthreads();
  if (threadIdx.x == 0) out[blockIdx.x] = smr[0] + smr[1] + clsb[c];
}

// ---- launch ------------------------------------------------------------------
extern "C" void kernel_launch(void* const* d_in, const int* in_sizes, int n_in,
                              void* d_out, int out_size, void* d_ws, size_t ws_size,
                              hipStream_t stream) {
  const float* x    = (const float*)d_in[0];
  const float* pew  = (const float*)d_in[1];
  const float* peb  = (const float*)d_in[2];
  const float* pos  = (const float*)d_in[3];
  const float* in_w = (const float*)d_in[4];
  const float* cw   = (const float*)d_in[5];
  const float* cb   = (const float*)d_in[6];
  const float* xpw  = (const float*)d_in[7];
  const float* dtw  = (const float*)d_in[8];
  const float* dtb  = (const float*)d_in[9];
  const float* alog = (const float*)d_in[10];
  const float* dp   = (const float*)d_in[11];
  const float* outw = (const float*)d_in[12];
  const float* lng  = (const float*)d_in[13];
  const float* lnb  = (const float*)d_in[14];
  const float* clsw = (const float*)d_in[15];
  const float* clsb = (const float*)d_in[16];

  float* ws    = (float*)d_ws;
  float* SCAL  = ws;                              // 13 scalars x 128 floats (8 slots)
  float* P2    = ws + 2048;                       // 492,800
  float* X2    = P2 + LDM_;                       // 7,884,800
  float* XZ    = X2 + NX_;                        // 10,485,760
  float* XC    = XZ + (long)ROWS_ * 512;          // 2 x 5,242,880
  float* PROJ  = XC + 2L * ROWS_ * DI_;           // 2 x 675,840
  float* Y     = PROJ + 2L * ROWS_ * 33;          // 2 x 5,242,880 (dt -> y in place)
  float* MO    = Y + 2L * ROWS_ * DI_;            // 7,884,800
  float* POOL  = MO + NX_;                        // 8,192
  float* PART  = POOL + 8192;                     // 123,200 (+pad)
  float* A2IN_f= PART + 131072;                   // 4,096,000 f (ushort overlay)
  float* W2I_f = A2IN_f + 4096000;                // 409,600 f
  float* W2O_f = W2I_f + 409600;                  // 393,216 f
  // aliases (disjoint lifetimes):
  float*  HEND = MO;                              // scan summaries, dead before out-GEMM
  float*  PEND = MO + 2097152;
  float*  CARR = MO + 4194304;
  ushort* A2Y  = (ushort*)XZ;                     // [20480][512], dead before next in-GEMM
  ushort* A2IN = (ushort*)A2IN_f;                 // [20480][400]
  ushort* W2TI = (ushort*)W2I_f;                  // 2 x [512][800]
  ushort* W2TO = (ushort*)W2O_f;                  // 2 x [512][768]

  // scalar entry i lives at SCAL + i*SCALW (8 slots, 64B apart)
  #define SC(i) (SCAL + (i) * SCALW)

  k_zero<<<8, 256, 0, stream>>>(SCAL);

  // weight splits for MFMA GEMMs (tiny)
  for (int blk = 0; blk < 2; blk++) {
    k_wsplit<<<1600, 256, 0, stream>>>(in_w + (long)blk * DM_ * 512,
                                       W2TI + (long)blk * 512 * KPI_,
                                       DM_, 512, KPA_, KPI_, 512L * KPI_, 2);
    k_wsplit<<<1536, 256, 0, stream>>>(outw + (long)blk * DI_ * DM_,
                                       W2TO + (long)blk * 512 * KPO_,
                                       DI_, DM_, 256, KPO_, 512L * KPO_, 3);
  }
  k_padzero<<<1200, 256, 0, stream>>>(A2IN);

  // absmaxes + fused patch-embed (x and w fq'd inline)
  k_absmax<<<2048, 256, 0, stream>>>(x, (long)B_ * H_ * W_, SC(0));
  k_absmax<<<8, 256, 0, stream>>>(pew, EMB * 2 * 16, SC(1));
  k_absmax<<<512, 256, 0, stream>>>(pos, LDM_, SC(4));
  k_patchfq<<<dim3(20, 11, 16), 320, 0, stream>>>(x, pew, peb, SC(0), SC(1), X2, SC(2));

  // pos = fq(fq(pos_embed)) == fq(pos_embed)  (fq idempotent)
  k_fq4<<<512, 256, 0, stream>>>((const float4*)pos, (float4*)P2, LDM_ / 4,
                                 SC(4), nullptr, nullptr);

  // x = fq(fq(x) + pos) with inner fq(x) = fq(patch_out, s2) (outer chain identity)
  k_addpos4<<<2048, 256, 0, stream>>>((float4*)X2, (const float4*)P2, SC(2), SC(6));
  k_fq4<<<2048, 256, 0, stream>>>((const float4*)X2, (float4*)X2, NX_ / 4,
                                  SC(6), nullptr, A2IN);

  const float* in_scale[2] = {SC(6), SC(8)};
  for (int blk = 0; blk < 2; blk++) {
    // in-proj: XZ = s * (q @ [w_hi; w_lo])   (MFMA bf16, A k-wrapped at 400)
    k_mgemm<false><<<dim3(4, 160), 256, 0, stream>>>(
        A2IN, W2TI + (long)blk * 512 * KPI_, XZ, 512, KPI_, KPA_, in_scale[blk], nullptr);
    // conv (both dirs), xp-proj (both dirs), dt precompute (into Y), chunked scan
    k_conv<<<40960, 256, 0, stream>>>(XZ, cw + blk * DI_ * K_, cb + blk * DI_, XC);
    k_gemm<false><<<dim3(1, 640), 256, 0, stream>>>(
        XC, xpw + (long)blk * DI_ * 33, PROJ, 2 * ROWS_, 33, DI_, nullptr);
    k_dtp<<<2560, 256, 0, stream>>>(PROJ, dtw + blk * DTR_ * DI_, dtb + blk * DI_, Y);
    k_scan1<<<dim3(CH_, B_, 2), 256, 0, stream>>>(XC, PROJ, alog + blk * DI_ * N_,
                                                  Y, HEND, PEND);
    k_carry<<<128, 256, 0, stream>>>(HEND, PEND, CARR);
    k_scan2<<<dim3(CH_, B_, 2), 256, 0, stream>>>(XC, PROJ, alog + blk * DI_ * N_,
                                                  dp + blk * DI_, XZ, CARR, Y);
    // out-proj: MO = [y_hi | y_lo] (wrapped) @ [w_hi; w_hi; w_lo]  (amax fused)
    k_asplit2<<<40960, 256, 0, stream>>>(Y, A2Y);
    k_mgemm<true><<<dim3(4, 160), 256, 0, stream>>>(
        A2Y, W2TO + (long)blk * 512 * KPO_, MO, DM_, KPO_, WAO_, nullptr, SC(7 + blk * 2));
    // x = fq(layernorm(x + fq(mo))); emit q for next block's in-proj
    k_ln<<<640, 256, 0, stream>>>(X2, MO, SC(7 + blk * 2),
                                  lng + blk * DM_, lnb + blk * DM_, SC(8 + blk * 2));
    k_fq4<<<2048, 256, 0, stream>>>((const float4*)MO, (float4*)X2, NX_ / 4,
                                    SC(8 + blk * 2), nullptr,
                                    blk == 0 ? A2IN : nullptr);
  }

  // mean-pool (2-stage), fq, classifier with fq(cls_w)
  k_pool1<<<dim3(16, 20), 256, 0, stream>>>(X2, PART);
  k_pool2<<<25, 256, 0, stream>>>(PART, POOL, SC(11));
  k_absmax<<<4, 256, 0, stream>>>(clsw, DM_ * 2, SC(12));
  k_cls<<<32, 128, 0, stream>>>(POOL, clsw, clsb, SC(11), SC(12), (float*)d_out);
}

// Round 8
// 697.206 us; speedup vs baseline: 7.1612x; 1.1047x over previous
//
#include <hip/hip_runtime.h>
#include <hip/hip_bf16.h>
#include <math.h>

// ---- problem constants -----------------------------------------------------
#define B_    16
#define H_    22
#define W_    20480
#define EMB   35
#define GH_   11
#define GW_   1280
#define L_    1280
#define DM_   385
#define DI_   256
#define N_    4
#define K_    4
#define DTR_  25
#define ROWS_ (B_*L_)              // 20480
#define NX_   ((long)ROWS_*DM_)    // 7,884,800
#define LDM_  ((long)L_*DM_)       // 492,800
#define CH_   64                   // scan chunks
#define CHL_  20                   // steps per chunk (CH_*CHL_ == L_)
#define KPI_  800                  // in_proj W K' (2 terms x 400)
#define KPA_  400                  // in_proj A width (q stored once, padded)
#define KPO_  768                  // out_proj W K' (3 terms x 256)
#define WAO_  512                  // out_proj A width ({hi,lo})

// amax scalars: 8 slots x 64B apart to break single-address atomic serialization
#define NSLOT 8
#define SSTR  16                   // floats between slots (64 B)
#define SCALW 128                  // floats per logical scalar (8 slots)

typedef __attribute__((ext_vector_type(8))) short short8;
typedef __attribute__((ext_vector_type(4))) float f32x4;
typedef unsigned short ushort;

// ---- helpers ---------------------------------------------------------------
__device__ __forceinline__ void atomicMaxF(float* a, float v) {
  atomicMax(reinterpret_cast<int*>(a), __float_as_int(v));
}

// faithful fq: s = max(mx,1e-8)/127 where mx = max over the 8 slots
__device__ __forceinline__ float fq_scale(const float* pmax) {
  float m = pmax[0];
  #pragma unroll
  for (int i = 1; i < NSLOT; i++) m = fmaxf(m, pmax[i * SSTR]);
  return fmaxf(m, 1e-8f) / 127.f;
}
__device__ __forceinline__ float fq_apply(float x, float s) {
  float r = rintf(x / s);
  r = fminf(fmaxf(r, -128.f), 127.f);
  return r * s;
}

__device__ __forceinline__ ushort f2bf(float f) {  // round-to-nearest-even
  union { float f; unsigned u; } v; v.f = f;
  unsigned r = v.u + 0x7FFF + ((v.u >> 16) & 1);
  return (ushort)(r >> 16);
}
__device__ __forceinline__ float bf2f(ushort h) {
  union { unsigned u; float f; } v; v.u = ((unsigned)h) << 16;
  return v.f;
}

// block max -> atomicMax into one of 8 slots (by block id). sm >= blockDim/64.
__device__ __forceinline__ void blockAtomicMax(float v, float* out, float* sm) {
  #pragma unroll
  for (int o = 32; o > 0; o >>= 1) v = fmaxf(v, __shfl_down(v, o));
  if ((threadIdx.x & 63) == 0) sm[threadIdx.x >> 6] = v;
  __syncthreads();
  if (threadIdx.x == 0) {
    int nw = (blockDim.x + 63) >> 6;
    for (int i = 1; i < nw; i++) v = fmaxf(v, sm[i]);
    int slot = (blockIdx.x + blockIdx.y * 4 + blockIdx.z) & (NSLOT - 1);
    atomicMaxF(out + slot * SSTR, v);
  }
}

// ---- small utility kernels -------------------------------------------------
__global__ void k_zero(float* s) { s[blockIdx.x * 256 + threadIdx.x] = 0.f; }

__global__ void k_absmax(const float* __restrict__ src, long n, float* __restrict__ out) {
  __shared__ float smr[8];
  float m = 0.f;
  for (long i = (long)blockIdx.x * blockDim.x + threadIdx.x; i < n;
       i += (long)gridDim.x * blockDim.x)
    m = fmaxf(m, fabsf(src[i]));
  blockAtomicMax(m, out, smr);
}

// vectorized fq: dst4 = fq(src4); optional absmax -> nextmax; optional bf16
// q-emit into A2 [M][KPA_]. dst may == src.
__global__ void k_fq4(const float4* __restrict__ src, float4* __restrict__ dst, long n4,
                      const float* __restrict__ pmax, float* __restrict__ nextmax,
                      ushort* __restrict__ a2) {
  __shared__ float smr[8];
  float s = fq_scale(pmax);
  float m = 0.f;
  for (long i = (long)blockIdx.x * blockDim.x + threadIdx.x; i < n4;
       i += (long)gridDim.x * blockDim.x) {
    float4 v = src[i];
    float r0 = fminf(fmaxf(rintf(v.x / s), -128.f), 127.f);
    float r1 = fminf(fmaxf(rintf(v.y / s), -128.f), 127.f);
    float r2 = fminf(fmaxf(rintf(v.z / s), -128.f), 127.f);
    float r3 = fminf(fmaxf(rintf(v.w / s), -128.f), 127.f);
    float4 q = make_float4(r0 * s, r1 * s, r2 * s, r3 * s);
    dst[i] = q;
    m = fmaxf(m, fmaxf(fmaxf(fabsf(q.x), fabsf(q.y)), fmaxf(fabsf(q.z), fabsf(q.w))));
    if (a2) {
      long ii = i * 4;
      long mm = ii / 385; int kk = (int)(ii - mm * 385);
      float rr[4] = {r0, r1, r2, r3};
      #pragma unroll
      for (int j = 0; j < 4; j++) {
        a2[mm * KPA_ + kk] = f2bf(rr[j]);
        if (++kk == 385) { kk = 0; mm++; }
      }
    }
  }
  if (nextmax) blockAtomicMax(m, nextmax, smr);
}

// x4[i] = fq(x4[i], s_pmax) + p2[i % LDM/4]; absmax -> nextmax
// (the reference's extra fq() layers are identities: fq(fq(t)) == fq(t))
__global__ void k_addpos4(float4* __restrict__ x, const float4* __restrict__ p2,
                          const float* __restrict__ pmax, float* __restrict__ nextmax) {
  __shared__ float smr[8];
  float s = fq_scale(pmax);
  float m = 0.f;
  const long n4 = NX_ / 4, l4 = LDM_ / 4;
  for (long i = (long)blockIdx.x * blockDim.x + threadIdx.x; i < n4;
       i += (long)gridDim.x * blockDim.x) {
    float4 v = x[i];
    float4 p = p2[i % l4];
    float4 o;
    o.x = fq_apply(v.x, s) + p.x;
    o.y = fq_apply(v.y, s) + p.y;
    o.z = fq_apply(v.z, s) + p.z;
    o.w = fq_apply(v.w, s) + p.w;
    x[i] = o;
    m = fmaxf(m, fmaxf(fmaxf(fabsf(o.x), fabsf(o.y)), fmaxf(fabsf(o.z), fabsf(o.w))));
  }
  blockAtomicMax(m, nextmax, smr);
}

// ---- fused patch embed: LDS-staged x (fq inline), fq'd weights in VGPRs -----
// block = (gw-tile of 64, gh, b); 320 threads (280 active in compute)
__global__ __launch_bounds__(320) void k_patchfq(const float* __restrict__ x,
                                                 const float* __restrict__ pew,
                                                 const float* __restrict__ peb,
                                                 const float* __restrict__ sx_,
                                                 const float* __restrict__ sw_,
                                                 float* __restrict__ out,
                                                 float* __restrict__ nextmax) {
  __shared__ float xs[2][64][20];   // [ph][gw_local][pw] padded to 20
  __shared__ float smr[8];
  int tid = threadIdx.x;
  int gwt = blockIdx.x, gh = blockIdx.y, b = blockIdx.z;
  float sx = fq_scale(sx_), sw = fq_scale(sw_);
  if (tid < 256) {
    int gwl = tid >> 2, pw = (tid & 3) * 4;
    #pragma unroll
    for (int ph = 0; ph < 2; ph++) {
      const float* src = x + ((long)b * H_ + gh * 2 + ph) * W_ + (long)gwt * 1024 + tid * 4;
      float4 v = *reinterpret_cast<const float4*>(src);
      xs[ph][gwl][pw + 0] = fq_apply(v.x, sx);
      xs[ph][gwl][pw + 1] = fq_apply(v.y, sx);
      xs[ph][gwl][pw + 2] = fq_apply(v.z, sx);
      xs[ph][gwl][pw + 3] = fq_apply(v.w, sx);
    }
  }
  __syncthreads();
  float mx = 0.f;
  if (tid < 280) {
    int e = tid % 35;
    int g0 = (tid / 35) * 8;
    float w[32];
    #pragma unroll
    for (int j = 0; j < 32; j++) w[j] = fq_apply(pew[e * 32 + j], sw);
    float bias = peb[e];
    long obase = ((long)b * GW_ + (long)gwt * 64) * DM_ + gh * 35 + e;
    #pragma unroll
    for (int gi = 0; gi < 8; gi++) {
      int gw = g0 + gi;
      float acc = bias;
      #pragma unroll
      for (int pw = 0; pw < 16; pw++) {
        acc = fmaf(xs[0][gw][pw], w[pw], acc);
        acc = fmaf(xs[1][gw][pw], w[16 + pw], acc);
      }
      out[obase + (long)gw * DM_] = acc;
      mx = fmaxf(mx, fabsf(acc));
    }
  }
  blockAtomicMax(mx, nextmax, smr);
}

// ---- weight split: W[K][N] f32 -> W2T[Npad][Kp] bf16 ------------------------
// term t occupies cols [t*Kw, t*Kw+K); value = lo at t==terms-1 else hi.
__global__ void k_wsplit(const float* __restrict__ W, ushort* __restrict__ out,
                         int K, int N, int Kw, int Kp, long total, int terms) {
  long idx = (long)blockIdx.x * 256 + threadIdx.x;
  if (idx >= total) return;
  int k = (int)(idx % Kp);
  int n = (int)(idx / Kp);
  int t = k / Kw, kk = k - t * Kw;
  ushort r = 0;
  if (n < N && kk < K) {
    float w = W[(long)kk * N + n];
    ushort hi = f2bf(w);
    r = (t == terms - 1) ? f2bf(w - bf2f(hi)) : hi;
  }
  out[idx] = r;
}

// ---- activation split: (Y0+Y1)[M][256] f32 -> A2[M][512] bf16 {hi,lo} -------
__global__ void k_asplit2(const float* __restrict__ Y, ushort* __restrict__ A2) {
  long idx = (long)blockIdx.x * 256 + threadIdx.x;   // M*512 threads
  long m = idx >> 9; int k = (int)(idx & 511);
  int t = k >> 8, kk = k & 255;
  float v = Y[m * DI_ + kk] + Y[(m + ROWS_) * DI_ + kk];
  ushort hi = f2bf(v);
  A2[idx] = t ? f2bf(v - bf2f(hi)) : hi;
}

// zero the pad columns [385, 400) of A2IN
__global__ void k_padzero(ushort* __restrict__ A2) {
  long idx = (long)blockIdx.x * 256 + threadIdx.x;   // ROWS_*15 threads
  long m = idx / 15; int c = (int)(idx - m * 15);
  A2[m * KPA_ + 385 + c] = 0;
}

// ---- bf16 MFMA GEMM: C[M][Nreal] = scale * (A2[M][Wa,wrapped] @ W2T[Npad][Kp]^T)
// A column for global k is (k % Wa) -- A stores each distinct segment once.
// 128x128 tile, BK=32, 4 waves (2x2), 16x16x32 MFMA.
template<bool AMAX>
__global__ __launch_bounds__(256) void k_mgemm(const ushort* __restrict__ A2,
                                               const ushort* __restrict__ W2T,
                                               float* __restrict__ C,
                                               int Nreal, int Kp, int Wa,
                                               const float* __restrict__ sptr,
                                               float* __restrict__ amax_out) {
  __shared__ ushort Alds[4][128][8];   // [k-slot][row][8k] 8 KB
  __shared__ ushort Blds[4][128][8];   // [k-slot][col][8k] 8 KB
  __shared__ float smr[8];
  int tid = threadIdx.x;
  int lane = tid & 63, wave = tid >> 6;
  int wm = wave >> 1, wn = wave & 1;
  int m0 = blockIdx.y * 128, n0 = blockIdx.x * 128;
  f32x4 acc[4][4];
  #pragma unroll
  for (int i = 0; i < 4; i++)
    #pragma unroll
    for (int j = 0; j < 4; j++) acc[i][j] = (f32x4){0.f, 0.f, 0.f, 0.f};

  for (int k0 = 0; k0 < Kp; k0 += 32) {
    #pragma unroll
    for (int r = 0; r < 2; r++) {
      int id = tid + r * 256;            // 0..511
      int row = id >> 2, sl = id & 3;    // coalesced 64B global segments
      int kc = k0 + sl * 8; if (kc >= Wa) kc -= Wa;   // A k-wrap (8-aligned)
      short8 va = *reinterpret_cast<const short8*>(A2 + (long)(m0 + row) * Wa + kc);
      *reinterpret_cast<short8*>(&Alds[sl][row][0]) = va;
      short8 vb = *reinterpret_cast<const short8*>(W2T + (long)(n0 + row) * Kp + k0 + sl * 8);
      *reinterpret_cast<short8*>(&Blds[sl][row][0]) = vb;
    }
    __syncthreads();
    int sl = lane >> 4, rr = lane & 15;
    short8 af[4], bf4[4];
    #pragma unroll
    for (int i = 0; i < 4; i++)
      af[i] = *reinterpret_cast<const short8*>(&Alds[sl][wm * 64 + i * 16 + rr][0]);
    #pragma unroll
    for (int j = 0; j < 4; j++)
      bf4[j] = *reinterpret_cast<const short8*>(&Blds[sl][wn * 64 + j * 16 + rr][0]);
    #pragma unroll
    for (int i = 0; i < 4; i++)
      #pragma unroll
      for (int j = 0; j < 4; j++)
        acc[i][j] = __builtin_amdgcn_mfma_f32_16x16x32_bf16(af[i], bf4[j], acc[i][j], 0, 0, 0);
    __syncthreads();
  }

  float s = sptr ? fq_scale(sptr) : 1.0f;
  float mx = 0.f;
  int cfr = lane & 15, rbase = (lane >> 4) * 4;
  #pragma unroll
  for (int i = 0; i < 4; i++) {
    int gmb = m0 + wm * 64 + i * 16 + rbase;
    #pragma unroll
    for (int j = 0; j < 4; j++) {
      int gn = n0 + wn * 64 + j * 16 + cfr;
      if (gn < Nreal) {
        #pragma unroll
        for (int rg = 0; rg < 4; rg++) {
          float v = acc[i][j][rg] * s;
          C[(long)(gmb + rg) * Nreal + gn] = v;
          mx = fmaxf(mx, fabsf(v));
        }
      }
    }
  }
  if (AMAX) blockAtomicMax(mx, amax_out, smr);
}

// ---- generic fp32 tiled GEMM (skinny xp projection, both dirs batched) ------
template<bool AMAX>
__global__ __launch_bounds__(256) void k_gemm(const float* __restrict__ A,
                                              const float* __restrict__ W,
                                              float* __restrict__ C,
                                              int M, int N, int Kd,
                                              float* __restrict__ amax_out) {
  __shared__ __align__(16) float As[16][68];
  __shared__ __align__(16) float Bs[16][68];
  __shared__ float smr[8];
  int tx = threadIdx.x & 15, ty = threadIdx.x >> 4;
  int m0 = blockIdx.y * 64, n0 = blockIdx.x * 64;
  float acc[4][4] = {};
  for (int k0 = 0; k0 < Kd; k0 += 16) {
    #pragma unroll
    for (int r = 0; r < 4; r++) {
      int id = threadIdx.x + r * 256;
      int mm = id >> 4, kk = id & 15;
      int gm = m0 + mm, gk = k0 + kk;
      As[kk][mm] = (gm < M && gk < Kd) ? A[(long)gm * Kd + gk] : 0.f;
    }
    #pragma unroll
    for (int r = 0; r < 4; r++) {
      int id = threadIdx.x + r * 256;
      int kk = id >> 6, nn = id & 63;
      int gk = k0 + kk, gn = n0 + nn;
      Bs[kk][nn] = (gk < Kd && gn < N) ? W[(long)gk * N + gn] : 0.f;
    }
    __syncthreads();
    #pragma unroll
    for (int kk = 0; kk < 16; kk++) {
      float4 a4 = *reinterpret_cast<const float4*>(&As[kk][ty * 4]);
      float4 b4 = *reinterpret_cast<const float4*>(&Bs[kk][tx * 4]);
      float av[4] = {a4.x, a4.y, a4.z, a4.w};
      float bv[4] = {b4.x, b4.y, b4.z, b4.w};
      #pragma unroll
      for (int i = 0; i < 4; i++)
        #pragma unroll
        for (int j = 0; j < 4; j++)
          acc[i][j] = fmaf(av[i], bv[j], acc[i][j]);
    }
    __syncthreads();
  }
  float mx = 0.f;
  #pragma unroll
  for (int i = 0; i < 4; i++) {
    int gm = m0 + ty * 4 + i;
    if (gm < M) {
      #pragma unroll
      for (int j = 0; j < 4; j++) {
        int gn = n0 + tx * 4 + j;
        if (gn < N) {
          C[(long)gm * N + gn] = acc[i][j];
          mx = fmaxf(mx, fabsf(acc[i][j]));
        }
      }
    }
  }
  if (AMAX) blockAtomicMax(mx, amax_out, smr);
}

// ---- depthwise causal conv1d (K=4) + SiLU, BOTH dirs from one window --------
// block = (t-tile of 16, b); thread = channel d. Window x[t0-3 .. t0+18] in
// registers (zero-filled at edges == reference zero-pad for both boundaries).
// dir0: xc0[t] = silu(cb + sum_j w[j]*x[t-3+j])
// dir1: xc1[p] = silu(cb + sum_j w[j]*x[p+3-j])  (taps beyond L-1 dropped)
__global__ __launch_bounds__(256) void k_conv2(const float* __restrict__ xz,
                                               const float* __restrict__ cw,
                                               const float* __restrict__ cb,
                                               float* __restrict__ xcout) {
  int d = threadIdx.x;
  int t0 = blockIdx.x * 16, b = blockIdx.y;
  long base = (long)b * L_;
  float w0 = cw[d * 4 + 0], w1 = cw[d * 4 + 1];
  float w2 = cw[d * 4 + 2], w3 = cw[d * 4 + 3];
  float bias = cb[d];
  float win[22];
  #pragma unroll
  for (int i = 0; i < 22; i++) {
    int t = t0 - 3 + i;
    win[i] = (t >= 0 && t < L_) ? xz[(base + t) * (2 * DI_) + d] : 0.f;
  }
  #pragma unroll
  for (int i = 0; i < 16; i++) {
    int t = t0 + i;
    // dir0, j ascending (bit-identical order to previous version)
    float a0 = bias;
    a0 = fmaf(w0, win[i + 0], a0);
    a0 = fmaf(w1, win[i + 1], a0);
    a0 = fmaf(w2, win[i + 2], a0);
    a0 = fmaf(w3, win[i + 3], a0);
    // dir1, j ascending: w0*x[t+3], w1*x[t+2], w2*x[t+1], w3*x[t]
    float a1 = bias;
    a1 = fmaf(w0, win[i + 6], a1);
    a1 = fmaf(w1, win[i + 5], a1);
    a1 = fmaf(w2, win[i + 4], a1);
    a1 = fmaf(w3, win[i + 3], a1);
    float s0 = 1.f / (1.f + expf(-a0));
    float s1 = 1.f / (1.f + expf(-a1));
    long o = (base + t) * DI_ + d;
    xcout[o] = a0 * s0;
    xcout[(long)ROWS_ * DI_ + o] = a1 * s1;
  }
}

// ---- dt precompute: dty[g][d] = softplus(proj[g][0:25] @ dtw[:,d] + dtb[d]) --
// g spans both dirs (2*ROWS rows). Written into the Y buffer (see aliasing note
// at k_scan2: scan2 reads dt then overwrites the same element with y).
__device__ __forceinline__ float softplusf(float x) {
  return fmaxf(x, 0.f) + log1pf(expf(-fabsf(x)));
}

__global__ __launch_bounds__(256) void k_dtp(const float* __restrict__ proj,
                                             const float* __restrict__ dtw,
                                             const float* __restrict__ dtb,
                                             float* __restrict__ dty) {
  __shared__ float pr[16][26];
  int d = threadIdx.x;
  long g0 = (long)blockIdx.x * 16;
  for (int i = threadIdx.x; i < 16 * DTR_; i += 256) {
    int r = i / DTR_, j = i - r * DTR_;
    pr[r][j] = proj[(g0 + r) * 33 + j];
  }
  float dwr[DTR_];
  #pragma unroll
  for (int r = 0; r < DTR_; r++) dwr[r] = dtw[r * DI_ + d];
  float dbv = dtb[d];
  __syncthreads();
  #pragma unroll
  for (int r = 0; r < 16; r++) {
    float acc = dbv;
    #pragma unroll
    for (int j = 0; j < DTR_; j++) acc = fmaf(pr[r][j], dwr[j], acc);
    dty[(g0 + r) * DI_ + d] = softplusf(acc);
  }
}

// ---- chunked parallel selective scan (dt preloaded, both dirs in grid.z) ----
__global__ __launch_bounds__(256) void k_scan1(const float* __restrict__ xc,
                                               const float* __restrict__ proj,
                                               const float* __restrict__ A_log,
                                               const float* __restrict__ dty,
                                               float* __restrict__ Hend,
                                               float* __restrict__ Pend) {
  int b = blockIdx.y, c = blockIdx.x, d = threadIdx.x, dir = blockIdx.z;
  float A[4];
  #pragma unroll
  for (int n = 0; n < 4; n++) A[n] = -expf(A_log[d * 4 + n]);
  long base = (long)b * L_;
  int step0 = c * CHL_;
  long row0 = base + (dir ? (L_ - 1 - step0) : step0);
  long doff = (long)dir * ROWS_;
  int rs = dir ? -1 : 1;
  long dstr = (long)rs * DI_;
  const float* pdt = dty + (doff + row0) * DI_ + d;
  const float* pxc = xc + (doff + row0) * DI_ + d;
  const float* pp  = proj + (doff + row0) * 33;
  float h[4] = {0.f, 0.f, 0.f, 0.f};
  float P[4] = {1.f, 1.f, 1.f, 1.f};
  for (int s = 0; s < CHL_; s++) {
    float dtv = *pdt;
    float xcv = *pxc;
    float dx = dtv * xcv;
    #pragma unroll
    for (int n = 0; n < 4; n++) {
      float dA = expf(dtv * A[n]);
      h[n] = dA * h[n] + dx * pp[DTR_ + n];
      P[n] *= dA;
    }
    pdt += dstr; pxc += dstr; pp += rs * 33;
  }
  long o = (((long)dir * B_ + b) * CH_ + c) * 1024 + d * 4;
  *reinterpret_cast<float4*>(Hend + o) = make_float4(h[0], h[1], h[2], h[3]);
  *reinterpret_cast<float4*>(Pend + o) = make_float4(P[0], P[1], P[2], P[3]);
}

__global__ __launch_bounds__(256) void k_carry(const float* __restrict__ Hend,
                                               const float* __restrict__ Pend,
                                               float* __restrict__ Carry) {
  int tid = blockIdx.x * 256 + threadIdx.x;   // 2*B_*1024 lanes
  int be = tid >> 10, i = tid & 1023;         // be = dir*16+b
  float carry = 0.f;
  for (int c = 0; c < CH_; c++) {
    long o = ((long)be * CH_ + c) * 1024 + i;
    Carry[o] = carry;
    carry = Pend[o] * carry + Hend[o];
  }
}

// dty holds dt on entry; each element is read once then overwritten with y
// by the unique owning thread (read-before-write, no cross-thread sharing).
__global__ __launch_bounds__(256) void k_scan2(const float* __restrict__ xc,
                                               const float* __restrict__ proj,
                                               const float* __restrict__ A_log,
                                               const float* __restrict__ Dp,
                                               const float* __restrict__ xz,
                                               const float* __restrict__ Carry,
                                               float* dty) {
  int b = blockIdx.y, c = blockIdx.x, d = threadIdx.x, dir = blockIdx.z;
  float A[4];
  #pragma unroll
  for (int n = 0; n < 4; n++) A[n] = -expf(A_log[d * 4 + n]);
  long base = (long)b * L_;
  int step0 = c * CHL_;
  long row0 = base + (dir ? (L_ - 1 - step0) : step0);
  long doff = (long)dir * ROWS_;
  int rs = dir ? -1 : 1;
  long dstr = (long)rs * DI_;
  float* pdy = dty + (doff + row0) * DI_ + d;
  const float* pxc = xc + (doff + row0) * DI_ + d;
  const float* pz  = xz + row0 * (2 * DI_) + DI_ + d;
  const float* pp  = proj + (doff + row0) * 33;
  long o = (((long)dir * B_ + b) * CH_ + c) * 1024 + d * 4;
  float4 cv = *reinterpret_cast<const float4*>(Carry + o);
  float h[4] = {cv.x, cv.y, cv.z, cv.w};
  float Dv = Dp[d];
  for (int s = 0; s < CHL_; s++) {
    float dtv = *pdy;
    float xcv = *pxc;
    float zv  = *pz;
    float dx = dtv * xcv;
    float acc = 0.f;
    #pragma unroll
    for (int n = 0; n < 4; n++) {
      float dA = expf(dtv * A[n]);
      h[n] = dA * h[n] + dx * pp[DTR_ + n];
      acc = fmaf(h[n], pp[DTR_ + N_ + n], acc);
    }
    float yv = fmaf(Dv, xcv, acc);
    float sig = 1.f / (1.f + expf(-zv));
    yv *= zv * sig;
    *pdy = yv;
    pdy += dstr; pxc += dstr; pz += rs * (2 * DI_); pp += rs * 33;
  }
}

// ---- residual + fq(mamba_out) + layernorm, wave-per-row ----------------------
// grid 640 x 256 (4 waves/block); each wave owns rows strided by 2560.
__global__ __launch_bounds__(256) void k_ln(const float* __restrict__ x2,
                                            float* __restrict__ mo,
                                            const float* __restrict__ smo,
                                            const float* __restrict__ g,
                                            const float* __restrict__ bta,
                                            float* __restrict__ nextmax) {
  __shared__ float smr[4];
  int lane = threadIdx.x & 63;
  int wid = blockIdx.x * 4 + (threadIdx.x >> 6);
  float s = fq_scale(smo);
  float wmax = 0.f;
  for (int row = wid; row < ROWS_; row += 2560) {
    const float* xr = x2 + (long)row * DM_;
    float* mr = mo + (long)row * DM_;
    float v[7];
    float lsum = 0.f;
    #pragma unroll
    for (int k = 0; k < 6; k++) {
      int c = lane + k * 64;
      v[k] = xr[c] + fq_apply(mr[c], s);
      lsum += v[k];
    }
    v[6] = 0.f;
    if (lane == 0) v[6] = xr[384] + fq_apply(mr[384], s);
    lsum += v[6];
    #pragma unroll
    for (int o = 32; o > 0; o >>= 1) lsum += __shfl_xor(lsum, o);
    float mean = lsum / 385.f;
    float lvar = 0.f;
    #pragma unroll
    for (int k = 0; k < 6; k++) { float dd = v[k] - mean; lvar += dd * dd; }
    if (lane == 0) { float dd = v[6] - mean; lvar += dd * dd; }
    #pragma unroll
    for (int o = 32; o > 0; o >>= 1) lvar += __shfl_xor(lvar, o);
    float rs = 1.f / sqrtf(lvar / 385.f + 1e-5f);
    #pragma unroll
    for (int k = 0; k < 6; k++) {
      int c = lane + k * 64;
      float o2 = (v[k] - mean) * rs * g[c] + bta[c];
      mr[c] = o2;
      wmax = fmaxf(wmax, fabsf(o2));
    }
    if (lane == 0) {
      float o2 = (v[6] - mean) * rs * g[384] + bta[384];
      mr[384] = o2;
      wmax = fmaxf(wmax, fabsf(o2));
    }
  }
  blockAtomicMax(wmax, nextmax, smr);
}

// ---- mean pool over L (two-stage, coalesced, deterministic) ------------------
__global__ __launch_bounds__(256) void k_pool1(const float* __restrict__ x2,
                                               float* __restrict__ part) {
  int b = blockIdx.x, ch = blockIdx.y, tid = threadIdx.x;
  float s0 = 0.f, s1 = 0.f;
  for (int l = ch * 64; l < ch * 64 + 64; l++) {
    const float* row = x2 + ((long)b * L_ + l) * DM_;
    s0 += row[tid];
    if (tid < DM_ - 256) s1 += row[tid + 256];
  }
  long o = ((long)b * 20 + ch) * DM_;
  part[o + tid] = s0;
  if (tid < DM_ - 256) part[o + tid + 256] = s1;
}

__global__ void k_pool2(const float* __restrict__ part, float* __restrict__ pool,
                        float* __restrict__ nextmax) {
  __shared__ float smr[8];
  int idx = blockIdx.x * 256 + threadIdx.x;
  float mv = 0.f;
  if (idx < B_ * DM_) {
    int b = idx / DM_, c = idx % DM_;
    float s = 0.f;
    for (int ch = 0; ch < 20; ch++) s += part[((long)b * 20 + ch) * DM_ + c];
    float mean = s / (float)L_;
    pool[idx] = mean;
    mv = fabsf(mean);
  }
  blockAtomicMax(mv, nextmax, smr);
}

// ---- classifier (parallel): grid 32 = (b,c), 128 threads reduce over K=385 --
__global__ __launch_bounds__(128) void k_cls(const float* __restrict__ pool,
                                             const float* __restrict__ clsw,
                                             const float* __restrict__ clsb,
                                             const float* __restrict__ sp_,
                                             const float* __restrict__ sw_,
                                             float* __restrict__ out) {
  __shared__ float smr[2];
  int b = blockIdx.x >> 1, c = blockIdx.x & 1;
  float sp = fq_scale(sp_), sw = fq_scale(sw_);
  float acc = 0.f;
  for (int k = threadIdx.x; k < DM_; k += 128) {
    float xv = fq_apply(pool[b * DM_ + k], sp);
    float wv = fq_apply(clsw[k * 2 + c], sw);
    acc = fmaf(xv, wv, acc);
  }
  #pragma unroll
  for (int o = 32; o > 0; o >>= 1) acc += __shfl_down(acc, o);
  if ((threadIdx.x & 63) == 0) smr[threadIdx.x >> 6] = acc;
  __syncthreads();
  if (threadIdx.x == 0) out[blockIdx.x] = smr[0] + smr[1] + clsb[c];
}

// ---- launch ------------------------------------------------------------------
extern "C" void kernel_launch(void* const* d_in, const int* in_sizes, int n_in,
                              void* d_out, int out_size, void* d_ws, size_t ws_size,
                              hipStream_t stream) {
  const float* x    = (const float*)d_in[0];
  const float* pew  = (const float*)d_in[1];
  const float* peb  = (const float*)d_in[2];
  const float* pos  = (const float*)d_in[3];
  const float* in_w = (const float*)d_in[4];
  const float* cw   = (const float*)d_in[5];
  const float* cb   = (const float*)d_in[6];
  const float* xpw  = (const float*)d_in[7];
  const float* dtw  = (const float*)d_in[8];
  const float* dtb  = (const float*)d_in[9];
  const float* alog = (const float*)d_in[10];
  const float* dp   = (const float*)d_in[11];
  const float* outw = (const float*)d_in[12];
  const float* lng  = (const float*)d_in[13];
  const float* lnb  = (const float*)d_in[14];
  const float* clsw = (const float*)d_in[15];
  const float* clsb = (const float*)d_in[16];

  float* ws    = (float*)d_ws;
  float* SCAL  = ws;                              // 13 scalars x 128 floats (8 slots)
  float* P2    = ws + 2048;                       // 492,800
  float* X2    = P2 + LDM_;                       // 7,884,800
  float* XZ    = X2 + NX_;                        // 10,485,760
  float* XC    = XZ + (long)ROWS_ * 512;          // 2 x 5,242,880
  float* PROJ  = XC + 2L * ROWS_ * DI_;           // 2 x 675,840
  float* Y     = PROJ + 2L * ROWS_ * 33;          // 2 x 5,242,880 (dt -> y in place)
  float* MO    = Y + 2L * ROWS_ * DI_;            // 7,884,800
  float* POOL  = MO + NX_;                        // 8,192
  float* PART  = POOL + 8192;                     // 123,200 (+pad)
  float* A2IN_f= PART + 131072;                   // 4,096,000 f (ushort overlay)
  float* W2I_f = A2IN_f + 4096000;                // 409,600 f
  float* W2O_f = W2I_f + 409600;                  // 393,216 f
  // aliases (disjoint lifetimes):
  float*  HEND = MO;                              // scan summaries, dead before out-GEMM
  float*  PEND = MO + 2097152;
  float*  CARR = MO + 4194304;
  ushort* A2Y  = (ushort*)XZ;                     // [20480][512], dead before next in-GEMM
  ushort* A2IN = (ushort*)A2IN_f;                 // [20480][400]
  ushort* W2TI = (ushort*)W2I_f;                  // 2 x [512][800]
  ushort* W2TO = (ushort*)W2O_f;                  // 2 x [512][768]

  // scalar entry i lives at SCAL + i*SCALW (8 slots, 64B apart)
  #define SC(i) (SCAL + (i) * SCALW)

  k_zero<<<8, 256, 0, stream>>>(SCAL);

  // weight splits for MFMA GEMMs (tiny)
  for (int blk = 0; blk < 2; blk++) {
    k_wsplit<<<1600, 256, 0, stream>>>(in_w + (long)blk * DM_ * 512,
                                       W2TI + (long)blk * 512 * KPI_,
                                       DM_, 512, KPA_, KPI_, 512L * KPI_, 2);
    k_wsplit<<<1536, 256, 0, stream>>>(outw + (long)blk * DI_ * DM_,
                                       W2TO + (long)blk * 512 * KPO_,
                                       DI_, DM_, 256, KPO_, 512L * KPO_, 3);
  }
  k_padzero<<<1200, 256, 0, stream>>>(A2IN);

  // absmaxes + fused patch-embed (x and w fq'd inline)
  k_absmax<<<2048, 256, 0, stream>>>(x, (long)B_ * H_ * W_, SC(0));
  k_absmax<<<8, 256, 0, stream>>>(pew, EMB * 2 * 16, SC(1));
  k_absmax<<<512, 256, 0, stream>>>(pos, LDM_, SC(4));
  k_patchfq<<<dim3(20, 11, 16), 320, 0, stream>>>(x, pew, peb, SC(0), SC(1), X2, SC(2));

  // pos = fq(fq(pos_embed)) == fq(pos_embed)  (fq idempotent)
  k_fq4<<<512, 256, 0, stream>>>((const float4*)pos, (float4*)P2, LDM_ / 4,
                                 SC(4), nullptr, nullptr);

  // x = fq(fq(x) + pos) with inner fq(x) = fq(patch_out, s2) (outer chain identity)
  k_addpos4<<<2048, 256, 0, stream>>>((float4*)X2, (const float4*)P2, SC(2), SC(6));
  k_fq4<<<2048, 256, 0, stream>>>((const float4*)X2, (float4*)X2, NX_ / 4,
                                  SC(6), nullptr, A2IN);

  const float* in_scale[2] = {SC(6), SC(8)};
  for (int blk = 0; blk < 2; blk++) {
    // in-proj: XZ = s * (q @ [w_hi; w_lo])   (MFMA bf16, A k-wrapped at 400)
    k_mgemm<false><<<dim3(4, 160), 256, 0, stream>>>(
        A2IN, W2TI + (long)blk * 512 * KPI_, XZ, 512, KPI_, KPA_, in_scale[blk], nullptr);
    // conv both dirs in one pass, xp-proj (both dirs), dt precompute, scans
    k_conv2<<<dim3(80, 16), 256, 0, stream>>>(XZ, cw + blk * DI_ * K_,
                                              cb + blk * DI_, XC);
    k_gemm<false><<<dim3(1, 640), 256, 0, stream>>>(
        XC, xpw + (long)blk * DI_ * 33, PROJ, 2 * ROWS_, 33, DI_, nullptr);
    k_dtp<<<2560, 256, 0, stream>>>(PROJ, dtw + blk * DTR_ * DI_, dtb + blk * DI_, Y);
    k_scan1<<<dim3(CH_, B_, 2), 256, 0, stream>>>(XC, PROJ, alog + blk * DI_ * N_,
                                                  Y, HEND, PEND);
    k_carry<<<128, 256, 0, stream>>>(HEND, PEND, CARR);
    k_scan2<<<dim3(CH_, B_, 2), 256, 0, stream>>>(XC, PROJ, alog + blk * DI_ * N_,
                                                  dp + blk * DI_, XZ, CARR, Y);
    // out-proj: MO = [y_hi | y_lo] (wrapped) @ [w_hi; w_hi; w_lo]  (amax fused)
    k_asplit2<<<40960, 256, 0, stream>>>(Y, A2Y);
    k_mgemm<true><<<dim3(4, 160), 256, 0, stream>>>(
        A2Y, W2TO + (long)blk * 512 * KPO_, MO, DM_, KPO_, WAO_, nullptr, SC(7 + blk * 2));
    // x = fq(layernorm(x + fq(mo))); emit q for next block's in-proj
    k_ln<<<640, 256, 0, stream>>>(X2, MO, SC(7 + blk * 2),
                                  lng + blk * DM_, lnb + blk * DM_, SC(8 + blk * 2));
    k_fq4<<<2048, 256, 0, stream>>>((const float4*)MO, (float4*)X2, NX_ / 4,
                                    SC(8 + blk * 2), nullptr,
                                    blk == 0 ? A2IN : nullptr);
  }

  // mean-pool (2-stage), fq, classifier with fq(cls_w)
  k_pool1<<<dim3(16, 20), 256, 0, stream>>>(X2, PART);
  k_pool2<<<25, 256, 0, stream>>>(PART, POOL, SC(11));
  k_absmax<<<4, 256, 0, stream>>>(clsw, DM_ * 2, SC(12));
  k_cls<<<32, 128, 0, stream>>>(POOL, clsw, clsb, SC(11), SC(12), (float*)d_out);
}

// Round 9
// 675.403 us; speedup vs baseline: 7.3923x; 1.0323x over previous
//
#include <hip/hip_runtime.h>
#include <hip/hip_bf16.h>
#include <math.h>

// ---- problem constants -----------------------------------------------------
#define B_    16
#define H_    22
#define W_    20480
#define EMB   35
#define GH_   11
#define GW_   1280
#define L_    1280
#define DM_   385
#define DI_   256
#define N_    4
#define K_    4
#define DTR_  25
#define ROWS_ (B_*L_)              // 20480
#define NX_   ((long)ROWS_*DM_)    // 7,884,800
#define LDM_  ((long)L_*DM_)       // 492,800
#define CH_   64                   // scan chunks
#define CHL_  20                   // steps per chunk (CH_*CHL_ == L_)
#define KPI_  800                  // in_proj W K' (2 terms x 400)
#define KPA_  400                  // in_proj A width (q stored once, padded)
#define KPO_  768                  // out/xp W K' (3 terms x 256)
#define WAO_  512                  // out/xp A width ({hi,lo})

// amax scalars: 8 slots x 64B apart to break single-address atomic serialization
#define NSLOT 8
#define SSTR  16                   // floats between slots (64 B)
#define SCALW 128                  // floats per logical scalar (8 slots)

typedef __attribute__((ext_vector_type(8))) short short8;
typedef __attribute__((ext_vector_type(4))) float f32x4;
typedef unsigned short ushort;

// ---- helpers ---------------------------------------------------------------
__device__ __forceinline__ void atomicMaxF(float* a, float v) {
  atomicMax(reinterpret_cast<int*>(a), __float_as_int(v));
}

// faithful fq: s = max(mx,1e-8)/127 where mx = max over the 8 slots
__device__ __forceinline__ float fq_scale(const float* pmax) {
  float m = pmax[0];
  #pragma unroll
  for (int i = 1; i < NSLOT; i++) m = fmaxf(m, pmax[i * SSTR]);
  return fmaxf(m, 1e-8f) / 127.f;
}
__device__ __forceinline__ float fq_apply(float x, float s) {
  float r = rintf(x / s);
  r = fminf(fmaxf(r, -128.f), 127.f);
  return r * s;
}

__device__ __forceinline__ ushort f2bf(float f) {  // round-to-nearest-even
  union { float f; unsigned u; } v; v.f = f;
  unsigned r = v.u + 0x7FFF + ((v.u >> 16) & 1);
  return (ushort)(r >> 16);
}
__device__ __forceinline__ float bf2f(ushort h) {
  union { unsigned u; float f; } v; v.u = ((unsigned)h) << 16;
  return v.f;
}

// block max -> atomicMax into one of 8 slots (by block id). sm >= blockDim/64.
__device__ __forceinline__ void blockAtomicMax(float v, float* out, float* sm) {
  #pragma unroll
  for (int o = 32; o > 0; o >>= 1) v = fmaxf(v, __shfl_down(v, o));
  if ((threadIdx.x & 63) == 0) sm[threadIdx.x >> 6] = v;
  __syncthreads();
  if (threadIdx.x == 0) {
    int nw = (blockDim.x + 63) >> 6;
    for (int i = 1; i < nw; i++) v = fmaxf(v, sm[i]);
    int slot = (blockIdx.x + blockIdx.y * 4 + blockIdx.z) & (NSLOT - 1);
    atomicMaxF(out + slot * SSTR, v);
  }
}

// ---- small utility kernels -------------------------------------------------
__global__ void k_zero(float* s) { s[blockIdx.x * 256 + threadIdx.x] = 0.f; }

__global__ void k_absmax(const float* __restrict__ src, long n, float* __restrict__ out) {
  __shared__ float smr[8];
  float m = 0.f;
  for (long i = (long)blockIdx.x * blockDim.x + threadIdx.x; i < n;
       i += (long)gridDim.x * blockDim.x)
    m = fmaxf(m, fabsf(src[i]));
  blockAtomicMax(m, out, smr);
}

// vectorized fq: dst4 = fq(src4); optional absmax -> nextmax; optional bf16
// q-emit into A2 [M][KPA_]. dst may == src.
__global__ void k_fq4(const float4* __restrict__ src, float4* __restrict__ dst, long n4,
                      const float* __restrict__ pmax, float* __restrict__ nextmax,
                      ushort* __restrict__ a2) {
  __shared__ float smr[8];
  float s = fq_scale(pmax);
  float m = 0.f;
  for (long i = (long)blockIdx.x * blockDim.x + threadIdx.x; i < n4;
       i += (long)gridDim.x * blockDim.x) {
    float4 v = src[i];
    float r0 = fminf(fmaxf(rintf(v.x / s), -128.f), 127.f);
    float r1 = fminf(fmaxf(rintf(v.y / s), -128.f), 127.f);
    float r2 = fminf(fmaxf(rintf(v.z / s), -128.f), 127.f);
    float r3 = fminf(fmaxf(rintf(v.w / s), -128.f), 127.f);
    float4 q = make_float4(r0 * s, r1 * s, r2 * s, r3 * s);
    dst[i] = q;
    m = fmaxf(m, fmaxf(fmaxf(fabsf(q.x), fabsf(q.y)), fmaxf(fabsf(q.z), fabsf(q.w))));
    if (a2) {
      long ii = i * 4;
      long mm = ii / 385; int kk = (int)(ii - mm * 385);
      float rr[4] = {r0, r1, r2, r3};
      #pragma unroll
      for (int j = 0; j < 4; j++) {
        a2[mm * KPA_ + kk] = f2bf(rr[j]);
        if (++kk == 385) { kk = 0; mm++; }
      }
    }
  }
  if (nextmax) blockAtomicMax(m, nextmax, smr);
}

// x4[i] = fq(x4[i], s_pmax) + p2[i % LDM/4]; absmax -> nextmax
// (the reference's extra fq() layers are identities: fq(fq(t)) == fq(t))
__global__ void k_addpos4(float4* __restrict__ x, const float4* __restrict__ p2,
                          const float* __restrict__ pmax, float* __restrict__ nextmax) {
  __shared__ float smr[8];
  float s = fq_scale(pmax);
  float m = 0.f;
  const long n4 = NX_ / 4, l4 = LDM_ / 4;
  for (long i = (long)blockIdx.x * blockDim.x + threadIdx.x; i < n4;
       i += (long)gridDim.x * blockDim.x) {
    float4 v = x[i];
    float4 p = p2[i % l4];
    float4 o;
    o.x = fq_apply(v.x, s) + p.x;
    o.y = fq_apply(v.y, s) + p.y;
    o.z = fq_apply(v.z, s) + p.z;
    o.w = fq_apply(v.w, s) + p.w;
    x[i] = o;
    m = fmaxf(m, fmaxf(fmaxf(fabsf(o.x), fabsf(o.y)), fmaxf(fabsf(o.z), fabsf(o.w))));
  }
  blockAtomicMax(m, nextmax, smr);
}

// ---- fused patch embed: LDS-staged x (fq inline), fq'd weights in VGPRs -----
// block = (gw-tile of 64, gh, b); 320 threads (280 active in compute)
__global__ __launch_bounds__(320) void k_patchfq(const float* __restrict__ x,
                                                 const float* __restrict__ pew,
                                                 const float* __restrict__ peb,
                                                 const float* __restrict__ sx_,
                                                 const float* __restrict__ sw_,
                                                 float* __restrict__ out,
                                                 float* __restrict__ nextmax) {
  __shared__ float xs[2][64][20];   // [ph][gw_local][pw] padded to 20
  __shared__ float smr[8];
  int tid = threadIdx.x;
  int gwt = blockIdx.x, gh = blockIdx.y, b = blockIdx.z;
  float sx = fq_scale(sx_), sw = fq_scale(sw_);
  if (tid < 256) {
    int gwl = tid >> 2, pw = (tid & 3) * 4;
    #pragma unroll
    for (int ph = 0; ph < 2; ph++) {
      const float* src = x + ((long)b * H_ + gh * 2 + ph) * W_ + (long)gwt * 1024 + tid * 4;
      float4 v = *reinterpret_cast<const float4*>(src);
      xs[ph][gwl][pw + 0] = fq_apply(v.x, sx);
      xs[ph][gwl][pw + 1] = fq_apply(v.y, sx);
      xs[ph][gwl][pw + 2] = fq_apply(v.z, sx);
      xs[ph][gwl][pw + 3] = fq_apply(v.w, sx);
    }
  }
  __syncthreads();
  float mx = 0.f;
  if (tid < 280) {
    int e = tid % 35;
    int g0 = (tid / 35) * 8;
    float w[32];
    #pragma unroll
    for (int j = 0; j < 32; j++) w[j] = fq_apply(pew[e * 32 + j], sw);
    float bias = peb[e];
    long obase = ((long)b * GW_ + (long)gwt * 64) * DM_ + gh * 35 + e;
    #pragma unroll
    for (int gi = 0; gi < 8; gi++) {
      int gw = g0 + gi;
      float acc = bias;
      #pragma unroll
      for (int pw = 0; pw < 16; pw++) {
        acc = fmaf(xs[0][gw][pw], w[pw], acc);
        acc = fmaf(xs[1][gw][pw], w[16 + pw], acc);
      }
      out[obase + (long)gw * DM_] = acc;
      mx = fmaxf(mx, fabsf(acc));
    }
  }
  blockAtomicMax(mx, nextmax, smr);
}

// ---- weight split: W[K][N] f32 -> W2T[Npad][Kp] bf16 ------------------------
// term t occupies cols [t*Kw, t*Kw+K); value = lo at t==terms-1 else hi.
__global__ void k_wsplit(const float* __restrict__ W, ushort* __restrict__ out,
                         int K, int N, int Kw, int Kp, long total, int terms) {
  long idx = (long)blockIdx.x * 256 + threadIdx.x;
  if (idx >= total) return;
  int k = (int)(idx % Kp);
  int n = (int)(idx / Kp);
  int t = k / Kw, kk = k - t * Kw;
  ushort r = 0;
  if (n < N && kk < K) {
    float w = W[(long)kk * N + n];
    ushort hi = f2bf(w);
    r = (t == terms - 1) ? f2bf(w - bf2f(hi)) : hi;
  }
  out[idx] = r;
}

// ---- activation split: (Y0+Y1)[M][256] f32 -> A2[M][512] bf16 {hi,lo} -------
__global__ void k_asplit2(const float* __restrict__ Y, ushort* __restrict__ A2) {
  long idx = (long)blockIdx.x * 256 + threadIdx.x;   // M*512 threads
  long m = idx >> 9; int k = (int)(idx & 511);
  int t = k >> 8, kk = k & 255;
  float v = Y[m * DI_ + kk] + Y[(m + ROWS_) * DI_ + kk];
  ushort hi = f2bf(v);
  A2[idx] = t ? f2bf(v - bf2f(hi)) : hi;
}

// zero the pad columns [385, 400) of A2IN
__global__ void k_padzero(ushort* __restrict__ A2) {
  long idx = (long)blockIdx.x * 256 + threadIdx.x;   // ROWS_*15 threads
  long m = idx / 15; int c = (int)(idx - m * 15);
  A2[m * KPA_ + 385 + c] = 0;
}

// ---- bf16 MFMA GEMM: C[M][Nreal] = scale * (A2[M][Wa,wrapped] @ W2T[Npad][Kp]^T)
// A column for global k is (k % Wa) -- A stores each distinct segment once.
// 128x128 tile, BK=32, 4 waves (2x2), 16x16x32 MFMA.
template<bool AMAX>
__global__ __launch_bounds__(256) void k_mgemm(const ushort* __restrict__ A2,
                                               const ushort* __restrict__ W2T,
                                               float* __restrict__ C,
                                               int Nreal, int Kp, int Wa,
                                               const float* __restrict__ sptr,
                                               float* __restrict__ amax_out) {
  __shared__ ushort Alds[4][128][8];   // [k-slot][row][8k] 8 KB
  __shared__ ushort Blds[4][128][8];   // [k-slot][col][8k] 8 KB
  __shared__ float smr[8];
  int tid = threadIdx.x;
  int lane = tid & 63, wave = tid >> 6;
  int wm = wave >> 1, wn = wave & 1;
  int m0 = blockIdx.y * 128, n0 = blockIdx.x * 128;
  f32x4 acc[4][4];
  #pragma unroll
  for (int i = 0; i < 4; i++)
    #pragma unroll
    for (int j = 0; j < 4; j++) acc[i][j] = (f32x4){0.f, 0.f, 0.f, 0.f};

  for (int k0 = 0; k0 < Kp; k0 += 32) {
    #pragma unroll
    for (int r = 0; r < 2; r++) {
      int id = tid + r * 256;            // 0..511
      int row = id >> 2, sl = id & 3;    // coalesced 64B global segments
      int kc = k0 + sl * 8; if (kc >= Wa) kc -= Wa;   // A k-wrap (8-aligned)
      short8 va = *reinterpret_cast<const short8*>(A2 + (long)(m0 + row) * Wa + kc);
      *reinterpret_cast<short8*>(&Alds[sl][row][0]) = va;
      short8 vb = *reinterpret_cast<const short8*>(W2T + (long)(n0 + row) * Kp + k0 + sl * 8);
      *reinterpret_cast<short8*>(&Blds[sl][row][0]) = vb;
    }
    __syncthreads();
    int sl = lane >> 4, rr = lane & 15;
    short8 af[4], bf4[4];
    #pragma unroll
    for (int i = 0; i < 4; i++)
      af[i] = *reinterpret_cast<const short8*>(&Alds[sl][wm * 64 + i * 16 + rr][0]);
    #pragma unroll
    for (int j = 0; j < 4; j++)
      bf4[j] = *reinterpret_cast<const short8*>(&Blds[sl][wn * 64 + j * 16 + rr][0]);
    #pragma unroll
    for (int i = 0; i < 4; i++)
      #pragma unroll
      for (int j = 0; j < 4; j++)
        acc[i][j] = __builtin_amdgcn_mfma_f32_16x16x32_bf16(af[i], bf4[j], acc[i][j], 0, 0, 0);
    __syncthreads();
  }

  float s = sptr ? fq_scale(sptr) : 1.0f;
  float mx = 0.f;
  int cfr = lane & 15, rbase = (lane >> 4) * 4;
  #pragma unroll
  for (int i = 0; i < 4; i++) {
    int gmb = m0 + wm * 64 + i * 16 + rbase;
    #pragma unroll
    for (int j = 0; j < 4; j++) {
      int gn = n0 + wn * 64 + j * 16 + cfr;
      if (gn < Nreal) {
        #pragma unroll
        for (int rg = 0; rg < 4; rg++) {
          float v = acc[i][j][rg] * s;
          C[(long)(gmb + rg) * Nreal + gn] = v;
          mx = fmaxf(mx, fabsf(v));
        }
      }
    }
  }
  if (AMAX) blockAtomicMax(mx, amax_out, smr);
}

// ---- depthwise causal conv1d (K=4) + SiLU, BOTH dirs from one window --------
// Emits xc directly as bf16 {hi | lo} split A2XC[g][512] (g = dir*ROWS + row)
// for the xp MFMA GEMM; scans reconstruct xc = hi + lo.
__global__ __launch_bounds__(256) void k_conv2(const float* __restrict__ xz,
                                               const float* __restrict__ cw,
                                               const float* __restrict__ cb,
                                               ushort* __restrict__ xch) {
  int d = threadIdx.x;
  int t0 = blockIdx.x * 16, b = blockIdx.y;
  long base = (long)b * L_;
  float w0 = cw[d * 4 + 0], w1 = cw[d * 4 + 1];
  float w2 = cw[d * 4 + 2], w3 = cw[d * 4 + 3];
  float bias = cb[d];
  float win[22];
  #pragma unroll
  for (int i = 0; i < 22; i++) {
    int t = t0 - 3 + i;
    win[i] = (t >= 0 && t < L_) ? xz[(base + t) * (2 * DI_) + d] : 0.f;
  }
  #pragma unroll
  for (int i = 0; i < 16; i++) {
    int t = t0 + i;
    // dir0, j ascending (bit-identical order)
    float a0 = bias;
    a0 = fmaf(w0, win[i + 0], a0);
    a0 = fmaf(w1, win[i + 1], a0);
    a0 = fmaf(w2, win[i + 2], a0);
    a0 = fmaf(w3, win[i + 3], a0);
    // dir1: taps reversed in t
    float a1 = bias;
    a1 = fmaf(w0, win[i + 6], a1);
    a1 = fmaf(w1, win[i + 5], a1);
    a1 = fmaf(w2, win[i + 4], a1);
    a1 = fmaf(w3, win[i + 3], a1);
    float v0 = a0 * (1.f / (1.f + expf(-a0)));
    float v1 = a1 * (1.f / (1.f + expf(-a1)));
    long g0o = (base + t) * 512 + d;
    ushort h0 = f2bf(v0), h1 = f2bf(v1);
    xch[g0o] = h0;
    xch[g0o + 256] = f2bf(v0 - bf2f(h0));
    long g1o = ((long)ROWS_ + base + t) * 512 + d;
    xch[g1o] = h1;
    xch[g1o + 256] = f2bf(v1 - bf2f(h1));
  }
}

// ---- dt precompute: dty[g][d] = softplus(proj[g][0:25] @ dtw[:,d] + dtb[d]) --
// g spans both dirs (2*ROWS rows). Written into the Y buffer (see aliasing note
// at k_scan2: scan2 reads dt then overwrites the same element with y).
__device__ __forceinline__ float softplusf(float x) {
  return fmaxf(x, 0.f) + log1pf(expf(-fabsf(x)));
}

__global__ __launch_bounds__(256) void k_dtp(const float* __restrict__ proj,
                                             const float* __restrict__ dtw,
                                             const float* __restrict__ dtb,
                                             float* __restrict__ dty) {
  __shared__ float pr[16][26];
  int d = threadIdx.x;
  long g0 = (long)blockIdx.x * 16;
  for (int i = threadIdx.x; i < 16 * DTR_; i += 256) {
    int r = i / DTR_, j = i - r * DTR_;
    pr[r][j] = proj[(g0 + r) * 33 + j];
  }
  float dwr[DTR_];
  #pragma unroll
  for (int r = 0; r < DTR_; r++) dwr[r] = dtw[r * DI_ + d];
  float dbv = dtb[d];
  __syncthreads();
  #pragma unroll
  for (int r = 0; r < 16; r++) {
    float acc = dbv;
    #pragma unroll
    for (int j = 0; j < DTR_; j++) acc = fmaf(pr[r][j], dwr[j], acc);
    dty[(g0 + r) * DI_ + d] = softplusf(acc);
  }
}

// ---- chunked parallel selective scan (dt preloaded, both dirs in grid.z) ----
// xc comes from the bf16 {hi|lo} split: xc = bf2f(hi) + bf2f(lo).
__global__ __launch_bounds__(256) void k_scan1(const ushort* __restrict__ xch,
                                               const float* __restrict__ proj,
                                               const float* __restrict__ A_log,
                                               const float* __restrict__ dty,
                                               float* __restrict__ Hend,
                                               float* __restrict__ Pend) {
  int b = blockIdx.y, c = blockIdx.x, d = threadIdx.x, dir = blockIdx.z;
  float A[4];
  #pragma unroll
  for (int n = 0; n < 4; n++) A[n] = -expf(A_log[d * 4 + n]);
  long base = (long)b * L_;
  int step0 = c * CHL_;
  long row0 = base + (dir ? (L_ - 1 - step0) : step0);
  long doff = (long)dir * ROWS_;
  int rs = dir ? -1 : 1;
  const float* pdt = dty + (doff + row0) * DI_ + d;
  const ushort* pxc = xch + (doff + row0) * 512 + d;
  const float* pp  = proj + (doff + row0) * 33;
  float h[4] = {0.f, 0.f, 0.f, 0.f};
  float P[4] = {1.f, 1.f, 1.f, 1.f};
  for (int s = 0; s < CHL_; s++) {
    float dtv = *pdt;
    float xcv = bf2f(pxc[0]) + bf2f(pxc[256]);
    float dx = dtv * xcv;
    #pragma unroll
    for (int n = 0; n < 4; n++) {
      float dA = expf(dtv * A[n]);
      h[n] = dA * h[n] + dx * pp[DTR_ + n];
      P[n] *= dA;
    }
    pdt += (long)rs * DI_; pxc += (long)rs * 512; pp += rs * 33;
  }
  long o = (((long)dir * B_ + b) * CH_ + c) * 1024 + d * 4;
  *reinterpret_cast<float4*>(Hend + o) = make_float4(h[0], h[1], h[2], h[3]);
  *reinterpret_cast<float4*>(Pend + o) = make_float4(P[0], P[1], P[2], P[3]);
}

__global__ __launch_bounds__(256) void k_carry(const float* __restrict__ Hend,
                                               const float* __restrict__ Pend,
                                               float* __restrict__ Carry) {
  int tid = blockIdx.x * 256 + threadIdx.x;   // 2*B_*1024 lanes
  int be = tid >> 10, i = tid & 1023;         // be = dir*16+b
  float carry = 0.f;
  for (int c = 0; c < CH_; c++) {
    long o = ((long)be * CH_ + c) * 1024 + i;
    Carry[o] = carry;
    carry = Pend[o] * carry + Hend[o];
  }
}

// dty holds dt on entry; each element is read once then overwritten with y
// by the unique owning thread (read-before-write, no cross-thread sharing).
__global__ __launch_bounds__(256) void k_scan2(const ushort* __restrict__ xch,
                                               const float* __restrict__ proj,
                                               const float* __restrict__ A_log,
                                               const float* __restrict__ Dp,
                                               const float* __restrict__ xz,
                                               const float* __restrict__ Carry,
                                               float* dty) {
  int b = blockIdx.y, c = blockIdx.x, d = threadIdx.x, dir = blockIdx.z;
  float A[4];
  #pragma unroll
  for (int n = 0; n < 4; n++) A[n] = -expf(A_log[d * 4 + n]);
  long base = (long)b * L_;
  int step0 = c * CHL_;
  long row0 = base + (dir ? (L_ - 1 - step0) : step0);
  long doff = (long)dir * ROWS_;
  int rs = dir ? -1 : 1;
  float* pdy = dty + (doff + row0) * DI_ + d;
  const ushort* pxc = xch + (doff + row0) * 512 + d;
  const float* pz  = xz + row0 * (2 * DI_) + DI_ + d;
  const float* pp  = proj + (doff + row0) * 33;
  long o = (((long)dir * B_ + b) * CH_ + c) * 1024 + d * 4;
  float4 cv = *reinterpret_cast<const float4*>(Carry + o);
  float h[4] = {cv.x, cv.y, cv.z, cv.w};
  float Dv = Dp[d];
  for (int s = 0; s < CHL_; s++) {
    float dtv = *pdy;
    float xcv = bf2f(pxc[0]) + bf2f(pxc[256]);
    float zv  = *pz;
    float dx = dtv * xcv;
    float acc = 0.f;
    #pragma unroll
    for (int n = 0; n < 4; n++) {
      float dA = expf(dtv * A[n]);
      h[n] = dA * h[n] + dx * pp[DTR_ + n];
      acc = fmaf(h[n], pp[DTR_ + N_ + n], acc);
    }
    float yv = fmaf(Dv, xcv, acc);
    float sig = 1.f / (1.f + expf(-zv));
    yv *= zv * sig;
    *pdy = yv;
    pdy += (long)rs * DI_; pxc += (long)rs * 512;
    pz += rs * (2 * DI_); pp += rs * 33;
  }
}

// ---- residual + fq(mamba_out) + layernorm, wave-per-row ----------------------
// grid 640 x 256 (4 waves/block); each wave owns rows strided by 2560.
__global__ __launch_bounds__(256) void k_ln(const float* __restrict__ x2,
                                            float* __restrict__ mo,
                                            const float* __restrict__ smo,
                                            const float* __restrict__ g,
                                            const float* __restrict__ bta,
                                            float* __restrict__ nextmax) {
  __shared__ float smr[4];
  int lane = threadIdx.x & 63;
  int wid = blockIdx.x * 4 + (threadIdx.x >> 6);
  float s = fq_scale(smo);
  float wmax = 0.f;
  for (int row = wid; row < ROWS_; row += 2560) {
    const float* xr = x2 + (long)row * DM_;
    float* mr = mo + (long)row * DM_;
    float v[7];
    float lsum = 0.f;
    #pragma unroll
    for (int k = 0; k < 6; k++) {
      int c = lane + k * 64;
      v[k] = xr[c] + fq_apply(mr[c], s);
      lsum += v[k];
    }
    v[6] = 0.f;
    if (lane == 0) v[6] = xr[384] + fq_apply(mr[384], s);
    lsum += v[6];
    #pragma unroll
    for (int o = 32; o > 0; o >>= 1) lsum += __shfl_xor(lsum, o);
    float mean = lsum / 385.f;
    float lvar = 0.f;
    #pragma unroll
    for (int k = 0; k < 6; k++) { float dd = v[k] - mean; lvar += dd * dd; }
    if (lane == 0) { float dd = v[6] - mean; lvar += dd * dd; }
    #pragma unroll
    for (int o = 32; o > 0; o >>= 1) lvar += __shfl_xor(lvar, o);
    float rs = 1.f / sqrtf(lvar / 385.f + 1e-5f);
    #pragma unroll
    for (int k = 0; k < 6; k++) {
      int c = lane + k * 64;
      float o2 = (v[k] - mean) * rs * g[c] + bta[c];
      mr[c] = o2;
      wmax = fmaxf(wmax, fabsf(o2));
    }
    if (lane == 0) {
      float o2 = (v[6] - mean) * rs * g[384] + bta[384];
      mr[384] = o2;
      wmax = fmaxf(wmax, fabsf(o2));
    }
  }
  blockAtomicMax(wmax, nextmax, smr);
}

// ---- mean pool over L (two-stage, coalesced, deterministic) ------------------
__global__ __launch_bounds__(256) void k_pool1(const float* __restrict__ x2,
                                               float* __restrict__ part) {
  int b = blockIdx.x, ch = blockIdx.y, tid = threadIdx.x;
  float s0 = 0.f, s1 = 0.f;
  for (int l = ch * 64; l < ch * 64 + 64; l++) {
    const float* row = x2 + ((long)b * L_ + l) * DM_;
    s0 += row[tid];
    if (tid < DM_ - 256) s1 += row[tid + 256];
  }
  long o = ((long)b * 20 + ch) * DM_;
  part[o + tid] = s0;
  if (tid < DM_ - 256) part[o + tid + 256] = s1;
}

__global__ void k_pool2(const float* __restrict__ part, float* __restrict__ pool,
                        float* __restrict__ nextmax) {
  __shared__ float smr[8];
  int idx = blockIdx.x * 256 + threadIdx.x;
  float mv = 0.f;
  if (idx < B_ * DM_) {
    int b = idx / DM_, c = idx % DM_;
    float s = 0.f;
    for (int ch = 0; ch < 20; ch++) s += part[((long)b * 20 + ch) * DM_ + c];
    float mean = s / (float)L_;
    pool[idx] = mean;
    mv = fabsf(mean);
  }
  blockAtomicMax(mv, nextmax, smr);
}

// ---- classifier (parallel): grid 32 = (b,c), 128 threads reduce over K=385 --
__global__ __launch_bounds__(128) void k_cls(const float* __restrict__ pool,
                                             const float* __restrict__ clsw,
                                             const float* __restrict__ clsb,
                                             const float* __restrict__ sp_,
                                             const float* __restrict__ sw_,
                                             float* __restrict__ out) {
  __shared__ float smr[2];
  int b = blockIdx.x >> 1, c = blockIdx.x & 1;
  float sp = fq_scale(sp_), sw = fq_scale(sw_);
  float acc = 0.f;
  for (int k = threadIdx.x; k < DM_; k += 128) {
    float xv = fq_apply(pool[b * DM_ + k], sp);
    float wv = fq_apply(clsw[k * 2 + c], sw);
    acc = fmaf(xv, wv, acc);
  }
  #pragma unroll
  for (int o = 32; o > 0; o >>= 1) acc += __shfl_down(acc, o);
  if ((threadIdx.x & 63) == 0) smr[threadIdx.x >> 6] = acc;
  __syncthreads();
  if (threadIdx.x == 0) out[blockIdx.x] = smr[0] + smr[1] + clsb[c];
}

// ---- launch ------------------------------------------------------------------
extern "C" void kernel_launch(void* const* d_in, const int* in_sizes, int n_in,
                              void* d_out, int out_size, void* d_ws, size_t ws_size,
                              hipStream_t stream) {
  const float* x    = (const float*)d_in[0];
  const float* pew  = (const float*)d_in[1];
  const float* peb  = (const float*)d_in[2];
  const float* pos  = (const float*)d_in[3];
  const float* in_w = (const float*)d_in[4];
  const float* cw   = (const float*)d_in[5];
  const float* cb   = (const float*)d_in[6];
  const float* xpw  = (const float*)d_in[7];
  const float* dtw  = (const float*)d_in[8];
  const float* dtb  = (const float*)d_in[9];
  const float* alog = (const float*)d_in[10];
  const float* dp   = (const float*)d_in[11];
  const float* outw = (const float*)d_in[12];
  const float* lng  = (const float*)d_in[13];
  const float* lnb  = (const float*)d_in[14];
  const float* clsw = (const float*)d_in[15];
  const float* clsb = (const float*)d_in[16];

  float* ws    = (float*)d_ws;
  float* SCAL  = ws;                              // 13 scalars x 128 floats (8 slots)
  float* P2    = ws + 2048;                       // 492,800
  float* X2    = P2 + LDM_;                       // 7,884,800
  float* XZ    = X2 + NX_;                        // 10,485,760
  float* XCH_f = XZ + (long)ROWS_ * 512;          // 10,485,760 (ushort [40960][512])
  float* PROJ  = XCH_f + 2L * ROWS_ * DI_;        // 40960*33 = 1,351,680
  float* Y     = PROJ + 2L * ROWS_ * 33;          // 2 x 5,242,880 (dt -> y in place)
  float* MO    = Y + 2L * ROWS_ * DI_;            // 7,884,800
  float* POOL  = MO + NX_;                        // 8,192
  float* PART  = POOL + 8192;                     // 123,200 (+pad)
  float* A2IN_f= PART + 131072;                   // 4,096,000 f (ushort overlay)
  float* W2I_f = A2IN_f + 4096000;                // 409,600 f
  float* W2O_f = W2I_f + 409600;                  // 393,216 f
  float* W2X_f = W2O_f + 393216;                  // 98,304 f (2 x [128][768] ushort)
  // aliases (disjoint lifetimes):
  float*  HEND = MO;                              // scan summaries, dead before out-GEMM
  float*  PEND = MO + 2097152;
  float*  CARR = MO + 4194304;
  ushort* A2Y  = (ushort*)XZ;                     // [20480][512], dead before next in-GEMM
  ushort* XCH  = (ushort*)XCH_f;                  // xc bf16 {hi|lo} [40960][512]
  ushort* A2IN = (ushort*)A2IN_f;                 // [20480][400]
  ushort* W2TI = (ushort*)W2I_f;                  // 2 x [512][800]
  ushort* W2TO = (ushort*)W2O_f;                  // 2 x [512][768]
  ushort* W2TX = (ushort*)W2X_f;                  // 2 x [128][768]

  // scalar entry i lives at SCAL + i*SCALW (8 slots, 64B apart)
  #define SC(i) (SCAL + (i) * SCALW)

  k_zero<<<8, 256, 0, stream>>>(SCAL);

  // weight splits for MFMA GEMMs (tiny)
  for (int blk = 0; blk < 2; blk++) {
    k_wsplit<<<1600, 256, 0, stream>>>(in_w + (long)blk * DM_ * 512,
                                       W2TI + (long)blk * 512 * KPI_,
                                       DM_, 512, KPA_, KPI_, 512L * KPI_, 2);
    k_wsplit<<<1536, 256, 0, stream>>>(outw + (long)blk * DI_ * DM_,
                                       W2TO + (long)blk * 512 * KPO_,
                                       DI_, DM_, 256, KPO_, 512L * KPO_, 3);
    k_wsplit<<<384, 256, 0, stream>>>(xpw + (long)blk * DI_ * 33,
                                      W2TX + (long)blk * 128 * KPO_,
                                      DI_, 33, 256, KPO_, 128L * KPO_, 3);
  }
  k_padzero<<<1200, 256, 0, stream>>>(A2IN);

  // absmaxes + fused patch-embed (x and w fq'd inline)
  k_absmax<<<2048, 256, 0, stream>>>(x, (long)B_ * H_ * W_, SC(0));
  k_absmax<<<8, 256, 0, stream>>>(pew, EMB * 2 * 16, SC(1));
  k_absmax<<<512, 256, 0, stream>>>(pos, LDM_, SC(4));
  k_patchfq<<<dim3(20, 11, 16), 320, 0, stream>>>(x, pew, peb, SC(0), SC(1), X2, SC(2));

  // pos = fq(fq(pos_embed)) == fq(pos_embed)  (fq idempotent)
  k_fq4<<<512, 256, 0, stream>>>((const float4*)pos, (float4*)P2, LDM_ / 4,
                                 SC(4), nullptr, nullptr);

  // x = fq(fq(x) + pos) with inner fq(x) = fq(patch_out, s2) (outer chain identity)
  k_addpos4<<<2048, 256, 0, stream>>>((float4*)X2, (const float4*)P2, SC(2), SC(6));
  k_fq4<<<2048, 256, 0, stream>>>((const float4*)X2, (float4*)X2, NX_ / 4,
                                  SC(6), nullptr, A2IN);

  const float* in_scale[2] = {SC(6), SC(8)};
  for (int blk = 0; blk < 2; blk++) {
    // in-proj: XZ = s * (q @ [w_hi; w_lo])   (MFMA bf16, A k-wrapped at 400)
    k_mgemm<false><<<dim3(4, 160), 256, 0, stream>>>(
        A2IN, W2TI + (long)blk * 512 * KPI_, XZ, 512, KPI_, KPA_, in_scale[blk], nullptr);
    // conv both dirs -> xc bf16 {hi|lo}; xp-proj via MFMA (N=33 in one tile)
    k_conv2<<<dim3(80, 16), 256, 0, stream>>>(XZ, cw + blk * DI_ * K_,
                                              cb + blk * DI_, XCH);
    k_mgemm<false><<<dim3(1, 320), 256, 0, stream>>>(
        XCH, W2TX + (long)blk * 128 * KPO_, PROJ, 33, KPO_, WAO_, nullptr, nullptr);
    k_dtp<<<2560, 256, 0, stream>>>(PROJ, dtw + blk * DTR_ * DI_, dtb + blk * DI_, Y);
    k_scan1<<<dim3(CH_, B_, 2), 256, 0, stream>>>(XCH, PROJ, alog + blk * DI_ * N_,
                                                  Y, HEND, PEND);
    k_carry<<<128, 256, 0, stream>>>(HEND, PEND, CARR);
    k_scan2<<<dim3(CH_, B_, 2), 256, 0, stream>>>(XCH, PROJ, alog + blk * DI_ * N_,
                                                  dp + blk * DI_, XZ, CARR, Y);
    // out-proj: MO = [y_hi | y_lo] (wrapped) @ [w_hi; w_hi; w_lo]  (amax fused)
    k_asplit2<<<40960, 256, 0, stream>>>(Y, A2Y);
    k_mgemm<true><<<dim3(4, 160), 256, 0, stream>>>(
        A2Y, W2TO + (long)blk * 512 * KPO_, MO, DM_, KPO_, WAO_, nullptr, SC(7 + blk * 2));
    // x = fq(layernorm(x + fq(mo))); emit q for next block's in-proj
    k_ln<<<640, 256, 0, stream>>>(X2, MO, SC(7 + blk * 2),
                                  lng + blk * DM_, lnb + blk * DM_, SC(8 + blk * 2));
    k_fq4<<<2048, 256, 0, stream>>>((const float4*)MO, (float4*)X2, NX_ / 4,
                                    SC(8 + blk * 2), nullptr,
                                    blk == 0 ? A2IN : nullptr);
  }

  // mean-pool (2-stage), fq, classifier with fq(cls_w)
  k_pool1<<<dim3(16, 20), 256, 0, stream>>>(X2, PART);
  k_pool2<<<25, 256, 0, stream>>>(PART, POOL, SC(11));
  k_absmax<<<4, 256, 0, stream>>>(clsw, DM_ * 2, SC(12));
  k_cls<<<32, 128, 0, stream>>>(POOL, clsw, clsb, SC(11), SC(12), (float*)d_out);
}

// Round 10
// 654.708 us; speedup vs baseline: 7.6260x; 1.0316x over previous
//
#include <hip/hip_runtime.h>
#include <hip/hip_bf16.h>
#include <math.h>

// ---- problem constants -----------------------------------------------------
#define B_    16
#define H_    22
#define W_    20480
#define EMB   35
#define GH_   11
#define GW_   1280
#define L_    1280
#define DM_   385
#define DI_   256
#define N_    4
#define K_    4
#define DTR_  25
#define ROWS_ (B_*L_)              // 20480
#define NX_   ((long)ROWS_*DM_)    // 7,884,800
#define LDM_  ((long)L_*DM_)       // 492,800
#define CH_   64                   // scan chunks
#define CHL_  20                   // steps per chunk (CH_*CHL_ == L_)
#define KPI_  800                  // in_proj W K' (2 terms x 400)
#define KPA_  400                  // in_proj A width (q stored once, padded)
#define KPO_  768                  // out/xp W K' (3 terms x 256)
#define WAO_  512                  // out/xp A width ({hi,lo})

// amax scalars: 8 slots x 64B apart to break single-address atomic serialization
#define NSLOT 8
#define SSTR  16                   // floats between slots (64 B)
#define SCALW 128                  // floats per logical scalar (8 slots)

// LDS sl-plane stride (ushorts): 128 rows x 8 + 8 pad -> +16B per plane.
// Byte granule becomes (sl+row)&7: conflict-free writes AND reads.
#define SLP_  2056

typedef __attribute__((ext_vector_type(8))) short short8;
typedef __attribute__((ext_vector_type(4))) float f32x4;
typedef unsigned short ushort;

// ---- helpers ---------------------------------------------------------------
__device__ __forceinline__ void atomicMaxF(float* a, float v) {
  atomicMax(reinterpret_cast<int*>(a), __float_as_int(v));
}

// faithful fq: s = max(mx,1e-8)/127 where mx = max over the 8 slots
__device__ __forceinline__ float fq_scale(const float* pmax) {
  float m = pmax[0];
  #pragma unroll
  for (int i = 1; i < NSLOT; i++) m = fmaxf(m, pmax[i * SSTR]);
  return fmaxf(m, 1e-8f) / 127.f;
}
__device__ __forceinline__ float fq_apply(float x, float s) {
  float r = rintf(x / s);
  r = fminf(fmaxf(r, -128.f), 127.f);
  return r * s;
}

__device__ __forceinline__ ushort f2bf(float f) {  // round-to-nearest-even
  union { float f; unsigned u; } v; v.f = f;
  unsigned r = v.u + 0x7FFF + ((v.u >> 16) & 1);
  return (ushort)(r >> 16);
}
__device__ __forceinline__ float bf2f(ushort h) {
  union { unsigned u; float f; } v; v.u = ((unsigned)h) << 16;
  return v.f;
}

// block max -> atomicMax into one of 8 slots (by block id). sm >= blockDim/64.
__device__ __forceinline__ void blockAtomicMax(float v, float* out, float* sm) {
  #pragma unroll
  for (int o = 32; o > 0; o >>= 1) v = fmaxf(v, __shfl_down(v, o));
  if ((threadIdx.x & 63) == 0) sm[threadIdx.x >> 6] = v;
  __syncthreads();
  if (threadIdx.x == 0) {
    int nw = (blockDim.x + 63) >> 6;
    for (int i = 1; i < nw; i++) v = fmaxf(v, sm[i]);
    int slot = (blockIdx.x + blockIdx.y * 4 + blockIdx.z) & (NSLOT - 1);
    atomicMaxF(out + slot * SSTR, v);
  }
}

// ---- small utility kernels -------------------------------------------------
__global__ void k_zero(float* s) { s[blockIdx.x * 256 + threadIdx.x] = 0.f; }

__global__ void k_absmax(const float* __restrict__ src, long n, float* __restrict__ out) {
  __shared__ float smr[8];
  float m = 0.f;
  for (long i = (long)blockIdx.x * blockDim.x + threadIdx.x; i < n;
       i += (long)gridDim.x * blockDim.x)
    m = fmaxf(m, fabsf(src[i]));
  blockAtomicMax(m, out, smr);
}

// vectorized fq: dst4 = fq(src4); optional absmax -> nextmax; optional bf16
// q-emit into A2 [M][KPA_]. dst may == src.
__global__ void k_fq4(const float4* __restrict__ src, float4* __restrict__ dst, long n4,
                      const float* __restrict__ pmax, float* __restrict__ nextmax,
                      ushort* __restrict__ a2) {
  __shared__ float smr[8];
  float s = fq_scale(pmax);
  float m = 0.f;
  for (long i = (long)blockIdx.x * blockDim.x + threadIdx.x; i < n4;
       i += (long)gridDim.x * blockDim.x) {
    float4 v = src[i];
    float r0 = fminf(fmaxf(rintf(v.x / s), -128.f), 127.f);
    float r1 = fminf(fmaxf(rintf(v.y / s), -128.f), 127.f);
    float r2 = fminf(fmaxf(rintf(v.z / s), -128.f), 127.f);
    float r3 = fminf(fmaxf(rintf(v.w / s), -128.f), 127.f);
    float4 q = make_float4(r0 * s, r1 * s, r2 * s, r3 * s);
    dst[i] = q;
    m = fmaxf(m, fmaxf(fmaxf(fabsf(q.x), fabsf(q.y)), fmaxf(fabsf(q.z), fabsf(q.w))));
    if (a2) {
      long ii = i * 4;
      long mm = ii / 385; int kk = (int)(ii - mm * 385);
      float rr[4] = {r0, r1, r2, r3};
      #pragma unroll
      for (int j = 0; j < 4; j++) {
        a2[mm * KPA_ + kk] = f2bf(rr[j]);
        if (++kk == 385) { kk = 0; mm++; }
      }
    }
  }
  if (nextmax) blockAtomicMax(m, nextmax, smr);
}

// x4[i] = fq(x4[i], s_pmax) + p2[i % LDM/4]; absmax -> nextmax
// (the reference's extra fq() layers are identities: fq(fq(t)) == fq(t))
__global__ void k_addpos4(float4* __restrict__ x, const float4* __restrict__ p2,
                          const float* __restrict__ pmax, float* __restrict__ nextmax) {
  __shared__ float smr[8];
  float s = fq_scale(pmax);
  float m = 0.f;
  const long n4 = NX_ / 4, l4 = LDM_ / 4;
  for (long i = (long)blockIdx.x * blockDim.x + threadIdx.x; i < n4;
       i += (long)gridDim.x * blockDim.x) {
    float4 v = x[i];
    float4 p = p2[i % l4];
    float4 o;
    o.x = fq_apply(v.x, s) + p.x;
    o.y = fq_apply(v.y, s) + p.y;
    o.z = fq_apply(v.z, s) + p.z;
    o.w = fq_apply(v.w, s) + p.w;
    x[i] = o;
    m = fmaxf(m, fmaxf(fmaxf(fabsf(o.x), fabsf(o.y)), fmaxf(fabsf(o.z), fabsf(o.w))));
  }
  blockAtomicMax(m, nextmax, smr);
}

// ---- fused patch embed: LDS-staged x (fq inline), fq'd weights in VGPRs -----
// block = (gw-tile of 64, gh, b); 320 threads (280 active in compute)
__global__ __launch_bounds__(320) void k_patchfq(const float* __restrict__ x,
                                                 const float* __restrict__ pew,
                                                 const float* __restrict__ peb,
                                                 const float* __restrict__ sx_,
                                                 const float* __restrict__ sw_,
                                                 float* __restrict__ out,
                                                 float* __restrict__ nextmax) {
  __shared__ float xs[2][64][20];   // [ph][gw_local][pw] padded to 20
  __shared__ float smr[8];
  int tid = threadIdx.x;
  int gwt = blockIdx.x, gh = blockIdx.y, b = blockIdx.z;
  float sx = fq_scale(sx_), sw = fq_scale(sw_);
  if (tid < 256) {
    int gwl = tid >> 2, pw = (tid & 3) * 4;
    #pragma unroll
    for (int ph = 0; ph < 2; ph++) {
      const float* src = x + ((long)b * H_ + gh * 2 + ph) * W_ + (long)gwt * 1024 + tid * 4;
      float4 v = *reinterpret_cast<const float4*>(src);
      xs[ph][gwl][pw + 0] = fq_apply(v.x, sx);
      xs[ph][gwl][pw + 1] = fq_apply(v.y, sx);
      xs[ph][gwl][pw + 2] = fq_apply(v.z, sx);
      xs[ph][gwl][pw + 3] = fq_apply(v.w, sx);
    }
  }
  __syncthreads();
  float mx = 0.f;
  if (tid < 280) {
    int e = tid % 35;
    int g0 = (tid / 35) * 8;
    float w[32];
    #pragma unroll
    for (int j = 0; j < 32; j++) w[j] = fq_apply(pew[e * 32 + j], sw);
    float bias = peb[e];
    long obase = ((long)b * GW_ + (long)gwt * 64) * DM_ + gh * 35 + e;
    #pragma unroll
    for (int gi = 0; gi < 8; gi++) {
      int gw = g0 + gi;
      float acc = bias;
      #pragma unroll
      for (int pw = 0; pw < 16; pw++) {
        acc = fmaf(xs[0][gw][pw], w[pw], acc);
        acc = fmaf(xs[1][gw][pw], w[16 + pw], acc);
      }
      out[obase + (long)gw * DM_] = acc;
      mx = fmaxf(mx, fabsf(acc));
    }
  }
  blockAtomicMax(mx, nextmax, smr);
}

// ---- weight split: W[K][N] f32 -> W2T[Npad][Kp] bf16 ------------------------
// term t occupies cols [t*Kw, t*Kw+K); value = lo at t==terms-1 else hi.
__global__ void k_wsplit(const float* __restrict__ W, ushort* __restrict__ out,
                         int K, int N, int Kw, int Kp, long total, int terms) {
  long idx = (long)blockIdx.x * 256 + threadIdx.x;
  if (idx >= total) return;
  int k = (int)(idx % Kp);
  int n = (int)(idx / Kp);
  int t = k / Kw, kk = k - t * Kw;
  ushort r = 0;
  if (n < N && kk < K) {
    float w = W[(long)kk * N + n];
    ushort hi = f2bf(w);
    r = (t == terms - 1) ? f2bf(w - bf2f(hi)) : hi;
  }
  out[idx] = r;
}

// ---- activation split: (Y0+Y1)[M][256] f32 -> A2[M][512] bf16 {hi,lo} -------
__global__ void k_asplit2(const float* __restrict__ Y, ushort* __restrict__ A2) {
  long idx = (long)blockIdx.x * 256 + threadIdx.x;   // M*512 threads
  long m = idx >> 9; int k = (int)(idx & 511);
  int t = k >> 8, kk = k & 255;
  float v = Y[m * DI_ + kk] + Y[(m + ROWS_) * DI_ + kk];
  ushort hi = f2bf(v);
  A2[idx] = t ? f2bf(v - bf2f(hi)) : hi;
}

// zero the pad columns [385, 400) of A2IN
__global__ void k_padzero(ushort* __restrict__ A2) {
  long idx = (long)blockIdx.x * 256 + threadIdx.x;   // ROWS_*15 threads
  long m = idx / 15; int c = (int)(idx - m * 15);
  A2[m * KPA_ + 385 + c] = 0;
}

// ---- bf16 MFMA GEMM: C[M][Nreal] = scale * (A2[M][Wa,wrapped] @ W2T[Npad][Kp]^T)
// 1-D grid NT*MT with m = bid%MT, n = bid/MT: same-m blocks are MT apart ->
// same XCD (MT % 8 == 0) -> shared L2 A-panel. LDS sl-stride padded (+16B)
// so write/read granule = (sl+row)&7: conflict-free.
template<bool AMAX>
__global__ __launch_bounds__(256) void k_mgemm(const ushort* __restrict__ A2,
                                               const ushort* __restrict__ W2T,
                                               float* __restrict__ C,
                                               int Nreal, int Kp, int Wa, int MT,
                                               const float* __restrict__ sptr,
                                               float* __restrict__ amax_out) {
  __shared__ ushort Alds[4 * SLP_];   // plane sl at sl*SLP_, row*8 within
  __shared__ ushort Blds[4 * SLP_];
  __shared__ float smr[8];
  int tid = threadIdx.x;
  int lane = tid & 63, wave = tid >> 6;
  int wm = wave >> 1, wn = wave & 1;
  int bid = blockIdx.x;
  int m0 = (bid % MT) * 128, n0 = (bid / MT) * 128;
  f32x4 acc[4][4];
  #pragma unroll
  for (int i = 0; i < 4; i++)
    #pragma unroll
    for (int j = 0; j < 4; j++) acc[i][j] = (f32x4){0.f, 0.f, 0.f, 0.f};

  for (int k0 = 0; k0 < Kp; k0 += 32) {
    #pragma unroll
    for (int r = 0; r < 2; r++) {
      int id = tid + r * 256;            // 0..511
      int row = id >> 2, sl = id & 3;    // coalesced 64B global segments
      int kc = k0 + sl * 8; if (kc >= Wa) kc -= Wa;   // A k-wrap (8-aligned)
      short8 va = *reinterpret_cast<const short8*>(A2 + (long)(m0 + row) * Wa + kc);
      *reinterpret_cast<short8*>(&Alds[sl * SLP_ + row * 8]) = va;
      short8 vb = *reinterpret_cast<const short8*>(W2T + (long)(n0 + row) * Kp + k0 + sl * 8);
      *reinterpret_cast<short8*>(&Blds[sl * SLP_ + row * 8]) = vb;
    }
    __syncthreads();
    int sl = lane >> 4, rr = lane & 15;
    short8 af[4], bf4[4];
    #pragma unroll
    for (int i = 0; i < 4; i++)
      af[i] = *reinterpret_cast<const short8*>(&Alds[sl * SLP_ + (wm * 64 + i * 16 + rr) * 8]);
    #pragma unroll
    for (int j = 0; j < 4; j++)
      bf4[j] = *reinterpret_cast<const short8*>(&Blds[sl * SLP_ + (wn * 64 + j * 16 + rr) * 8]);
    #pragma unroll
    for (int i = 0; i < 4; i++)
      #pragma unroll
      for (int j = 0; j < 4; j++)
        acc[i][j] = __builtin_amdgcn_mfma_f32_16x16x32_bf16(af[i], bf4[j], acc[i][j], 0, 0, 0);
    __syncthreads();
  }

  float s = sptr ? fq_scale(sptr) : 1.0f;
  float mx = 0.f;
  int cfr = lane & 15, rbase = (lane >> 4) * 4;
  #pragma unroll
  for (int i = 0; i < 4; i++) {
    int gmb = m0 + wm * 64 + i * 16 + rbase;
    #pragma unroll
    for (int j = 0; j < 4; j++) {
      int gn = n0 + wn * 64 + j * 16 + cfr;
      if (gn < Nreal) {
        #pragma unroll
        for (int rg = 0; rg < 4; rg++) {
          float v = acc[i][j][rg] * s;
          C[(long)(gmb + rg) * Nreal + gn] = v;
          mx = fmaxf(mx, fabsf(v));
        }
      }
    }
  }
  if (AMAX) blockAtomicMax(mx, amax_out, smr);
}

// ---- depthwise causal conv1d (K=4) + SiLU, BOTH dirs from one window --------
// Emits xc directly as bf16 {hi | lo} split A2XC[g][512] (g = dir*ROWS + row)
// for the xp MFMA GEMM; scans reconstruct xc = hi + lo.
__global__ __launch_bounds__(256) void k_conv2(const float* __restrict__ xz,
                                               const float* __restrict__ cw,
                                               const float* __restrict__ cb,
                                               ushort* __restrict__ xch) {
  int d = threadIdx.x;
  int t0 = blockIdx.x * 16, b = blockIdx.y;
  long base = (long)b * L_;
  float w0 = cw[d * 4 + 0], w1 = cw[d * 4 + 1];
  float w2 = cw[d * 4 + 2], w3 = cw[d * 4 + 3];
  float bias = cb[d];
  float win[22];
  #pragma unroll
  for (int i = 0; i < 22; i++) {
    int t = t0 - 3 + i;
    win[i] = (t >= 0 && t < L_) ? xz[(base + t) * (2 * DI_) + d] : 0.f;
  }
  #pragma unroll
  for (int i = 0; i < 16; i++) {
    int t = t0 + i;
    // dir0, j ascending (bit-identical order)
    float a0 = bias;
    a0 = fmaf(w0, win[i + 0], a0);
    a0 = fmaf(w1, win[i + 1], a0);
    a0 = fmaf(w2, win[i + 2], a0);
    a0 = fmaf(w3, win[i + 3], a0);
    // dir1: taps reversed in t
    float a1 = bias;
    a1 = fmaf(w0, win[i + 6], a1);
    a1 = fmaf(w1, win[i + 5], a1);
    a1 = fmaf(w2, win[i + 4], a1);
    a1 = fmaf(w3, win[i + 3], a1);
    float v0 = a0 * (1.f / (1.f + expf(-a0)));
    float v1 = a1 * (1.f / (1.f + expf(-a1)));
    long g0o = (base + t) * 512 + d;
    ushort h0 = f2bf(v0), h1 = f2bf(v1);
    xch[g0o] = h0;
    xch[g0o + 256] = f2bf(v0 - bf2f(h0));
    long g1o = ((long)ROWS_ + base + t) * 512 + d;
    xch[g1o] = h1;
    xch[g1o + 256] = f2bf(v1 - bf2f(h1));
  }
}

// ---- dt precompute: dty[g][d] = softplus(proj[g][0:25] @ dtw[:,d] + dtb[d]) --
// g spans both dirs (2*ROWS rows). Written into the Y buffer (see aliasing note
// at k_scan2: scan2 reads dt then overwrites the same element with y).
__device__ __forceinline__ float softplusf(float x) {
  return fmaxf(x, 0.f) + log1pf(expf(-fabsf(x)));
}

__global__ __launch_bounds__(256) void k_dtp(const float* __restrict__ proj,
                                             const float* __restrict__ dtw,
                                             const float* __restrict__ dtb,
                                             float* __restrict__ dty) {
  __shared__ float pr[16][26];
  int d = threadIdx.x;
  long g0 = (long)blockIdx.x * 16;
  for (int i = threadIdx.x; i < 16 * DTR_; i += 256) {
    int r = i / DTR_, j = i - r * DTR_;
    pr[r][j] = proj[(g0 + r) * 33 + j];
  }
  float dwr[DTR_];
  #pragma unroll
  for (int r = 0; r < DTR_; r++) dwr[r] = dtw[r * DI_ + d];
  float dbv = dtb[d];
  __syncthreads();
  #pragma unroll
  for (int r = 0; r < 16; r++) {
    float acc = dbv;
    #pragma unroll
    for (int j = 0; j < DTR_; j++) acc = fmaf(pr[r][j], dwr[j], acc);
    dty[(g0 + r) * DI_ + d] = softplusf(acc);
  }
}

// ---- chunked parallel selective scan (dt preloaded, both dirs in grid.z) ----
// xc comes from the bf16 {hi|lo} split: xc = bf2f(hi) + bf2f(lo).
__global__ __launch_bounds__(256) void k_scan1(const ushort* __restrict__ xch,
                                               const float* __restrict__ proj,
                                               const float* __restrict__ A_log,
                                               const float* __restrict__ dty,
                                               float* __restrict__ Hend,
                                               float* __restrict__ Pend) {
  int b = blockIdx.y, c = blockIdx.x, d = threadIdx.x, dir = blockIdx.z;
  float A[4];
  #pragma unroll
  for (int n = 0; n < 4; n++) A[n] = -expf(A_log[d * 4 + n]);
  long base = (long)b * L_;
  int step0 = c * CHL_;
  long row0 = base + (dir ? (L_ - 1 - step0) : step0);
  long doff = (long)dir * ROWS_;
  int rs = dir ? -1 : 1;
  const float* pdt = dty + (doff + row0) * DI_ + d;
  const ushort* pxc = xch + (doff + row0) * 512 + d;
  const float* pp  = proj + (doff + row0) * 33;
  float h[4] = {0.f, 0.f, 0.f, 0.f};
  float P[4] = {1.f, 1.f, 1.f, 1.f};
  for (int s = 0; s < CHL_; s++) {
    float dtv = *pdt;
    float xcv = bf2f(pxc[0]) + bf2f(pxc[256]);
    float dx = dtv * xcv;
    #pragma unroll
    for (int n = 0; n < 4; n++) {
      float dA = expf(dtv * A[n]);
      h[n] = dA * h[n] + dx * pp[DTR_ + n];
      P[n] *= dA;
    }
    pdt += (long)rs * DI_; pxc += (long)rs * 512; pp += rs * 33;
  }
  long o = (((long)dir * B_ + b) * CH_ + c) * 1024 + d * 4;
  *reinterpret_cast<float4*>(Hend + o) = make_float4(h[0], h[1], h[2], h[3]);
  *reinterpret_cast<float4*>(Pend + o) = make_float4(P[0], P[1], P[2], P[3]);
}

__global__ __launch_bounds__(256) void k_carry(const float* __restrict__ Hend,
                                               const float* __restrict__ Pend,
                                               float* __restrict__ Carry) {
  int tid = blockIdx.x * 256 + threadIdx.x;   // 2*B_*1024 lanes
  int be = tid >> 10, i = tid & 1023;         // be = dir*16+b
  float carry = 0.f;
  for (int c = 0; c < CH_; c++) {
    long o = ((long)be * CH_ + c) * 1024 + i;
    Carry[o] = carry;
    carry = Pend[o] * carry + Hend[o];
  }
}

// dty holds dt on entry; each element is read once then overwritten with y
// by the unique owning thread (read-before-write, no cross-thread sharing).
__global__ __launch_bounds__(256) void k_scan2(const ushort* __restrict__ xch,
                                               const float* __restrict__ proj,
                                               const float* __restrict__ A_log,
                                               const float* __restrict__ Dp,
                                               const float* __restrict__ xz,
                                               const float* __restrict__ Carry,
                                               float* dty) {
  int b = blockIdx.y, c = blockIdx.x, d = threadIdx.x, dir = blockIdx.z;
  float A[4];
  #pragma unroll
  for (int n = 0; n < 4; n++) A[n] = -expf(A_log[d * 4 + n]);
  long base = (long)b * L_;
  int step0 = c * CHL_;
  long row0 = base + (dir ? (L_ - 1 - step0) : step0);
  long doff = (long)dir * ROWS_;
  int rs = dir ? -1 : 1;
  float* pdy = dty + (doff + row0) * DI_ + d;
  const ushort* pxc = xch + (doff + row0) * 512 + d;
  const float* pz  = xz + row0 * (2 * DI_) + DI_ + d;
  const float* pp  = proj + (doff + row0) * 33;
  long o = (((long)dir * B_ + b) * CH_ + c) * 1024 + d * 4;
  float4 cv = *reinterpret_cast<const float4*>(Carry + o);
  float h[4] = {cv.x, cv.y, cv.z, cv.w};
  float Dv = Dp[d];
  for (int s = 0; s < CHL_; s++) {
    float dtv = *pdy;
    float xcv = bf2f(pxc[0]) + bf2f(pxc[256]);
    float zv  = *pz;
    float dx = dtv * xcv;
    float acc = 0.f;
    #pragma unroll
    for (int n = 0; n < 4; n++) {
      float dA = expf(dtv * A[n]);
      h[n] = dA * h[n] + dx * pp[DTR_ + n];
      acc = fmaf(h[n], pp[DTR_ + N_ + n], acc);
    }
    float yv = fmaf(Dv, xcv, acc);
    float sig = 1.f / (1.f + expf(-zv));
    yv *= zv * sig;
    *pdy = yv;
    pdy += (long)rs * DI_; pxc += (long)rs * 512;
    pz += rs * (2 * DI_); pp += rs * 33;
  }
}

// ---- residual + fq(mamba_out) + layernorm, wave-per-row ----------------------
// grid 640 x 256 (4 waves/block); each wave owns rows strided by 2560.
__global__ __launch_bounds__(256) void k_ln(const float* __restrict__ x2,
                                            float* __restrict__ mo,
                                            const float* __restrict__ smo,
                                            const float* __restrict__ g,
                                            const float* __restrict__ bta,
                                            float* __restrict__ nextmax) {
  __shared__ float smr[4];
  int lane = threadIdx.x & 63;
  int wid = blockIdx.x * 4 + (threadIdx.x >> 6);
  float s = fq_scale(smo);
  float wmax = 0.f;
  for (int row = wid; row < ROWS_; row += 2560) {
    const float* xr = x2 + (long)row * DM_;
    float* mr = mo + (long)row * DM_;
    float v[7];
    float lsum = 0.f;
    #pragma unroll
    for (int k = 0; k < 6; k++) {
      int c = lane + k * 64;
      v[k] = xr[c] + fq_apply(mr[c], s);
      lsum += v[k];
    }
    v[6] = 0.f;
    if (lane == 0) v[6] = xr[384] + fq_apply(mr[384], s);
    lsum += v[6];
    #pragma unroll
    for (int o = 32; o > 0; o >>= 1) lsum += __shfl_xor(lsum, o);
    float mean = lsum / 385.f;
    float lvar = 0.f;
    #pragma unroll
    for (int k = 0; k < 6; k++) { float dd = v[k] - mean; lvar += dd * dd; }
    if (lane == 0) { float dd = v[6] - mean; lvar += dd * dd; }
    #pragma unroll
    for (int o = 32; o > 0; o >>= 1) lvar += __shfl_xor(lvar, o);
    float rs = 1.f / sqrtf(lvar / 385.f + 1e-5f);
    #pragma unroll
    for (int k = 0; k < 6; k++) {
      int c = lane + k * 64;
      float o2 = (v[k] - mean) * rs * g[c] + bta[c];
      mr[c] = o2;
      wmax = fmaxf(wmax, fabsf(o2));
    }
    if (lane == 0) {
      float o2 = (v[6] - mean) * rs * g[384] + bta[384];
      mr[384] = o2;
      wmax = fmaxf(wmax, fabsf(o2));
    }
  }
  blockAtomicMax(wmax, nextmax, smr);
}

// ---- mean pool over L (two-stage, coalesced, deterministic) ------------------
__global__ __launch_bounds__(256) void k_pool1(const float* __restrict__ x2,
                                               float* __restrict__ part) {
  int b = blockIdx.x, ch = blockIdx.y, tid = threadIdx.x;
  float s0 = 0.f, s1 = 0.f;
  for (int l = ch * 64; l < ch * 64 + 64; l++) {
    const float* row = x2 + ((long)b * L_ + l) * DM_;
    s0 += row[tid];
    if (tid < DM_ - 256) s1 += row[tid + 256];
  }
  long o = ((long)b * 20 + ch) * DM_;
  part[o + tid] = s0;
  if (tid < DM_ - 256) part[o + tid + 256] = s1;
}

__global__ void k_pool2(const float* __restrict__ part, float* __restrict__ pool,
                        float* __restrict__ nextmax) {
  __shared__ float smr[8];
  int idx = blockIdx.x * 256 + threadIdx.x;
  float mv = 0.f;
  if (idx < B_ * DM_) {
    int b = idx / DM_, c = idx % DM_;
    float s = 0.f;
    for (int ch = 0; ch < 20; ch++) s += part[((long)b * 20 + ch) * DM_ + c];
    float mean = s / (float)L_;
    pool[idx] = mean;
    mv = fabsf(mean);
  }
  blockAtomicMax(mv, nextmax, smr);
}

// ---- classifier (parallel): grid 32 = (b,c), 128 threads reduce over K=385 --
__global__ __launch_bounds__(128) void k_cls(const float* __restrict__ pool,
                                             const float* __restrict__ clsw,
                                             const float* __restrict__ clsb,
                                             const float* __restrict__ sp_,
                                             const float* __restrict__ sw_,
                                             float* __restrict__ out) {
  __shared__ float smr[2];
  int b = blockIdx.x >> 1, c = blockIdx.x & 1;
  float sp = fq_scale(sp_), sw = fq_scale(sw_);
  float acc = 0.f;
  for (int k = threadIdx.x; k < DM_; k += 128) {
    float xv = fq_apply(pool[b * DM_ + k], sp);
    float wv = fq_apply(clsw[k * 2 + c], sw);
    acc = fmaf(xv, wv, acc);
  }
  #pragma unroll
  for (int o = 32; o > 0; o >>= 1) acc += __shfl_down(acc, o);
  if ((threadIdx.x & 63) == 0) smr[threadIdx.x >> 6] = acc;
  __syncthreads();
  if (threadIdx.x == 0) out[blockIdx.x] = smr[0] + smr[1] + clsb[c];
}

// ---- launch ------------------------------------------------------------------
extern "C" void kernel_launch(void* const* d_in, const int* in_sizes, int n_in,
                              void* d_out, int out_size, void* d_ws, size_t ws_size,
                              hipStream_t stream) {
  const float* x    = (const float*)d_in[0];
  const float* pew  = (const float*)d_in[1];
  const float* peb  = (const float*)d_in[2];
  const float* pos  = (const float*)d_in[3];
  const float* in_w = (const float*)d_in[4];
  const float* cw   = (const float*)d_in[5];
  const float* cb   = (const float*)d_in[6];
  const float* xpw  = (const float*)d_in[7];
  const float* dtw  = (const float*)d_in[8];
  const float* dtb  = (const float*)d_in[9];
  const float* alog = (const float*)d_in[10];
  const float* dp   = (const float*)d_in[11];
  const float* outw = (const float*)d_in[12];
  const float* lng  = (const float*)d_in[13];
  const float* lnb  = (const float*)d_in[14];
  const float* clsw = (const float*)d_in[15];
  const float* clsb = (const float*)d_in[16];

  float* ws    = (float*)d_ws;
  float* SCAL  = ws;                              // 13 scalars x 128 floats (8 slots)
  float* P2    = ws + 2048;                       // 492,800
  float* X2    = P2 + LDM_;                       // 7,884,800
  float* XZ    = X2 + NX_;                        // 10,485,760
  float* XCH_f = XZ + (long)ROWS_ * 512;          // 10,485,760 (ushort [40960][512])
  float* PROJ  = XCH_f + 2L * ROWS_ * DI_;        // 40960*33 = 1,351,680
  float* Y     = PROJ + 2L * ROWS_ * 33;          // 2 x 5,242,880 (dt -> y in place)
  float* MO    = Y + 2L * ROWS_ * DI_;            // 7,884,800
  float* POOL  = MO + NX_;                        // 8,192
  float* PART  = POOL + 8192;                     // 123,200 (+pad)
  float* A2IN_f= PART + 131072;                   // 4,096,000 f (ushort overlay)
  float* W2I_f = A2IN_f + 4096000;                // 409,600 f
  float* W2O_f = W2I_f + 409600;                  // 393,216 f
  float* W2X_f = W2O_f + 393216;                  // 98,304 f (2 x [128][768] ushort)
  // aliases (disjoint lifetimes):
  float*  HEND = MO;                              // scan summaries, dead before out-GEMM
  float*  PEND = MO + 2097152;
  float*  CARR = MO + 4194304;
  ushort* A2Y  = (ushort*)XZ;                     // [20480][512], dead before next in-GEMM
  ushort* XCH  = (ushort*)XCH_f;                  // xc bf16 {hi|lo} [40960][512]
  ushort* A2IN = (ushort*)A2IN_f;                 // [20480][400]
  ushort* W2TI = (ushort*)W2I_f;                  // 2 x [512][800]
  ushort* W2TO = (ushort*)W2O_f;                  // 2 x [512][768]
  ushort* W2TX = (ushort*)W2X_f;                  // 2 x [128][768]

  // scalar entry i lives at SCAL + i*SCALW (8 slots, 64B apart)
  #define SC(i) (SCAL + (i) * SCALW)

  k_zero<<<8, 256, 0, stream>>>(SCAL);

  // weight splits for MFMA GEMMs (tiny)
  for (int blk = 0; blk < 2; blk++) {
    k_wsplit<<<1600, 256, 0, stream>>>(in_w + (long)blk * DM_ * 512,
                                       W2TI + (long)blk * 512 * KPI_,
                                       DM_, 512, KPA_, KPI_, 512L * KPI_, 2);
    k_wsplit<<<1536, 256, 0, stream>>>(outw + (long)blk * DI_ * DM_,
                                       W2TO + (long)blk * 512 * KPO_,
                                       DI_, DM_, 256, KPO_, 512L * KPO_, 3);
    k_wsplit<<<384, 256, 0, stream>>>(xpw + (long)blk * DI_ * 33,
                                      W2TX + (long)blk * 128 * KPO_,
                                      DI_, 33, 256, KPO_, 128L * KPO_, 3);
  }
  k_padzero<<<1200, 256, 0, stream>>>(A2IN);

  // absmaxes + fused patch-embed (x and w fq'd inline)
  k_absmax<<<2048, 256, 0, stream>>>(x, (long)B_ * H_ * W_, SC(0));
  k_absmax<<<8, 256, 0, stream>>>(pew, EMB * 2 * 16, SC(1));
  k_absmax<<<512, 256, 0, stream>>>(pos, LDM_, SC(4));
  k_patchfq<<<dim3(20, 11, 16), 320, 0, stream>>>(x, pew, peb, SC(0), SC(1), X2, SC(2));

  // pos = fq(fq(pos_embed)) == fq(pos_embed)  (fq idempotent)
  k_fq4<<<512, 256, 0, stream>>>((const float4*)pos, (float4*)P2, LDM_ / 4,
                                 SC(4), nullptr, nullptr);

  // x = fq(fq(x) + pos) with inner fq(x) = fq(patch_out, s2) (outer chain identity)
  k_addpos4<<<2048, 256, 0, stream>>>((float4*)X2, (const float4*)P2, SC(2), SC(6));
  k_fq4<<<2048, 256, 0, stream>>>((const float4*)X2, (float4*)X2, NX_ / 4,
                                  SC(6), nullptr, A2IN);

  const float* in_scale[2] = {SC(6), SC(8)};
  for (int blk = 0; blk < 2; blk++) {
    // in-proj: XZ = s * (q @ [w_hi; w_lo])   (MFMA bf16, A k-wrapped at 400)
    k_mgemm<false><<<640, 256, 0, stream>>>(
        A2IN, W2TI + (long)blk * 512 * KPI_, XZ, 512, KPI_, KPA_, 160,
        in_scale[blk], nullptr);
    // conv both dirs -> xc bf16 {hi|lo}; xp-proj via MFMA (N=33 in one tile)
    k_conv2<<<dim3(80, 16), 256, 0, stream>>>(XZ, cw + blk * DI_ * K_,
                                              cb + blk * DI_, XCH);
    k_mgemm<false><<<320, 256, 0, stream>>>(
        XCH, W2TX + (long)blk * 128 * KPO_, PROJ, 33, KPO_, WAO_, 320,
        nullptr, nullptr);
    k_dtp<<<2560, 256, 0, stream>>>(PROJ, dtw + blk * DTR_ * DI_, dtb + blk * DI_, Y);
    k_scan1<<<dim3(CH_, B_, 2), 256, 0, stream>>>(XCH, PROJ, alog + blk * DI_ * N_,
                                                  Y, HEND, PEND);
    k_carry<<<128, 256, 0, stream>>>(HEND, PEND, CARR);
    k_scan2<<<dim3(CH_, B_, 2), 256, 0, stream>>>(XCH, PROJ, alog + blk * DI_ * N_,
                                                  dp + blk * DI_, XZ, CARR, Y);
    // out-proj: MO = [y_hi | y_lo] (wrapped) @ [w_hi; w_hi; w_lo]  (amax fused)
    k_asplit2<<<40960, 256, 0, stream>>>(Y, A2Y);
    k_mgemm<true><<<640, 256, 0, stream>>>(
        A2Y, W2TO + (long)blk * 512 * KPO_, MO, DM_, KPO_, WAO_, 160,
        nullptr, SC(7 + blk * 2));
    // x = fq(layernorm(x + fq(mo))); emit q for next block's in-proj
    k_ln<<<640, 256, 0, stream>>>(X2, MO, SC(7 + blk * 2),
                                  lng + blk * DM_, lnb + blk * DM_, SC(8 + blk * 2));
    k_fq4<<<2048, 256, 0, stream>>>((const float4*)MO, (float4*)X2, NX_ / 4,
                                    SC(8 + blk * 2), nullptr,
                                    blk == 0 ? A2IN : nullptr);
  }

  // mean-pool (2-stage), fq, classifier with fq(cls_w)
  k_pool1<<<dim3(16, 20), 256, 0, stream>>>(X2, PART);
  k_pool2<<<25, 256, 0, stream>>>(PART, POOL, SC(11));
  k_absmax<<<4, 256, 0, stream>>>(clsw, DM_ * 2, SC(12));
  k_cls<<<32, 128, 0, stream>>>(POOL, clsw, clsb, SC(11), SC(12), (float*)d_out);
}

// Round 11
// 641.135 us; speedup vs baseline: 7.7874x; 1.0212x over previous
//
#include <hip/hip_runtime.h>
#include <hip/hip_bf16.h>
#include <math.h>

// ---- problem constants -----------------------------------------------------
#define B_    16
#define H_    22
#define W_    20480
#define EMB   35
#define GH_   11
#define GW_   1280
#define L_    1280
#define DM_   385
#define DI_   256
#define N_    4
#define K_    4
#define DTR_  25
#define ROWS_ (B_*L_)              // 20480
#define NX_   ((long)ROWS_*DM_)    // 7,884,800
#define LDM_  ((long)L_*DM_)       // 492,800
#define CH_   64                   // scan chunks
#define CHL_  20                   // steps per chunk (CH_*CHL_ == L_)
#define KPI_  800                  // in_proj W K' (2 terms x 400)
#define KPA_  400                  // in_proj A width (q stored once, padded)
#define KPO_  768                  // out/xp W K' (3 terms x 256)
#define WAO_  512                  // out/xp A width ({hi,lo})

// amax scalars: 8 slots x 64B apart to break single-address atomic serialization
#define NSLOT 8
#define SSTR  16                   // floats between slots (64 B)
#define SCALW 128                  // floats per logical scalar (8 slots)

// LDS sl-plane stride (ushorts): 128 rows x 8 + 8 pad -> +16B per plane.
// Byte granule becomes (sl+row)&7: conflict-free writes AND reads.
#define SLP_  2056

typedef __attribute__((ext_vector_type(8))) short short8;
typedef __attribute__((ext_vector_type(4))) float f32x4;
typedef unsigned short ushort;

// ---- helpers ---------------------------------------------------------------
__device__ __forceinline__ void atomicMaxF(float* a, float v) {
  atomicMax(reinterpret_cast<int*>(a), __float_as_int(v));
}

// faithful fq: s = max(mx,1e-8)/127 where mx = max over the 8 slots
__device__ __forceinline__ float fq_scale(const float* pmax) {
  float m = pmax[0];
  #pragma unroll
  for (int i = 1; i < NSLOT; i++) m = fmaxf(m, pmax[i * SSTR]);
  return fmaxf(m, 1e-8f) / 127.f;
}
__device__ __forceinline__ float fq_apply(float x, float s) {
  float r = rintf(x / s);
  r = fminf(fmaxf(r, -128.f), 127.f);
  return r * s;
}

__device__ __forceinline__ ushort f2bf(float f) {  // round-to-nearest-even
  union { float f; unsigned u; } v; v.f = f;
  unsigned r = v.u + 0x7FFF + ((v.u >> 16) & 1);
  return (ushort)(r >> 16);
}
__device__ __forceinline__ float bf2f(ushort h) {
  union { unsigned u; float f; } v; v.u = ((unsigned)h) << 16;
  return v.f;
}

// block max -> atomicMax into one of 8 slots (by block id). sm >= blockDim/64.
__device__ __forceinline__ void blockAtomicMax(float v, float* out, float* sm) {
  #pragma unroll
  for (int o = 32; o > 0; o >>= 1) v = fmaxf(v, __shfl_down(v, o));
  if ((threadIdx.x & 63) == 0) sm[threadIdx.x >> 6] = v;
  __syncthreads();
  if (threadIdx.x == 0) {
    int nw = (blockDim.x + 63) >> 6;
    for (int i = 1; i < nw; i++) v = fmaxf(v, sm[i]);
    int slot = (blockIdx.x + blockIdx.y * 4 + blockIdx.z) & (NSLOT - 1);
    atomicMaxF(out + slot * SSTR, v);
  }
}

// ---- small utility kernels -------------------------------------------------
__global__ void k_zero(float* s) { s[blockIdx.x * 256 + threadIdx.x] = 0.f; }

__global__ void k_absmax(const float* __restrict__ src, long n, float* __restrict__ out) {
  __shared__ float smr[8];
  float m = 0.f;
  for (long i = (long)blockIdx.x * blockDim.x + threadIdx.x; i < n;
       i += (long)gridDim.x * blockDim.x)
    m = fmaxf(m, fabsf(src[i]));
  blockAtomicMax(m, out, smr);
}

// vectorized fq: dst4 = fq(src4); optional absmax -> nextmax; optional bf16
// q-emit into A2 [M][KPA_]. dst may == src.
__global__ void k_fq4(const float4* __restrict__ src, float4* __restrict__ dst, long n4,
                      const float* __restrict__ pmax, float* __restrict__ nextmax,
                      ushort* __restrict__ a2) {
  __shared__ float smr[8];
  float s = fq_scale(pmax);
  float m = 0.f;
  for (long i = (long)blockIdx.x * blockDim.x + threadIdx.x; i < n4;
       i += (long)gridDim.x * blockDim.x) {
    float4 v = src[i];
    float r0 = fminf(fmaxf(rintf(v.x / s), -128.f), 127.f);
    float r1 = fminf(fmaxf(rintf(v.y / s), -128.f), 127.f);
    float r2 = fminf(fmaxf(rintf(v.z / s), -128.f), 127.f);
    float r3 = fminf(fmaxf(rintf(v.w / s), -128.f), 127.f);
    float4 q = make_float4(r0 * s, r1 * s, r2 * s, r3 * s);
    dst[i] = q;
    m = fmaxf(m, fmaxf(fmaxf(fabsf(q.x), fabsf(q.y)), fmaxf(fabsf(q.z), fabsf(q.w))));
    if (a2) {
      long ii = i * 4;
      long mm = ii / 385; int kk = (int)(ii - mm * 385);
      float rr[4] = {r0, r1, r2, r3};
      #pragma unroll
      for (int j = 0; j < 4; j++) {
        a2[mm * KPA_ + kk] = f2bf(rr[j]);
        if (++kk == 385) { kk = 0; mm++; }
      }
    }
  }
  if (nextmax) blockAtomicMax(m, nextmax, smr);
}

// x4[i] = fq(x4[i], s_pmax) + p2[i % LDM/4]; absmax -> nextmax
// (the reference's extra fq() layers are identities: fq(fq(t)) == fq(t))
__global__ void k_addpos4(float4* __restrict__ x, const float4* __restrict__ p2,
                          const float* __restrict__ pmax, float* __restrict__ nextmax) {
  __shared__ float smr[8];
  float s = fq_scale(pmax);
  float m = 0.f;
  const long n4 = NX_ / 4, l4 = LDM_ / 4;
  for (long i = (long)blockIdx.x * blockDim.x + threadIdx.x; i < n4;
       i += (long)gridDim.x * blockDim.x) {
    float4 v = x[i];
    float4 p = p2[i % l4];
    float4 o;
    o.x = fq_apply(v.x, s) + p.x;
    o.y = fq_apply(v.y, s) + p.y;
    o.z = fq_apply(v.z, s) + p.z;
    o.w = fq_apply(v.w, s) + p.w;
    x[i] = o;
    m = fmaxf(m, fmaxf(fmaxf(fabsf(o.x), fabsf(o.y)), fmaxf(fabsf(o.z), fabsf(o.w))));
  }
  blockAtomicMax(m, nextmax, smr);
}

// ---- fused patch embed: LDS-staged x (fq inline), fq'd weights in VGPRs -----
// block = (gw-tile of 64, gh, b); 320 threads (280 active in compute)
__global__ __launch_bounds__(320) void k_patchfq(const float* __restrict__ x,
                                                 const float* __restrict__ pew,
                                                 const float* __restrict__ peb,
                                                 const float* __restrict__ sx_,
                                                 const float* __restrict__ sw_,
                                                 float* __restrict__ out,
                                                 float* __restrict__ nextmax) {
  __shared__ float xs[2][64][20];   // [ph][gw_local][pw] padded to 20
  __shared__ float smr[8];
  int tid = threadIdx.x;
  int gwt = blockIdx.x, gh = blockIdx.y, b = blockIdx.z;
  float sx = fq_scale(sx_), sw = fq_scale(sw_);
  if (tid < 256) {
    int gwl = tid >> 2, pw = (tid & 3) * 4;
    #pragma unroll
    for (int ph = 0; ph < 2; ph++) {
      const float* src = x + ((long)b * H_ + gh * 2 + ph) * W_ + (long)gwt * 1024 + tid * 4;
      float4 v = *reinterpret_cast<const float4*>(src);
      xs[ph][gwl][pw + 0] = fq_apply(v.x, sx);
      xs[ph][gwl][pw + 1] = fq_apply(v.y, sx);
      xs[ph][gwl][pw + 2] = fq_apply(v.z, sx);
      xs[ph][gwl][pw + 3] = fq_apply(v.w, sx);
    }
  }
  __syncthreads();
  float mx = 0.f;
  if (tid < 280) {
    int e = tid % 35;
    int g0 = (tid / 35) * 8;
    float w[32];
    #pragma unroll
    for (int j = 0; j < 32; j++) w[j] = fq_apply(pew[e * 32 + j], sw);
    float bias = peb[e];
    long obase = ((long)b * GW_ + (long)gwt * 64) * DM_ + gh * 35 + e;
    #pragma unroll
    for (int gi = 0; gi < 8; gi++) {
      int gw = g0 + gi;
      float acc = bias;
      #pragma unroll
      for (int pw = 0; pw < 16; pw++) {
        acc = fmaf(xs[0][gw][pw], w[pw], acc);
        acc = fmaf(xs[1][gw][pw], w[16 + pw], acc);
      }
      out[obase + (long)gw * DM_] = acc;
      mx = fmaxf(mx, fabsf(acc));
    }
  }
  blockAtomicMax(mx, nextmax, smr);
}

// ---- weight split: W[K][N] f32 -> W2T[Npad][Kp] bf16 ------------------------
// term t occupies cols [t*Kw, t*Kw+K); value = lo at t==terms-1 else hi.
__global__ void k_wsplit(const float* __restrict__ W, ushort* __restrict__ out,
                         int K, int N, int Kw, int Kp, long total, int terms) {
  long idx = (long)blockIdx.x * 256 + threadIdx.x;
  if (idx >= total) return;
  int k = (int)(idx % Kp);
  int n = (int)(idx / Kp);
  int t = k / Kw, kk = k - t * Kw;
  ushort r = 0;
  if (n < N && kk < K) {
    float w = W[(long)kk * N + n];
    ushort hi = f2bf(w);
    r = (t == terms - 1) ? f2bf(w - bf2f(hi)) : hi;
  }
  out[idx] = r;
}

// ---- activation split: (Y0+Y1)[M][256] f32 -> A2[M][512] bf16 {hi,lo} -------
__global__ void k_asplit2(const float* __restrict__ Y, ushort* __restrict__ A2) {
  long idx = (long)blockIdx.x * 256 + threadIdx.x;   // M*512 threads
  long m = idx >> 9; int k = (int)(idx & 511);
  int t = k >> 8, kk = k & 255;
  float v = Y[m * DI_ + kk] + Y[(m + ROWS_) * DI_ + kk];
  ushort hi = f2bf(v);
  A2[idx] = t ? f2bf(v - bf2f(hi)) : hi;
}

// zero the pad columns [385, 400) of A2IN
__global__ void k_padzero(ushort* __restrict__ A2) {
  long idx = (long)blockIdx.x * 256 + threadIdx.x;   // ROWS_*15 threads
  long m = idx / 15; int c = (int)(idx - m * 15);
  A2[m * KPA_ + 385 + c] = 0;
}

// ---- bf16 MFMA GEMM: C[M][Nreal] = scale * (A2[M][Wa,wrapped] @ W2T[Npad][Kp]^T)
// 1-D grid NT*MT with m = bid%MT, n = bid/MT: same-m blocks are MT apart ->
// same XCD (MT % 8 == 0) -> shared L2 A-panel. LDS sl-stride padded (+16B)
// so write/read granule = (sl+row)&7: conflict-free.
template<bool AMAX>
__global__ __launch_bounds__(256) void k_mgemm(const ushort* __restrict__ A2,
                                               const ushort* __restrict__ W2T,
                                               float* __restrict__ C,
                                               int Nreal, int Kp, int Wa, int MT,
                                               const float* __restrict__ sptr,
                                               float* __restrict__ amax_out) {
  __shared__ ushort Alds[4 * SLP_];   // plane sl at sl*SLP_, row*8 within
  __shared__ ushort Blds[4 * SLP_];
  __shared__ float smr[8];
  int tid = threadIdx.x;
  int lane = tid & 63, wave = tid >> 6;
  int wm = wave >> 1, wn = wave & 1;
  int bid = blockIdx.x;
  int m0 = (bid % MT) * 128, n0 = (bid / MT) * 128;
  f32x4 acc[4][4];
  #pragma unroll
  for (int i = 0; i < 4; i++)
    #pragma unroll
    for (int j = 0; j < 4; j++) acc[i][j] = (f32x4){0.f, 0.f, 0.f, 0.f};

  for (int k0 = 0; k0 < Kp; k0 += 32) {
    #pragma unroll
    for (int r = 0; r < 2; r++) {
      int id = tid + r * 256;            // 0..511
      int row = id >> 2, sl = id & 3;    // coalesced 64B global segments
      int kc = k0 + sl * 8; if (kc >= Wa) kc -= Wa;   // A k-wrap (8-aligned)
      short8 va = *reinterpret_cast<const short8*>(A2 + (long)(m0 + row) * Wa + kc);
      *reinterpret_cast<short8*>(&Alds[sl * SLP_ + row * 8]) = va;
      short8 vb = *reinterpret_cast<const short8*>(W2T + (long)(n0 + row) * Kp + k0 + sl * 8);
      *reinterpret_cast<short8*>(&Blds[sl * SLP_ + row * 8]) = vb;
    }
    __syncthreads();
    int sl = lane >> 4, rr = lane & 15;
    short8 af[4], bf4[4];
    #pragma unroll
    for (int i = 0; i < 4; i++)
      af[i] = *reinterpret_cast<const short8*>(&Alds[sl * SLP_ + (wm * 64 + i * 16 + rr) * 8]);
    #pragma unroll
    for (int j = 0; j < 4; j++)
      bf4[j] = *reinterpret_cast<const short8*>(&Blds[sl * SLP_ + (wn * 64 + j * 16 + rr) * 8]);
    #pragma unroll
    for (int i = 0; i < 4; i++)
      #pragma unroll
      for (int j = 0; j < 4; j++)
        acc[i][j] = __builtin_amdgcn_mfma_f32_16x16x32_bf16(af[i], bf4[j], acc[i][j], 0, 0, 0);
    __syncthreads();
  }

  float s = sptr ? fq_scale(sptr) : 1.0f;
  float mx = 0.f;
  int cfr = lane & 15, rbase = (lane >> 4) * 4;
  #pragma unroll
  for (int i = 0; i < 4; i++) {
    int gmb = m0 + wm * 64 + i * 16 + rbase;
    #pragma unroll
    for (int j = 0; j < 4; j++) {
      int gn = n0 + wn * 64 + j * 16 + cfr;
      if (gn < Nreal) {
        #pragma unroll
        for (int rg = 0; rg < 4; rg++) {
          float v = acc[i][j][rg] * s;
          C[(long)(gmb + rg) * Nreal + gn] = v;
          mx = fmaxf(mx, fabsf(v));
        }
      }
    }
  }
  if (AMAX) blockAtomicMax(mx, amax_out, smr);
}

// ---- depthwise causal conv1d (K=4) + SiLU, BOTH dirs from one window --------
// Emits xc directly as bf16 {hi | lo} split A2XC[g][512] (g = dir*ROWS + row)
// for the xp MFMA GEMM; scans reconstruct xc = hi + lo.
__global__ __launch_bounds__(256) void k_conv2(const float* __restrict__ xz,
                                               const float* __restrict__ cw,
                                               const float* __restrict__ cb,
                                               ushort* __restrict__ xch) {
  int d = threadIdx.x;
  int t0 = blockIdx.x * 16, b = blockIdx.y;
  long base = (long)b * L_;
  float w0 = cw[d * 4 + 0], w1 = cw[d * 4 + 1];
  float w2 = cw[d * 4 + 2], w3 = cw[d * 4 + 3];
  float bias = cb[d];
  float win[22];
  #pragma unroll
  for (int i = 0; i < 22; i++) {
    int t = t0 - 3 + i;
    win[i] = (t >= 0 && t < L_) ? xz[(base + t) * (2 * DI_) + d] : 0.f;
  }
  #pragma unroll
  for (int i = 0; i < 16; i++) {
    int t = t0 + i;
    // dir0, j ascending (bit-identical order)
    float a0 = bias;
    a0 = fmaf(w0, win[i + 0], a0);
    a0 = fmaf(w1, win[i + 1], a0);
    a0 = fmaf(w2, win[i + 2], a0);
    a0 = fmaf(w3, win[i + 3], a0);
    // dir1: taps reversed in t
    float a1 = bias;
    a1 = fmaf(w0, win[i + 6], a1);
    a1 = fmaf(w1, win[i + 5], a1);
    a1 = fmaf(w2, win[i + 4], a1);
    a1 = fmaf(w3, win[i + 3], a1);
    float v0 = a0 * (1.f / (1.f + expf(-a0)));
    float v1 = a1 * (1.f / (1.f + expf(-a1)));
    long g0o = (base + t) * 512 + d;
    ushort h0 = f2bf(v0), h1 = f2bf(v1);
    xch[g0o] = h0;
    xch[g0o + 256] = f2bf(v0 - bf2f(h0));
    long g1o = ((long)ROWS_ + base + t) * 512 + d;
    xch[g1o] = h1;
    xch[g1o + 256] = f2bf(v1 - bf2f(h1));
  }
}

// ---- dt precompute: dty[g][d] = softplus(proj[g][0:25] @ dtw[:,d] + dtb[d]) --
// g spans both dirs (2*ROWS rows). Written into the Y buffer (see aliasing note
// at k_scan2: scan2 reads dt then overwrites the same element with y).
__device__ __forceinline__ float softplusf(float x) {
  return fmaxf(x, 0.f) + log1pf(expf(-fabsf(x)));
}

__global__ __launch_bounds__(256) void k_dtp(const float* __restrict__ proj,
                                             const float* __restrict__ dtw,
                                             const float* __restrict__ dtb,
                                             float* __restrict__ dty) {
  __shared__ float pr[16][26];
  int d = threadIdx.x;
  long g0 = (long)blockIdx.x * 16;
  for (int i = threadIdx.x; i < 16 * DTR_; i += 256) {
    int r = i / DTR_, j = i - r * DTR_;
    pr[r][j] = proj[(g0 + r) * 33 + j];
  }
  float dwr[DTR_];
  #pragma unroll
  for (int r = 0; r < DTR_; r++) dwr[r] = dtw[r * DI_ + d];
  float dbv = dtb[d];
  __syncthreads();
  #pragma unroll
  for (int r = 0; r < 16; r++) {
    float acc = dbv;
    #pragma unroll
    for (int j = 0; j < DTR_; j++) acc = fmaf(pr[r][j], dwr[j], acc);
    dty[(g0 + r) * DI_ + d] = softplusf(acc);
  }
}

// ---- chunked parallel selective scan (dt preloaded, both dirs in grid.z) ----
// xc from bf16 {hi|lo}: xc = bf2f(hi) + bf2f(lo).
// exp reduction: (a) P[n] = exp(A[n] * sum(dt)) computed once per chunk
// (exactly Π exp(dt_s A[n]) mathematically); (b) when A[n] == (n+1)*A[0]
// (true for this model: A = -(1,2,3,4)), dA_n = e1^(n+1) with a single
// exp per step. Guarded at runtime; falls back to the general 4-exp loop.
__global__ __launch_bounds__(256) void k_scan1(const ushort* __restrict__ xch,
                                               const float* __restrict__ proj,
                                               const float* __restrict__ A_log,
                                               const float* __restrict__ dty,
                                               float* __restrict__ Hend,
                                               float* __restrict__ Pend) {
  int b = blockIdx.y, c = blockIdx.x, d = threadIdx.x, dir = blockIdx.z;
  float A[4];
  #pragma unroll
  for (int n = 0; n < 4; n++) A[n] = -expf(A_log[d * 4 + n]);
  bool fast = true;
  #pragma unroll
  for (int n = 1; n < 4; n++)
    fast = fast && (fabsf(A[n] - (float)(n + 1) * A[0]) <= 1e-4f * fabsf(A[n]));
  long base = (long)b * L_;
  int step0 = c * CHL_;
  long row0 = base + (dir ? (L_ - 1 - step0) : step0);
  long doff = (long)dir * ROWS_;
  int rs = dir ? -1 : 1;
  const float* pdt = dty + (doff + row0) * DI_ + d;
  const ushort* pxc = xch + (doff + row0) * 512 + d;
  const float* pp  = proj + (doff + row0) * 33;
  float h[4] = {0.f, 0.f, 0.f, 0.f};
  float sdt = 0.f;
  if (fast) {
    float A0 = A[0];
    for (int s = 0; s < CHL_; s++) {
      float dtv = *pdt;
      float xcv = bf2f(pxc[0]) + bf2f(pxc[256]);
      float dx = dtv * xcv;
      float e1 = expf(dtv * A0);
      float e2 = e1 * e1, e3 = e2 * e1, e4 = e3 * e1;
      h[0] = e1 * h[0] + dx * pp[DTR_ + 0];
      h[1] = e2 * h[1] + dx * pp[DTR_ + 1];
      h[2] = e3 * h[2] + dx * pp[DTR_ + 2];
      h[3] = e4 * h[3] + dx * pp[DTR_ + 3];
      sdt += dtv;
      pdt += (long)rs * DI_; pxc += (long)rs * 512; pp += rs * 33;
    }
  } else {
    for (int s = 0; s < CHL_; s++) {
      float dtv = *pdt;
      float xcv = bf2f(pxc[0]) + bf2f(pxc[256]);
      float dx = dtv * xcv;
      #pragma unroll
      for (int n = 0; n < 4; n++) {
        float dA = expf(dtv * A[n]);
        h[n] = dA * h[n] + dx * pp[DTR_ + n];
      }
      sdt += dtv;
      pdt += (long)rs * DI_; pxc += (long)rs * 512; pp += rs * 33;
    }
  }
  float P[4];
  #pragma unroll
  for (int n = 0; n < 4; n++) P[n] = expf(A[n] * sdt);
  long o = (((long)dir * B_ + b) * CH_ + c) * 1024 + d * 4;
  *reinterpret_cast<float4*>(Hend + o) = make_float4(h[0], h[1], h[2], h[3]);
  *reinterpret_cast<float4*>(Pend + o) = make_float4(P[0], P[1], P[2], P[3]);
}

__global__ __launch_bounds__(256) void k_carry(const float* __restrict__ Hend,
                                               const float* __restrict__ Pend,
                                               float* __restrict__ Carry) {
  int tid = blockIdx.x * 256 + threadIdx.x;   // 2*B_*1024 lanes
  int be = tid >> 10, i = tid & 1023;         // be = dir*16+b
  float carry = 0.f;
  for (int c = 0; c < CH_; c++) {
    long o = ((long)be * CH_ + c) * 1024 + i;
    Carry[o] = carry;
    carry = Pend[o] * carry + Hend[o];
  }
}

// dty holds dt on entry; each element is read once then overwritten with y
// by the unique owning thread (read-before-write, no cross-thread sharing).
// Same exp-reduction fast path as k_scan1.
__global__ __launch_bounds__(256) void k_scan2(const ushort* __restrict__ xch,
                                               const float* __restrict__ proj,
                                               const float* __restrict__ A_log,
                                               const float* __restrict__ Dp,
                                               const float* __restrict__ xz,
                                               const float* __restrict__ Carry,
                                               float* dty) {
  int b = blockIdx.y, c = blockIdx.x, d = threadIdx.x, dir = blockIdx.z;
  float A[4];
  #pragma unroll
  for (int n = 0; n < 4; n++) A[n] = -expf(A_log[d * 4 + n]);
  bool fast = true;
  #pragma unroll
  for (int n = 1; n < 4; n++)
    fast = fast && (fabsf(A[n] - (float)(n + 1) * A[0]) <= 1e-4f * fabsf(A[n]));
  long base = (long)b * L_;
  int step0 = c * CHL_;
  long row0 = base + (dir ? (L_ - 1 - step0) : step0);
  long doff = (long)dir * ROWS_;
  int rs = dir ? -1 : 1;
  float* pdy = dty + (doff + row0) * DI_ + d;
  const ushort* pxc = xch + (doff + row0) * 512 + d;
  const float* pz  = xz + row0 * (2 * DI_) + DI_ + d;
  const float* pp  = proj + (doff + row0) * 33;
  long o = (((long)dir * B_ + b) * CH_ + c) * 1024 + d * 4;
  float4 cv = *reinterpret_cast<const float4*>(Carry + o);
  float h[4] = {cv.x, cv.y, cv.z, cv.w};
  float Dv = Dp[d];
  if (fast) {
    float A0 = A[0];
    for (int s = 0; s < CHL_; s++) {
      float dtv = *pdy;
      float xcv = bf2f(pxc[0]) + bf2f(pxc[256]);
      float zv  = *pz;
      float dx = dtv * xcv;
      float e1 = expf(dtv * A0);
      float e2 = e1 * e1, e3 = e2 * e1, e4 = e3 * e1;
      h[0] = e1 * h[0] + dx * pp[DTR_ + 0];
      h[1] = e2 * h[1] + dx * pp[DTR_ + 1];
      h[2] = e3 * h[2] + dx * pp[DTR_ + 2];
      h[3] = e4 * h[3] + dx * pp[DTR_ + 3];
      float acc = 0.f;
      acc = fmaf(h[0], pp[DTR_ + N_ + 0], acc);
      acc = fmaf(h[1], pp[DTR_ + N_ + 1], acc);
      acc = fmaf(h[2], pp[DTR_ + N_ + 2], acc);
      acc = fmaf(h[3], pp[DTR_ + N_ + 3], acc);
      float yv = fmaf(Dv, xcv, acc);
      float sig = 1.f / (1.f + expf(-zv));
      yv *= zv * sig;
      *pdy = yv;
      pdy += (long)rs * DI_; pxc += (long)rs * 512;
      pz += rs * (2 * DI_); pp += rs * 33;
    }
  } else {
    for (int s = 0; s < CHL_; s++) {
      float dtv = *pdy;
      float xcv = bf2f(pxc[0]) + bf2f(pxc[256]);
      float zv  = *pz;
      float dx = dtv * xcv;
      float acc = 0.f;
      #pragma unroll
      for (int n = 0; n < 4; n++) {
        float dA = expf(dtv * A[n]);
        h[n] = dA * h[n] + dx * pp[DTR_ + n];
        acc = fmaf(h[n], pp[DTR_ + N_ + n], acc);
      }
      float yv = fmaf(Dv, xcv, acc);
      float sig = 1.f / (1.f + expf(-zv));
      yv *= zv * sig;
      *pdy = yv;
      pdy += (long)rs * DI_; pxc += (long)rs * 512;
      pz += rs * (2 * DI_); pp += rs * 33;
    }
  }
}

// ---- residual + fq(mamba_out) + layernorm, wave-per-row ----------------------
// grid 640 x 256 (4 waves/block); each wave owns rows strided by 2560.
__global__ __launch_bounds__(256) void k_ln(const float* __restrict__ x2,
                                            float* __restrict__ mo,
                                            const float* __restrict__ smo,
                                            const float* __restrict__ g,
                                            const float* __restrict__ bta,
                                            float* __restrict__ nextmax) {
  __shared__ float smr[4];
  int lane = threadIdx.x & 63;
  int wid = blockIdx.x * 4 + (threadIdx.x >> 6);
  float s = fq_scale(smo);
  float wmax = 0.f;
  for (int row = wid; row < ROWS_; row += 2560) {
    const float* xr = x2 + (long)row * DM_;
    float* mr = mo + (long)row * DM_;
    float v[7];
    float lsum = 0.f;
    #pragma unroll
    for (int k = 0; k < 6; k++) {
      int c = lane + k * 64;
      v[k] = xr[c] + fq_apply(mr[c], s);
      lsum += v[k];
    }
    v[6] = 0.f;
    if (lane == 0) v[6] = xr[384] + fq_apply(mr[384], s);
    lsum += v[6];
    #pragma unroll
    for (int o = 32; o > 0; o >>= 1) lsum += __shfl_xor(lsum, o);
    float mean = lsum / 385.f;
    float lvar = 0.f;
    #pragma unroll
    for (int k = 0; k < 6; k++) { float dd = v[k] - mean; lvar += dd * dd; }
    if (lane == 0) { float dd = v[6] - mean; lvar += dd * dd; }
    #pragma unroll
    for (int o = 32; o > 0; o >>= 1) lvar += __shfl_xor(lvar, o);
    float rs = 1.f / sqrtf(lvar / 385.f + 1e-5f);
    #pragma unroll
    for (int k = 0; k < 6; k++) {
      int c = lane + k * 64;
      float o2 = (v[k] - mean) * rs * g[c] + bta[c];
      mr[c] = o2;
      wmax = fmaxf(wmax, fabsf(o2));
    }
    if (lane == 0) {
      float o2 = (v[6] - mean) * rs * g[384] + bta[384];
      mr[384] = o2;
      wmax = fmaxf(wmax, fabsf(o2));
    }
  }
  blockAtomicMax(wmax, nextmax, smr);
}

// ---- mean pool over L (two-stage, coalesced, deterministic) ------------------
__global__ __launch_bounds__(256) void k_pool1(const float* __restrict__ x2,
                                               float* __restrict__ part) {
  int b = blockIdx.x, ch = blockIdx.y, tid = threadIdx.x;
  float s0 = 0.f, s1 = 0.f;
  for (int l = ch * 64; l < ch * 64 + 64; l++) {
    const float* row = x2 + ((long)b * L_ + l) * DM_;
    s0 += row[tid];
    if (tid < DM_ - 256) s1 += row[tid + 256];
  }
  long o = ((long)b * 20 + ch) * DM_;
  part[o + tid] = s0;
  if (tid < DM_ - 256) part[o + tid + 256] = s1;
}

__global__ void k_pool2(const float* __restrict__ part, float* __restrict__ pool,
                        float* __restrict__ nextmax) {
  __shared__ float smr[8];
  int idx = blockIdx.x * 256 + threadIdx.x;
  float mv = 0.f;
  if (idx < B_ * DM_) {
    int b = idx / DM_, c = idx % DM_;
    float s = 0.f;
    for (int ch = 0; ch < 20; ch++) s += part[((long)b * 20 + ch) * DM_ + c];
    float mean = s / (float)L_;
    pool[idx] = mean;
    mv = fabsf(mean);
  }
  blockAtomicMax(mv, nextmax, smr);
}

// ---- classifier (parallel): grid 32 = (b,c), 128 threads reduce over K=385 --
__global__ __launch_bounds__(128) void k_cls(const float* __restrict__ pool,
                                             const float* __restrict__ clsw,
                                             const float* __restrict__ clsb,
                                             const float* __restrict__ sp_,
                                             const float* __restrict__ sw_,
                                             float* __restrict__ out) {
  __shared__ float smr[2];
  int b = blockIdx.x >> 1, c = blockIdx.x & 1;
  float sp = fq_scale(sp_), sw = fq_scale(sw_);
  float acc = 0.f;
  for (int k = threadIdx.x; k < DM_; k += 128) {
    float xv = fq_apply(pool[b * DM_ + k], sp);
    float wv = fq_apply(clsw[k * 2 + c], sw);
    acc = fmaf(xv, wv, acc);
  }
  #pragma unroll
  for (int o = 32; o > 0; o >>= 1) acc += __shfl_down(acc, o);
  if ((threadIdx.x & 63) == 0) smr[threadIdx.x >> 6] = acc;
  __syncthreads();
  if (threadIdx.x == 0) out[blockIdx.x] = smr[0] + smr[1] + clsb[c];
}

// ---- launch ------------------------------------------------------------------
extern "C" void kernel_launch(void* const* d_in, const int* in_sizes, int n_in,
                              void* d_out, int out_size, void* d_ws, size_t ws_size,
                              hipStream_t stream) {
  const float* x    = (const float*)d_in[0];
  const float* pew  = (const float*)d_in[1];
  const float* peb  = (const float*)d_in[2];
  const float* pos  = (const float*)d_in[3];
  const float* in_w = (const float*)d_in[4];
  const float* cw   = (const float*)d_in[5];
  const float* cb   = (const float*)d_in[6];
  const float* xpw  = (const float*)d_in[7];
  const float* dtw  = (const float*)d_in[8];
  const float* dtb  = (const float*)d_in[9];
  const float* alog = (const float*)d_in[10];
  const float* dp   = (const float*)d_in[11];
  const float* outw = (const float*)d_in[12];
  const float* lng  = (const float*)d_in[13];
  const float* lnb  = (const float*)d_in[14];
  const float* clsw = (const float*)d_in[15];
  const float* clsb = (const float*)d_in[16];

  float* ws    = (float*)d_ws;
  float* SCAL  = ws;                              // 13 scalars x 128 floats (8 slots)
  float* P2    = ws + 2048;                       // 492,800
  float* X2    = P2 + LDM_;                       // 7,884,800
  float* XZ    = X2 + NX_;                        // 10,485,760
  float* XCH_f = XZ + (long)ROWS_ * 512;          // 10,485,760 (ushort [40960][512])
  float* PROJ  = XCH_f + 2L * ROWS_ * DI_;        // 40960*33 = 1,351,680
  float* Y     = PROJ + 2L * ROWS_ * 33;          // 2 x 5,242,880 (dt -> y in place)
  float* MO    = Y + 2L * ROWS_ * DI_;            // 7,884,800
  float* POOL  = MO + NX_;                        // 8,192
  float* PART  = POOL + 8192;                     // 123,200 (+pad)
  float* A2IN_f= PART + 131072;                   // 4,096,000 f (ushort overlay)
  float* W2I_f = A2IN_f + 4096000;                // 409,600 f
  float* W2O_f = W2I_f + 409600;                  // 393,216 f
  float* W2X_f = W2O_f + 393216;                  // 98,304 f (2 x [128][768] ushort)
  // aliases (disjoint lifetimes):
  float*  HEND = MO;                              // scan summaries, dead before out-GEMM
  float*  PEND = MO + 2097152;
  float*  CARR = MO + 4194304;
  ushort* A2Y  = (ushort*)XZ;                     // [20480][512], dead before next in-GEMM
  ushort* XCH  = (ushort*)XCH_f;                  // xc bf16 {hi|lo} [40960][512]
  ushort* A2IN = (ushort*)A2IN_f;                 // [20480][400]
  ushort* W2TI = (ushort*)W2I_f;                  // 2 x [512][800]
  ushort* W2TO = (ushort*)W2O_f;                  // 2 x [512][768]
  ushort* W2TX = (ushort*)W2X_f;                  // 2 x [128][768]

  // scalar entry i lives at SCAL + i*SCALW (8 slots, 64B apart)
  #define SC(i) (SCAL + (i) * SCALW)

  k_zero<<<8, 256, 0, stream>>>(SCAL);

  // weight splits for MFMA GEMMs (tiny)
  for (int blk = 0; blk < 2; blk++) {
    k_wsplit<<<1600, 256, 0, stream>>>(in_w + (long)blk * DM_ * 512,
                                       W2TI + (long)blk * 512 * KPI_,
                                       DM_, 512, KPA_, KPI_, 512L * KPI_, 2);
    k_wsplit<<<1536, 256, 0, stream>>>(outw + (long)blk * DI_ * DM_,
                                       W2TO + (long)blk * 512 * KPO_,
                                       DI_, DM_, 256, KPO_, 512L * KPO_, 3);
    k_wsplit<<<384, 256, 0, stream>>>(xpw + (long)blk * DI_ * 33,
                                      W2TX + (long)blk * 128 * KPO_,
                                      DI_, 33, 256, KPO_, 128L * KPO_, 3);
  }
  k_padzero<<<1200, 256, 0, stream>>>(A2IN);

  // absmaxes + fused patch-embed (x and w fq'd inline)
  k_absmax<<<2048, 256, 0, stream>>>(x, (long)B_ * H_ * W_, SC(0));
  k_absmax<<<8, 256, 0, stream>>>(pew, EMB * 2 * 16, SC(1));
  k_absmax<<<512, 256, 0, stream>>>(pos, LDM_, SC(4));
  k_patchfq<<<dim3(20, 11, 16), 320, 0, stream>>>(x, pew, peb, SC(0), SC(1), X2, SC(2));

  // pos = fq(fq(pos_embed)) == fq(pos_embed)  (fq idempotent)
  k_fq4<<<512, 256, 0, stream>>>((const float4*)pos, (float4*)P2, LDM_ / 4,
                                 SC(4), nullptr, nullptr);

  // x = fq(fq(x) + pos) with inner fq(x) = fq(patch_out, s2) (outer chain identity)
  k_addpos4<<<2048, 256, 0, stream>>>((float4*)X2, (const float4*)P2, SC(2), SC(6));
  k_fq4<<<2048, 256, 0, stream>>>((const float4*)X2, (float4*)X2, NX_ / 4,
                                  SC(6), nullptr, A2IN);

  const float* in_scale[2] = {SC(6), SC(8)};
  for (int blk = 0; blk < 2; blk++) {
    // in-proj: XZ = s * (q @ [w_hi; w_lo])   (MFMA bf16, A k-wrapped at 400)
    k_mgemm<false><<<640, 256, 0, stream>>>(
        A2IN, W2TI + (long)blk * 512 * KPI_, XZ, 512, KPI_, KPA_, 160,
        in_scale[blk], nullptr);
    // conv both dirs -> xc bf16 {hi|lo}; xp-proj via MFMA (N=33 in one tile)
    k_conv2<<<dim3(80, 16), 256, 0, stream>>>(XZ, cw + blk * DI_ * K_,
                                              cb + blk * DI_, XCH);
    k_mgemm<false><<<320, 256, 0, stream>>>(
        XCH, W2TX + (long)blk * 128 * KPO_, PROJ, 33, KPO_, WAO_, 320,
        nullptr, nullptr);
    k_dtp<<<2560, 256, 0, stream>>>(PROJ, dtw + blk * DTR_ * DI_, dtb + blk * DI_, Y);
    k_scan1<<<dim3(CH_, B_, 2), 256, 0, stream>>>(XCH, PROJ, alog + blk * DI_ * N_,
                                                  Y, HEND, PEND);
    k_carry<<<128, 256, 0, stream>>>(HEND, PEND, CARR);
    k_scan2<<<dim3(CH_, B_, 2), 256, 0, stream>>>(XCH, PROJ, alog + blk * DI_ * N_,
                                                  dp + blk * DI_, XZ, CARR, Y);
    // out-proj: MO = [y_hi | y_lo] (wrapped) @ [w_hi; w_hi; w_lo]  (amax fused)
    k_asplit2<<<40960, 256, 0, stream>>>(Y, A2Y);
    k_mgemm<true><<<640, 256, 0, stream>>>(
        A2Y, W2TO + (long)blk * 512 * KPO_, MO, DM_, KPO_, WAO_, 160,
        nullptr, SC(7 + blk * 2));
    // x = fq(layernorm(x + fq(mo))); emit q for next block's in-proj
    k_ln<<<640, 256, 0, stream>>>(X2, MO, SC(7 + blk * 2),
                                  lng + blk * DM_, lnb + blk * DM_, SC(8 + blk * 2));
    k_fq4<<<2048, 256, 0, stream>>>((const float4*)MO, (float4*)X2, NX_ / 4,
                                    SC(8 + blk * 2), nullptr,
                                    blk == 0 ? A2IN : nullptr);
  }

  // mean-pool (2-stage), fq, classifier with fq(cls_w)
  k_pool1<<<dim3(16, 20), 256, 0, stream>>>(X2, PART);
  k_pool2<<<25, 256, 0, stream>>>(PART, POOL, SC(11));
  k_absmax<<<4, 256, 0, stream>>>(clsw, DM_ * 2, SC(12));
  k_cls<<<32, 128, 0, stream>>>(POOL, clsw, clsb, SC(11), SC(12), (float*)d_out);
}

// Round 12
// 632.815 us; speedup vs baseline: 7.8898x; 1.0131x over previous
//
#include <hip/hip_runtime.h>
#include <hip/hip_bf16.h>
#include <math.h>

// ---- problem constants -----------------------------------------------------
#define B_    16
#define H_    22
#define W_    20480
#define EMB   35
#define GH_   11
#define GW_   1280
#define L_    1280
#define DM_   385
#define DI_   256
#define N_    4
#define K_    4
#define DTR_  25
#define ROWS_ (B_*L_)              // 20480
#define NX_   ((long)ROWS_*DM_)    // 7,884,800
#define LDM_  ((long)L_*DM_)       // 492,800
#define CH_   64                   // scan chunks
#define CHL_  20                   // steps per chunk (CH_*CHL_ == L_)
#define KPI_  800                  // in_proj W K' (2 terms x 400)
#define KPA_  400                  // in_proj A width (q stored once, padded)
#define KPO_  768                  // out/xp W K' (3 terms x 256)
#define WAO_  512                  // out/xp A width ({hi,lo})

// amax scalars: 8 slots x 64B apart to break single-address atomic serialization
#define NSLOT 8
#define SSTR  16                   // floats between slots (64 B)
#define SCALW 128                  // floats per logical scalar (8 slots)

// LDS sl-plane stride (ushorts): 128 rows x 8 + 8 pad -> +16B per plane.
#define SLP_  2056

typedef __attribute__((ext_vector_type(8))) short short8;
typedef __attribute__((ext_vector_type(4))) float f32x4;
typedef unsigned short ushort;

// ---- helpers ---------------------------------------------------------------
__device__ __forceinline__ void atomicMaxF(float* a, float v) {
  atomicMax(reinterpret_cast<int*>(a), __float_as_int(v));
}

// faithful fq: s = max(mx,1e-8)/127 where mx = max over the 8 slots
__device__ __forceinline__ float fq_scale(const float* pmax) {
  float m = pmax[0];
  #pragma unroll
  for (int i = 1; i < NSLOT; i++) m = fmaxf(m, pmax[i * SSTR]);
  return fmaxf(m, 1e-8f) / 127.f;
}
__device__ __forceinline__ float fq_apply(float x, float s) {
  float r = rintf(x / s);
  r = fminf(fmaxf(r, -128.f), 127.f);
  return r * s;
}

__device__ __forceinline__ ushort f2bf(float f) {  // round-to-nearest-even
  union { float f; unsigned u; } v; v.f = f;
  unsigned r = v.u + 0x7FFF + ((v.u >> 16) & 1);
  return (ushort)(r >> 16);
}
__device__ __forceinline__ float bf2f(ushort h) {
  union { unsigned u; float f; } v; v.u = ((unsigned)h) << 16;
  return v.f;
}

// block max -> atomicMax into one of 8 slots (by block id). sm >= blockDim/64.
__device__ __forceinline__ void blockAtomicMax(float v, float* out, float* sm) {
  #pragma unroll
  for (int o = 32; o > 0; o >>= 1) v = fmaxf(v, __shfl_down(v, o));
  if ((threadIdx.x & 63) == 0) sm[threadIdx.x >> 6] = v;
  __syncthreads();
  if (threadIdx.x == 0) {
    int nw = (blockDim.x + 63) >> 6;
    for (int i = 1; i < nw; i++) v = fmaxf(v, sm[i]);
    int slot = (blockIdx.x + blockIdx.y * 4 + blockIdx.z) & (NSLOT - 1);
    atomicMaxF(out + slot * SSTR, v);
  }
}

// ---- small utility kernels -------------------------------------------------
__global__ void k_zero(float* s) { s[blockIdx.x * 256 + threadIdx.x] = 0.f; }

__global__ void k_absmax(const float* __restrict__ src, long n, float* __restrict__ out) {
  __shared__ float smr[8];
  float m = 0.f;
  for (long i = (long)blockIdx.x * blockDim.x + threadIdx.x; i < n;
       i += (long)gridDim.x * blockDim.x)
    m = fmaxf(m, fabsf(src[i]));
  blockAtomicMax(m, out, smr);
}

// simple elementwise fq into a fresh buffer (patch weights only; tiny)
__global__ void k_qx(const float* __restrict__ src, float* __restrict__ dst, long n,
                     const float* __restrict__ pmax) {
  float s = fq_scale(pmax);
  for (long i = (long)blockIdx.x * blockDim.x + threadIdx.x; i < n;
       i += (long)gridDim.x * blockDim.x)
    dst[i] = fq_apply(src[i], s);
}

// vectorized fq: dst4 = fq(src4); optional absmax -> nextmax; optional bf16
// q-emit into A2 [M][KPA_]. dst may == src.
__global__ void k_fq4(const float4* __restrict__ src, float4* __restrict__ dst, long n4,
                      const float* __restrict__ pmax, float* __restrict__ nextmax,
                      ushort* __restrict__ a2) {
  __shared__ float smr[8];
  float s = fq_scale(pmax);
  float m = 0.f;
  for (long i = (long)blockIdx.x * blockDim.x + threadIdx.x; i < n4;
       i += (long)gridDim.x * blockDim.x) {
    float4 v = src[i];
    float r0 = fminf(fmaxf(rintf(v.x / s), -128.f), 127.f);
    float r1 = fminf(fmaxf(rintf(v.y / s), -128.f), 127.f);
    float r2 = fminf(fmaxf(rintf(v.z / s), -128.f), 127.f);
    float r3 = fminf(fmaxf(rintf(v.w / s), -128.f), 127.f);
    float4 q = make_float4(r0 * s, r1 * s, r2 * s, r3 * s);
    dst[i] = q;
    m = fmaxf(m, fmaxf(fmaxf(fabsf(q.x), fabsf(q.y)), fmaxf(fabsf(q.z), fabsf(q.w))));
    if (a2) {
      long ii = i * 4;
      long mm = ii / 385; int kk = (int)(ii - mm * 385);
      float rr[4] = {r0, r1, r2, r3};
      #pragma unroll
      for (int j = 0; j < 4; j++) {
        a2[mm * KPA_ + kk] = f2bf(rr[j]);
        if (++kk == 385) { kk = 0; mm++; }
      }
    }
  }
  if (nextmax) blockAtomicMax(m, nextmax, smr);
}

// x4[i] = fq(x4[i], s_pmax) + p2[i % LDM/4]; absmax -> nextmax
__global__ void k_addpos4(float4* __restrict__ x, const float4* __restrict__ p2,
                          const float* __restrict__ pmax, float* __restrict__ nextmax) {
  __shared__ float smr[8];
  float s = fq_scale(pmax);
  float m = 0.f;
  const long n4 = NX_ / 4, l4 = LDM_ / 4;
  for (long i = (long)blockIdx.x * blockDim.x + threadIdx.x; i < n4;
       i += (long)gridDim.x * blockDim.x) {
    float4 v = x[i];
    float4 p = p2[i % l4];
    float4 o;
    o.x = fq_apply(v.x, s) + p.x;
    o.y = fq_apply(v.y, s) + p.y;
    o.z = fq_apply(v.z, s) + p.z;
    o.w = fq_apply(v.w, s) + p.w;
    x[i] = o;
    m = fmaxf(m, fmaxf(fmaxf(fabsf(o.x), fabsf(o.y)), fmaxf(fabsf(o.z), fabsf(o.w))));
  }
  blockAtomicMax(m, nextmax, smr);
}

// ---- fused patch embed: LDS-staged x (fq inline), PRE-QUANTIZED weights -----
// block = (gw-tile of 64, gh, b); 320 threads (280 active in compute)
__global__ __launch_bounds__(320) void k_patchfq(const float* __restrict__ x,
                                                 const float* __restrict__ wq,
                                                 const float* __restrict__ peb,
                                                 const float* __restrict__ sx_,
                                                 float* __restrict__ out,
                                                 float* __restrict__ nextmax) {
  __shared__ float xs[2][64][20];   // [ph][gw_local][pw] padded to 20
  __shared__ float smr[8];
  int tid = threadIdx.x;
  int gwt = blockIdx.x, gh = blockIdx.y, b = blockIdx.z;
  float sx = fq_scale(sx_);
  if (tid < 256) {
    int gwl = tid >> 2, pw = (tid & 3) * 4;
    #pragma unroll
    for (int ph = 0; ph < 2; ph++) {
      const float* src = x + ((long)b * H_ + gh * 2 + ph) * W_ + (long)gwt * 1024 + tid * 4;
      float4 v = *reinterpret_cast<const float4*>(src);
      xs[ph][gwl][pw + 0] = fq_apply(v.x, sx);
      xs[ph][gwl][pw + 1] = fq_apply(v.y, sx);
      xs[ph][gwl][pw + 2] = fq_apply(v.z, sx);
      xs[ph][gwl][pw + 3] = fq_apply(v.w, sx);
    }
  }
  __syncthreads();
  float mx = 0.f;
  if (tid < 280) {
    int e = tid % 35;
    int g0 = (tid / 35) * 8;
    float w[32];
    #pragma unroll
    for (int j = 0; j < 32; j++) w[j] = wq[e * 32 + j];
    float bias = peb[e];
    long obase = ((long)b * GW_ + (long)gwt * 64) * DM_ + gh * 35 + e;
    #pragma unroll
    for (int gi = 0; gi < 8; gi++) {
      int gw = g0 + gi;
      float acc = bias;
      #pragma unroll
      for (int pw = 0; pw < 16; pw++) {
        acc = fmaf(xs[0][gw][pw], w[pw], acc);
        acc = fmaf(xs[1][gw][pw], w[16 + pw], acc);
      }
      out[obase + (long)gw * DM_] = acc;
      mx = fmaxf(mx, fabsf(acc));
    }
  }
  blockAtomicMax(mx, nextmax, smr);
}

// ---- weight split: W[K][N] f32 -> W2T[Npad][Kp] bf16 ------------------------
__global__ void k_wsplit(const float* __restrict__ W, ushort* __restrict__ out,
                         int K, int N, int Kw, int Kp, long total, int terms) {
  long idx = (long)blockIdx.x * 256 + threadIdx.x;
  if (idx >= total) return;
  int k = (int)(idx % Kp);
  int n = (int)(idx / Kp);
  int t = k / Kw, kk = k - t * Kw;
  ushort r = 0;
  if (n < N && kk < K) {
    float w = W[(long)kk * N + n];
    ushort hi = f2bf(w);
    r = (t == terms - 1) ? f2bf(w - bf2f(hi)) : hi;
  }
  out[idx] = r;
}

// ---- activation split: (Y0+Y1)[M][256] f32 -> A2[M][512] bf16 {hi,lo} -------
__global__ void k_asplit2(const float* __restrict__ Y, ushort* __restrict__ A2) {
  long idx = (long)blockIdx.x * 256 + threadIdx.x;   // M*512 threads
  long m = idx >> 9; int k = (int)(idx & 511);
  int t = k >> 8, kk = k & 255;
  float v = Y[m * DI_ + kk] + Y[(m + ROWS_) * DI_ + kk];
  ushort hi = f2bf(v);
  A2[idx] = t ? f2bf(v - bf2f(hi)) : hi;
}

// zero the pad columns [385, 400) of A2IN
__global__ void k_padzero(ushort* __restrict__ A2) {
  long idx = (long)blockIdx.x * 256 + threadIdx.x;   // ROWS_*15 threads
  long m = idx / 15; int c = (int)(idx - m * 15);
  A2[m * KPA_ + 385 + c] = 0;
}

// ---- bf16 MFMA GEMM: C[M][Nreal] = scale * (A2[M][Wa,wrapped] @ W2T[Npad][Kp]^T)
// 1-D grid NT*MT (m = bid%MT, n = bid/MT): same-m blocks share XCD L2 A-panel.
// LDS sl-stride padded (+16B): conflict-free write/read granule (sl+row)&7.
template<bool AMAX>
__global__ __launch_bounds__(256) void k_mgemm(const ushort* __restrict__ A2,
                                               const ushort* __restrict__ W2T,
                                               float* __restrict__ C,
                                               int Nreal, int Kp, int Wa, int MT,
                                               const float* __restrict__ sptr,
                                               float* __restrict__ amax_out) {
  __shared__ ushort Alds[4 * SLP_];
  __shared__ ushort Blds[4 * SLP_];
  __shared__ float smr[8];
  int tid = threadIdx.x;
  int lane = tid & 63, wave = tid >> 6;
  int wm = wave >> 1, wn = wave & 1;
  int bid = blockIdx.x;
  int m0 = (bid % MT) * 128, n0 = (bid / MT) * 128;
  f32x4 acc[4][4];
  #pragma unroll
  for (int i = 0; i < 4; i++)
    #pragma unroll
    for (int j = 0; j < 4; j++) acc[i][j] = (f32x4){0.f, 0.f, 0.f, 0.f};

  for (int k0 = 0; k0 < Kp; k0 += 32) {
    #pragma unroll
    for (int r = 0; r < 2; r++) {
      int id = tid + r * 256;            // 0..511
      int row = id >> 2, sl = id & 3;    // coalesced 64B global segments
      int kc = k0 + sl * 8; if (kc >= Wa) kc -= Wa;   // A k-wrap (8-aligned)
      short8 va = *reinterpret_cast<const short8*>(A2 + (long)(m0 + row) * Wa + kc);
      *reinterpret_cast<short8*>(&Alds[sl * SLP_ + row * 8]) = va;
      short8 vb = *reinterpret_cast<const short8*>(W2T + (long)(n0 + row) * Kp + k0 + sl * 8);
      *reinterpret_cast<short8*>(&Blds[sl * SLP_ + row * 8]) = vb;
    }
    __syncthreads();
    int sl = lane >> 4, rr = lane & 15;
    short8 af[4], bf4[4];
    #pragma unroll
    for (int i = 0; i < 4; i++)
      af[i] = *reinterpret_cast<const short8*>(&Alds[sl * SLP_ + (wm * 64 + i * 16 + rr) * 8]);
    #pragma unroll
    for (int j = 0; j < 4; j++)
      bf4[j] = *reinterpret_cast<const short8*>(&Blds[sl * SLP_ + (wn * 64 + j * 16 + rr) * 8]);
    #pragma unroll
    for (int i = 0; i < 4; i++)
      #pragma unroll
      for (int j = 0; j < 4; j++)
        acc[i][j] = __builtin_amdgcn_mfma_f32_16x16x32_bf16(af[i], bf4[j], acc[i][j], 0, 0, 0);
    __syncthreads();
  }

  float s = sptr ? fq_scale(sptr) : 1.0f;
  float mx = 0.f;
  int cfr = lane & 15, rbase = (lane >> 4) * 4;
  #pragma unroll
  for (int i = 0; i < 4; i++) {
    int gmb = m0 + wm * 64 + i * 16 + rbase;
    #pragma unroll
    for (int j = 0; j < 4; j++) {
      int gn = n0 + wn * 64 + j * 16 + cfr;
      if (gn < Nreal) {
        #pragma unroll
        for (int rg = 0; rg < 4; rg++) {
          float v = acc[i][j][rg] * s;
          C[(long)(gmb + rg) * Nreal + gn] = v;
          mx = fmaxf(mx, fabsf(v));
        }
      }
    }
  }
  if (AMAX) blockAtomicMax(mx, amax_out, smr);
}

// ---- depthwise causal conv1d (K=4) + SiLU, BOTH dirs from one window --------
__global__ __launch_bounds__(256) void k_conv2(const float* __restrict__ xz,
                                               const float* __restrict__ cw,
                                               const float* __restrict__ cb,
                                               ushort* __restrict__ xch) {
  int d = threadIdx.x;
  int t0 = blockIdx.x * 16, b = blockIdx.y;
  long base = (long)b * L_;
  float w0 = cw[d * 4 + 0], w1 = cw[d * 4 + 1];
  float w2 = cw[d * 4 + 2], w3 = cw[d * 4 + 3];
  float bias = cb[d];
  float win[22];
  #pragma unroll
  for (int i = 0; i < 22; i++) {
    int t = t0 - 3 + i;
    win[i] = (t >= 0 && t < L_) ? xz[(base + t) * (2 * DI_) + d] : 0.f;
  }
  #pragma unroll
  for (int i = 0; i < 16; i++) {
    int t = t0 + i;
    float a0 = bias;
    a0 = fmaf(w0, win[i + 0], a0);
    a0 = fmaf(w1, win[i + 1], a0);
    a0 = fmaf(w2, win[i + 2], a0);
    a0 = fmaf(w3, win[i + 3], a0);
    float a1 = bias;
    a1 = fmaf(w0, win[i + 6], a1);
    a1 = fmaf(w1, win[i + 5], a1);
    a1 = fmaf(w2, win[i + 4], a1);
    a1 = fmaf(w3, win[i + 3], a1);
    float v0 = a0 * (1.f / (1.f + expf(-a0)));
    float v1 = a1 * (1.f / (1.f + expf(-a1)));
    long g0o = (base + t) * 512 + d;
    ushort h0 = f2bf(v0), h1 = f2bf(v1);
    xch[g0o] = h0;
    xch[g0o + 256] = f2bf(v0 - bf2f(h0));
    long g1o = ((long)ROWS_ + base + t) * 512 + d;
    xch[g1o] = h1;
    xch[g1o + 256] = f2bf(v1 - bf2f(h1));
  }
}

// ---- dt precompute into Y (scan2 reads dt then overwrites with y in place) --
__device__ __forceinline__ float softplusf(float x) {
  return fmaxf(x, 0.f) + log1pf(expf(-fabsf(x)));
}

__global__ __launch_bounds__(256) void k_dtp(const float* __restrict__ proj,
                                             const float* __restrict__ dtw,
                                             const float* __restrict__ dtb,
                                             float* __restrict__ dty) {
  __shared__ float pr[16][26];
  int d = threadIdx.x;
  long g0 = (long)blockIdx.x * 16;
  for (int i = threadIdx.x; i < 16 * DTR_; i += 256) {
    int r = i / DTR_, j = i - r * DTR_;
    pr[r][j] = proj[(g0 + r) * 33 + j];
  }
  float dwr[DTR_];
  #pragma unroll
  for (int r = 0; r < DTR_; r++) dwr[r] = dtw[r * DI_ + d];
  float dbv = dtb[d];
  __syncthreads();
  #pragma unroll
  for (int r = 0; r < 16; r++) {
    float acc = dbv;
    #pragma unroll
    for (int j = 0; j < DTR_; j++) acc = fmaf(pr[r][j], dwr[j], acc);
    dty[(g0 + r) * DI_ + d] = softplusf(acc);
  }
}

// ---- chunked parallel selective scan (exp-reduced, both dirs in grid.z) -----
__global__ __launch_bounds__(256) void k_scan1(const ushort* __restrict__ xch,
                                               const float* __restrict__ proj,
                                               const float* __restrict__ A_log,
                                               const float* __restrict__ dty,
                                               float* __restrict__ Hend,
                                               float* __restrict__ Pend) {
  int b = blockIdx.y, c = blockIdx.x, d = threadIdx.x, dir = blockIdx.z;
  float A[4];
  #pragma unroll
  for (int n = 0; n < 4; n++) A[n] = -expf(A_log[d * 4 + n]);
  bool fast = true;
  #pragma unroll
  for (int n = 1; n < 4; n++)
    fast = fast && (fabsf(A[n] - (float)(n + 1) * A[0]) <= 1e-4f * fabsf(A[n]));
  long base = (long)b * L_;
  int step0 = c * CHL_;
  long row0 = base + (dir ? (L_ - 1 - step0) : step0);
  long doff = (long)dir * ROWS_;
  int rs = dir ? -1 : 1;
  const float* pdt = dty + (doff + row0) * DI_ + d;
  const ushort* pxc = xch + (doff + row0) * 512 + d;
  const float* pp  = proj + (doff + row0) * 33;
  float h[4] = {0.f, 0.f, 0.f, 0.f};
  float sdt = 0.f;
  if (fast) {
    float A0 = A[0];
    for (int s = 0; s < CHL_; s++) {
      float dtv = *pdt;
      float xcv = bf2f(pxc[0]) + bf2f(pxc[256]);
      float dx = dtv * xcv;
      float e1 = expf(dtv * A0);
      float e2 = e1 * e1, e3 = e2 * e1, e4 = e3 * e1;
      h[0] = e1 * h[0] + dx * pp[DTR_ + 0];
      h[1] = e2 * h[1] + dx * pp[DTR_ + 1];
      h[2] = e3 * h[2] + dx * pp[DTR_ + 2];
      h[3] = e4 * h[3] + dx * pp[DTR_ + 3];
      sdt += dtv;
      pdt += (long)rs * DI_; pxc += (long)rs * 512; pp += rs * 33;
    }
  } else {
    for (int s = 0; s < CHL_; s++) {
      float dtv = *pdt;
      float xcv = bf2f(pxc[0]) + bf2f(pxc[256]);
      float dx = dtv * xcv;
      #pragma unroll
      for (int n = 0; n < 4; n++) {
        float dA = expf(dtv * A[n]);
        h[n] = dA * h[n] + dx * pp[DTR_ + n];
      }
      sdt += dtv;
      pdt += (long)rs * DI_; pxc += (long)rs * 512; pp += rs * 33;
    }
  }
  float P[4];
  #pragma unroll
  for (int n = 0; n < 4; n++) P[n] = expf(A[n] * sdt);
  long o = (((long)dir * B_ + b) * CH_ + c) * 1024 + d * 4;
  *reinterpret_cast<float4*>(Hend + o) = make_float4(h[0], h[1], h[2], h[3]);
  *reinterpret_cast<float4*>(Pend + o) = make_float4(P[0], P[1], P[2], P[3]);
}

__global__ __launch_bounds__(256) void k_carry(const float* __restrict__ Hend,
                                               const float* __restrict__ Pend,
                                               float* __restrict__ Carry) {
  int tid = blockIdx.x * 256 + threadIdx.x;   // 2*B_*1024 lanes
  int be = tid >> 10, i = tid & 1023;         // be = dir*16+b
  float carry = 0.f;
  for (int c = 0; c < CH_; c++) {
    long o = ((long)be * CH_ + c) * 1024 + i;
    Carry[o] = carry;
    carry = Pend[o] * carry + Hend[o];
  }
}

// dty holds dt on entry; read-once-then-overwrite with y (same thread).
__global__ __launch_bounds__(256) void k_scan2(const ushort* __restrict__ xch,
                                               const float* __restrict__ proj,
                                               const float* __restrict__ A_log,
                                               const float* __restrict__ Dp,
                                               const float* __restrict__ xz,
                                               const float* __restrict__ Carry,
                                               float* dty) {
  int b = blockIdx.y, c = blockIdx.x, d = threadIdx.x, dir = blockIdx.z;
  float A[4];
  #pragma unroll
  for (int n = 0; n < 4; n++) A[n] = -expf(A_log[d * 4 + n]);
  bool fast = true;
  #pragma unroll
  for (int n = 1; n < 4; n++)
    fast = fast && (fabsf(A[n] - (float)(n + 1) * A[0]) <= 1e-4f * fabsf(A[n]));
  long base = (long)b * L_;
  int step0 = c * CHL_;
  long row0 = base + (dir ? (L_ - 1 - step0) : step0);
  long doff = (long)dir * ROWS_;
  int rs = dir ? -1 : 1;
  float* pdy = dty + (doff + row0) * DI_ + d;
  const ushort* pxc = xch + (doff + row0) * 512 + d;
  const float* pz  = xz + row0 * (2 * DI_) + DI_ + d;
  const float* pp  = proj + (doff + row0) * 33;
  long o = (((long)dir * B_ + b) * CH_ + c) * 1024 + d * 4;
  float4 cv = *reinterpret_cast<const float4*>(Carry + o);
  float h[4] = {cv.x, cv.y, cv.z, cv.w};
  float Dv = Dp[d];
  if (fast) {
    float A0 = A[0];
    for (int s = 0; s < CHL_; s++) {
      float dtv = *pdy;
      float xcv = bf2f(pxc[0]) + bf2f(pxc[256]);
      float zv  = *pz;
      float dx = dtv * xcv;
      float e1 = expf(dtv * A0);
      float e2 = e1 * e1, e3 = e2 * e1, e4 = e3 * e1;
      h[0] = e1 * h[0] + dx * pp[DTR_ + 0];
      h[1] = e2 * h[1] + dx * pp[DTR_ + 1];
      h[2] = e3 * h[2] + dx * pp[DTR_ + 2];
      h[3] = e4 * h[3] + dx * pp[DTR_ + 3];
      float acc = 0.f;
      acc = fmaf(h[0], pp[DTR_ + N_ + 0], acc);
      acc = fmaf(h[1], pp[DTR_ + N_ + 1], acc);
      acc = fmaf(h[2], pp[DTR_ + N_ + 2], acc);
      acc = fmaf(h[3], pp[DTR_ + N_ + 3], acc);
      float yv = fmaf(Dv, xcv, acc);
      float sig = 1.f / (1.f + expf(-zv));
      yv *= zv * sig;
      *pdy = yv;
      pdy += (long)rs * DI_; pxc += (long)rs * 512;
      pz += rs * (2 * DI_); pp += rs * 33;
    }
  } else {
    for (int s = 0; s < CHL_; s++) {
      float dtv = *pdy;
      float xcv = bf2f(pxc[0]) + bf2f(pxc[256]);
      float zv  = *pz;
      float dx = dtv * xcv;
      float acc = 0.f;
      #pragma unroll
      for (int n = 0; n < 4; n++) {
        float dA = expf(dtv * A[n]);
        h[n] = dA * h[n] + dx * pp[DTR_ + n];
        acc = fmaf(h[n], pp[DTR_ + N_ + n], acc);
      }
      float yv = fmaf(Dv, xcv, acc);
      float sig = 1.f / (1.f + expf(-zv));
      yv *= zv * sig;
      *pdy = yv;
      pdy += (long)rs * DI_; pxc += (long)rs * 512;
      pz += rs * (2 * DI_); pp += rs * 33;
    }
  }
}

// ---- residual + fq(mamba_out) + layernorm, wave-per-row ----------------------
__global__ __launch_bounds__(256) void k_ln(const float* __restrict__ x2,
                                            float* __restrict__ mo,
                                            const float* __restrict__ smo,
                                            const float* __restrict__ g,
                                            const float* __restrict__ bta,
                                            float* __restrict__ nextmax) {
  __shared__ float smr[4];
  int lane = threadIdx.x & 63;
  int wid = blockIdx.x * 4 + (threadIdx.x >> 6);
  float s = fq_scale(smo);
  float wmax = 0.f;
  for (int row = wid; row < ROWS_; row += 2560) {
    const float* xr = x2 + (long)row * DM_;
    float* mr = mo + (long)row * DM_;
    float v[7];
    float lsum = 0.f;
    #pragma unroll
    for (int k = 0; k < 6; k++) {
      int c = lane + k * 64;
      v[k] = xr[c] + fq_apply(mr[c], s);
      lsum += v[k];
    }
    v[6] = 0.f;
    if (lane == 0) v[6] = xr[384] + fq_apply(mr[384], s);
    lsum += v[6];
    #pragma unroll
    for (int o = 32; o > 0; o >>= 1) lsum += __shfl_xor(lsum, o);
    float mean = lsum / 385.f;
    float lvar = 0.f;
    #pragma unroll
    for (int k = 0; k < 6; k++) { float dd = v[k] - mean; lvar += dd * dd; }
    if (lane == 0) { float dd = v[6] - mean; lvar += dd * dd; }
    #pragma unroll
    for (int o = 32; o > 0; o >>= 1) lvar += __shfl_xor(lvar, o);
    float rs = 1.f / sqrtf(lvar / 385.f + 1e-5f);
    #pragma unroll
    for (int k = 0; k < 6; k++) {
      int c = lane + k * 64;
      float o2 = (v[k] - mean) * rs * g[c] + bta[c];
      mr[c] = o2;
      wmax = fmaxf(wmax, fabsf(o2));
    }
    if (lane == 0) {
      float o2 = (v[6] - mean) * rs * g[384] + bta[384];
      mr[384] = o2;
      wmax = fmaxf(wmax, fabsf(o2));
    }
  }
  blockAtomicMax(wmax, nextmax, smr);
}

// ---- mean pool over L (two-stage, coalesced, deterministic) ------------------
__global__ __launch_bounds__(256) void k_pool1(const float* __restrict__ x2,
                                               float* __restrict__ part) {
  int b = blockIdx.x, ch = blockIdx.y, tid = threadIdx.x;
  float s0 = 0.f, s1 = 0.f;
  for (int l = ch * 64; l < ch * 64 + 64; l++) {
    const float* row = x2 + ((long)b * L_ + l) * DM_;
    s0 += row[tid];
    if (tid < DM_ - 256) s1 += row[tid + 256];
  }
  long o = ((long)b * 20 + ch) * DM_;
  part[o + tid] = s0;
  if (tid < DM_ - 256) part[o + tid + 256] = s1;
}

__global__ void k_pool2(const float* __restrict__ part, float* __restrict__ pool,
                        float* __restrict__ nextmax) {
  __shared__ float smr[8];
  int idx = blockIdx.x * 256 + threadIdx.x;
  float mv = 0.f;
  if (idx < B_ * DM_) {
    int b = idx / DM_, c = idx % DM_;
    float s = 0.f;
    for (int ch = 0; ch < 20; ch++) s += part[((long)b * 20 + ch) * DM_ + c];
    float mean = s / (float)L_;
    pool[idx] = mean;
    mv = fabsf(mean);
  }
  blockAtomicMax(mv, nextmax, smr);
}

// ---- classifier (parallel): grid 32 = (b,c), 128 threads reduce over K=385 --
__global__ __launch_bounds__(128) void k_cls(const float* __restrict__ pool,
                                             const float* __restrict__ clsw,
                                             const float* __restrict__ clsb,
                                             const float* __restrict__ sp_,
                                             const float* __restrict__ sw_,
                                             float* __restrict__ out) {
  __shared__ float smr[2];
  int b = blockIdx.x >> 1, c = blockIdx.x & 1;
  float sp = fq_scale(sp_), sw = fq_scale(sw_);
  float acc = 0.f;
  for (int k = threadIdx.x; k < DM_; k += 128) {
    float xv = fq_apply(pool[b * DM_ + k], sp);
    float wv = fq_apply(clsw[k * 2 + c], sw);
    acc = fmaf(xv, wv, acc);
  }
  #pragma unroll
  for (int o = 32; o > 0; o >>= 1) acc += __shfl_down(acc, o);
  if ((threadIdx.x & 63) == 0) smr[threadIdx.x >> 6] = acc;
  __syncthreads();
  if (threadIdx.x == 0) out[blockIdx.x] = smr[0] + smr[1] + clsb[c];
}

// ---- launch ------------------------------------------------------------------
extern "C" void kernel_launch(void* const* d_in, const int* in_sizes, int n_in,
                              void* d_out, int out_size, void* d_ws, size_t ws_size,
                              hipStream_t stream) {
  const float* x    = (const float*)d_in[0];
  const float* pew  = (const float*)d_in[1];
  const float* peb  = (const float*)d_in[2];
  const float* pos  = (const float*)d_in[3];
  const float* in_w = (const float*)d_in[4];
  const float* cw   = (const float*)d_in[5];
  const float* cb   = (const float*)d_in[6];
  const float* xpw  = (const float*)d_in[7];
  const float* dtw  = (const float*)d_in[8];
  const float* dtb  = (const float*)d_in[9];
  const float* alog = (const float*)d_in[10];
  const float* dp   = (const float*)d_in[11];
  const float* outw = (const float*)d_in[12];
  const float* lng  = (const float*)d_in[13];
  const float* lnb  = (const float*)d_in[14];
  const float* clsw = (const float*)d_in[15];
  const float* clsb = (const float*)d_in[16];

  float* ws    = (float*)d_ws;
  float* SCAL  = ws;                              // 13 scalars x 128 floats (8 slots)
  float* WQ    = ws + 2048;                       // 2048 (1120 used)
  float* P2    = WQ + 2048;                       // 492,800
  float* X2    = P2 + LDM_;                       // 7,884,800
  float* XZ    = X2 + NX_;                        // 10,485,760
  float* XCH_f = XZ + (long)ROWS_ * 512;          // 10,485,760 (ushort [40960][512])
  float* PROJ  = XCH_f + 2L * ROWS_ * DI_;        // 40960*33 = 1,351,680
  float* Y     = PROJ + 2L * ROWS_ * 33;          // 2 x 5,242,880 (dt -> y in place)
  float* MO    = Y + 2L * ROWS_ * DI_;            // 7,884,800
  float* POOL  = MO + NX_;                        // 8,192
  float* PART  = POOL + 8192;                     // 123,200 (+pad)
  float* A2IN_f= PART + 131072;                   // 4,096,000 f (ushort overlay)
  float* W2I_f = A2IN_f + 4096000;                // 409,600 f
  float* W2O_f = W2I_f + 409600;                  // 393,216 f
  float* W2X_f = W2O_f + 393216;                  // 98,304 f (2 x [128][768] ushort)
  // aliases (disjoint lifetimes):
  float*  HEND = MO;                              // scan summaries, dead before out-GEMM
  float*  PEND = MO + 2097152;
  float*  CARR = MO + 4194304;
  ushort* A2Y  = (ushort*)XZ;                     // [20480][512], dead before next in-GEMM
  ushort* XCH  = (ushort*)XCH_f;                  // xc bf16 {hi|lo} [40960][512]
  ushort* A2IN = (ushort*)A2IN_f;                 // [20480][400]
  ushort* W2TI = (ushort*)W2I_f;                  // 2 x [512][800]
  ushort* W2TO = (ushort*)W2O_f;                  // 2 x [512][768]
  ushort* W2TX = (ushort*)W2X_f;                  // 2 x [128][768]

  // scalar entry i lives at SCAL + i*SCALW (8 slots, 64B apart)
  #define SC(i) (SCAL + (i) * SCALW)

  k_zero<<<8, 256, 0, stream>>>(SCAL);

  // weight splits for MFMA GEMMs (tiny)
  for (int blk = 0; blk < 2; blk++) {
    k_wsplit<<<1600, 256, 0, stream>>>(in_w + (long)blk * DM_ * 512,
                                       W2TI + (long)blk * 512 * KPI_,
                                       DM_, 512, KPA_, KPI_, 512L * KPI_, 2);
    k_wsplit<<<1536, 256, 0, stream>>>(outw + (long)blk * DI_ * DM_,
                                       W2TO + (long)blk * 512 * KPO_,
                                       DI_, DM_, 256, KPO_, 512L * KPO_, 3);
    k_wsplit<<<384, 256, 0, stream>>>(xpw + (long)blk * DI_ * 33,
                                      W2TX + (long)blk * 128 * KPO_,
                                      DI_, 33, 256, KPO_, 128L * KPO_, 3);
  }
  k_padzero<<<1200, 256, 0, stream>>>(A2IN);

  // absmaxes; pre-quantize patch weights once; fused patch-embed
  k_absmax<<<2048, 256, 0, stream>>>(x, (long)B_ * H_ * W_, SC(0));
  k_absmax<<<8, 256, 0, stream>>>(pew, EMB * 2 * 16, SC(1));
  k_absmax<<<512, 256, 0, stream>>>(pos, LDM_, SC(4));
  k_qx<<<5, 256, 0, stream>>>(pew, WQ, EMB * 2 * 16, SC(1));
  k_patchfq<<<dim3(20, 11, 16), 320, 0, stream>>>(x, WQ, peb, SC(0), X2, SC(2));

  // pos = fq(fq(pos_embed)) == fq(pos_embed)  (fq idempotent)
  k_fq4<<<512, 256, 0, stream>>>((const float4*)pos, (float4*)P2, LDM_ / 4,
                                 SC(4), nullptr, nullptr);

  // x = fq(fq(x) + pos) with inner fq(x) = fq(patch_out, s2) (outer chain identity)
  k_addpos4<<<2048, 256, 0, stream>>>((float4*)X2, (const float4*)P2, SC(2), SC(6));
  k_fq4<<<2048, 256, 0, stream>>>((const float4*)X2, (float4*)X2, NX_ / 4,
                                  SC(6), nullptr, A2IN);

  const float* in_scale[2] = {SC(6), SC(8)};
  for (int blk = 0; blk < 2; blk++) {
    // in-proj: XZ = s * (q @ [w_hi; w_lo])   (MFMA bf16, A k-wrapped at 400)
    k_mgemm<false><<<640, 256, 0, stream>>>(
        A2IN, W2TI + (long)blk * 512 * KPI_, XZ, 512, KPI_, KPA_, 160,
        in_scale[blk], nullptr);
    // conv both dirs -> xc bf16 {hi|lo}; xp-proj via MFMA (N=33 in one tile)
    k_conv2<<<dim3(80, 16), 256, 0, stream>>>(XZ, cw + blk * DI_ * K_,
                                              cb + blk * DI_, XCH);
    k_mgemm<false><<<320, 256, 0, stream>>>(
        XCH, W2TX + (long)blk * 128 * KPO_, PROJ, 33, KPO_, WAO_, 320,
        nullptr, nullptr);
    k_dtp<<<2560, 256, 0, stream>>>(PROJ, dtw + blk * DTR_ * DI_, dtb + blk * DI_, Y);
    k_scan1<<<dim3(CH_, B_, 2), 256, 0, stream>>>(XCH, PROJ, alog + blk * DI_ * N_,
                                                  Y, HEND, PEND);
    k_carry<<<128, 256, 0, stream>>>(HEND, PEND, CARR);
    k_scan2<<<dim3(CH_, B_, 2), 256, 0, stream>>>(XCH, PROJ, alog + blk * DI_ * N_,
                                                  dp + blk * DI_, XZ, CARR, Y);
    // out-proj: MO = [y_hi | y_lo] (wrapped) @ [w_hi; w_hi; w_lo]  (amax fused)
    k_asplit2<<<40960, 256, 0, stream>>>(Y, A2Y);
    k_mgemm<true><<<640, 256, 0, stream>>>(
        A2Y, W2TO + (long)blk * 512 * KPO_, MO, DM_, KPO_, WAO_, 160,
        nullptr, SC(7 + blk * 2));
    // x = fq(layernorm(x + fq(mo))); emit q for next block's in-proj
    k_ln<<<640, 256, 0, stream>>>(X2, MO, SC(7 + blk * 2),
                                  lng + blk * DM_, lnb + blk * DM_, SC(8 + blk * 2));
    k_fq4<<<2048, 256, 0, stream>>>((const float4*)MO, (float4*)X2, NX_ / 4,
                                    SC(8 + blk * 2), nullptr,
                                    blk == 0 ? A2IN : nullptr);
  }

  // mean-pool (2-stage), fq, classifier with fq(cls_w)
  k_pool1<<<dim3(16, 20), 256, 0, stream>>>(X2, PART);
  k_pool2<<<25, 256, 0, stream>>>(PART, POOL, SC(11));
  k_absmax<<<4, 256, 0, stream>>>(clsw, DM_ * 2, SC(12));
  k_cls<<<32, 128, 0, stream>>>(POOL, clsw, clsb, SC(11), SC(12), (float*)d_out);
}

// Round 13
// 606.468 us; speedup vs baseline: 8.2326x; 1.0434x over previous
//
#include <hip/hip_runtime.h>
#include <hip/hip_bf16.h>
#include <math.h>

// ---- problem constants -----------------------------------------------------
#define B_    16
#define H_    22
#define W_    20480
#define EMB   35
#define GH_   11
#define GW_   1280
#define L_    1280
#define DM_   385
#define DI_   256
#define N_    4
#define K_    4
#define DTR_  25
#define ROWS_ (B_*L_)              // 20480
#define NX_   ((long)ROWS_*DM_)    // 7,884,800
#define LDM_  ((long)L_*DM_)       // 492,800
#define CH_   64                   // scan chunks
#define CHL_  20                   // steps per chunk (CH_*CHL_ == L_)
#define KPI_  800                  // in_proj W K' (2 terms x 400)
#define KPA_  400                  // in_proj A width (q stored once, padded)
#define KPO_  768                  // out/xp W K' (3 terms x 256)
#define WAO_  512                  // out/xp A width ({hi,lo})

// amax scalars: 8 slots x 64B apart to break single-address atomic serialization
#define NSLOT 8
#define SSTR  16                   // floats between slots (64 B)
#define SCALW 128                  // floats per logical scalar (8 slots)

// LDS sl-plane stride (ushorts): 128 rows x 8 + 8 pad -> +16B per plane.
#define SLP_  2056

typedef __attribute__((ext_vector_type(8))) short short8;
typedef __attribute__((ext_vector_type(4))) float f32x4;
typedef unsigned short ushort;

// ---- helpers ---------------------------------------------------------------
__device__ __forceinline__ void atomicMaxF(float* a, float v) {
  atomicMax(reinterpret_cast<int*>(a), __float_as_int(v));
}

// faithful fq: s = max(mx,1e-8)/127 where mx = max over the 8 slots
__device__ __forceinline__ float fq_scale(const float* pmax) {
  float m = pmax[0];
  #pragma unroll
  for (int i = 1; i < NSLOT; i++) m = fmaxf(m, pmax[i * SSTR]);
  return fmaxf(m, 1e-8f) / 127.f;
}
__device__ __forceinline__ float fq_apply(float x, float s) {
  float r = rintf(x / s);
  r = fminf(fmaxf(r, -128.f), 127.f);
  return r * s;
}

__device__ __forceinline__ ushort f2bf(float f) {  // round-to-nearest-even
  union { float f; unsigned u; } v; v.f = f;
  unsigned r = v.u + 0x7FFF + ((v.u >> 16) & 1);
  return (ushort)(r >> 16);
}
__device__ __forceinline__ float bf2f(ushort h) {
  union { unsigned u; float f; } v; v.u = ((unsigned)h) << 16;
  return v.f;
}

// block max -> atomicMax into one of 8 slots (by block id). sm >= blockDim/64.
__device__ __forceinline__ void blockAtomicMax(float v, float* out, float* sm) {
  #pragma unroll
  for (int o = 32; o > 0; o >>= 1) v = fmaxf(v, __shfl_down(v, o));
  if ((threadIdx.x & 63) == 0) sm[threadIdx.x >> 6] = v;
  __syncthreads();
  if (threadIdx.x == 0) {
    int nw = (blockDim.x + 63) >> 6;
    for (int i = 1; i < nw; i++) v = fmaxf(v, sm[i]);
    int slot = (blockIdx.x + blockIdx.y * 4 + blockIdx.z) & (NSLOT - 1);
    atomicMaxF(out + slot * SSTR, v);
  }
}

// ---- setup: weight splits + A2IN pad zero + scalar zero, one launch ---------
// wsplit body: W[K][N] f32 -> out[Npad][Kp] bf16; term t at cols [t*Kw, t*Kw+K)
__device__ __forceinline__ void wsplit_body(const float* __restrict__ W,
                                            ushort* __restrict__ out,
                                            int K, int N, int Kw, int Kp,
                                            long total, int terms, long idx) {
  if (idx >= total) return;
  int k = (int)(idx % Kp);
  int n = (int)(idx / Kp);
  int t = k / Kw, kk = k - t * Kw;
  ushort r = 0;
  if (n < N && kk < K) {
    float w = W[(long)kk * N + n];
    ushort hi = f2bf(w);
    r = (t == terms - 1) ? f2bf(w - bf2f(hi)) : hi;
  }
  out[idx] = r;
}

__global__ __launch_bounds__(256) void k_setup(const float* __restrict__ in_w,
                                               const float* __restrict__ outw,
                                               const float* __restrict__ xpw,
                                               ushort* __restrict__ W2TI,
                                               ushort* __restrict__ W2TO,
                                               ushort* __restrict__ W2TX,
                                               ushort* __restrict__ A2IN,
                                               float* __restrict__ SCAL) {
  int bid = blockIdx.x;
  if (bid < 3200) {                       // in_w splits (2 x 1600)
    int blk = bid / 1600;
    long idx = (long)(bid % 1600) * 256 + threadIdx.x;
    wsplit_body(in_w + (long)blk * DM_ * 512, W2TI + (long)blk * 512 * KPI_,
                DM_, 512, KPA_, KPI_, 512L * KPI_, 2, idx);
    return;
  }
  bid -= 3200;
  if (bid < 3072) {                       // outw splits (2 x 1536)
    int blk = bid / 1536;
    long idx = (long)(bid % 1536) * 256 + threadIdx.x;
    wsplit_body(outw + (long)blk * DI_ * DM_, W2TO + (long)blk * 512 * KPO_,
                DI_, DM_, 256, KPO_, 512L * KPO_, 3, idx);
    return;
  }
  bid -= 3072;
  if (bid < 768) {                        // xpw splits (2 x 384)
    int blk = bid / 384;
    long idx = (long)(bid % 384) * 256 + threadIdx.x;
    wsplit_body(xpw + (long)blk * DI_ * 33, W2TX + (long)blk * 128 * KPO_,
                DI_, 33, 256, KPO_, 128L * KPO_, 3, idx);
    return;
  }
  bid -= 768;
  if (bid < 1200) {                       // A2IN pad zero (ROWS_*15 elems)
    long idx = (long)bid * 256 + threadIdx.x;
    long m = idx / 15; int c = (int)(idx - m * 15);
    A2IN[m * KPA_ + 385 + c] = 0;
    return;
  }
  bid -= 1200;                            // zero 8*256 scalar floats
  SCAL[bid * 256 + threadIdx.x] = 0.f;
}

// ---- fused absmax of x (1024 blk), pos (256 blk), pew (1 blk), float4 -------
__global__ __launch_bounds__(256) void k_absmax3(const float* __restrict__ x,
                                                 const float* __restrict__ pos,
                                                 const float* __restrict__ pew,
                                                 float* __restrict__ sx,
                                                 float* __restrict__ spos,
                                                 float* __restrict__ spew) {
  __shared__ float smr[8];
  int bid = blockIdx.x;
  float m = 0.f;
  if (bid < 1024) {
    const float4* p = (const float4*)x;
    const long n4 = (long)B_ * H_ * W_ / 4;
    for (long i = (long)bid * 256 + threadIdx.x; i < n4; i += 1024L * 256) {
      float4 v = p[i];
      m = fmaxf(m, fmaxf(fmaxf(fabsf(v.x), fabsf(v.y)), fmaxf(fabsf(v.z), fabsf(v.w))));
    }
    blockAtomicMax(m, sx, smr);
  } else if (bid < 1280) {
    const float4* p = (const float4*)pos;
    const long n4 = LDM_ / 4;
    for (long i = (long)(bid - 1024) * 256 + threadIdx.x; i < n4; i += 256L * 256) {
      float4 v = p[i];
      m = fmaxf(m, fmaxf(fmaxf(fabsf(v.x), fabsf(v.y)), fmaxf(fabsf(v.z), fabsf(v.w))));
    }
    blockAtomicMax(m, spos, smr);
  } else {
    for (int i = threadIdx.x; i < EMB * 32; i += 256) m = fmaxf(m, fabsf(pew[i]));
    blockAtomicMax(m, spew, smr);
  }
}

// simple elementwise fq into a fresh buffer (patch weights only; tiny)
__global__ void k_qx(const float* __restrict__ src, float* __restrict__ dst, long n,
                     const float* __restrict__ pmax) {
  float s = fq_scale(pmax);
  for (long i = (long)blockIdx.x * blockDim.x + threadIdx.x; i < n;
       i += (long)gridDim.x * blockDim.x)
    dst[i] = fq_apply(src[i], s);
}

// vectorized fq: dst4 = fq(src4); optional absmax -> nextmax; optional bf16
// q-emit into A2 [M][KPA_]. dst may == src.
__global__ void k_fq4(const float4* __restrict__ src, float4* __restrict__ dst, long n4,
                      const float* __restrict__ pmax, float* __restrict__ nextmax,
                      ushort* __restrict__ a2) {
  __shared__ float smr[8];
  float s = fq_scale(pmax);
  float m = 0.f;
  for (long i = (long)blockIdx.x * blockDim.x + threadIdx.x; i < n4;
       i += (long)gridDim.x * blockDim.x) {
    float4 v = src[i];
    float r0 = fminf(fmaxf(rintf(v.x / s), -128.f), 127.f);
    float r1 = fminf(fmaxf(rintf(v.y / s), -128.f), 127.f);
    float r2 = fminf(fmaxf(rintf(v.z / s), -128.f), 127.f);
    float r3 = fminf(fmaxf(rintf(v.w / s), -128.f), 127.f);
    float4 q = make_float4(r0 * s, r1 * s, r2 * s, r3 * s);
    dst[i] = q;
    m = fmaxf(m, fmaxf(fmaxf(fabsf(q.x), fabsf(q.y)), fmaxf(fabsf(q.z), fabsf(q.w))));
    if (a2) {
      long ii = i * 4;
      long mm = ii / 385; int kk = (int)(ii - mm * 385);
      float rr[4] = {r0, r1, r2, r3};
      #pragma unroll
      for (int j = 0; j < 4; j++) {
        a2[mm * KPA_ + kk] = f2bf(rr[j]);
        if (++kk == 385) { kk = 0; mm++; }
      }
    }
  }
  if (nextmax) blockAtomicMax(m, nextmax, smr);
}

// x4[i] = fq(x4[i], s_pmax) + p2[i % LDM/4]; absmax -> nextmax
__global__ void k_addpos4(float4* __restrict__ x, const float4* __restrict__ p2,
                          const float* __restrict__ pmax, float* __restrict__ nextmax) {
  __shared__ float smr[8];
  float s = fq_scale(pmax);
  float m = 0.f;
  const long n4 = NX_ / 4, l4 = LDM_ / 4;
  for (long i = (long)blockIdx.x * blockDim.x + threadIdx.x; i < n4;
       i += (long)gridDim.x * blockDim.x) {
    float4 v = x[i];
    float4 p = p2[i % l4];
    float4 o;
    o.x = fq_apply(v.x, s) + p.x;
    o.y = fq_apply(v.y, s) + p.y;
    o.z = fq_apply(v.z, s) + p.z;
    o.w = fq_apply(v.w, s) + p.w;
    x[i] = o;
    m = fmaxf(m, fmaxf(fmaxf(fabsf(o.x), fabsf(o.y)), fmaxf(fabsf(o.z), fabsf(o.w))));
  }
  blockAtomicMax(m, nextmax, smr);
}

// ---- fused patch embed: LDS-staged x (fq inline), PRE-QUANTIZED weights -----
// block = (gw-tile of 64, gh, b); 320 threads (280 active in compute)
__global__ __launch_bounds__(320) void k_patchfq(const float* __restrict__ x,
                                                 const float* __restrict__ wq,
                                                 const float* __restrict__ peb,
                                                 const float* __restrict__ sx_,
                                                 float* __restrict__ out,
                                                 float* __restrict__ nextmax) {
  __shared__ float xs[2][64][20];   // [ph][gw_local][pw] padded to 20
  __shared__ float smr[8];
  int tid = threadIdx.x;
  int gwt = blockIdx.x, gh = blockIdx.y, b = blockIdx.z;
  float sx = fq_scale(sx_);
  if (tid < 256) {
    int gwl = tid >> 2, pw = (tid & 3) * 4;
    #pragma unroll
    for (int ph = 0; ph < 2; ph++) {
      const float* src = x + ((long)b * H_ + gh * 2 + ph) * W_ + (long)gwt * 1024 + tid * 4;
      float4 v = *reinterpret_cast<const float4*>(src);
      xs[ph][gwl][pw + 0] = fq_apply(v.x, sx);
      xs[ph][gwl][pw + 1] = fq_apply(v.y, sx);
      xs[ph][gwl][pw + 2] = fq_apply(v.z, sx);
      xs[ph][gwl][pw + 3] = fq_apply(v.w, sx);
    }
  }
  __syncthreads();
  float mx = 0.f;
  if (tid < 280) {
    int e = tid % 35;
    int g0 = (tid / 35) * 8;
    float w[32];
    #pragma unroll
    for (int j = 0; j < 32; j++) w[j] = wq[e * 32 + j];
    float bias = peb[e];
    long obase = ((long)b * GW_ + (long)gwt * 64) * DM_ + gh * 35 + e;
    #pragma unroll
    for (int gi = 0; gi < 8; gi++) {
      int gw = g0 + gi;
      float acc = bias;
      #pragma unroll
      for (int pw = 0; pw < 16; pw++) {
        acc = fmaf(xs[0][gw][pw], w[pw], acc);
        acc = fmaf(xs[1][gw][pw], w[16 + pw], acc);
      }
      out[obase + (long)gw * DM_] = acc;
      mx = fmaxf(mx, fabsf(acc));
    }
  }
  blockAtomicMax(mx, nextmax, smr);
}

// ---- activation split: (Y0+Y1)[M][256] f32 -> A2[M][512] bf16 {hi,lo} -------
__global__ void k_asplit2(const float* __restrict__ Y, ushort* __restrict__ A2) {
  long idx = (long)blockIdx.x * 256 + threadIdx.x;   // M*512 threads
  long m = idx >> 9; int k = (int)(idx & 511);
  int t = k >> 8, kk = k & 255;
  float v = Y[m * DI_ + kk] + Y[(m + ROWS_) * DI_ + kk];
  ushort hi = f2bf(v);
  A2[idx] = t ? f2bf(v - bf2f(hi)) : hi;
}

// ---- bf16 MFMA GEMM: C[M][Nreal] = scale * (A2[M][Wa,wrapped] @ W2T[Npad][Kp]^T)
// 1-D grid NT*MT (m = bid%MT, n = bid/MT): same-m blocks share XCD L2 A-panel.
// LDS sl-stride padded (+16B): conflict-free write/read granule (sl+row)&7.
template<bool AMAX>
__global__ __launch_bounds__(256) void k_mgemm(const ushort* __restrict__ A2,
                                               const ushort* __restrict__ W2T,
                                               float* __restrict__ C,
                                               int Nreal, int Kp, int Wa, int MT,
                                               const float* __restrict__ sptr,
                                               float* __restrict__ amax_out) {
  __shared__ ushort Alds[4 * SLP_];
  __shared__ ushort Blds[4 * SLP_];
  __shared__ float smr[8];
  int tid = threadIdx.x;
  int lane = tid & 63, wave = tid >> 6;
  int wm = wave >> 1, wn = wave & 1;
  int bid = blockIdx.x;
  int m0 = (bid % MT) * 128, n0 = (bid / MT) * 128;
  f32x4 acc[4][4];
  #pragma unroll
  for (int i = 0; i < 4; i++)
    #pragma unroll
    for (int j = 0; j < 4; j++) acc[i][j] = (f32x4){0.f, 0.f, 0.f, 0.f};

  for (int k0 = 0; k0 < Kp; k0 += 32) {
    #pragma unroll
    for (int r = 0; r < 2; r++) {
      int id = tid + r * 256;            // 0..511
      int row = id >> 2, sl = id & 3;    // coalesced 64B global segments
      int kc = k0 + sl * 8; if (kc >= Wa) kc -= Wa;   // A k-wrap (8-aligned)
      short8 va = *reinterpret_cast<const short8*>(A2 + (long)(m0 + row) * Wa + kc);
      *reinterpret_cast<short8*>(&Alds[sl * SLP_ + row * 8]) = va;
      short8 vb = *reinterpret_cast<const short8*>(W2T + (long)(n0 + row) * Kp + k0 + sl * 8);
      *reinterpret_cast<short8*>(&Blds[sl * SLP_ + row * 8]) = vb;
    }
    __syncthreads();
    int sl = lane >> 4, rr = lane & 15;
    short8 af[4], bf4[4];
    #pragma unroll
    for (int i = 0; i < 4; i++)
      af[i] = *reinterpret_cast<const short8*>(&Alds[sl * SLP_ + (wm * 64 + i * 16 + rr) * 8]);
    #pragma unroll
    for (int j = 0; j < 4; j++)
      bf4[j] = *reinterpret_cast<const short8*>(&Blds[sl * SLP_ + (wn * 64 + j * 16 + rr) * 8]);
    #pragma unroll
    for (int i = 0; i < 4; i++)
      #pragma unroll
      for (int j = 0; j < 4; j++)
        acc[i][j] = __builtin_amdgcn_mfma_f32_16x16x32_bf16(af[i], bf4[j], acc[i][j], 0, 0, 0);
    __syncthreads();
  }

  float s = sptr ? fq_scale(sptr) : 1.0f;
  float mx = 0.f;
  int cfr = lane & 15, rbase = (lane >> 4) * 4;
  #pragma unroll
  for (int i = 0; i < 4; i++) {
    int gmb = m0 + wm * 64 + i * 16 + rbase;
    #pragma unroll
    for (int j = 0; j < 4; j++) {
      int gn = n0 + wn * 64 + j * 16 + cfr;
      if (gn < Nreal) {
        #pragma unroll
        for (int rg = 0; rg < 4; rg++) {
          float v = acc[i][j][rg] * s;
          C[(long)(gmb + rg) * Nreal + gn] = v;
          mx = fmaxf(mx, fabsf(v));
        }
      }
    }
  }
  if (AMAX) blockAtomicMax(mx, amax_out, smr);
}

// ---- depthwise causal conv1d (K=4) + SiLU, BOTH dirs from one window --------
__global__ __launch_bounds__(256) void k_conv2(const float* __restrict__ xz,
                                               const float* __restrict__ cw,
                                               const float* __restrict__ cb,
                                               ushort* __restrict__ xch) {
  int d = threadIdx.x;
  int t0 = blockIdx.x * 16, b = blockIdx.y;
  long base = (long)b * L_;
  float w0 = cw[d * 4 + 0], w1 = cw[d * 4 + 1];
  float w2 = cw[d * 4 + 2], w3 = cw[d * 4 + 3];
  float bias = cb[d];
  float win[22];
  #pragma unroll
  for (int i = 0; i < 22; i++) {
    int t = t0 - 3 + i;
    win[i] = (t >= 0 && t < L_) ? xz[(base + t) * (2 * DI_) + d] : 0.f;
  }
  #pragma unroll
  for (int i = 0; i < 16; i++) {
    int t = t0 + i;
    float a0 = bias;
    a0 = fmaf(w0, win[i + 0], a0);
    a0 = fmaf(w1, win[i + 1], a0);
    a0 = fmaf(w2, win[i + 2], a0);
    a0 = fmaf(w3, win[i + 3], a0);
    float a1 = bias;
    a1 = fmaf(w0, win[i + 6], a1);
    a1 = fmaf(w1, win[i + 5], a1);
    a1 = fmaf(w2, win[i + 4], a1);
    a1 = fmaf(w3, win[i + 3], a1);
    float v0 = a0 * (1.f / (1.f + expf(-a0)));
    float v1 = a1 * (1.f / (1.f + expf(-a1)));
    long g0o = (base + t) * 512 + d;
    ushort h0 = f2bf(v0), h1 = f2bf(v1);
    xch[g0o] = h0;
    xch[g0o + 256] = f2bf(v0 - bf2f(h0));
    long g1o = ((long)ROWS_ + base + t) * 512 + d;
    xch[g1o] = h1;
    xch[g1o + 256] = f2bf(v1 - bf2f(h1));
  }
}

// ---- dt precompute into Y (scan2 reads dt then overwrites with y in place) --
__device__ __forceinline__ float softplusf(float x) {
  return fmaxf(x, 0.f) + log1pf(expf(-fabsf(x)));
}

__global__ __launch_bounds__(256) void k_dtp(const float* __restrict__ proj,
                                             const float* __restrict__ dtw,
                                             const float* __restrict__ dtb,
                                             float* __restrict__ dty) {
  __shared__ float pr[16][26];
  int d = threadIdx.x;
  long g0 = (long)blockIdx.x * 16;
  for (int i = threadIdx.x; i < 16 * DTR_; i += 256) {
    int r = i / DTR_, j = i - r * DTR_;
    pr[r][j] = proj[(g0 + r) * 33 + j];
  }
  float dwr[DTR_];
  #pragma unroll
  for (int r = 0; r < DTR_; r++) dwr[r] = dtw[r * DI_ + d];
  float dbv = dtb[d];
  __syncthreads();
  #pragma unroll
  for (int r = 0; r < 16; r++) {
    float acc = dbv;
    #pragma unroll
    for (int j = 0; j < DTR_; j++) acc = fmaf(pr[r][j], dwr[j], acc);
    dty[(g0 + r) * DI_ + d] = softplusf(acc);
  }
}

// ---- chunked parallel selective scan (exp-reduced, both dirs in grid.z) -----
__global__ __launch_bounds__(256) void k_scan1(const ushort* __restrict__ xch,
                                               const float* __restrict__ proj,
                                               const float* __restrict__ A_log,
                                               const float* __restrict__ dty,
                                               float* __restrict__ Hend,
                                               float* __restrict__ Pend) {
  int b = blockIdx.y, c = blockIdx.x, d = threadIdx.x, dir = blockIdx.z;
  float A[4];
  #pragma unroll
  for (int n = 0; n < 4; n++) A[n] = -expf(A_log[d * 4 + n]);
  bool fast = true;
  #pragma unroll
  for (int n = 1; n < 4; n++)
    fast = fast && (fabsf(A[n] - (float)(n + 1) * A[0]) <= 1e-4f * fabsf(A[n]));
  long base = (long)b * L_;
  int step0 = c * CHL_;
  long row0 = base + (dir ? (L_ - 1 - step0) : step0);
  long doff = (long)dir * ROWS_;
  int rs = dir ? -1 : 1;
  const float* pdt = dty + (doff + row0) * DI_ + d;
  const ushort* pxc = xch + (doff + row0) * 512 + d;
  const float* pp  = proj + (doff + row0) * 33;
  float h[4] = {0.f, 0.f, 0.f, 0.f};
  float sdt = 0.f;
  if (fast) {
    float A0 = A[0];
    for (int s = 0; s < CHL_; s++) {
      float dtv = *pdt;
      float xcv = bf2f(pxc[0]) + bf2f(pxc[256]);
      float dx = dtv * xcv;
      float e1 = expf(dtv * A0);
      float e2 = e1 * e1, e3 = e2 * e1, e4 = e3 * e1;
      h[0] = e1 * h[0] + dx * pp[DTR_ + 0];
      h[1] = e2 * h[1] + dx * pp[DTR_ + 1];
      h[2] = e3 * h[2] + dx * pp[DTR_ + 2];
      h[3] = e4 * h[3] + dx * pp[DTR_ + 3];
      sdt += dtv;
      pdt += (long)rs * DI_; pxc += (long)rs * 512; pp += rs * 33;
    }
  } else {
    for (int s = 0; s < CHL_; s++) {
      float dtv = *pdt;
      float xcv = bf2f(pxc[0]) + bf2f(pxc[256]);
      float dx = dtv * xcv;
      #pragma unroll
      for (int n = 0; n < 4; n++) {
        float dA = expf(dtv * A[n]);
        h[n] = dA * h[n] + dx * pp[DTR_ + n];
      }
      sdt += dtv;
      pdt += (long)rs * DI_; pxc += (long)rs * 512; pp += rs * 33;
    }
  }
  float P[4];
  #pragma unroll
  for (int n = 0; n < 4; n++) P[n] = expf(A[n] * sdt);
  long o = (((long)dir * B_ + b) * CH_ + c) * 1024 + d * 4;
  *reinterpret_cast<float4*>(Hend + o) = make_float4(h[0], h[1], h[2], h[3]);
  *reinterpret_cast<float4*>(Pend + o) = make_float4(P[0], P[1], P[2], P[3]);
}

__global__ __launch_bounds__(256) void k_carry(const float* __restrict__ Hend,
                                               const float* __restrict__ Pend,
                                               float* __restrict__ Carry) {
  int tid = blockIdx.x * 256 + threadIdx.x;   // 2*B_*1024 lanes
  int be = tid >> 10, i = tid & 1023;         // be = dir*16+b
  float carry = 0.f;
  for (int c = 0; c < CH_; c++) {
    long o = ((long)be * CH_ + c) * 1024 + i;
    Carry[o] = carry;
    carry = Pend[o] * carry + Hend[o];
  }
}

// dty holds dt on entry; read-once-then-overwrite with y (same thread).
__global__ __launch_bounds__(256) void k_scan2(const ushort* __restrict__ xch,
                                               const float* __restrict__ proj,
                                               const float* __restrict__ A_log,
                                               const float* __restrict__ Dp,
                                               const float* __restrict__ xz,
                                               const float* __restrict__ Carry,
                                               float* dty) {
  int b = blockIdx.y, c = blockIdx.x, d = threadIdx.x, dir = blockIdx.z;
  float A[4];
  #pragma unroll
  for (int n = 0; n < 4; n++) A[n] = -expf(A_log[d * 4 + n]);
  bool fast = true;
  #pragma unroll
  for (int n = 1; n < 4; n++)
    fast = fast && (fabsf(A[n] - (float)(n + 1) * A[0]) <= 1e-4f * fabsf(A[n]));
  long base = (long)b * L_;
  int step0 = c * CHL_;
  long row0 = base + (dir ? (L_ - 1 - step0) : step0);
  long doff = (long)dir * ROWS_;
  int rs = dir ? -1 : 1;
  float* pdy = dty + (doff + row0) * DI_ + d;
  const ushort* pxc = xch + (doff + row0) * 512 + d;
  const float* pz  = xz + row0 * (2 * DI_) + DI_ + d;
  const float* pp  = proj + (doff + row0) * 33;
  long o = (((long)dir * B_ + b) * CH_ + c) * 1024 + d * 4;
  float4 cv = *reinterpret_cast<const float4*>(Carry + o);
  float h[4] = {cv.x, cv.y, cv.z, cv.w};
  float Dv = Dp[d];
  if (fast) {
    float A0 = A[0];
    for (int s = 0; s < CHL_; s++) {
      float dtv = *pdy;
      float xcv = bf2f(pxc[0]) + bf2f(pxc[256]);
      float zv  = *pz;
      float dx = dtv * xcv;
      float e1 = expf(dtv * A0);
      float e2 = e1 * e1, e3 = e2 * e1, e4 = e3 * e1;
      h[0] = e1 * h[0] + dx * pp[DTR_ + 0];
      h[1] = e2 * h[1] + dx * pp[DTR_ + 1];
      h[2] = e3 * h[2] + dx * pp[DTR_ + 2];
      h[3] = e4 * h[3] + dx * pp[DTR_ + 3];
      float acc = 0.f;
      acc = fmaf(h[0], pp[DTR_ + N_ + 0], acc);
      acc = fmaf(h[1], pp[DTR_ + N_ + 1], acc);
      acc = fmaf(h[2], pp[DTR_ + N_ + 2], acc);
      acc = fmaf(h[3], pp[DTR_ + N_ + 3], acc);
      float yv = fmaf(Dv, xcv, acc);
      float sig = 1.f / (1.f + expf(-zv));
      yv *= zv * sig;
      *pdy = yv;
      pdy += (long)rs * DI_; pxc += (long)rs * 512;
      pz += rs * (2 * DI_); pp += rs * 33;
    }
  } else {
    for (int s = 0; s < CHL_; s++) {
      float dtv = *pdy;
      float xcv = bf2f(pxc[0]) + bf2f(pxc[256]);
      float zv  = *pz;
      float dx = dtv * xcv;
      float acc = 0.f;
      #pragma unroll
      for (int n = 0; n < 4; n++) {
        float dA = expf(dtv * A[n]);
        h[n] = dA * h[n] + dx * pp[DTR_ + n];
        acc = fmaf(h[n], pp[DTR_ + N_ + n], acc);
      }
      float yv = fmaf(Dv, xcv, acc);
      float sig = 1.f / (1.f + expf(-zv));
      yv *= zv * sig;
      *pdy = yv;
      pdy += (long)rs * DI_; pxc += (long)rs * 512;
      pz += rs * (2 * DI_); pp += rs * 33;
    }
  }
}

// ---- residual + fq(mamba_out) + layernorm, wave-per-row ----------------------
__global__ __launch_bounds__(256) void k_ln(const float* __restrict__ x2,
                                            float* __restrict__ mo,
                                            const float* __restrict__ smo,
                                            const float* __restrict__ g,
                                            const float* __restrict__ bta,
                                            float* __restrict__ nextmax) {
  __shared__ float smr[4];
  int lane = threadIdx.x & 63;
  int wid = blockIdx.x * 4 + (threadIdx.x >> 6);
  float s = fq_scale(smo);
  float wmax = 0.f;
  for (int row = wid; row < ROWS_; row += 2560) {
    const float* xr = x2 + (long)row * DM_;
    float* mr = mo + (long)row * DM_;
    float v[7];
    float lsum = 0.f;
    #pragma unroll
    for (int k = 0; k < 6; k++) {
      int c = lane + k * 64;
      v[k] = xr[c] + fq_apply(mr[c], s);
      lsum += v[k];
    }
    v[6] = 0.f;
    if (lane == 0) v[6] = xr[384] + fq_apply(mr[384], s);
    lsum += v[6];
    #pragma unroll
    for (int o = 32; o > 0; o >>= 1) lsum += __shfl_xor(lsum, o);
    float mean = lsum / 385.f;
    float lvar = 0.f;
    #pragma unroll
    for (int k = 0; k < 6; k++) { float dd = v[k] - mean; lvar += dd * dd; }
    if (lane == 0) { float dd = v[6] - mean; lvar += dd * dd; }
    #pragma unroll
    for (int o = 32; o > 0; o >>= 1) lvar += __shfl_xor(lvar, o);
    float rs = 1.f / sqrtf(lvar / 385.f + 1e-5f);
    #pragma unroll
    for (int k = 0; k < 6; k++) {
      int c = lane + k * 64;
      float o2 = (v[k] - mean) * rs * g[c] + bta[c];
      mr[c] = o2;
      wmax = fmaxf(wmax, fabsf(o2));
    }
    if (lane == 0) {
      float o2 = (v[6] - mean) * rs * g[384] + bta[384];
      mr[384] = o2;
      wmax = fmaxf(wmax, fabsf(o2));
    }
  }
  blockAtomicMax(wmax, nextmax, smr);
}

// ---- mean pool over L (two-stage, coalesced, deterministic) ------------------
__global__ __launch_bounds__(256) void k_pool1(const float* __restrict__ x2,
                                               float* __restrict__ part) {
  int b = blockIdx.x, ch = blockIdx.y, tid = threadIdx.x;
  float s0 = 0.f, s1 = 0.f;
  for (int l = ch * 64; l < ch * 64 + 64; l++) {
    const float* row = x2 + ((long)b * L_ + l) * DM_;
    s0 += row[tid];
    if (tid < DM_ - 256) s1 += row[tid + 256];
  }
  long o = ((long)b * 20 + ch) * DM_;
  part[o + tid] = s0;
  if (tid < DM_ - 256) part[o + tid + 256] = s1;
}

// blocks 0..24: pool reduce + amax(pool) -> spool; blocks 25..28: amax(clsw) -> sclsw
__global__ void k_pool2c(const float* __restrict__ part, float* __restrict__ pool,
                         const float* __restrict__ clsw,
                         float* __restrict__ spool, float* __restrict__ sclsw) {
  __shared__ float smr[8];
  int bid = blockIdx.x;
  if (bid < 25) {
    int idx = bid * 256 + threadIdx.x;
    float mv = 0.f;
    if (idx < B_ * DM_) {
      int b = idx / DM_, c = idx % DM_;
      float s = 0.f;
      for (int ch = 0; ch < 20; ch++) s += part[((long)b * 20 + ch) * DM_ + c];
      float mean = s / (float)L_;
      pool[idx] = mean;
      mv = fabsf(mean);
    }
    blockAtomicMax(mv, spool, smr);
  } else {
    float m = 0.f;
    for (int i = (bid - 25) * 256 + threadIdx.x; i < DM_ * 2; i += 4 * 256)
      m = fmaxf(m, fabsf(clsw[i]));
    blockAtomicMax(m, sclsw, smr);
  }
}

// ---- classifier (parallel): grid 32 = (b,c), 128 threads reduce over K=385 --
__global__ __launch_bounds__(128) void k_cls(const float* __restrict__ pool,
                                             const float* __restrict__ clsw,
                                             const float* __restrict__ clsb,
                                             const float* __restrict__ sp_,
                                             const float* __restrict__ sw_,
                                             float* __restrict__ out) {
  __shared__ float smr[2];
  int b = blockIdx.x >> 1, c = blockIdx.x & 1;
  float sp = fq_scale(sp_), sw = fq_scale(sw_);
  float acc = 0.f;
  for (int k = threadIdx.x; k < DM_; k += 128) {
    float xv = fq_apply(pool[b * DM_ + k], sp);
    float wv = fq_apply(clsw[k * 2 + c], sw);
    acc = fmaf(xv, wv, acc);
  }
  #pragma unroll
  for (int o = 32; o > 0; o >>= 1) acc += __shfl_down(acc, o);
  if ((threadIdx.x & 63) == 0) smr[threadIdx.x >> 6] = acc;
  __syncthreads();
  if (threadIdx.x == 0) out[blockIdx.x] = smr[0] + smr[1] + clsb[c];
}

// ---- launch ------------------------------------------------------------------
extern "C" void kernel_launch(void* const* d_in, const int* in_sizes, int n_in,
                              void* d_out, int out_size, void* d_ws, size_t ws_size,
                              hipStream_t stream) {
  const float* x    = (const float*)d_in[0];
  const float* pew  = (const float*)d_in[1];
  const float* peb  = (const float*)d_in[2];
  const float* pos  = (const float*)d_in[3];
  const float* in_w = (const float*)d_in[4];
  const float* cw   = (const float*)d_in[5];
  const float* cb   = (const float*)d_in[6];
  const float* xpw  = (const float*)d_in[7];
  const float* dtw  = (const float*)d_in[8];
  const float* dtb  = (const float*)d_in[9];
  const float* alog = (const float*)d_in[10];
  const float* dp   = (const float*)d_in[11];
  const float* outw = (const float*)d_in[12];
  const float* lng  = (const float*)d_in[13];
  const float* lnb  = (const float*)d_in[14];
  const float* clsw = (const float*)d_in[15];
  const float* clsb = (const float*)d_in[16];

  float* ws    = (float*)d_ws;
  float* SCAL  = ws;                              // 13 scalars x 128 floats (8 slots)
  float* WQ    = ws + 2048;                       // 2048 (1120 used)
  float* P2    = WQ + 2048;                       // 492,800
  float* X2    = P2 + LDM_;                       // 7,884,800
  float* XZ    = X2 + NX_;                        // 10,485,760
  float* XCH_f = XZ + (long)ROWS_ * 512;          // 10,485,760 (ushort [40960][512])
  float* PROJ  = XCH_f + 2L * ROWS_ * DI_;        // 40960*33 = 1,351,680
  float* Y     = PROJ + 2L * ROWS_ * 33;          // 2 x 5,242,880 (dt -> y in place)
  float* MO    = Y + 2L * ROWS_ * DI_;            // 7,884,800
  float* POOL  = MO + NX_;                        // 8,192
  float* PART  = POOL + 8192;                     // 123,200 (+pad)
  float* A2IN_f= PART + 131072;                   // 4,096,000 f (ushort overlay)
  float* W2I_f = A2IN_f + 4096000;                // 409,600 f
  float* W2O_f = W2I_f + 409600;                  // 393,216 f
  float* W2X_f = W2O_f + 393216;                  // 98,304 f (2 x [128][768] ushort)
  // aliases (disjoint lifetimes):
  float*  HEND = MO;                              // scan summaries, dead before out-GEMM
  float*  PEND = MO + 2097152;
  float*  CARR = MO + 4194304;
  ushort* A2Y  = (ushort*)XZ;                     // [20480][512], dead before next in-GEMM
  ushort* XCH  = (ushort*)XCH_f;                  // xc bf16 {hi|lo} [40960][512]
  ushort* A2IN = (ushort*)A2IN_f;                 // [20480][400]
  ushort* W2TI = (ushort*)W2I_f;                  // 2 x [512][800]
  ushort* W2TO = (ushort*)W2O_f;                  // 2 x [512][768]
  ushort* W2TX = (ushort*)W2X_f;                  // 2 x [128][768]

  // scalar entry i lives at SCAL + i*SCALW (8 slots, 64B apart)
  #define SC(i) (SCAL + (i) * SCALW)

  // one consolidated setup launch: all weight splits + A2IN pad + SCAL zero
  k_setup<<<8248, 256, 0, stream>>>(in_w, outw, xpw, W2TI, W2TO, W2TX, A2IN, SCAL);

  // fused absmax of x / pos / pew (one launch), then pre-quantize patch weights
  k_absmax3<<<1281, 256, 0, stream>>>(x, pos, pew, SC(0), SC(4), SC(1));
  k_qx<<<5, 256, 0, stream>>>(pew, WQ, EMB * 2 * 16, SC(1));
  k_patchfq<<<dim3(20, 11, 16), 320, 0, stream>>>(x, WQ, peb, SC(0), X2, SC(2));

  // pos = fq(fq(pos_embed)) == fq(pos_embed)  (fq idempotent)
  k_fq4<<<512, 256, 0, stream>>>((const float4*)pos, (float4*)P2, LDM_ / 4,
                                 SC(4), nullptr, nullptr);

  // x = fq(fq(x) + pos) with inner fq(x) = fq(patch_out, s2) (outer chain identity)
  k_addpos4<<<2048, 256, 0, stream>>>((float4*)X2, (const float4*)P2, SC(2), SC(6));
  k_fq4<<<2048, 256, 0, stream>>>((const float4*)X2, (float4*)X2, NX_ / 4,
                                  SC(6), nullptr, A2IN);

  const float* in_scale[2] = {SC(6), SC(8)};
  for (int blk = 0; blk < 2; blk++) {
    // in-proj: XZ = s * (q @ [w_hi; w_lo])   (MFMA bf16, A k-wrapped at 400)
    k_mgemm<false><<<640, 256, 0, stream>>>(
        A2IN, W2TI + (long)blk * 512 * KPI_, XZ, 512, KPI_, KPA_, 160,
        in_scale[blk], nullptr);
    // conv both dirs -> xc bf16 {hi|lo}; xp-proj via MFMA (N=33 in one tile)
    k_conv2<<<dim3(80, 16), 256, 0, stream>>>(XZ, cw + blk * DI_ * K_,
                                              cb + blk * DI_, XCH);
    k_mgemm<false><<<320, 256, 0, stream>>>(
        XCH, W2TX + (long)blk * 128 * KPO_, PROJ, 33, KPO_, WAO_, 320,
        nullptr, nullptr);
    k_dtp<<<2560, 256, 0, stream>>>(PROJ, dtw + blk * DTR_ * DI_, dtb + blk * DI_, Y);
    k_scan1<<<dim3(CH_, B_, 2), 256, 0, stream>>>(XCH, PROJ, alog + blk * DI_ * N_,
                                                  Y, HEND, PEND);
    k_carry<<<128, 256, 0, stream>>>(HEND, PEND, CARR);
    k_scan2<<<dim3(CH_, B_, 2), 256, 0, stream>>>(XCH, PROJ, alog + blk * DI_ * N_,
                                                  dp + blk * DI_, XZ, CARR, Y);
    // out-proj: MO = [y_hi | y_lo] (wrapped) @ [w_hi; w_hi; w_lo]  (amax fused)
    k_asplit2<<<40960, 256, 0, stream>>>(Y, A2Y);
    k_mgemm<true><<<640, 256, 0, stream>>>(
        A2Y, W2TO + (long)blk * 512 * KPO_, MO, DM_, KPO_, WAO_, 160,
        nullptr, SC(7 + blk * 2));
    // x = fq(layernorm(x + fq(mo))); emit q for next block's in-proj
    k_ln<<<640, 256, 0, stream>>>(X2, MO, SC(7 + blk * 2),
                                  lng + blk * DM_, lnb + blk * DM_, SC(8 + blk * 2));
    k_fq4<<<2048, 256, 0, stream>>>((const float4*)MO, (float4*)X2, NX_ / 4,
                                    SC(8 + blk * 2), nullptr,
                                    blk == 0 ? A2IN : nullptr);
  }

  // mean-pool (2-stage, clsw amax folded into stage 2), fq, classifier
  k_pool1<<<dim3(16, 20), 256, 0, stream>>>(X2, PART);
  k_pool2c<<<29, 256, 0, stream>>>(PART, POOL, clsw, SC(11), SC(12));
  k_cls<<<32, 128, 0, stream>>>(POOL, clsw, clsb, SC(11), SC(12), (float*)d_out);
}